// Round 1
// baseline (2432.939 us; speedup 1.0000x reference)
//
#include <hip/hip_runtime.h>
#include <math.h>

// Dims
constexpr int Bn = 4, Cc = 128, Hh = 128, Wn = 128, Dd = 48;
constexpr int Ntok = Hh * Wn;        // 16384
constexpr int CHID = 88;             // (C+D)/2
constexpr float SCALE = 0.25f;       // 16^-0.5

static __device__ __forceinline__ float gelu_f(float v) {
    return 0.5f * v * (1.0f + erff(v * 0.70710678118654752f));
}

// ---------------------------------------------------------------------------
// K1: cost volume. grid (H/2, B), 256 threads. Each half-block owns one (b,h) row.
__global__ __launch_bounds__(256) void k_cost(const float* __restrict__ fl,
                                              const float* __restrict__ fr,
                                              float* __restrict__ cost) {
    int tid = threadIdx.x;
    int lr = tid >> 7, w = tid & 127;
    int h = blockIdx.x * 2 + lr;
    int b = blockIdx.y;
    __shared__ float s_fr[2][128];
    float acc[48];
#pragma unroll
    for (int d = 0; d < 48; ++d) acc[d] = 0.f;
    const float* flb = fl + ((size_t)b * 128 * 16384) + h * 128;
    const float* frb = fr + ((size_t)b * 128 * 16384) + h * 128;
    for (int c = 0; c < 128; ++c) {
        float flv = flb[(size_t)c * 16384 + w];
        s_fr[lr][w] = frb[(size_t)c * 16384 + w];
        __syncthreads();
#pragma unroll
        for (int d = 0; d < 48; ++d) {
            if (d <= w) acc[d] += flv * s_fr[lr][w - d];
        }
        __syncthreads();
    }
    const float inv = 1.0f / 128.0f;
#pragma unroll
    for (int d = 0; d < 48; ++d) {
        cost[(((size_t)b * 48 + d) << 14) + h * 128 + w] = acc[d] * inv;
    }
}

// ---------------------------------------------------------------------------
// K2: unary = gelu(tok@W1+b1)@W2+b2 -> x.  64 tokens per block, 256 threads.
__global__ __launch_bounds__(256) void k_unary(const float* __restrict__ feat_l,
                                               const float* __restrict__ w1,
                                               const float* __restrict__ b1,
                                               const float* __restrict__ w2,
                                               const float* __restrict__ b2,
                                               float* __restrict__ x) {
    __shared__ float s_a[64 * 129];
    __shared__ float s_h[64 * 129];
    __shared__ float s_w[128 * 128];
    int tid = threadIdx.x;
    int n0g = blockIdx.x * 64;            // global token id
    int b = n0g >> 14;
    int nb = n0g & 16383;
    // load token tile (coalesced over n, transposed into n-major LDS)
    for (int idx = tid; idx < 64 * 128; idx += 256) {
        int c = idx >> 6, nl = idx & 63;
        s_a[nl * 129 + c] = feat_l[((size_t)(b * 128 + c) << 14) + nb + nl];
    }
    for (int idx = tid; idx < 128 * 128; idx += 256) s_w[idx] = w1[idx];
    __syncthreads();

    int tn = tid >> 4, tj = tid & 15;
    int n0 = tn * 4, j0 = tj * 8;
    float accA[4][8];
#pragma unroll
    for (int i = 0; i < 4; ++i)
#pragma unroll
        for (int u = 0; u < 8; ++u) accA[i][u] = b1[j0 + u];
    for (int c = 0; c < 128; ++c) {
        float a0 = s_a[(n0 + 0) * 129 + c];
        float a1 = s_a[(n0 + 1) * 129 + c];
        float a2 = s_a[(n0 + 2) * 129 + c];
        float a3 = s_a[(n0 + 3) * 129 + c];
        float4 bv0 = *(const float4*)&s_w[c * 128 + j0];
        float4 bv1 = *(const float4*)&s_w[c * 128 + j0 + 4];
        float bb[8] = {bv0.x, bv0.y, bv0.z, bv0.w, bv1.x, bv1.y, bv1.z, bv1.w};
#pragma unroll
        for (int u = 0; u < 8; ++u) {
            accA[0][u] += a0 * bb[u];
            accA[1][u] += a1 * bb[u];
            accA[2][u] += a2 * bb[u];
            accA[3][u] += a3 * bb[u];
        }
    }
#pragma unroll
    for (int i = 0; i < 4; ++i)
#pragma unroll
        for (int u = 0; u < 8; ++u)
            s_h[(n0 + i) * 129 + j0 + u] = gelu_f(accA[i][u]);
    __syncthreads();
    for (int idx = tid; idx < 128 * 128; idx += 256) s_w[idx] = w2[idx];
    __syncthreads();
    float accB[4][8];
#pragma unroll
    for (int i = 0; i < 4; ++i)
#pragma unroll
        for (int u = 0; u < 8; ++u) accB[i][u] = b2[j0 + u];
    for (int c = 0; c < 128; ++c) {
        float a0 = s_h[(n0 + 0) * 129 + c];
        float a1 = s_h[(n0 + 1) * 129 + c];
        float a2 = s_h[(n0 + 2) * 129 + c];
        float a3 = s_h[(n0 + 3) * 129 + c];
        float4 bv0 = *(const float4*)&s_w[c * 128 + j0];
        float4 bv1 = *(const float4*)&s_w[c * 128 + j0 + 4];
        float bb[8] = {bv0.x, bv0.y, bv0.z, bv0.w, bv1.x, bv1.y, bv1.z, bv1.w};
#pragma unroll
        for (int u = 0; u < 8; ++u) {
            accB[0][u] += a0 * bb[u];
            accB[1][u] += a1 * bb[u];
            accB[2][u] += a2 * bb[u];
            accB[3][u] += a3 * bb[u];
        }
    }
#pragma unroll
    for (int i = 0; i < 4; ++i) {
        size_t base = ((size_t)(n0g + n0 + i)) * 128 + j0;
        float4 o0 = {accB[i][0], accB[i][1], accB[i][2], accB[i][3]};
        float4 o1 = {accB[i][4], accB[i][5], accB[i][6], accB[i][7]};
        *(float4*)&x[base] = o0;
        *(float4*)&x[base + 4] = o1;
    }
}

// ---------------------------------------------------------------------------
// K3: window attention. one block per window (1024 blocks), 256 threads.
__global__ __launch_bounds__(256) void k_attn(const float* __restrict__ feat_l,
                                              const float* __restrict__ wq, const float* __restrict__ bq,
                                              const float* __restrict__ wk, const float* __restrict__ bk,
                                              const float* __restrict__ wv, const float* __restrict__ bv,
                                              const float* __restrict__ wp, const float* __restrict__ bp,
                                              const float* __restrict__ rpb,
                                              const float* __restrict__ g1, const float* __restrict__ bt1,
                                              float* __restrict__ x) {
    __shared__ float s_nf[128 * 64];     // normed tokens, [c][n]
    __shared__ float s_o[64 * 130];      // attention output, [n][c] padded
    __shared__ float s_big[128 * 128];   // per-head scratch, then wp
    int tid = threadIdx.x;
    int bw = blockIdx.x;
    int b = bw >> 8, wh = (bw >> 4) & 15, ww = bw & 15;

    // load window tokens into [c][n]
    for (int idx = tid; idx < 8192; idx += 256) {
        int c = idx >> 6, n = idx & 63;
        int h = wh * 8 + (n >> 3), w = ww * 8 + (n & 7);
        s_nf[c * 64 + n] = feat_l[((size_t)(b * 128 + c) << 14) + h * 128 + w];
    }
    __syncthreads();
    // LayerNorm per token (4 lanes per row)
    {
        int n = tid >> 2, q = tid & 3;
        float s = 0.f, s2 = 0.f;
        for (int c = q * 32; c < q * 32 + 32; ++c) {
            float v = s_nf[c * 64 + n];
            s += v; s2 += v * v;
        }
        s += __shfl_xor(s, 1); s += __shfl_xor(s, 2);
        s2 += __shfl_xor(s2, 1); s2 += __shfl_xor(s2, 2);
        float mean = s * (1.f / 128.f);
        float var = s2 * (1.f / 128.f) - mean * mean;
        float rstd = rsqrtf(var + 1e-5f);
        for (int c = q * 32; c < q * 32 + 32; ++c) {
            float v = s_nf[c * 64 + n];
            s_nf[c * 64 + n] = (v - mean) * rstd * g1[c] + bt1[c];
        }
    }
    __syncthreads();

    float* s_ws = s_big;          // [128][16]
    float* s_q = s_big + 2048;    // [16][64]
    float* s_k = s_big + 3072;    // [16][64]
    float* s_v = s_big + 4096;    // [16][64]
    float* s_at = s_big + 5120;   // [64][66]

    for (int hh = 0; hh < 8; ++hh) {
        const float* wmats[3] = {wq, wk, wv};
        const float* bvecs[3] = {bq, bk, bv};
        float* outs[3] = {s_q, s_k, s_v};
#pragma unroll 1
        for (int mm = 0; mm < 3; ++mm) {
            for (int idx = tid; idx < 2048; idx += 256) {
                int c = idx >> 4, u = idx & 15;
                s_ws[idx] = wmats[mm][c * 128 + hh * 16 + u];
            }
            __syncthreads();
            {
                int n = tid & 63, ug = tid >> 6;
                float acc[4];
#pragma unroll
                for (int i = 0; i < 4; ++i) acc[i] = bvecs[mm][hh * 16 + ug * 4 + i];
                for (int c = 0; c < 128; ++c) {
                    float av = s_nf[c * 64 + n];
                    float4 w4 = *(const float4*)&s_ws[c * 16 + ug * 4];
                    acc[0] += av * w4.x; acc[1] += av * w4.y;
                    acc[2] += av * w4.z; acc[3] += av * w4.w;
                }
                float* dst = outs[mm];
#pragma unroll
                for (int i = 0; i < 4; ++i) dst[(ug * 4 + i) * 64 + n] = acc[i];
            }
            __syncthreads();
        }
        // attention scores + bias
        {
            int m = tid & 63, ng = tid >> 6;
            for (int n = ng * 16; n < ng * 16 + 16; ++n) {
                float s = 0.f;
#pragma unroll
                for (int d = 0; d < 16; ++d) s += s_q[d * 64 + n] * s_k[d * 64 + m];
                int relidx = (((n >> 3) - (m >> 3)) + 7) * 15 + (((n & 7) - (m & 7)) + 7);
                s_at[n * 66 + m] = s * SCALE + rpb[relidx * 8 + hh];
            }
        }
        __syncthreads();
        // softmax rows (wave handles 16 rows; 4 lanes per row chunks of 16 m)
        {
            int wid = tid >> 6, lane = tid & 63;
            int r = wid * 16 + (lane & 15);
            int mc = lane >> 4;
            float e[16];
            float mx = -1e30f;
#pragma unroll
            for (int i = 0; i < 16; ++i) {
                e[i] = s_at[r * 66 + mc * 16 + i];
                mx = fmaxf(mx, e[i]);
            }
            mx = fmaxf(mx, __shfl_xor(mx, 16));
            mx = fmaxf(mx, __shfl_xor(mx, 32));
            float sum = 0.f;
#pragma unroll
            for (int i = 0; i < 16; ++i) { e[i] = expf(e[i] - mx); sum += e[i]; }
            sum += __shfl_xor(sum, 16);
            sum += __shfl_xor(sum, 32);
            float invs = 1.0f / sum;
#pragma unroll
            for (int i = 0; i < 16; ++i) s_at[r * 66 + mc * 16 + i] = e[i] * invs;
        }
        __syncthreads();
        // o = attn @ v
        {
            int n = tid & 63, dg = tid >> 6;
            float acc[4] = {0.f, 0.f, 0.f, 0.f};
            for (int m = 0; m < 64; ++m) {
                float p = s_at[n * 66 + m];
                acc[0] += p * s_v[(dg * 4 + 0) * 64 + m];
                acc[1] += p * s_v[(dg * 4 + 1) * 64 + m];
                acc[2] += p * s_v[(dg * 4 + 2) * 64 + m];
                acc[3] += p * s_v[(dg * 4 + 3) * 64 + m];
            }
#pragma unroll
            for (int i = 0; i < 4; ++i) s_o[n * 130 + hh * 16 + dg * 4 + i] = acc[i];
        }
        __syncthreads();
    }
    // pairwise projection, accumulate into x
    for (int idx = tid; idx < 16384; idx += 256) s_big[idx] = wp[idx];
    __syncthreads();
    {
        int tn = tid >> 4, tj = tid & 15;
        int n0 = tn * 4, j0 = tj * 8;
        float acc[4][8];
#pragma unroll
        for (int i = 0; i < 4; ++i)
#pragma unroll
            for (int u = 0; u < 8; ++u) acc[i][u] = bp[j0 + u];
        for (int c = 0; c < 128; ++c) {
            float a0 = s_o[(n0 + 0) * 130 + c];
            float a1 = s_o[(n0 + 1) * 130 + c];
            float a2 = s_o[(n0 + 2) * 130 + c];
            float a3 = s_o[(n0 + 3) * 130 + c];
            float4 bv0 = *(const float4*)&s_big[c * 128 + j0];
            float4 bv1 = *(const float4*)&s_big[c * 128 + j0 + 4];
            float bb[8] = {bv0.x, bv0.y, bv0.z, bv0.w, bv1.x, bv1.y, bv1.z, bv1.w};
#pragma unroll
            for (int u = 0; u < 8; ++u) {
                acc[0][u] += a0 * bb[u];
                acc[1][u] += a1 * bb[u];
                acc[2][u] += a2 * bb[u];
                acc[3][u] += a3 * bb[u];
            }
        }
#pragma unroll
        for (int i = 0; i < 4; ++i) {
            int n = n0 + i;
            int h = wh * 8 + (n >> 3), w = ww * 8 + (n & 7);
            size_t base = ((size_t)(b * 16384) + h * 128 + w) * 128 + j0;
            float4 x0 = *(const float4*)&x[base];
            float4 x1 = *(const float4*)&x[base + 4];
            x0.x += acc[i][0]; x0.y += acc[i][1]; x0.z += acc[i][2]; x0.w += acc[i][3];
            x1.x += acc[i][4]; x1.y += acc[i][5]; x1.z += acc[i][6]; x1.w += acc[i][7];
            *(float4*)&x[base] = x0;
            *(float4*)&x[base + 4] = x1;
        }
    }
}

// ---------------------------------------------------------------------------
// K4: x = x + gelu(LN2(x)@W1+b1)@W2   (NOTE: mlp_b2 is multiplied by 0 in ref)
__global__ __launch_bounds__(256) void k_mlp(float* __restrict__ x,
                                             const float* __restrict__ g2, const float* __restrict__ bt2,
                                             const float* __restrict__ w1, const float* __restrict__ b1,
                                             const float* __restrict__ w2) {
    __shared__ float s_a[64 * 129];
    __shared__ float s_h[64 * 129];
    __shared__ float s_w[128 * 128];
    int tid = threadIdx.x;
    int n0g = blockIdx.x * 64;
    for (int idx = tid; idx < 8192; idx += 256) {
        int n = idx >> 7, c = idx & 127;
        s_a[n * 129 + c] = x[(size_t)(n0g + n) * 128 + c];
    }
    __syncthreads();
    {
        int n = tid >> 2, q = tid & 3;
        float s = 0.f, s2 = 0.f;
        for (int c = q * 32; c < q * 32 + 32; ++c) {
            float v = s_a[n * 129 + c];
            s += v; s2 += v * v;
        }
        s += __shfl_xor(s, 1); s += __shfl_xor(s, 2);
        s2 += __shfl_xor(s2, 1); s2 += __shfl_xor(s2, 2);
        float mean = s * (1.f / 128.f);
        float var = s2 * (1.f / 128.f) - mean * mean;
        float rstd = rsqrtf(var + 1e-5f);
        for (int c = q * 32; c < q * 32 + 32; ++c) {
            float v = s_a[n * 129 + c];
            s_a[n * 129 + c] = (v - mean) * rstd * g2[c] + bt2[c];
        }
    }
    __syncthreads();
    int tn = tid >> 4, tj = tid & 15;
    int n0 = tn * 4, j0 = tj * 8;
    float out[4][8];
#pragma unroll
    for (int i = 0; i < 4; ++i)
#pragma unroll
        for (int u = 0; u < 8; ++u) out[i][u] = 0.f;
#pragma unroll 1
    for (int hc = 0; hc < 4; ++hc) {
        for (int idx = tid; idx < 16384; idx += 256) {
            int c = idx >> 7, j = idx & 127;
            s_w[idx] = w1[(size_t)c * 512 + hc * 128 + j];
        }
        __syncthreads();
        float acc[4][8];
#pragma unroll
        for (int i = 0; i < 4; ++i)
#pragma unroll
            for (int u = 0; u < 8; ++u) acc[i][u] = b1[hc * 128 + j0 + u];
        for (int c = 0; c < 128; ++c) {
            float a0 = s_a[(n0 + 0) * 129 + c];
            float a1 = s_a[(n0 + 1) * 129 + c];
            float a2 = s_a[(n0 + 2) * 129 + c];
            float a3 = s_a[(n0 + 3) * 129 + c];
            float4 bv0 = *(const float4*)&s_w[c * 128 + j0];
            float4 bv1 = *(const float4*)&s_w[c * 128 + j0 + 4];
            float bb[8] = {bv0.x, bv0.y, bv0.z, bv0.w, bv1.x, bv1.y, bv1.z, bv1.w};
#pragma unroll
            for (int u = 0; u < 8; ++u) {
                acc[0][u] += a0 * bb[u];
                acc[1][u] += a1 * bb[u];
                acc[2][u] += a2 * bb[u];
                acc[3][u] += a3 * bb[u];
            }
        }
#pragma unroll
        for (int i = 0; i < 4; ++i)
#pragma unroll
            for (int u = 0; u < 8; ++u)
                s_h[(n0 + i) * 129 + j0 + u] = gelu_f(acc[i][u]);
        __syncthreads();
        for (int idx = tid; idx < 16384; idx += 256) {
            s_w[idx] = w2[(size_t)hc * 128 * 128 + idx];
        }
        __syncthreads();
        for (int k = 0; k < 128; ++k) {
            float a0 = s_h[(n0 + 0) * 129 + k];
            float a1 = s_h[(n0 + 1) * 129 + k];
            float a2 = s_h[(n0 + 2) * 129 + k];
            float a3 = s_h[(n0 + 3) * 129 + k];
            float4 bv0 = *(const float4*)&s_w[k * 128 + j0];
            float4 bv1 = *(const float4*)&s_w[k * 128 + j0 + 4];
            float bb[8] = {bv0.x, bv0.y, bv0.z, bv0.w, bv1.x, bv1.y, bv1.z, bv1.w};
#pragma unroll
            for (int u = 0; u < 8; ++u) {
                out[0][u] += a0 * bb[u];
                out[1][u] += a1 * bb[u];
                out[2][u] += a2 * bb[u];
                out[3][u] += a3 * bb[u];
            }
        }
        __syncthreads();
    }
#pragma unroll
    for (int i = 0; i < 4; ++i) {
        size_t base = (size_t)(n0g + n0 + i) * 128 + j0;
        float4 x0 = *(const float4*)&x[base];
        float4 x1 = *(const float4*)&x[base + 4];
        x0.x += out[i][0]; x0.y += out[i][1]; x0.z += out[i][2]; x0.w += out[i][3];
        x1.x += out[i][4]; x1.y += out[i][5]; x1.z += out[i][6]; x1.w += out[i][7];
        *(float4*)&x[base] = x0;
        *(float4*)&x[base + 4] = x1;
    }
}

// ---------------------------------------------------------------------------
// K5: conv3x3([crf|cost]) + BN-ish + relu -> h1. grid (8,8,4), 256 threads.
__global__ __launch_bounds__(256) void k_conv(const float* __restrict__ x,
                                              const float* __restrict__ cost,
                                              const float* __restrict__ w1, const float* __restrict__ b1,
                                              const float* __restrict__ bng, const float* __restrict__ bnb,
                                              float* __restrict__ h1) {
    __shared__ float s_p[16 * 324];     // patch chunk [16ci][18][18]
    __shared__ float s_wt[144 * 88];    // weights chunk [ci_l*9+tap][co]
    int tid = threadIdx.x;
    int tx0 = blockIdx.x * 16, ty0 = blockIdx.y * 16, b = blockIdx.z;
    int py = tid >> 4, px = tid & 15;
    float acc[88];
#pragma unroll
    for (int co = 0; co < 88; ++co) acc[co] = 0.f;
#pragma unroll 1
    for (int chunk = 0; chunk < 11; ++chunk) {
        int ci0 = chunk * 16;
        if (ci0 < 128) {
            for (int idx = tid; idx < 324; idx += 256) {
                int yy = idx / 18, xx = idx % 18;
                int gy = ty0 + yy - 1, gx = tx0 + xx - 1;
                float vv[16];
                if (gy >= 0 && gy < 128 && gx >= 0 && gx < 128) {
                    const float4* src = (const float4*)&x[((size_t)(b << 14) + gy * 128 + gx) * 128 + ci0];
                    float4 v0 = src[0], v1 = src[1], v2 = src[2], v3 = src[3];
                    vv[0] = v0.x; vv[1] = v0.y; vv[2] = v0.z; vv[3] = v0.w;
                    vv[4] = v1.x; vv[5] = v1.y; vv[6] = v1.z; vv[7] = v1.w;
                    vv[8] = v2.x; vv[9] = v2.y; vv[10] = v2.z; vv[11] = v2.w;
                    vv[12] = v3.x; vv[13] = v3.y; vv[14] = v3.z; vv[15] = v3.w;
                } else {
#pragma unroll
                    for (int cl = 0; cl < 16; ++cl) vv[cl] = 0.f;
                }
#pragma unroll
                for (int cl = 0; cl < 16; ++cl) s_p[cl * 324 + idx] = vv[cl];
            }
        } else {
            int d0 = ci0 - 128;
            for (int idx = tid; idx < 16 * 324; idx += 256) {
                int cl = idx / 324, r = idx % 324;
                int yy = r / 18, xx = r % 18;
                int gy = ty0 + yy - 1, gx = tx0 + xx - 1;
                float v = 0.f;
                if (gy >= 0 && gy < 128 && gx >= 0 && gx < 128)
                    v = cost[((size_t)(b * 48 + d0 + cl) << 14) + gy * 128 + gx];
                s_p[cl * 324 + r] = v;
            }
        }
        for (int idx = tid; idx < 88 * 144; idx += 256) {
            int co = idx / 144, r = idx % 144;
            s_wt[r * 88 + co] = w1[(size_t)co * 1584 + ci0 * 9 + r];
        }
        __syncthreads();
#pragma unroll 1
        for (int cl = 0; cl < 16; ++cl) {
#pragma unroll
            for (int dy = 0; dy < 3; ++dy) {
#pragma unroll
                for (int dx = 0; dx < 3; ++dx) {
                    float av = s_p[cl * 324 + (py + dy) * 18 + (px + dx)];
                    const float4* wrow = (const float4*)&s_wt[(cl * 9 + dy * 3 + dx) * 88];
#pragma unroll
                    for (int c4 = 0; c4 < 22; ++c4) {
                        float4 wv = wrow[c4];
                        acc[c4 * 4 + 0] += av * wv.x;
                        acc[c4 * 4 + 1] += av * wv.y;
                        acc[c4 * 4 + 2] += av * wv.z;
                        acc[c4 * 4 + 3] += av * wv.w;
                    }
                }
            }
        }
        __syncthreads();
    }
    const float rs = 0.9999950000374997f;   // rsqrt(1 + 1e-5)
    int h = ty0 + py, w = tx0 + px;
#pragma unroll
    for (int co = 0; co < 88; ++co) {
        float v = (acc[co] + b1[co]) * rs * bng[co] + bnb[co];
        h1[((size_t)(b * 88 + co) << 14) + h * 128 + w] = fmaxf(v, 0.f);
    }
}

// ---------------------------------------------------------------------------
// K6: pv = conv1x1(h1) + b2; softmax over D; pred = 4*sum(d*p). 256 blocks.
__global__ __launch_bounds__(256) void k_head(const float* __restrict__ h1,
                                              const float* __restrict__ w2, const float* __restrict__ b2,
                                              float* __restrict__ out) {
    __shared__ float s_wt[88 * 48];   // [k][d]
    __shared__ float s_b[48];
    int tid = threadIdx.x;
    for (int idx = tid; idx < 48 * 88; idx += 256) {
        int d = idx / 88, k = idx % 88;
        s_wt[k * 48 + d] = w2[idx];
    }
    if (tid < 48) s_b[tid] = b2[tid];
    __syncthreads();
    int px = blockIdx.x * 256 + tid;
    int b = px >> 14, r = px & 16383;
    float acc[48];
#pragma unroll
    for (int d = 0; d < 48; ++d) acc[d] = s_b[d];
    for (int k = 0; k < 88; ++k) {
        float hv = h1[((size_t)(b * 88 + k) << 14) + r];
        const float4* wrow = (const float4*)&s_wt[k * 48];
#pragma unroll
        for (int d4 = 0; d4 < 12; ++d4) {
            float4 wv = wrow[d4];
            acc[d4 * 4 + 0] += hv * wv.x;
            acc[d4 * 4 + 1] += hv * wv.y;
            acc[d4 * 4 + 2] += hv * wv.z;
            acc[d4 * 4 + 3] += hv * wv.w;
        }
    }
    float mx = -1e30f;
#pragma unroll
    for (int d = 0; d < 48; ++d) mx = fmaxf(mx, acc[d]);
    float sum = 0.f, wsum = 0.f;
#pragma unroll
    for (int d = 0; d < 48; ++d) {
        float e = expf(acc[d] - mx);
        sum += e;
        wsum += e * (float)d;
    }
    out[px] = 4.0f * wsum / sum;
}

// ---------------------------------------------------------------------------
extern "C" void kernel_launch(void* const* d_in, const int* in_sizes, int n_in,
                              void* d_out, int out_size, void* d_ws, size_t ws_size,
                              hipStream_t stream) {
    const float* feat_l = (const float*)d_in[0];
    const float* feat_r = (const float*)d_in[1];
    const float* wq = (const float*)d_in[2];
    const float* bq = (const float*)d_in[3];
    const float* wk = (const float*)d_in[4];
    const float* bk = (const float*)d_in[5];
    const float* wv = (const float*)d_in[6];
    const float* bv = (const float*)d_in[7];
    const float* wp = (const float*)d_in[8];
    const float* bp = (const float*)d_in[9];
    const float* rpb = (const float*)d_in[10];
    const float* ln1_g = (const float*)d_in[11];
    const float* ln1_b = (const float*)d_in[12];
    const float* ln2_g = (const float*)d_in[13];
    const float* ln2_b = (const float*)d_in[14];
    const float* mlp_w1 = (const float*)d_in[15];
    const float* mlp_b1 = (const float*)d_in[16];
    const float* mlp_w2 = (const float*)d_in[17];
    // d_in[18] = mlp_b2 is multiplied by 0.0 in the reference -> unused
    const float* un_w1 = (const float*)d_in[19];
    const float* un_b1 = (const float*)d_in[20];
    const float* un_w2 = (const float*)d_in[21];
    const float* un_b2 = (const float*)d_in[22];
    const float* dp_w1 = (const float*)d_in[23];
    const float* dp_b1 = (const float*)d_in[24];
    const float* bn_g = (const float*)d_in[25];
    const float* bn_b = (const float*)d_in[26];
    const float* dp_w2 = (const float*)d_in[27];
    const float* dp_b2 = (const float*)d_in[28];

    float* ws = (float*)d_ws;
    float* cost = ws;                               // 4*48*16384   = 3,145,728
    float* x = ws + 3145728;                        // 4*16384*128  = 8,388,608
    float* h1 = ws + 3145728 + 8388608;             // 4*88*16384   = 5,767,168
    float* out = (float*)d_out;

    k_cost<<<dim3(64, 4), 256, 0, stream>>>(feat_l, feat_r, cost);
    k_unary<<<1024, 256, 0, stream>>>(feat_l, un_w1, un_b1, un_w2, un_b2, x);
    k_attn<<<1024, 256, 0, stream>>>(feat_l, wq, bq, wk, bk, wv, bv, wp, bp,
                                     rpb, ln1_g, ln1_b, x);
    k_mlp<<<1024, 256, 0, stream>>>(x, ln2_g, ln2_b, mlp_w1, mlp_b1, mlp_w2);
    k_conv<<<dim3(8, 8, 4), 256, 0, stream>>>(x, cost, dp_w1, dp_b1, bn_g, bn_b, h1);
    k_head<<<256, 256, 0, stream>>>(h1, dp_w2, dp_b2, out);
}

// Round 2
// 1419.148 us; speedup vs baseline: 1.7144x; 1.7144x over previous
//
#include <hip/hip_runtime.h>
#include <math.h>

// Dims
constexpr int Bn = 4, Cc = 128, Hh = 128, Wn = 128, Dd = 48;
constexpr float SCALE = 0.25f;       // 16^-0.5

typedef short  bf16x8 __attribute__((ext_vector_type(8)));
typedef float  f32x4  __attribute__((ext_vector_type(4)));
typedef unsigned short u16x8 __attribute__((ext_vector_type(8)));

static __device__ __forceinline__ float gelu_f(float v) {
    return 0.5f * v * (1.0f + erff(v * 0.70710678118654752f));
}

static __device__ __forceinline__ unsigned short f2bf(float f) {
    unsigned int u = __float_as_uint(f);
    u = (u + 0x7fffu + ((u >> 16) & 1u)) >> 16;   // RNE
    return (unsigned short)u;
}

// ---------------------------------------------------------------------------
// K1: cost volume. grid (H/2, B), 256 threads. Each half-block owns one (b,h) row.
__global__ __launch_bounds__(256) void k_cost(const float* __restrict__ fl,
                                              const float* __restrict__ fr,
                                              float* __restrict__ cost) {
    int tid = threadIdx.x;
    int lr = tid >> 7, w = tid & 127;
    int h = blockIdx.x * 2 + lr;
    int b = blockIdx.y;
    __shared__ float s_fr[2][128];
    float acc[48];
#pragma unroll
    for (int d = 0; d < 48; ++d) acc[d] = 0.f;
    const float* flb = fl + ((size_t)b * 128 * 16384) + h * 128;
    const float* frb = fr + ((size_t)b * 128 * 16384) + h * 128;
    for (int c = 0; c < 128; ++c) {
        float flv = flb[(size_t)c * 16384 + w];
        s_fr[lr][w] = frb[(size_t)c * 16384 + w];
        __syncthreads();
#pragma unroll
        for (int d = 0; d < 48; ++d) {
            if (d <= w) acc[d] += flv * s_fr[lr][w - d];
        }
        __syncthreads();
    }
    const float inv = 1.0f / 128.0f;
#pragma unroll
    for (int d = 0; d < 48; ++d) {
        cost[(((size_t)b * 48 + d) << 14) + h * 128 + w] = acc[d] * inv;
    }
}

// ---------------------------------------------------------------------------
// K2: unary = gelu(tok@W1+b1)@W2+b2 -> x.  64 tokens per block, 256 threads.
__global__ __launch_bounds__(256) void k_unary(const float* __restrict__ feat_l,
                                               const float* __restrict__ w1,
                                               const float* __restrict__ b1,
                                               const float* __restrict__ w2,
                                               const float* __restrict__ b2,
                                               float* __restrict__ x) {
    __shared__ float s_a[64 * 129];
    __shared__ float s_h[64 * 129];
    __shared__ float s_w[128 * 128];
    int tid = threadIdx.x;
    int n0g = blockIdx.x * 64;            // global token id
    int b = n0g >> 14;
    int nb = n0g & 16383;
    for (int idx = tid; idx < 64 * 128; idx += 256) {
        int c = idx >> 6, nl = idx & 63;
        s_a[nl * 129 + c] = feat_l[((size_t)(b * 128 + c) << 14) + nb + nl];
    }
    for (int idx = tid; idx < 128 * 128; idx += 256) s_w[idx] = w1[idx];
    __syncthreads();

    int tn = tid >> 4, tj = tid & 15;
    int n0 = tn * 4, j0 = tj * 8;
    float accA[4][8];
#pragma unroll
    for (int i = 0; i < 4; ++i)
#pragma unroll
        for (int u = 0; u < 8; ++u) accA[i][u] = b1[j0 + u];
    for (int c = 0; c < 128; ++c) {
        float a0 = s_a[(n0 + 0) * 129 + c];
        float a1 = s_a[(n0 + 1) * 129 + c];
        float a2 = s_a[(n0 + 2) * 129 + c];
        float a3 = s_a[(n0 + 3) * 129 + c];
        float4 bv0 = *(const float4*)&s_w[c * 128 + j0];
        float4 bv1 = *(const float4*)&s_w[c * 128 + j0 + 4];
        float bb[8] = {bv0.x, bv0.y, bv0.z, bv0.w, bv1.x, bv1.y, bv1.z, bv1.w};
#pragma unroll
        for (int u = 0; u < 8; ++u) {
            accA[0][u] += a0 * bb[u];
            accA[1][u] += a1 * bb[u];
            accA[2][u] += a2 * bb[u];
            accA[3][u] += a3 * bb[u];
        }
    }
#pragma unroll
    for (int i = 0; i < 4; ++i)
#pragma unroll
        for (int u = 0; u < 8; ++u)
            s_h[(n0 + i) * 129 + j0 + u] = gelu_f(accA[i][u]);
    __syncthreads();
    for (int idx = tid; idx < 128 * 128; idx += 256) s_w[idx] = w2[idx];
    __syncthreads();
    float accB[4][8];
#pragma unroll
    for (int i = 0; i < 4; ++i)
#pragma unroll
        for (int u = 0; u < 8; ++u) accB[i][u] = b2[j0 + u];
    for (int c = 0; c < 128; ++c) {
        float a0 = s_h[(n0 + 0) * 129 + c];
        float a1 = s_h[(n0 + 1) * 129 + c];
        float a2 = s_h[(n0 + 2) * 129 + c];
        float a3 = s_h[(n0 + 3) * 129 + c];
        float4 bv0 = *(const float4*)&s_w[c * 128 + j0];
        float4 bv1 = *(const float4*)&s_w[c * 128 + j0 + 4];
        float bb[8] = {bv0.x, bv0.y, bv0.z, bv0.w, bv1.x, bv1.y, bv1.z, bv1.w};
#pragma unroll
        for (int u = 0; u < 8; ++u) {
            accB[0][u] += a0 * bb[u];
            accB[1][u] += a1 * bb[u];
            accB[2][u] += a2 * bb[u];
            accB[3][u] += a3 * bb[u];
        }
    }
#pragma unroll
    for (int i = 0; i < 4; ++i) {
        size_t base = ((size_t)(n0g + n0 + i)) * 128 + j0;
        float4 o0 = {accB[i][0], accB[i][1], accB[i][2], accB[i][3]};
        float4 o1 = {accB[i][4], accB[i][5], accB[i][6], accB[i][7]};
        *(float4*)&x[base] = o0;
        *(float4*)&x[base + 4] = o1;
    }
}

// ---------------------------------------------------------------------------
// K3: window attention. one block per window (1024 blocks), 256 threads.
__global__ __launch_bounds__(256) void k_attn(const float* __restrict__ feat_l,
                                              const float* __restrict__ wq, const float* __restrict__ bq,
                                              const float* __restrict__ wk, const float* __restrict__ bk,
                                              const float* __restrict__ wv, const float* __restrict__ bv,
                                              const float* __restrict__ wp, const float* __restrict__ bp,
                                              const float* __restrict__ rpb,
                                              const float* __restrict__ g1, const float* __restrict__ bt1,
                                              float* __restrict__ x) {
    __shared__ float s_nf[128 * 64];     // normed tokens, [c][n]
    __shared__ float s_o[64 * 130];      // attention output, [n][c] padded
    __shared__ float s_big[128 * 128];   // per-head scratch, then wp
    int tid = threadIdx.x;
    int bw = blockIdx.x;
    int b = bw >> 8, wh = (bw >> 4) & 15, ww = bw & 15;

    for (int idx = tid; idx < 8192; idx += 256) {
        int c = idx >> 6, n = idx & 63;
        int h = wh * 8 + (n >> 3), w = ww * 8 + (n & 7);
        s_nf[c * 64 + n] = feat_l[((size_t)(b * 128 + c) << 14) + h * 128 + w];
    }
    __syncthreads();
    {
        int n = tid >> 2, q = tid & 3;
        float s = 0.f, s2 = 0.f;
        for (int c = q * 32; c < q * 32 + 32; ++c) {
            float v = s_nf[c * 64 + n];
            s += v; s2 += v * v;
        }
        s += __shfl_xor(s, 1); s += __shfl_xor(s, 2);
        s2 += __shfl_xor(s2, 1); s2 += __shfl_xor(s2, 2);
        float mean = s * (1.f / 128.f);
        float var = s2 * (1.f / 128.f) - mean * mean;
        float rstd = rsqrtf(var + 1e-5f);
        for (int c = q * 32; c < q * 32 + 32; ++c) {
            float v = s_nf[c * 64 + n];
            s_nf[c * 64 + n] = (v - mean) * rstd * g1[c] + bt1[c];
        }
    }
    __syncthreads();

    float* s_ws = s_big;          // [128][16]
    float* s_q = s_big + 2048;    // [16][64]
    float* s_k = s_big + 3072;    // [16][64]
    float* s_v = s_big + 4096;    // [16][64]
    float* s_at = s_big + 5120;   // [64][66]

    for (int hh = 0; hh < 8; ++hh) {
        const float* wmats[3] = {wq, wk, wv};
        const float* bvecs[3] = {bq, bk, bv};
        float* outs[3] = {s_q, s_k, s_v};
#pragma unroll 1
        for (int mm = 0; mm < 3; ++mm) {
            for (int idx = tid; idx < 2048; idx += 256) {
                int c = idx >> 4, u = idx & 15;
                s_ws[idx] = wmats[mm][c * 128 + hh * 16 + u];
            }
            __syncthreads();
            {
                int n = tid & 63, ug = tid >> 6;
                float acc[4];
#pragma unroll
                for (int i = 0; i < 4; ++i) acc[i] = bvecs[mm][hh * 16 + ug * 4 + i];
                for (int c = 0; c < 128; ++c) {
                    float av = s_nf[c * 64 + n];
                    float4 w4 = *(const float4*)&s_ws[c * 16 + ug * 4];
                    acc[0] += av * w4.x; acc[1] += av * w4.y;
                    acc[2] += av * w4.z; acc[3] += av * w4.w;
                }
                float* dst = outs[mm];
#pragma unroll
                for (int i = 0; i < 4; ++i) dst[(ug * 4 + i) * 64 + n] = acc[i];
            }
            __syncthreads();
        }
        {
            int m = tid & 63, ng = tid >> 6;
            for (int n = ng * 16; n < ng * 16 + 16; ++n) {
                float s = 0.f;
#pragma unroll
                for (int d = 0; d < 16; ++d) s += s_q[d * 64 + n] * s_k[d * 64 + m];
                int relidx = (((n >> 3) - (m >> 3)) + 7) * 15 + (((n & 7) - (m & 7)) + 7);
                s_at[n * 66 + m] = s * SCALE + rpb[relidx * 8 + hh];
            }
        }
        __syncthreads();
        {
            int wid = tid >> 6, lane = tid & 63;
            int r = wid * 16 + (lane & 15);
            int mc = lane >> 4;
            float e[16];
            float mx = -1e30f;
#pragma unroll
            for (int i = 0; i < 16; ++i) {
                e[i] = s_at[r * 66 + mc * 16 + i];
                mx = fmaxf(mx, e[i]);
            }
            mx = fmaxf(mx, __shfl_xor(mx, 16));
            mx = fmaxf(mx, __shfl_xor(mx, 32));
            float sum = 0.f;
#pragma unroll
            for (int i = 0; i < 16; ++i) { e[i] = expf(e[i] - mx); sum += e[i]; }
            sum += __shfl_xor(sum, 16);
            sum += __shfl_xor(sum, 32);
            float invs = 1.0f / sum;
#pragma unroll
            for (int i = 0; i < 16; ++i) s_at[r * 66 + mc * 16 + i] = e[i] * invs;
        }
        __syncthreads();
        {
            int n = tid & 63, dg = tid >> 6;
            float acc[4] = {0.f, 0.f, 0.f, 0.f};
            for (int m = 0; m < 64; ++m) {
                float p = s_at[n * 66 + m];
                acc[0] += p * s_v[(dg * 4 + 0) * 64 + m];
                acc[1] += p * s_v[(dg * 4 + 1) * 64 + m];
                acc[2] += p * s_v[(dg * 4 + 2) * 64 + m];
                acc[3] += p * s_v[(dg * 4 + 3) * 64 + m];
            }
#pragma unroll
            for (int i = 0; i < 4; ++i) s_o[n * 130 + hh * 16 + dg * 4 + i] = acc[i];
        }
        __syncthreads();
    }
    for (int idx = tid; idx < 16384; idx += 256) s_big[idx] = wp[idx];
    __syncthreads();
    {
        int tn = tid >> 4, tj = tid & 15;
        int n0 = tn * 4, j0 = tj * 8;
        float acc[4][8];
#pragma unroll
        for (int i = 0; i < 4; ++i)
#pragma unroll
            for (int u = 0; u < 8; ++u) acc[i][u] = bp[j0 + u];
        for (int c = 0; c < 128; ++c) {
            float a0 = s_o[(n0 + 0) * 130 + c];
            float a1 = s_o[(n0 + 1) * 130 + c];
            float a2 = s_o[(n0 + 2) * 130 + c];
            float a3 = s_o[(n0 + 3) * 130 + c];
            float4 bv0 = *(const float4*)&s_big[c * 128 + j0];
            float4 bv1 = *(const float4*)&s_big[c * 128 + j0 + 4];
            float bb[8] = {bv0.x, bv0.y, bv0.z, bv0.w, bv1.x, bv1.y, bv1.z, bv1.w};
#pragma unroll
            for (int u = 0; u < 8; ++u) {
                acc[0][u] += a0 * bb[u];
                acc[1][u] += a1 * bb[u];
                acc[2][u] += a2 * bb[u];
                acc[3][u] += a3 * bb[u];
            }
        }
#pragma unroll
        for (int i = 0; i < 4; ++i) {
            int n = n0 + i;
            int h = wh * 8 + (n >> 3), w = ww * 8 + (n & 7);
            size_t base = ((size_t)(b * 16384) + h * 128 + w) * 128 + j0;
            float4 x0 = *(const float4*)&x[base];
            float4 x1 = *(const float4*)&x[base + 4];
            x0.x += acc[i][0]; x0.y += acc[i][1]; x0.z += acc[i][2]; x0.w += acc[i][3];
            x1.x += acc[i][4]; x1.y += acc[i][5]; x1.z += acc[i][6]; x1.w += acc[i][7];
            *(float4*)&x[base] = x0;
            *(float4*)&x[base + 4] = x1;
        }
    }
}

// ---------------------------------------------------------------------------
// K4: x = x + gelu(LN2(x)@W1+b1)@W2   (NOTE: mlp_b2 is multiplied by 0 in ref)
__global__ __launch_bounds__(256) void k_mlp(float* __restrict__ x,
                                             const float* __restrict__ g2, const float* __restrict__ bt2,
                                             const float* __restrict__ w1, const float* __restrict__ b1,
                                             const float* __restrict__ w2) {
    __shared__ float s_a[64 * 129];
    __shared__ float s_h[64 * 129];
    __shared__ float s_w[128 * 128];
    int tid = threadIdx.x;
    int n0g = blockIdx.x * 64;
    for (int idx = tid; idx < 8192; idx += 256) {
        int n = idx >> 7, c = idx & 127;
        s_a[n * 129 + c] = x[(size_t)(n0g + n) * 128 + c];
    }
    __syncthreads();
    {
        int n = tid >> 2, q = tid & 3;
        float s = 0.f, s2 = 0.f;
        for (int c = q * 32; c < q * 32 + 32; ++c) {
            float v = s_a[n * 129 + c];
            s += v; s2 += v * v;
        }
        s += __shfl_xor(s, 1); s += __shfl_xor(s, 2);
        s2 += __shfl_xor(s2, 1); s2 += __shfl_xor(s2, 2);
        float mean = s * (1.f / 128.f);
        float var = s2 * (1.f / 128.f) - mean * mean;
        float rstd = rsqrtf(var + 1e-5f);
        for (int c = q * 32; c < q * 32 + 32; ++c) {
            float v = s_a[n * 129 + c];
            s_a[n * 129 + c] = (v - mean) * rstd * g2[c] + bt2[c];
        }
    }
    __syncthreads();
    int tn = tid >> 4, tj = tid & 15;
    int n0 = tn * 4, j0 = tj * 8;
    float out[4][8];
#pragma unroll
    for (int i = 0; i < 4; ++i)
#pragma unroll
        for (int u = 0; u < 8; ++u) out[i][u] = 0.f;
#pragma unroll 1
    for (int hc = 0; hc < 4; ++hc) {
        for (int idx = tid; idx < 16384; idx += 256) {
            int c = idx >> 7, j = idx & 127;
            s_w[idx] = w1[(size_t)c * 512 + hc * 128 + j];
        }
        __syncthreads();
        float acc[4][8];
#pragma unroll
        for (int i = 0; i < 4; ++i)
#pragma unroll
            for (int u = 0; u < 8; ++u) acc[i][u] = b1[hc * 128 + j0 + u];
        for (int c = 0; c < 128; ++c) {
            float a0 = s_a[(n0 + 0) * 129 + c];
            float a1 = s_a[(n0 + 1) * 129 + c];
            float a2 = s_a[(n0 + 2) * 129 + c];
            float a3 = s_a[(n0 + 3) * 129 + c];
            float4 bv0 = *(const float4*)&s_w[c * 128 + j0];
            float4 bv1 = *(const float4*)&s_w[c * 128 + j0 + 4];
            float bb[8] = {bv0.x, bv0.y, bv0.z, bv0.w, bv1.x, bv1.y, bv1.z, bv1.w};
#pragma unroll
            for (int u = 0; u < 8; ++u) {
                acc[0][u] += a0 * bb[u];
                acc[1][u] += a1 * bb[u];
                acc[2][u] += a2 * bb[u];
                acc[3][u] += a3 * bb[u];
            }
        }
#pragma unroll
        for (int i = 0; i < 4; ++i)
#pragma unroll
            for (int u = 0; u < 8; ++u)
                s_h[(n0 + i) * 129 + j0 + u] = gelu_f(acc[i][u]);
        __syncthreads();
        for (int idx = tid; idx < 16384; idx += 256) {
            s_w[idx] = w2[(size_t)hc * 128 * 128 + idx];
        }
        __syncthreads();
        for (int k = 0; k < 128; ++k) {
            float a0 = s_h[(n0 + 0) * 129 + k];
            float a1 = s_h[(n0 + 1) * 129 + k];
            float a2 = s_h[(n0 + 2) * 129 + k];
            float a3 = s_h[(n0 + 3) * 129 + k];
            float4 bv0 = *(const float4*)&s_w[k * 128 + j0];
            float4 bv1 = *(const float4*)&s_w[k * 128 + j0 + 4];
            float bb[8] = {bv0.x, bv0.y, bv0.z, bv0.w, bv1.x, bv1.y, bv1.z, bv1.w};
#pragma unroll
            for (int u = 0; u < 8; ++u) {
                out[0][u] += a0 * bb[u];
                out[1][u] += a1 * bb[u];
                out[2][u] += a2 * bb[u];
                out[3][u] += a3 * bb[u];
            }
        }
        __syncthreads();
    }
#pragma unroll
    for (int i = 0; i < 4; ++i) {
        size_t base = (size_t)(n0g + n0 + i) * 128 + j0;
        float4 x0 = *(const float4*)&x[base];
        float4 x1 = *(const float4*)&x[base + 4];
        x0.x += out[i][0]; x0.y += out[i][1]; x0.z += out[i][2]; x0.w += out[i][3];
        x1.x += out[i][4]; x1.y += out[i][5]; x1.z += out[i][6]; x1.w += out[i][7];
        *(float4*)&x[base] = x0;
        *(float4*)&x[base + 4] = x1;
    }
}

// ---------------------------------------------------------------------------
// K5a: pack conv weights for MFMA A-fragments, folding BN scale.
// pk layout: [chunk(6)][tap(9)][cotile(6)][lane(64)][8] bf16
//   co = cotile*16 + (lane&15);  ci = chunk*32 + (lane>>4)*8 + j  (zero-padded)
__global__ __launch_bounds__(64) void k_pack(const float* __restrict__ w1,
                                             const float* __restrict__ b1,
                                             const float* __restrict__ bng,
                                             const float* __restrict__ bnb,
                                             unsigned short* __restrict__ pk,
                                             float* __restrict__ bias2) {
    const float rs = 0.9999950000374997f;   // rsqrt(1 + 1e-5)
    int blk = blockIdx.x;                   // (chunk*9+tap)*6 + cotile, 0..323
    int lane = threadIdx.x;
    int ct = blk % 6;
    int taplin = blk / 6;
    int tap = taplin % 9, chunk = taplin / 9;
    int co = ct * 16 + (lane & 15);
    int cibase = chunk * 32 + (lane >> 4) * 8;
    u16x8 out;
#pragma unroll
    for (int j = 0; j < 8; ++j) {
        int ci = cibase + j;
        float v = 0.f;
        if (co < 88 && ci < 176) v = w1[(size_t)co * 1584 + ci * 9 + tap] * rs * bng[co];
        out[j] = f2bf(v);
    }
    *(u16x8*)(pk + ((size_t)blk * 64 + lane) * 8) = out;
    if (blk == 0) {
        for (int i = lane; i < 96; i += 64)
            bias2[i] = (i < 88) ? (b1[i] * rs * bng[i] + bnb[i]) : 0.f;
    }
}

// ---------------------------------------------------------------------------
// K5b: conv3x3 as bf16 implicit-GEMM MFMA. grid (8,8,4), 256 threads.
// Per block: 16x16 spatial tile, all 96(pad) output channels.
// A = packed weights (M=co), B = LDS patch (N=px). D: co=(lane>>4)*4+r, px=lane&15.
__global__ __launch_bounds__(256) void k_conv_mfma(const float* __restrict__ x,
                                                   const float* __restrict__ cost,
                                                   const unsigned short* __restrict__ pk,
                                                   const float* __restrict__ bias2,
                                                   float* __restrict__ h1) {
    __shared__ __align__(16) unsigned short s_p[324 * 40];   // [pos 18x18][ci 32 pad40]
    int tid = threadIdx.x;
    int wid = tid >> 6, lane = tid & 63;
    int g = lane >> 4, t = lane & 15;
    int tx0 = blockIdx.x * 16, ty0 = blockIdx.y * 16, b = blockIdx.z;

    f32x4 acc[4][6];
#pragma unroll
    for (int p = 0; p < 4; ++p)
#pragma unroll
        for (int ct = 0; ct < 6; ++ct) acc[p][ct] = (f32x4){0.f, 0.f, 0.f, 0.f};

#pragma unroll 1
    for (int chunk = 0; chunk < 6; ++chunk) {
        // ---- stage patch chunk (32 channels, 18x18, zero-padded borders) ----
        if (chunk < 4) {
            int ci0 = chunk * 32;
            for (int u = tid; u < 648; u += 256) {
                int pos = u >> 1, half = u & 1;
                int yy = pos / 18, xx = pos - yy * 18;
                int gy = ty0 + yy - 1, gx = tx0 + xx - 1;
                u16x8 lo, hi;
                if (gy >= 0 && gy < 128 && gx >= 0 && gx < 128) {
                    const float4* src = (const float4*)&x[((size_t)(b << 14) + gy * 128 + gx) * 128 + ci0 + half * 16];
                    float4 v0 = src[0], v1 = src[1], v2 = src[2], v3 = src[3];
                    lo[0] = f2bf(v0.x); lo[1] = f2bf(v0.y); lo[2] = f2bf(v0.z); lo[3] = f2bf(v0.w);
                    lo[4] = f2bf(v1.x); lo[5] = f2bf(v1.y); lo[6] = f2bf(v1.z); lo[7] = f2bf(v1.w);
                    hi[0] = f2bf(v2.x); hi[1] = f2bf(v2.y); hi[2] = f2bf(v2.z); hi[3] = f2bf(v2.w);
                    hi[4] = f2bf(v3.x); hi[5] = f2bf(v3.y); hi[6] = f2bf(v3.z); hi[7] = f2bf(v3.w);
                } else {
                    lo = (u16x8)(unsigned short)0; hi = (u16x8)(unsigned short)0;
                }
                unsigned short* dst = &s_p[pos * 40 + half * 16];
                *(u16x8*)dst = lo;
                *(u16x8*)(dst + 8) = hi;
            }
        } else {
            int d0 = (chunk - 4) * 32;
            for (int u = tid; u < 576; u += 256) {
                int cl = u / 18, yy = u - cl * 18;
                int d = d0 + cl;
                int gy = ty0 + yy - 1;
                bool rowok = (d < 48) && (gy >= 0) && (gy < 128);
                const float* srow = cost + ((size_t)(b * 48 + (rowok ? d : 0)) << 14) + (rowok ? gy : 0) * 128;
                for (int xx = 0; xx < 18; ++xx) {
                    int gx = tx0 + xx - 1;
                    float v = (rowok && gx >= 0 && gx < 128) ? srow[gx] : 0.f;
                    s_p[(yy * 18 + xx) * 40 + cl] = f2bf(v);
                }
            }
        }
        __syncthreads();

        // ---- 9 taps of K=32 MFMA accumulation ----
#pragma unroll 1
        for (int tap = 0; tap < 9; ++tap) {
            int dy = tap / 3, dx = tap - dy * 3;
            const unsigned short* pkt = pk + ((size_t)(chunk * 9 + tap)) * 6 * 512;
            bf16x8 afr[6];
#pragma unroll
            for (int ct = 0; ct < 6; ++ct)
                afr[ct] = *(const bf16x8*)(pkt + ct * 512 + lane * 8);
            bf16x8 bfr[4];
#pragma unroll
            for (int p = 0; p < 4; ++p) {
                int pos = (wid * 4 + p + dy) * 18 + t + dx;
                bfr[p] = *(const bf16x8*)&s_p[pos * 40 + g * 8];
            }
#pragma unroll
            for (int p = 0; p < 4; ++p)
#pragma unroll
                for (int ct = 0; ct < 6; ++ct)
                    acc[p][ct] = __builtin_amdgcn_mfma_f32_16x16x32_bf16(afr[ct], bfr[p], acc[p][ct], 0, 0, 0);
        }
        __syncthreads();
    }

    // ---- epilogue: bias + relu, coalesced stores (px = lane&15 contiguous) ----
#pragma unroll
    for (int p = 0; p < 4; ++p) {
        int y = ty0 + wid * 4 + p;
#pragma unroll
        for (int ct = 0; ct < 6; ++ct) {
#pragma unroll
            for (int r = 0; r < 4; ++r) {
                int co = ct * 16 + g * 4 + r;
                if (co < 88) {
                    float v = acc[p][ct][r] + bias2[co];
                    h1[((size_t)(b * 88 + co) << 14) + y * 128 + tx0 + t] = fmaxf(v, 0.f);
                }
            }
        }
    }
}

// ---------------------------------------------------------------------------
// K6: pv = conv1x1(h1) + b2; softmax over D; pred = 4*sum(d*p). 256 blocks.
__global__ __launch_bounds__(256) void k_head(const float* __restrict__ h1,
                                              const float* __restrict__ w2, const float* __restrict__ b2,
                                              float* __restrict__ out) {
    __shared__ float s_wt[88 * 48];   // [k][d]
    __shared__ float s_b[48];
    int tid = threadIdx.x;
    for (int idx = tid; idx < 48 * 88; idx += 256) {
        int d = idx / 88, k = idx % 88;
        s_wt[k * 48 + d] = w2[idx];
    }
    if (tid < 48) s_b[tid] = b2[tid];
    __syncthreads();
    int px = blockIdx.x * 256 + tid;
    int b = px >> 14, r = px & 16383;
    float acc[48];
#pragma unroll
    for (int d = 0; d < 48; ++d) acc[d] = s_b[d];
    for (int k = 0; k < 88; ++k) {
        float hv = h1[((size_t)(b * 88 + k) << 14) + r];
        const float4* wrow = (const float4*)&s_wt[k * 48];
#pragma unroll
        for (int d4 = 0; d4 < 12; ++d4) {
            float4 wv = wrow[d4];
            acc[d4 * 4 + 0] += hv * wv.x;
            acc[d4 * 4 + 1] += hv * wv.y;
            acc[d4 * 4 + 2] += hv * wv.z;
            acc[d4 * 4 + 3] += hv * wv.w;
        }
    }
    float mx = -1e30f;
#pragma unroll
    for (int d = 0; d < 48; ++d) mx = fmaxf(mx, acc[d]);
    float sum = 0.f, wsum = 0.f;
#pragma unroll
    for (int d = 0; d < 48; ++d) {
        float e = expf(acc[d] - mx);
        sum += e;
        wsum += e * (float)d;
    }
    out[px] = 4.0f * wsum / sum;
}

// ---------------------------------------------------------------------------
extern "C" void kernel_launch(void* const* d_in, const int* in_sizes, int n_in,
                              void* d_out, int out_size, void* d_ws, size_t ws_size,
                              hipStream_t stream) {
    const float* feat_l = (const float*)d_in[0];
    const float* feat_r = (const float*)d_in[1];
    const float* wq = (const float*)d_in[2];
    const float* bq = (const float*)d_in[3];
    const float* wk = (const float*)d_in[4];
    const float* bk = (const float*)d_in[5];
    const float* wv = (const float*)d_in[6];
    const float* bv = (const float*)d_in[7];
    const float* wp = (const float*)d_in[8];
    const float* bp = (const float*)d_in[9];
    const float* rpb = (const float*)d_in[10];
    const float* ln1_g = (const float*)d_in[11];
    const float* ln1_b = (const float*)d_in[12];
    const float* ln2_g = (const float*)d_in[13];
    const float* ln2_b = (const float*)d_in[14];
    const float* mlp_w1 = (const float*)d_in[15];
    const float* mlp_b1 = (const float*)d_in[16];
    const float* mlp_w2 = (const float*)d_in[17];
    // d_in[18] = mlp_b2 is multiplied by 0.0 in the reference -> unused
    const float* un_w1 = (const float*)d_in[19];
    const float* un_b1 = (const float*)d_in[20];
    const float* un_w2 = (const float*)d_in[21];
    const float* un_b2 = (const float*)d_in[22];
    const float* dp_w1 = (const float*)d_in[23];
    const float* dp_b1 = (const float*)d_in[24];
    const float* bn_g = (const float*)d_in[25];
    const float* bn_b = (const float*)d_in[26];
    const float* dp_w2 = (const float*)d_in[27];
    const float* dp_b2 = (const float*)d_in[28];

    float* ws = (float*)d_ws;
    float* cost = ws;                               // 4*48*16384   = 3,145,728 f
    float* x = ws + 3145728;                        // 4*16384*128  = 8,388,608 f
    float* h1 = ws + 3145728 + 8388608;             // 4*88*16384   = 5,767,168 f
    unsigned short* pk = (unsigned short*)(ws + 17301504);  // 165,888 bf16
    float* bias2 = ws + 17301504 + 82944;           // 96 f
    float* out = (float*)d_out;

    k_pack<<<324, 64, 0, stream>>>(dp_w1, dp_b1, bn_g, bn_b, pk, bias2);
    k_cost<<<dim3(64, 4), 256, 0, stream>>>(feat_l, feat_r, cost);
    k_unary<<<1024, 256, 0, stream>>>(feat_l, un_w1, un_b1, un_w2, un_b2, x);
    k_attn<<<1024, 256, 0, stream>>>(feat_l, wq, bq, wk, bk, wv, bv, wp, bp,
                                     rpb, ln1_g, ln1_b, x);
    k_mlp<<<1024, 256, 0, stream>>>(x, ln2_g, ln2_b, mlp_w1, mlp_b1, mlp_w2);
    k_conv_mfma<<<dim3(8, 8, 4), 256, 0, stream>>>(x, cost, pk, bias2, h1);
    k_head<<<256, 256, 0, stream>>>(h1, dp_w2, dp_b2, out);
}

// Round 3
// 935.849 us; speedup vs baseline: 2.5997x; 1.5164x over previous
//
#include <hip/hip_runtime.h>
#include <math.h>

// Dims
constexpr int Bn = 4, Cc = 128, Hh = 128, Wn = 128, Dd = 48;
constexpr float SCALE = 0.25f;       // 16^-0.5

typedef short  bf16x8 __attribute__((ext_vector_type(8)));
typedef float  f32x4  __attribute__((ext_vector_type(4)));
typedef unsigned short u16x8 __attribute__((ext_vector_type(8)));

static __device__ __forceinline__ float gelu_f(float v) {
    return 0.5f * v * (1.0f + erff(v * 0.70710678118654752f));
}

static __device__ __forceinline__ unsigned short f2bf(float f) {
    unsigned int u = __float_as_uint(f);
    u = (u + 0x7fffu + ((u >> 16) & 1u)) >> 16;   // RNE
    return (unsigned short)u;
}

// ---------------------------------------------------------------------------
// K1: cost volume. grid (H/2, B), 256 threads. Each half-block owns one (b,h) row.
__global__ __launch_bounds__(256) void k_cost(const float* __restrict__ fl,
                                              const float* __restrict__ fr,
                                              float* __restrict__ cost) {
    int tid = threadIdx.x;
    int lr = tid >> 7, w = tid & 127;
    int h = blockIdx.x * 2 + lr;
    int b = blockIdx.y;
    __shared__ float s_fr[2][128];
    float acc[48];
#pragma unroll
    for (int d = 0; d < 48; ++d) acc[d] = 0.f;
    const float* flb = fl + ((size_t)b * 128 * 16384) + h * 128;
    const float* frb = fr + ((size_t)b * 128 * 16384) + h * 128;
    for (int c = 0; c < 128; ++c) {
        float flv = flb[(size_t)c * 16384 + w];
        s_fr[lr][w] = frb[(size_t)c * 16384 + w];
        __syncthreads();
#pragma unroll
        for (int d = 0; d < 48; ++d) {
            if (d <= w) acc[d] += flv * s_fr[lr][w - d];
        }
        __syncthreads();
    }
    const float inv = 1.0f / 128.0f;
#pragma unroll
    for (int d = 0; d < 48; ++d) {
        cost[(((size_t)b * 48 + d) << 14) + h * 128 + w] = acc[d] * inv;
    }
}

// ---------------------------------------------------------------------------
// K2: unary = gelu(tok@W1+b1)@W2+b2 -> x.  64 tokens per block, 256 threads.
__global__ __launch_bounds__(256) void k_unary(const float* __restrict__ feat_l,
                                               const float* __restrict__ w1,
                                               const float* __restrict__ b1,
                                               const float* __restrict__ w2,
                                               const float* __restrict__ b2,
                                               float* __restrict__ x) {
    __shared__ float s_a[64 * 129];
    __shared__ float s_h[64 * 129];
    __shared__ float s_w[128 * 128];
    int tid = threadIdx.x;
    int n0g = blockIdx.x * 64;            // global token id
    int b = n0g >> 14;
    int nb = n0g & 16383;
    for (int idx = tid; idx < 64 * 128; idx += 256) {
        int c = idx >> 6, nl = idx & 63;
        s_a[nl * 129 + c] = feat_l[((size_t)(b * 128 + c) << 14) + nb + nl];
    }
    for (int idx = tid; idx < 128 * 128; idx += 256) s_w[idx] = w1[idx];
    __syncthreads();

    int tn = tid >> 4, tj = tid & 15;
    int n0 = tn * 4, j0 = tj * 8;
    float accA[4][8];
#pragma unroll
    for (int i = 0; i < 4; ++i)
#pragma unroll
        for (int u = 0; u < 8; ++u) accA[i][u] = b1[j0 + u];
    for (int c = 0; c < 128; ++c) {
        float a0 = s_a[(n0 + 0) * 129 + c];
        float a1 = s_a[(n0 + 1) * 129 + c];
        float a2 = s_a[(n0 + 2) * 129 + c];
        float a3 = s_a[(n0 + 3) * 129 + c];
        float4 bv0 = *(const float4*)&s_w[c * 128 + j0];
        float4 bv1 = *(const float4*)&s_w[c * 128 + j0 + 4];
        float bb[8] = {bv0.x, bv0.y, bv0.z, bv0.w, bv1.x, bv1.y, bv1.z, bv1.w};
#pragma unroll
        for (int u = 0; u < 8; ++u) {
            accA[0][u] += a0 * bb[u];
            accA[1][u] += a1 * bb[u];
            accA[2][u] += a2 * bb[u];
            accA[3][u] += a3 * bb[u];
        }
    }
#pragma unroll
    for (int i = 0; i < 4; ++i)
#pragma unroll
        for (int u = 0; u < 8; ++u)
            s_h[(n0 + i) * 129 + j0 + u] = gelu_f(accA[i][u]);
    __syncthreads();
    for (int idx = tid; idx < 128 * 128; idx += 256) s_w[idx] = w2[idx];
    __syncthreads();
    float accB[4][8];
#pragma unroll
    for (int i = 0; i < 4; ++i)
#pragma unroll
        for (int u = 0; u < 8; ++u) accB[i][u] = b2[j0 + u];
    for (int c = 0; c < 128; ++c) {
        float a0 = s_h[(n0 + 0) * 129 + c];
        float a1 = s_h[(n0 + 1) * 129 + c];
        float a2 = s_h[(n0 + 2) * 129 + c];
        float a3 = s_h[(n0 + 3) * 129 + c];
        float4 bv0 = *(const float4*)&s_w[c * 128 + j0];
        float4 bv1 = *(const float4*)&s_w[c * 128 + j0 + 4];
        float bb[8] = {bv0.x, bv0.y, bv0.z, bv0.w, bv1.x, bv1.y, bv1.z, bv1.w};
#pragma unroll
        for (int u = 0; u < 8; ++u) {
            accB[0][u] += a0 * bb[u];
            accB[1][u] += a1 * bb[u];
            accB[2][u] += a2 * bb[u];
            accB[3][u] += a3 * bb[u];
        }
    }
#pragma unroll
    for (int i = 0; i < 4; ++i) {
        size_t base = ((size_t)(n0g + n0 + i)) * 128 + j0;
        float4 o0 = {accB[i][0], accB[i][1], accB[i][2], accB[i][3]};
        float4 o1 = {accB[i][4], accB[i][5], accB[i][6], accB[i][7]};
        *(float4*)&x[base] = o0;
        *(float4*)&x[base + 4] = o1;
    }
}

// ---------------------------------------------------------------------------
// K3a: pack wq/wk/wv/wp into bf16 B-fragments.
// pkw[mat(4)][nt(8)][ks(4)][lane(64)][8]: elem j = W[ks*32+(lane>>4)*8+j][nt*16+(lane&15)]
__global__ __launch_bounds__(64) void k_packw(const float* __restrict__ wq,
                                              const float* __restrict__ wk,
                                              const float* __restrict__ wv,
                                              const float* __restrict__ wp,
                                              unsigned short* __restrict__ pkw) {
    int blk = blockIdx.x;                 // mat*32 + nt*4 + ks
    int lane = threadIdx.x;
    int ks = blk & 3, nt = (blk >> 2) & 7, mat = blk >> 5;
    const float* W = (mat == 0) ? wq : (mat == 1) ? wk : (mat == 2) ? wv : wp;
    int col = nt * 16 + (lane & 15);
    int k0 = ks * 32 + (lane >> 4) * 8;
    u16x8 o;
#pragma unroll
    for (int j = 0; j < 8; ++j) o[j] = f2bf(W[(size_t)(k0 + j) * 128 + col]);
    *(u16x8*)(pkw + ((size_t)blk * 64 + lane) * 8) = o;
}

// K3b: pack rpb into per-(head,tile) f32x4 C-init fragments.
// pb[h(8)][mt(4)][nt(4)][lane(64)][4]: r -> bias at row mt*16+(lane>>4)*4+r, col nt*16+(lane&15)
__global__ __launch_bounds__(64) void k_packb(const float* __restrict__ rpb,
                                              float* __restrict__ pb) {
    int blk = blockIdx.x;                 // h*16 + mt*4 + nt
    int lane = threadIdx.x;
    int nt = blk & 3, mt = (blk >> 2) & 3, h = blk >> 4;
    int m = nt * 16 + (lane & 15);
    int g = lane >> 4;
    float o[4];
#pragma unroll
    for (int r = 0; r < 4; ++r) {
        int n = mt * 16 + g * 4 + r;
        int relidx = (((n >> 3) - (m >> 3)) + 7) * 15 + ((n & 7) - (m & 7)) + 7;
        o[r] = rpb[relidx * 8 + h];
    }
    float4 v = {o[0], o[1], o[2], o[3]};
    *(float4*)(pb + ((size_t)blk * 64 + lane) * 4) = v;
}

// ---------------------------------------------------------------------------
// K3c: window attention, MFMA. 1024 blocks (one window), 256 threads (4 waves).
// Wave w handles heads {w, w+4} fully independently, then block-wide proj GEMM.
__global__ __launch_bounds__(256) void k_attn_mfma(const float* __restrict__ feat_l,
                                                   const unsigned short* __restrict__ pkw,
                                                   const float* __restrict__ pb,
                                                   const float* __restrict__ bq,
                                                   const float* __restrict__ bk,
                                                   const float* __restrict__ bv,
                                                   const float* __restrict__ bp,
                                                   const float* __restrict__ g1,
                                                   const float* __restrict__ bt1,
                                                   float* __restrict__ x) {
    // per-wave scratch: sQ[64][40] (hd 0..15 data, 16..31 zero) | sK[64][40] | sV[16][72]
    // sP[64][72] overlays sQ+sK.  s_nf[64][136] bf16 overlays s_u (freed after frag hoist).
    __shared__ __align__(16) unsigned short s_u[4][6272];
    __shared__ __align__(16) unsigned short s_o[64 * 136];   // also f32 staging [64][68]
    int tid = threadIdx.x;
    int wid = tid >> 6, lane = tid & 63;
    int g = lane >> 4, t = lane & 15;
    int bw = blockIdx.x;
    int b = bw >> 8, wh = (bw >> 4) & 15, ww = bw & 15;

    unsigned short* s_nf = &s_u[0][0];        // [64][136]
    float* sf = (float*)s_o;                  // [64][68] f32 staging

    // ---- load window tokens (f32) into staging ----
    for (int idx = tid; idx < 8192; idx += 256) {
        int c = idx >> 6, n = idx & 63;
        int hy = wh * 8 + (n >> 3), wx = ww * 8 + (n & 7);
        sf[n * 68 + c] = feat_l[((size_t)(b * 128 + c) << 14) + hy * 128 + wx];
    }
    __syncthreads();
    // ---- LayerNorm -> bf16 s_nf[tok][136] ----
    {
        int tok = tid >> 2, q = tid & 3;
        float s = 0.f, s2 = 0.f;
        for (int c = q * 32; c < q * 32 + 32; ++c) {
            float v = sf[tok * 68 + c];
            s += v; s2 += v * v;
        }
        s += __shfl_xor(s, 1); s += __shfl_xor(s, 2);
        s2 += __shfl_xor(s2, 1); s2 += __shfl_xor(s2, 2);
        float mean = s * (1.f / 128.f);
        float var = s2 * (1.f / 128.f) - mean * mean;
        float rstd = rsqrtf(var + 1e-5f);
        for (int c = q * 32; c < q * 32 + 32; c += 2) {
            float v0 = (sf[tok * 68 + c] - mean) * rstd * g1[c] + bt1[c];
            float v1 = (sf[tok * 68 + c + 1] - mean) * rstd * g1[c + 1] + bt1[c + 1];
            unsigned int pk2 = (unsigned int)f2bf(v0) | ((unsigned int)f2bf(v1) << 16);
            *(unsigned int*)&s_nf[tok * 136 + c] = pk2;
        }
    }
    __syncthreads();
    // ---- hoist X A-fragments to registers (reused for both heads x 3 matrices) ----
    bf16x8 af[4][4];   // [Mt][ks]
#pragma unroll
    for (int Mt = 0; Mt < 4; ++Mt)
#pragma unroll
        for (int ks = 0; ks < 4; ++ks)
            af[Mt][ks] = *(const bf16x8*)&s_nf[(Mt * 16 + t) * 136 + ks * 32 + g * 8];
    __syncthreads();   // all waves hoisted; s_u now free for per-wave scratch

    unsigned short* sQ = &s_u[wid][0];
    unsigned short* sK = sQ + 2560;
    unsigned short* sV = sQ + 5120;
    unsigned short* sP = sQ;

#pragma unroll 1
    for (int hi = 0; hi < 2; ++hi) {
        int h = wid + hi * 4;
        // zero the K-padding region (hd 16..31) of this lane's row in sQ/sK
        u16x8 z8 = {0, 0, 0, 0, 0, 0, 0, 0};
        *(u16x8*)&sQ[lane * 40 + 16] = z8;
        *(u16x8*)&sQ[lane * 40 + 24] = z8;
        *(u16x8*)&sK[lane * 40 + 16] = z8;
        *(u16x8*)&sK[lane * 40 + 24] = z8;

        // ---- QKV projection for head h ----
        float bqv = bq[h * 16 + t], bkv = bk[h * 16 + t], bvv = bv[h * 16 + t];
        f32x4 qa[4], ka[4], va[4];
#pragma unroll
        for (int Mt = 0; Mt < 4; ++Mt) {
            qa[Mt] = (f32x4){bqv, bqv, bqv, bqv};
            ka[Mt] = (f32x4){bkv, bkv, bkv, bkv};
            va[Mt] = (f32x4){bvv, bvv, bvv, bvv};
        }
#pragma unroll
        for (int ks = 0; ks < 4; ++ks) {
            const unsigned short* wbase = pkw + ((size_t)((h * 4 + ks) * 64 + lane) * 8);
            bf16x8 bfq = *(const bf16x8*)(wbase);
            bf16x8 bfk = *(const bf16x8*)(wbase + 16384);
            bf16x8 bfv = *(const bf16x8*)(wbase + 32768);
#pragma unroll
            for (int Mt = 0; Mt < 4; ++Mt) {
                qa[Mt] = __builtin_amdgcn_mfma_f32_16x16x32_bf16(af[Mt][ks], bfq, qa[Mt], 0, 0, 0);
                ka[Mt] = __builtin_amdgcn_mfma_f32_16x16x32_bf16(af[Mt][ks], bfk, ka[Mt], 0, 0, 0);
                va[Mt] = __builtin_amdgcn_mfma_f32_16x16x32_bf16(af[Mt][ks], bfv, va[Mt], 0, 0, 0);
            }
        }
        // write Q (scale folded), K, V^T to wave LDS
#pragma unroll
        for (int Mt = 0; Mt < 4; ++Mt)
#pragma unroll
            for (int r = 0; r < 4; ++r) {
                int tok = Mt * 16 + g * 4 + r;
                sQ[tok * 40 + t] = f2bf(qa[Mt][r] * SCALE);
                sK[tok * 40 + t] = f2bf(ka[Mt][r]);
                sV[t * 72 + tok] = f2bf(va[Mt][r]);
            }

        // ---- S = Q K^T (K padded 16->32) + bias(C-init) ----
        f32x4 s[4][4];
#pragma unroll
        for (int Mt = 0; Mt < 4; ++Mt)
#pragma unroll
            for (int Nt = 0; Nt < 4; ++Nt)
                s[Mt][Nt] = *(const f32x4*)(pb + ((size_t)((h * 16 + Mt * 4 + Nt) * 64 + lane) * 4));
        bf16x8 aq[4], bk2[4];
#pragma unroll
        for (int Mt = 0; Mt < 4; ++Mt) aq[Mt] = *(const bf16x8*)&sQ[(Mt * 16 + t) * 40 + g * 8];
#pragma unroll
        for (int Nt = 0; Nt < 4; ++Nt) bk2[Nt] = *(const bf16x8*)&sK[(Nt * 16 + t) * 40 + g * 8];
#pragma unroll
        for (int Mt = 0; Mt < 4; ++Mt)
#pragma unroll
            for (int Nt = 0; Nt < 4; ++Nt)
                s[Mt][Nt] = __builtin_amdgcn_mfma_f32_16x16x32_bf16(aq[Mt], bk2[Nt], s[Mt][Nt], 0, 0, 0);

        // ---- softmax (unnormalized; divide after PV) ----
        f32x4 rsm[4];
#pragma unroll
        for (int Mt = 0; Mt < 4; ++Mt) {
            f32x4 m = s[Mt][0];
#pragma unroll
            for (int Nt = 1; Nt < 4; ++Nt)
#pragma unroll
                for (int r = 0; r < 4; ++r) m[r] = fmaxf(m[r], s[Mt][Nt][r]);
#pragma unroll
            for (int sh = 1; sh <= 8; sh <<= 1)
#pragma unroll
                for (int r = 0; r < 4; ++r) m[r] = fmaxf(m[r], __shfl_xor(m[r], sh));
            f32x4 sum = (f32x4){0.f, 0.f, 0.f, 0.f};
#pragma unroll
            for (int Nt = 0; Nt < 4; ++Nt)
#pragma unroll
                for (int r = 0; r < 4; ++r) {
                    float e = __expf(s[Mt][Nt][r] - m[r]);
                    s[Mt][Nt][r] = e;
                    sum[r] += e;
                }
#pragma unroll
            for (int sh = 1; sh <= 8; sh <<= 1)
#pragma unroll
                for (int r = 0; r < 4; ++r) sum[r] += __shfl_xor(sum[r], sh);
            rsm[Mt] = sum;
        }
        // write P (bf16) -- overlays Q,K
#pragma unroll
        for (int Mt = 0; Mt < 4; ++Mt)
#pragma unroll
            for (int Nt = 0; Nt < 4; ++Nt)
#pragma unroll
                for (int r = 0; r < 4; ++r)
                    sP[(Mt * 16 + g * 4 + r) * 72 + Nt * 16 + t] = f2bf(s[Mt][Nt][r]);

        // ---- O = P @ V ----
        f32x4 oa[4];
#pragma unroll
        for (int Mt = 0; Mt < 4; ++Mt) oa[Mt] = (f32x4){0.f, 0.f, 0.f, 0.f};
#pragma unroll
        for (int ksv = 0; ksv < 2; ++ksv) {
            bf16x8 bv2 = *(const bf16x8*)&sV[t * 72 + ksv * 32 + g * 8];
#pragma unroll
            for (int Mt = 0; Mt < 4; ++Mt) {
                bf16x8 ap = *(const bf16x8*)&sP[(Mt * 16 + t) * 72 + ksv * 32 + g * 8];
                oa[Mt] = __builtin_amdgcn_mfma_f32_16x16x32_bf16(ap, bv2, oa[Mt], 0, 0, 0);
            }
        }
        // normalize + write o columns for this head
#pragma unroll
        for (int Mt = 0; Mt < 4; ++Mt)
#pragma unroll
            for (int r = 0; r < 4; ++r)
                s_o[(Mt * 16 + g * 4 + r) * 136 + h * 16 + t] = f2bf(oa[Mt][r] / rsm[Mt][r]);
    }
    __syncthreads();

    // ---- proj: x += o @ wp + bp. wave handles col-tiles {2w, 2w+1} ----
    float bp0 = bp[wid * 32 + t], bp1 = bp[wid * 32 + 16 + t];
    f32x4 pa[4][2];
#pragma unroll
    for (int Mt = 0; Mt < 4; ++Mt) {
        pa[Mt][0] = (f32x4){bp0, bp0, bp0, bp0};
        pa[Mt][1] = (f32x4){bp1, bp1, bp1, bp1};
    }
#pragma unroll
    for (int ks = 0; ks < 4; ++ks) {
        bf16x8 b0 = *(const bf16x8*)(pkw + 49152 + (size_t)(((wid * 2 + 0) * 4 + ks) * 64 + lane) * 8);
        bf16x8 b1 = *(const bf16x8*)(pkw + 49152 + (size_t)(((wid * 2 + 1) * 4 + ks) * 64 + lane) * 8);
#pragma unroll
        for (int Mt = 0; Mt < 4; ++Mt) {
            bf16x8 a = *(const bf16x8*)&s_o[(Mt * 16 + t) * 136 + ks * 32 + g * 8];
            pa[Mt][0] = __builtin_amdgcn_mfma_f32_16x16x32_bf16(a, b0, pa[Mt][0], 0, 0, 0);
            pa[Mt][1] = __builtin_amdgcn_mfma_f32_16x16x32_bf16(a, b1, pa[Mt][1], 0, 0, 0);
        }
    }
#pragma unroll
    for (int Mt = 0; Mt < 4; ++Mt)
#pragma unroll
        for (int i = 0; i < 2; ++i)
#pragma unroll
            for (int r = 0; r < 4; ++r) {
                int tok = Mt * 16 + g * 4 + r;
                int hy = wh * 8 + (tok >> 3), wx = ww * 8 + (tok & 7);
                size_t addr = ((size_t)(b * 16384) + hy * 128 + wx) * 128 + (wid * 2 + i) * 16 + t;
                x[addr] += pa[Mt][i][r];
            }
}

// ---------------------------------------------------------------------------
// K4: x = x + gelu(LN2(x)@W1+b1)@W2   (NOTE: mlp_b2 is multiplied by 0 in ref)
__global__ __launch_bounds__(256) void k_mlp(float* __restrict__ x,
                                             const float* __restrict__ g2, const float* __restrict__ bt2,
                                             const float* __restrict__ w1, const float* __restrict__ b1,
                                             const float* __restrict__ w2) {
    __shared__ float s_a[64 * 129];
    __shared__ float s_h[64 * 129];
    __shared__ float s_w[128 * 128];
    int tid = threadIdx.x;
    int n0g = blockIdx.x * 64;
    for (int idx = tid; idx < 8192; idx += 256) {
        int n = idx >> 7, c = idx & 127;
        s_a[n * 129 + c] = x[(size_t)(n0g + n) * 128 + c];
    }
    __syncthreads();
    {
        int n = tid >> 2, q = tid & 3;
        float s = 0.f, s2 = 0.f;
        for (int c = q * 32; c < q * 32 + 32; ++c) {
            float v = s_a[n * 129 + c];
            s += v; s2 += v * v;
        }
        s += __shfl_xor(s, 1); s += __shfl_xor(s, 2);
        s2 += __shfl_xor(s2, 1); s2 += __shfl_xor(s2, 2);
        float mean = s * (1.f / 128.f);
        float var = s2 * (1.f / 128.f) - mean * mean;
        float rstd = rsqrtf(var + 1e-5f);
        for (int c = q * 32; c < q * 32 + 32; ++c) {
            float v = s_a[n * 129 + c];
            s_a[n * 129 + c] = (v - mean) * rstd * g2[c] + bt2[c];
        }
    }
    __syncthreads();
    int tn = tid >> 4, tj = tid & 15;
    int n0 = tn * 4, j0 = tj * 8;
    float out[4][8];
#pragma unroll
    for (int i = 0; i < 4; ++i)
#pragma unroll
        for (int u = 0; u < 8; ++u) out[i][u] = 0.f;
#pragma unroll 1
    for (int hc = 0; hc < 4; ++hc) {
        for (int idx = tid; idx < 16384; idx += 256) {
            int c = idx >> 7, j = idx & 127;
            s_w[idx] = w1[(size_t)c * 512 + hc * 128 + j];
        }
        __syncthreads();
        float acc[4][8];
#pragma unroll
        for (int i = 0; i < 4; ++i)
#pragma unroll
            for (int u = 0; u < 8; ++u) acc[i][u] = b1[hc * 128 + j0 + u];
        for (int c = 0; c < 128; ++c) {
            float a0 = s_a[(n0 + 0) * 129 + c];
            float a1 = s_a[(n0 + 1) * 129 + c];
            float a2 = s_a[(n0 + 2) * 129 + c];
            float a3 = s_a[(n0 + 3) * 129 + c];
            float4 bv0 = *(const float4*)&s_w[c * 128 + j0];
            float4 bv1 = *(const float4*)&s_w[c * 128 + j0 + 4];
            float bb[8] = {bv0.x, bv0.y, bv0.z, bv0.w, bv1.x, bv1.y, bv1.z, bv1.w};
#pragma unroll
            for (int u = 0; u < 8; ++u) {
                acc[0][u] += a0 * bb[u];
                acc[1][u] += a1 * bb[u];
                acc[2][u] += a2 * bb[u];
                acc[3][u] += a3 * bb[u];
            }
        }
#pragma unroll
        for (int i = 0; i < 4; ++i)
#pragma unroll
            for (int u = 0; u < 8; ++u)
                s_h[(n0 + i) * 129 + j0 + u] = gelu_f(acc[i][u]);
        __syncthreads();
        for (int idx = tid; idx < 16384; idx += 256) {
            s_w[idx] = w2[(size_t)hc * 128 * 128 + idx];
        }
        __syncthreads();
        for (int k = 0; k < 128; ++k) {
            float a0 = s_h[(n0 + 0) * 129 + k];
            float a1 = s_h[(n0 + 1) * 129 + k];
            float a2 = s_h[(n0 + 2) * 129 + k];
            float a3 = s_h[(n0 + 3) * 129 + k];
            float4 bv0 = *(const float4*)&s_w[k * 128 + j0];
            float4 bv1 = *(const float4*)&s_w[k * 128 + j0 + 4];
            float bb[8] = {bv0.x, bv0.y, bv0.z, bv0.w, bv1.x, bv1.y, bv1.z, bv1.w};
#pragma unroll
            for (int u = 0; u < 8; ++u) {
                out[0][u] += a0 * bb[u];
                out[1][u] += a1 * bb[u];
                out[2][u] += a2 * bb[u];
                out[3][u] += a3 * bb[u];
            }
        }
        __syncthreads();
    }
#pragma unroll
    for (int i = 0; i < 4; ++i) {
        size_t base = (size_t)(n0g + n0 + i) * 128 + j0;
        float4 x0 = *(const float4*)&x[base];
        float4 x1 = *(const float4*)&x[base + 4];
        x0.x += out[i][0]; x0.y += out[i][1]; x0.z += out[i][2]; x0.w += out[i][3];
        x1.x += out[i][4]; x1.y += out[i][5]; x1.z += out[i][6]; x1.w += out[i][7];
        *(float4*)&x[base] = x0;
        *(float4*)&x[base + 4] = x1;
    }
}

// ---------------------------------------------------------------------------
// K5a: pack conv weights for MFMA A-fragments, folding BN scale.
__global__ __launch_bounds__(64) void k_pack(const float* __restrict__ w1,
                                             const float* __restrict__ b1,
                                             const float* __restrict__ bng,
                                             const float* __restrict__ bnb,
                                             unsigned short* __restrict__ pk,
                                             float* __restrict__ bias2) {
    const float rs = 0.9999950000374997f;   // rsqrt(1 + 1e-5)
    int blk = blockIdx.x;                   // (chunk*9+tap)*6 + cotile, 0..323
    int lane = threadIdx.x;
    int ct = blk % 6;
    int taplin = blk / 6;
    int tap = taplin % 9, chunk = taplin / 9;
    int co = ct * 16 + (lane & 15);
    int cibase = chunk * 32 + (lane >> 4) * 8;
    u16x8 out;
#pragma unroll
    for (int j = 0; j < 8; ++j) {
        int ci = cibase + j;
        float v = 0.f;
        if (co < 88 && ci < 176) v = w1[(size_t)co * 1584 + ci * 9 + tap] * rs * bng[co];
        out[j] = f2bf(v);
    }
    *(u16x8*)(pk + ((size_t)blk * 64 + lane) * 8) = out;
    if (blk == 0) {
        for (int i = lane; i < 96; i += 64)
            bias2[i] = (i < 88) ? (b1[i] * rs * bng[i] + bnb[i]) : 0.f;
    }
}

// ---------------------------------------------------------------------------
// K5b: conv3x3 as bf16 implicit-GEMM MFMA. grid (8,8,4), 256 threads.
__global__ __launch_bounds__(256) void k_conv_mfma(const float* __restrict__ x,
                                                   const float* __restrict__ cost,
                                                   const unsigned short* __restrict__ pk,
                                                   const float* __restrict__ bias2,
                                                   float* __restrict__ h1) {
    __shared__ __align__(16) unsigned short s_p[324 * 40];   // [pos 18x18][ci 32 pad40]
    int tid = threadIdx.x;
    int wid = tid >> 6, lane = tid & 63;
    int g = lane >> 4, t = lane & 15;
    int tx0 = blockIdx.x * 16, ty0 = blockIdx.y * 16, b = blockIdx.z;

    f32x4 acc[4][6];
#pragma unroll
    for (int p = 0; p < 4; ++p)
#pragma unroll
        for (int ct = 0; ct < 6; ++ct) acc[p][ct] = (f32x4){0.f, 0.f, 0.f, 0.f};

#pragma unroll 1
    for (int chunk = 0; chunk < 6; ++chunk) {
        if (chunk < 4) {
            int ci0 = chunk * 32;
            for (int u = tid; u < 648; u += 256) {
                int pos = u >> 1, half = u & 1;
                int yy = pos / 18, xx = pos - yy * 18;
                int gy = ty0 + yy - 1, gx = tx0 + xx - 1;
                u16x8 lo, hi;
                if (gy >= 0 && gy < 128 && gx >= 0 && gx < 128) {
                    const float4* src = (const float4*)&x[((size_t)(b << 14) + gy * 128 + gx) * 128 + ci0 + half * 16];
                    float4 v0 = src[0], v1 = src[1], v2 = src[2], v3 = src[3];
                    lo[0] = f2bf(v0.x); lo[1] = f2bf(v0.y); lo[2] = f2bf(v0.z); lo[3] = f2bf(v0.w);
                    lo[4] = f2bf(v1.x); lo[5] = f2bf(v1.y); lo[6] = f2bf(v1.z); lo[7] = f2bf(v1.w);
                    hi[0] = f2bf(v2.x); hi[1] = f2bf(v2.y); hi[2] = f2bf(v2.z); hi[3] = f2bf(v2.w);
                    hi[4] = f2bf(v3.x); hi[5] = f2bf(v3.y); hi[6] = f2bf(v3.z); hi[7] = f2bf(v3.w);
                } else {
                    lo = (u16x8)(unsigned short)0; hi = (u16x8)(unsigned short)0;
                }
                unsigned short* dst = &s_p[pos * 40 + half * 16];
                *(u16x8*)dst = lo;
                *(u16x8*)(dst + 8) = hi;
            }
        } else {
            int d0 = (chunk - 4) * 32;
            for (int u = tid; u < 576; u += 256) {
                int cl = u / 18, yy = u - cl * 18;
                int d = d0 + cl;
                int gy = ty0 + yy - 1;
                bool rowok = (d < 48) && (gy >= 0) && (gy < 128);
                const float* srow = cost + ((size_t)(b * 48 + (rowok ? d : 0)) << 14) + (rowok ? gy : 0) * 128;
                for (int xx = 0; xx < 18; ++xx) {
                    int gx = tx0 + xx - 1;
                    float v = (rowok && gx >= 0 && gx < 128) ? srow[gx] : 0.f;
                    s_p[(yy * 18 + xx) * 40 + cl] = f2bf(v);
                }
            }
        }
        __syncthreads();

#pragma unroll 1
        for (int tap = 0; tap < 9; ++tap) {
            int dy = tap / 3, dx = tap - dy * 3;
            const unsigned short* pkt = pk + ((size_t)(chunk * 9 + tap)) * 6 * 512;
            bf16x8 afr[6];
#pragma unroll
            for (int ct = 0; ct < 6; ++ct)
                afr[ct] = *(const bf16x8*)(pkt + ct * 512 + lane * 8);
            bf16x8 bfr[4];
#pragma unroll
            for (int p = 0; p < 4; ++p) {
                int pos = (wid * 4 + p + dy) * 18 + t + dx;
                bfr[p] = *(const bf16x8*)&s_p[pos * 40 + g * 8];
            }
#pragma unroll
            for (int p = 0; p < 4; ++p)
#pragma unroll
                for (int ct = 0; ct < 6; ++ct)
                    acc[p][ct] = __builtin_amdgcn_mfma_f32_16x16x32_bf16(afr[ct], bfr[p], acc[p][ct], 0, 0, 0);
        }
        __syncthreads();
    }

#pragma unroll
    for (int p = 0; p < 4; ++p) {
        int y = ty0 + wid * 4 + p;
#pragma unroll
        for (int ct = 0; ct < 6; ++ct) {
#pragma unroll
            for (int r = 0; r < 4; ++r) {
                int co = ct * 16 + g * 4 + r;
                if (co < 88) {
                    float v = acc[p][ct][r] + bias2[co];
                    h1[((size_t)(b * 88 + co) << 14) + y * 128 + tx0 + t] = fmaxf(v, 0.f);
                }
            }
        }
    }
}

// ---------------------------------------------------------------------------
// K6: pv = conv1x1(h1) + b2; softmax over D; pred = 4*sum(d*p). 256 blocks.
__global__ __launch_bounds__(256) void k_head(const float* __restrict__ h1,
                                              const float* __restrict__ w2, const float* __restrict__ b2,
                                              float* __restrict__ out) {
    __shared__ float s_wt[88 * 48];   // [k][d]
    __shared__ float s_b[48];
    int tid = threadIdx.x;
    for (int idx = tid; idx < 48 * 88; idx += 256) {
        int d = idx / 88, k = idx % 88;
        s_wt[k * 48 + d] = w2[idx];
    }
    if (tid < 48) s_b[tid] = b2[tid];
    __syncthreads();
    int px = blockIdx.x * 256 + tid;
    int b = px >> 14, r = px & 16383;
    float acc[48];
#pragma unroll
    for (int d = 0; d < 48; ++d) acc[d] = s_b[d];
    for (int k = 0; k < 88; ++k) {
        float hv = h1[((size_t)(b * 88 + k) << 14) + r];
        const float4* wrow = (const float4*)&s_wt[k * 48];
#pragma unroll
        for (int d4 = 0; d4 < 12; ++d4) {
            float4 wv = wrow[d4];
            acc[d4 * 4 + 0] += hv * wv.x;
            acc[d4 * 4 + 1] += hv * wv.y;
            acc[d4 * 4 + 2] += hv * wv.z;
            acc[d4 * 4 + 3] += hv * wv.w;
        }
    }
    float mx = -1e30f;
#pragma unroll
    for (int d = 0; d < 48; ++d) mx = fmaxf(mx, acc[d]);
    float sum = 0.f, wsum = 0.f;
#pragma unroll
    for (int d = 0; d < 48; ++d) {
        float e = expf(acc[d] - mx);
        sum += e;
        wsum += e * (float)d;
    }
    out[px] = 4.0f * wsum / sum;
}

// ---------------------------------------------------------------------------
extern "C" void kernel_launch(void* const* d_in, const int* in_sizes, int n_in,
                              void* d_out, int out_size, void* d_ws, size_t ws_size,
                              hipStream_t stream) {
    const float* feat_l = (const float*)d_in[0];
    const float* feat_r = (const float*)d_in[1];
    const float* wq = (const float*)d_in[2];
    const float* bq = (const float*)d_in[3];
    const float* wk = (const float*)d_in[4];
    const float* bk = (const float*)d_in[5];
    const float* wv = (const float*)d_in[6];
    const float* bv = (const float*)d_in[7];
    const float* wp = (const float*)d_in[8];
    const float* bp = (const float*)d_in[9];
    const float* rpb = (const float*)d_in[10];
    const float* ln1_g = (const float*)d_in[11];
    const float* ln1_b = (const float*)d_in[12];
    const float* ln2_g = (const float*)d_in[13];
    const float* ln2_b = (const float*)d_in[14];
    const float* mlp_w1 = (const float*)d_in[15];
    const float* mlp_b1 = (const float*)d_in[16];
    const float* mlp_w2 = (const float*)d_in[17];
    // d_in[18] = mlp_b2 is multiplied by 0.0 in the reference -> unused
    const float* un_w1 = (const float*)d_in[19];
    const float* un_b1 = (const float*)d_in[20];
    const float* un_w2 = (const float*)d_in[21];
    const float* un_b2 = (const float*)d_in[22];
    const float* dp_w1 = (const float*)d_in[23];
    const float* dp_b1 = (const float*)d_in[24];
    const float* bn_g = (const float*)d_in[25];
    const float* bn_b = (const float*)d_in[26];
    const float* dp_w2 = (const float*)d_in[27];
    const float* dp_b2 = (const float*)d_in[28];

    float* ws = (float*)d_ws;
    float* cost = ws;                               // 3,145,728 f
    float* x = ws + 3145728;                        // 8,388,608 f
    float* h1 = ws + 11534336;                      // 5,767,168 f
    unsigned short* pk = (unsigned short*)(ws + 17301504);   // 82,944 u16 region
    float* bias2 = ws + 17301504 + 82944;           // 96 f (legacy offset, safe)
    unsigned short* pkw = (unsigned short*)(ws + 17301504 + 82944 + 96);  // 65,536 u16
    float* pb = ws + 17301504 + 82944 + 96 + 32768; // 32,768 f
    float* out = (float*)d_out;

    k_pack<<<324, 64, 0, stream>>>(dp_w1, dp_b1, bn_g, bn_b, pk, bias2);
    k_packw<<<128, 64, 0, stream>>>(wq, wk, wv, wp, pkw);
    k_packb<<<128, 64, 0, stream>>>(rpb, pb);
    k_cost<<<dim3(64, 4), 256, 0, stream>>>(feat_l, feat_r, cost);
    k_unary<<<1024, 256, 0, stream>>>(feat_l, un_w1, un_b1, un_w2, un_b2, x);
    k_attn_mfma<<<1024, 256, 0, stream>>>(feat_l, pkw, pb, bq, bk, bv, bp,
                                          ln1_g, ln1_b, x);
    k_mlp<<<1024, 256, 0, stream>>>(x, ln2_g, ln2_b, mlp_w1, mlp_b1, mlp_w2);
    k_conv_mfma<<<dim3(8, 8, 4), 256, 0, stream>>>(x, cost, pk, bias2, h1);
    k_head<<<256, 256, 0, stream>>>(h1, dp_w2, dp_b2, out);
}

// Round 4
// 569.962 us; speedup vs baseline: 4.2686x; 1.6420x over previous
//
#include <hip/hip_runtime.h>
#include <math.h>

// Dims
constexpr int Bn = 4, Cc = 128, Hh = 128, Wn = 128, Dd = 48;
constexpr float SCALE = 0.25f;       // 16^-0.5

typedef short  bf16x8 __attribute__((ext_vector_type(8)));
typedef float  f32x4  __attribute__((ext_vector_type(4)));
typedef unsigned short u16x8 __attribute__((ext_vector_type(8)));

static __device__ __forceinline__ float gelu_f(float v) {
    return 0.5f * v * (1.0f + erff(v * 0.70710678118654752f));
}

static __device__ __forceinline__ unsigned short f2bf(float f) {
    unsigned int u = __float_as_uint(f);
    u = (u + 0x7fffu + ((u >> 16) & 1u)) >> 16;   // RNE
    return (unsigned short)u;
}

static __device__ __forceinline__ unsigned int pack2bf(float a, float b) {
    return (unsigned int)f2bf(a) | ((unsigned int)f2bf(b) << 16);
}

// ---------------------------------------------------------------------------
// K1: cost volume. grid (H/2, B), 256 threads.
__global__ __launch_bounds__(256) void k_cost(const float* __restrict__ fl,
                                              const float* __restrict__ fr,
                                              float* __restrict__ cost) {
    int tid = threadIdx.x;
    int lr = tid >> 7, w = tid & 127;
    int h = blockIdx.x * 2 + lr;
    int b = blockIdx.y;
    __shared__ float s_fr[2][128];
    float acc[48];
#pragma unroll
    for (int d = 0; d < 48; ++d) acc[d] = 0.f;
    const float* flb = fl + ((size_t)b * 128 * 16384) + h * 128;
    const float* frb = fr + ((size_t)b * 128 * 16384) + h * 128;
    for (int c = 0; c < 128; ++c) {
        float flv = flb[(size_t)c * 16384 + w];
        s_fr[lr][w] = frb[(size_t)c * 16384 + w];
        __syncthreads();
#pragma unroll
        for (int d = 0; d < 48; ++d) {
            if (d <= w) acc[d] += flv * s_fr[lr][w - d];
        }
        __syncthreads();
    }
    const float inv = 1.0f / 128.0f;
#pragma unroll
    for (int d = 0; d < 48; ++d) {
        cost[(((size_t)b * 48 + d) << 14) + h * 128 + w] = acc[d] * inv;
    }
}

// ---------------------------------------------------------------------------
// Generic B-fragment packer for [nrows x ncols] f32 matrix -> bf16 fragments.
// blk = kc*(ntiles*4) + nt*4 + ks ; frag elem j = W[kc*128+ks*32+(lane>>4)*8+j][nt*16+(lane&15)]
__global__ __launch_bounds__(64) void k_packg(const float* __restrict__ W,
                                              unsigned short* __restrict__ out,
                                              int ncols) {
    int blk = blockIdx.x;
    int lane = threadIdx.x;
    int ntiles = ncols >> 4;
    int ks = blk & 3;
    int nt = (blk >> 2) % ntiles;
    int kc = blk / (4 * ntiles);
    int col = nt * 16 + (lane & 15);
    int k0 = kc * 128 + ks * 32 + (lane >> 4) * 8;
    u16x8 o;
#pragma unroll
    for (int j = 0; j < 8; ++j) o[j] = f2bf(W[(size_t)(k0 + j) * ncols + col]);
    *(u16x8*)(out + ((size_t)blk * 64 + lane) * 8) = o;
}

// ---------------------------------------------------------------------------
// K3a: pack wq/wk/wv/wp into bf16 B-fragments.
__global__ __launch_bounds__(64) void k_packw(const float* __restrict__ wq,
                                              const float* __restrict__ wk,
                                              const float* __restrict__ wv,
                                              const float* __restrict__ wp,
                                              unsigned short* __restrict__ pkw) {
    int blk = blockIdx.x;                 // mat*32 + nt*4 + ks
    int lane = threadIdx.x;
    int ks = blk & 3, nt = (blk >> 2) & 7, mat = blk >> 5;
    const float* W = (mat == 0) ? wq : (mat == 1) ? wk : (mat == 2) ? wv : wp;
    int col = nt * 16 + (lane & 15);
    int k0 = ks * 32 + (lane >> 4) * 8;
    u16x8 o;
#pragma unroll
    for (int j = 0; j < 8; ++j) o[j] = f2bf(W[(size_t)(k0 + j) * 128 + col]);
    *(u16x8*)(pkw + ((size_t)blk * 64 + lane) * 8) = o;
}

// K3b: pack rpb into per-(head,tile) f32x4 C-init fragments.
__global__ __launch_bounds__(64) void k_packb(const float* __restrict__ rpb,
                                              float* __restrict__ pb) {
    int blk = blockIdx.x;                 // h*16 + mt*4 + nt
    int lane = threadIdx.x;
    int nt = blk & 3, mt = (blk >> 2) & 3, h = blk >> 4;
    int m = nt * 16 + (lane & 15);
    int g = lane >> 4;
    float o[4];
#pragma unroll
    for (int r = 0; r < 4; ++r) {
        int n = mt * 16 + g * 4 + r;
        int relidx = (((n >> 3) - (m >> 3)) + 7) * 15 + ((n & 7) - (m & 7)) + 7;
        o[r] = rpb[relidx * 8 + h];
    }
    float4 v = {o[0], o[1], o[2], o[3]};
    *(float4*)(pb + ((size_t)blk * 64 + lane) * 4) = v;
}

// ---------------------------------------------------------------------------
// K3c: window attention, MFMA. 1024 blocks (one window), 256 threads (4 waves).
__global__ __launch_bounds__(256) void k_attn_mfma(const float* __restrict__ feat_l,
                                                   const unsigned short* __restrict__ pkw,
                                                   const float* __restrict__ pb,
                                                   const float* __restrict__ bq,
                                                   const float* __restrict__ bk,
                                                   const float* __restrict__ bv,
                                                   const float* __restrict__ bp,
                                                   const float* __restrict__ g1,
                                                   const float* __restrict__ bt1,
                                                   float* __restrict__ x) {
    // s_u: phase A = f32 staging sf[64][129] (33024 B <= 50176 B); phase B = per-wave scratch.
    // s_o: phase A = LN'd bf16 s_nf[64][136]; phase B (post-hoist) = attention output.
    __shared__ __align__(16) unsigned short s_u[4][6272];
    __shared__ __align__(16) unsigned short s_o[64 * 136];
    int tid = threadIdx.x;
    int wid = tid >> 6, lane = tid & 63;
    int g = lane >> 4, t = lane & 15;
    int bw = blockIdx.x;
    int b = bw >> 8, wh = (bw >> 4) & 15, ww = bw & 15;

    float* sf = (float*)&s_u[0][0];           // [64][129] f32 staging
    unsigned short* s_nf = s_o;               // [64][136] bf16 LN'd tokens

    // ---- load window tokens (f32) into staging (stride 129: conflict-free) ----
    for (int idx = tid; idx < 8192; idx += 256) {
        int c = idx >> 6, n = idx & 63;
        int hy = wh * 8 + (n >> 3), wx = ww * 8 + (n & 7);
        sf[n * 129 + c] = feat_l[((size_t)(b * 128 + c) << 14) + hy * 128 + wx];
    }
    __syncthreads();
    // ---- LayerNorm -> bf16 s_nf ----
    {
        int tok = tid >> 2, q = tid & 3;
        float s = 0.f, s2 = 0.f;
        for (int c = q * 32; c < q * 32 + 32; ++c) {
            float v = sf[tok * 129 + c];
            s += v; s2 += v * v;
        }
        s += __shfl_xor(s, 1); s += __shfl_xor(s, 2);
        s2 += __shfl_xor(s2, 1); s2 += __shfl_xor(s2, 2);
        float mean = s * (1.f / 128.f);
        float var = s2 * (1.f / 128.f) - mean * mean;
        float rstd = rsqrtf(var + 1e-5f);
        for (int c = q * 32; c < q * 32 + 32; c += 2) {
            float v0 = (sf[tok * 129 + c] - mean) * rstd * g1[c] + bt1[c];
            float v1 = (sf[tok * 129 + c + 1] - mean) * rstd * g1[c + 1] + bt1[c + 1];
            *(unsigned int*)&s_nf[tok * 136 + c] = pack2bf(v0, v1);
        }
    }
    __syncthreads();
    // ---- hoist X A-fragments to registers ----
    bf16x8 af[4][4];   // [Mt][ks]
#pragma unroll
    for (int Mt = 0; Mt < 4; ++Mt)
#pragma unroll
        for (int ks = 0; ks < 4; ++ks)
            af[Mt][ks] = *(const bf16x8*)&s_nf[(Mt * 16 + t) * 136 + ks * 32 + g * 8];
    __syncthreads();   // all waves hoisted; s_u and s_o now reusable

    unsigned short* sQ = &s_u[wid][0];
    unsigned short* sK = sQ + 2560;
    unsigned short* sV = sQ + 5120;
    unsigned short* sP = sQ;

#pragma unroll 1
    for (int hi = 0; hi < 2; ++hi) {
        int h = wid + hi * 4;
        u16x8 z8 = {0, 0, 0, 0, 0, 0, 0, 0};
        *(u16x8*)&sQ[lane * 40 + 16] = z8;
        *(u16x8*)&sQ[lane * 40 + 24] = z8;
        *(u16x8*)&sK[lane * 40 + 16] = z8;
        *(u16x8*)&sK[lane * 40 + 24] = z8;

        // ---- QKV projection for head h ----
        float bqv = bq[h * 16 + t], bkv = bk[h * 16 + t], bvv = bv[h * 16 + t];
        f32x4 qa[4], ka[4], va[4];
#pragma unroll
        for (int Mt = 0; Mt < 4; ++Mt) {
            qa[Mt] = (f32x4){bqv, bqv, bqv, bqv};
            ka[Mt] = (f32x4){bkv, bkv, bkv, bkv};
            va[Mt] = (f32x4){bvv, bvv, bvv, bvv};
        }
#pragma unroll
        for (int ks = 0; ks < 4; ++ks) {
            const unsigned short* wbase = pkw + ((size_t)((h * 4 + ks) * 64 + lane) * 8);
            bf16x8 bfq = *(const bf16x8*)(wbase);
            bf16x8 bfk = *(const bf16x8*)(wbase + 16384);
            bf16x8 bfv = *(const bf16x8*)(wbase + 32768);
#pragma unroll
            for (int Mt = 0; Mt < 4; ++Mt) {
                qa[Mt] = __builtin_amdgcn_mfma_f32_16x16x32_bf16(af[Mt][ks], bfq, qa[Mt], 0, 0, 0);
                ka[Mt] = __builtin_amdgcn_mfma_f32_16x16x32_bf16(af[Mt][ks], bfk, ka[Mt], 0, 0, 0);
                va[Mt] = __builtin_amdgcn_mfma_f32_16x16x32_bf16(af[Mt][ks], bfv, va[Mt], 0, 0, 0);
            }
        }
#pragma unroll
        for (int Mt = 0; Mt < 4; ++Mt)
#pragma unroll
            for (int r = 0; r < 4; ++r) {
                int tok = Mt * 16 + g * 4 + r;
                sQ[tok * 40 + t] = f2bf(qa[Mt][r] * SCALE);
                sK[tok * 40 + t] = f2bf(ka[Mt][r]);
                sV[t * 72 + tok] = f2bf(va[Mt][r]);
            }

        // ---- S = Q K^T + bias ----
        f32x4 s[4][4];
#pragma unroll
        for (int Mt = 0; Mt < 4; ++Mt)
#pragma unroll
            for (int Nt = 0; Nt < 4; ++Nt)
                s[Mt][Nt] = *(const f32x4*)(pb + ((size_t)((h * 16 + Mt * 4 + Nt) * 64 + lane) * 4));
        bf16x8 aq[4], bk2[4];
#pragma unroll
        for (int Mt = 0; Mt < 4; ++Mt) aq[Mt] = *(const bf16x8*)&sQ[(Mt * 16 + t) * 40 + g * 8];
#pragma unroll
        for (int Nt = 0; Nt < 4; ++Nt) bk2[Nt] = *(const bf16x8*)&sK[(Nt * 16 + t) * 40 + g * 8];
#pragma unroll
        for (int Mt = 0; Mt < 4; ++Mt)
#pragma unroll
            for (int Nt = 0; Nt < 4; ++Nt)
                s[Mt][Nt] = __builtin_amdgcn_mfma_f32_16x16x32_bf16(aq[Mt], bk2[Nt], s[Mt][Nt], 0, 0, 0);

        // ---- softmax (unnormalized; divide after PV) ----
        f32x4 rsm[4];
#pragma unroll
        for (int Mt = 0; Mt < 4; ++Mt) {
            f32x4 m = s[Mt][0];
#pragma unroll
            for (int Nt = 1; Nt < 4; ++Nt)
#pragma unroll
                for (int r = 0; r < 4; ++r) m[r] = fmaxf(m[r], s[Mt][Nt][r]);
#pragma unroll
            for (int sh = 1; sh <= 8; sh <<= 1)
#pragma unroll
                for (int r = 0; r < 4; ++r) m[r] = fmaxf(m[r], __shfl_xor(m[r], sh));
            f32x4 sum = (f32x4){0.f, 0.f, 0.f, 0.f};
#pragma unroll
            for (int Nt = 0; Nt < 4; ++Nt)
#pragma unroll
                for (int r = 0; r < 4; ++r) {
                    float e = __expf(s[Mt][Nt][r] - m[r]);
                    s[Mt][Nt][r] = e;
                    sum[r] += e;
                }
#pragma unroll
            for (int sh = 1; sh <= 8; sh <<= 1)
#pragma unroll
                for (int r = 0; r < 4; ++r) sum[r] += __shfl_xor(sum[r], sh);
            rsm[Mt] = sum;
        }
#pragma unroll
        for (int Mt = 0; Mt < 4; ++Mt)
#pragma unroll
            for (int Nt = 0; Nt < 4; ++Nt)
#pragma unroll
                for (int r = 0; r < 4; ++r)
                    sP[(Mt * 16 + g * 4 + r) * 72 + Nt * 16 + t] = f2bf(s[Mt][Nt][r]);

        // ---- O = P @ V ----
        f32x4 oa[4];
#pragma unroll
        for (int Mt = 0; Mt < 4; ++Mt) oa[Mt] = (f32x4){0.f, 0.f, 0.f, 0.f};
#pragma unroll
        for (int ksv = 0; ksv < 2; ++ksv) {
            bf16x8 bv2 = *(const bf16x8*)&sV[t * 72 + ksv * 32 + g * 8];
#pragma unroll
            for (int Mt = 0; Mt < 4; ++Mt) {
                bf16x8 ap = *(const bf16x8*)&sP[(Mt * 16 + t) * 72 + ksv * 32 + g * 8];
                oa[Mt] = __builtin_amdgcn_mfma_f32_16x16x32_bf16(ap, bv2, oa[Mt], 0, 0, 0);
            }
        }
#pragma unroll
        for (int Mt = 0; Mt < 4; ++Mt)
#pragma unroll
            for (int r = 0; r < 4; ++r)
                s_o[(Mt * 16 + g * 4 + r) * 136 + h * 16 + t] = f2bf(oa[Mt][r] / rsm[Mt][r]);
    }
    __syncthreads();

    // ---- proj: x += o @ wp + bp ----
    float bp0 = bp[wid * 32 + t], bp1 = bp[wid * 32 + 16 + t];
    f32x4 pa[4][2];
#pragma unroll
    for (int Mt = 0; Mt < 4; ++Mt) {
        pa[Mt][0] = (f32x4){bp0, bp0, bp0, bp0};
        pa[Mt][1] = (f32x4){bp1, bp1, bp1, bp1};
    }
#pragma unroll
    for (int ks = 0; ks < 4; ++ks) {
        bf16x8 b0 = *(const bf16x8*)(pkw + 49152 + (size_t)(((wid * 2 + 0) * 4 + ks) * 64 + lane) * 8);
        bf16x8 b1 = *(const bf16x8*)(pkw + 49152 + (size_t)(((wid * 2 + 1) * 4 + ks) * 64 + lane) * 8);
#pragma unroll
        for (int Mt = 0; Mt < 4; ++Mt) {
            bf16x8 a = *(const bf16x8*)&s_o[(Mt * 16 + t) * 136 + ks * 32 + g * 8];
            pa[Mt][0] = __builtin_amdgcn_mfma_f32_16x16x32_bf16(a, b0, pa[Mt][0], 0, 0, 0);
            pa[Mt][1] = __builtin_amdgcn_mfma_f32_16x16x32_bf16(a, b1, pa[Mt][1], 0, 0, 0);
        }
    }
#pragma unroll
    for (int Mt = 0; Mt < 4; ++Mt)
#pragma unroll
        for (int i = 0; i < 2; ++i)
#pragma unroll
            for (int r = 0; r < 4; ++r) {
                int tok = Mt * 16 + g * 4 + r;
                int hy = wh * 8 + (tok >> 3), wx = ww * 8 + (tok & 7);
                size_t addr = ((size_t)(b * 16384) + hy * 128 + wx) * 128 + (wid * 2 + i) * 16 + t;
                x[addr] += pa[Mt][i][r];
            }
}

// ---------------------------------------------------------------------------
// K2: unary MLP via MFMA. 1024 blocks x 64 tokens, 256 threads (4 waves).
// x = gelu(tok@W1+b1)@W2+b2 (writes x).
__global__ __launch_bounds__(256) void k_unary_mfma(const float* __restrict__ feat_l,
                                                    const unsigned short* __restrict__ pu1,
                                                    const float* __restrict__ b1,
                                                    const unsigned short* __restrict__ pu2,
                                                    const float* __restrict__ b2,
                                                    float* __restrict__ x) {
    __shared__ __align__(16) unsigned short s_a[64 * 136];
    __shared__ __align__(16) unsigned short s_h[64 * 136];
    int tid = threadIdx.x;
    int wid = tid >> 6, lane = tid & 63;
    int g = lane >> 4, t = lane & 15;
    int n0g = blockIdx.x * 64;
    int b = n0g >> 14;
    int nb = n0g & 16383;

    // transpose-load tokens -> bf16 s_a[tok][136]
    for (int idx = tid; idx < 4096; idx += 256) {
        int c2 = idx >> 6, nl = idx & 63;
        float v0 = feat_l[((size_t)(b * 128 + 2 * c2) << 14) + nb + nl];
        float v1 = feat_l[((size_t)(b * 128 + 2 * c2 + 1) << 14) + nb + nl];
        *(unsigned int*)&s_a[nl * 136 + 2 * c2] = pack2bf(v0, v1);
    }
    __syncthreads();

    bf16x8 af[4][4];
#pragma unroll
    for (int Mt = 0; Mt < 4; ++Mt)
#pragma unroll
        for (int ks = 0; ks < 4; ++ks)
            af[Mt][ks] = *(const bf16x8*)&s_a[(Mt * 16 + t) * 136 + ks * 32 + g * 8];

    // GEMM1: hidden tiles {wid*2, wid*2+1}
    f32x4 acc1[4][2];
#pragma unroll
    for (int nt2 = 0; nt2 < 2; ++nt2) {
        float bv = b1[(wid * 2 + nt2) * 16 + t];
#pragma unroll
        for (int Mt = 0; Mt < 4; ++Mt) acc1[Mt][nt2] = (f32x4){bv, bv, bv, bv};
    }
#pragma unroll
    for (int ks = 0; ks < 4; ++ks) {
        bf16x8 bf0 = *(const bf16x8*)(pu1 + (size_t)(((wid * 2 + 0) * 4 + ks) * 64 + lane) * 8);
        bf16x8 bf1 = *(const bf16x8*)(pu1 + (size_t)(((wid * 2 + 1) * 4 + ks) * 64 + lane) * 8);
#pragma unroll
        for (int Mt = 0; Mt < 4; ++Mt) {
            acc1[Mt][0] = __builtin_amdgcn_mfma_f32_16x16x32_bf16(af[Mt][ks], bf0, acc1[Mt][0], 0, 0, 0);
            acc1[Mt][1] = __builtin_amdgcn_mfma_f32_16x16x32_bf16(af[Mt][ks], bf1, acc1[Mt][1], 0, 0, 0);
        }
    }
#pragma unroll
    for (int Mt = 0; Mt < 4; ++Mt)
#pragma unroll
        for (int nt2 = 0; nt2 < 2; ++nt2)
#pragma unroll
            for (int r = 0; r < 4; ++r)
                s_h[(Mt * 16 + g * 4 + r) * 136 + (wid * 2 + nt2) * 16 + t] = f2bf(gelu_f(acc1[Mt][nt2][r]));
    __syncthreads();

    bf16x8 a2[4][4];
#pragma unroll
    for (int Mt = 0; Mt < 4; ++Mt)
#pragma unroll
        for (int ks = 0; ks < 4; ++ks)
            a2[Mt][ks] = *(const bf16x8*)&s_h[(Mt * 16 + t) * 136 + ks * 32 + g * 8];

    f32x4 acc2[4][2];
#pragma unroll
    for (int nt2 = 0; nt2 < 2; ++nt2) {
        float bv = b2[(wid * 2 + nt2) * 16 + t];
#pragma unroll
        for (int Mt = 0; Mt < 4; ++Mt) acc2[Mt][nt2] = (f32x4){bv, bv, bv, bv};
    }
#pragma unroll
    for (int ks = 0; ks < 4; ++ks) {
        bf16x8 bf0 = *(const bf16x8*)(pu2 + (size_t)(((wid * 2 + 0) * 4 + ks) * 64 + lane) * 8);
        bf16x8 bf1 = *(const bf16x8*)(pu2 + (size_t)(((wid * 2 + 1) * 4 + ks) * 64 + lane) * 8);
#pragma unroll
        for (int Mt = 0; Mt < 4; ++Mt) {
            acc2[Mt][0] = __builtin_amdgcn_mfma_f32_16x16x32_bf16(a2[Mt][ks], bf0, acc2[Mt][0], 0, 0, 0);
            acc2[Mt][1] = __builtin_amdgcn_mfma_f32_16x16x32_bf16(a2[Mt][ks], bf1, acc2[Mt][1], 0, 0, 0);
        }
    }
#pragma unroll
    for (int Mt = 0; Mt < 4; ++Mt)
#pragma unroll
        for (int nt2 = 0; nt2 < 2; ++nt2)
#pragma unroll
            for (int r = 0; r < 4; ++r) {
                int tok = Mt * 16 + g * 4 + r;
                x[(size_t)(n0g + tok) * 128 + (wid * 2 + nt2) * 16 + t] = acc2[Mt][nt2][r];
            }
}

// ---------------------------------------------------------------------------
// K4: x = x + gelu(LN2(x)@W1+b1)@W2 via MFMA. 1024 blocks x 64 tokens, 4 waves.
// (mlp_b2 is multiplied by 0 in the reference -> not added)
__global__ __launch_bounds__(256) void k_mlp_mfma(float* __restrict__ x,
                                                  const float* __restrict__ g2,
                                                  const float* __restrict__ bt2,
                                                  const unsigned short* __restrict__ pm1,
                                                  const float* __restrict__ b1,
                                                  const unsigned short* __restrict__ pm2) {
    // smem: [0, 33792) = sf f32 [64][132]  (reused as s_h bf16 [64][136] after LN)
    //       [33792, 51200) = s_a bf16 [64][136]
    __shared__ __align__(16) char smem[51200];
    float* sf = (float*)smem;
    unsigned short* s_h = (unsigned short*)smem;
    unsigned short* s_a = (unsigned short*)(smem + 33792);
    int tid = threadIdx.x;
    int wid = tid >> 6, lane = tid & 63;
    int g = lane >> 4, t = lane & 15;
    int n0g = blockIdx.x * 64;

    // load x tile (coalesced float4) -> sf
    for (int idx = tid; idx < 2048; idx += 256) {
        int n = idx >> 5, c4 = idx & 31;
        float4 v = *(const float4*)&x[(size_t)(n0g + n) * 128 + c4 * 4];
        *(float4*)&sf[n * 132 + c4 * 4] = v;
    }
    __syncthreads();
    // LayerNorm -> bf16 s_a
    {
        int tok = tid >> 2, q = tid & 3;
        float s = 0.f, s2 = 0.f;
        for (int c = q * 32; c < q * 32 + 32; ++c) {
            float v = sf[tok * 132 + c];
            s += v; s2 += v * v;
        }
        s += __shfl_xor(s, 1); s += __shfl_xor(s, 2);
        s2 += __shfl_xor(s2, 1); s2 += __shfl_xor(s2, 2);
        float mean = s * (1.f / 128.f);
        float var = s2 * (1.f / 128.f) - mean * mean;
        float rstd = rsqrtf(var + 1e-5f);
        for (int c = q * 32; c < q * 32 + 32; c += 2) {
            float v0 = (sf[tok * 132 + c] - mean) * rstd * g2[c] + bt2[c];
            float v1 = (sf[tok * 132 + c + 1] - mean) * rstd * g2[c + 1] + bt2[c + 1];
            *(unsigned int*)&s_a[tok * 136 + c] = pack2bf(v0, v1);
        }
    }
    __syncthreads();
    bf16x8 af[4][4];
#pragma unroll
    for (int Mt = 0; Mt < 4; ++Mt)
#pragma unroll
        for (int ks = 0; ks < 4; ++ks)
            af[Mt][ks] = *(const bf16x8*)&s_a[(Mt * 16 + t) * 136 + ks * 32 + g * 8];

    f32x4 out[4][2];
#pragma unroll
    for (int Mt = 0; Mt < 4; ++Mt) {
        out[Mt][0] = (f32x4){0.f, 0.f, 0.f, 0.f};
        out[Mt][1] = (f32x4){0.f, 0.f, 0.f, 0.f};
    }

#pragma unroll 1
    for (int hc = 0; hc < 4; ++hc) {
        // GEMM1 for this hidden chunk: wave covers col-tiles {wid*2, wid*2+1}
        f32x4 acc1[4][2];
#pragma unroll
        for (int nt2 = 0; nt2 < 2; ++nt2) {
            float bv = b1[hc * 128 + (wid * 2 + nt2) * 16 + t];
#pragma unroll
            for (int Mt = 0; Mt < 4; ++Mt) acc1[Mt][nt2] = (f32x4){bv, bv, bv, bv};
        }
#pragma unroll
        for (int ks = 0; ks < 4; ++ks) {
            bf16x8 bf0 = *(const bf16x8*)(pm1 + (size_t)(((hc * 8 + wid * 2 + 0) * 4 + ks) * 64 + lane) * 8);
            bf16x8 bf1 = *(const bf16x8*)(pm1 + (size_t)(((hc * 8 + wid * 2 + 1) * 4 + ks) * 64 + lane) * 8);
#pragma unroll
            for (int Mt = 0; Mt < 4; ++Mt) {
                acc1[Mt][0] = __builtin_amdgcn_mfma_f32_16x16x32_bf16(af[Mt][ks], bf0, acc1[Mt][0], 0, 0, 0);
                acc1[Mt][1] = __builtin_amdgcn_mfma_f32_16x16x32_bf16(af[Mt][ks], bf1, acc1[Mt][1], 0, 0, 0);
            }
        }
        // gelu -> s_h
#pragma unroll
        for (int Mt = 0; Mt < 4; ++Mt)
#pragma unroll
            for (int nt2 = 0; nt2 < 2; ++nt2)
#pragma unroll
                for (int r = 0; r < 4; ++r)
                    s_h[(Mt * 16 + g * 4 + r) * 136 + (wid * 2 + nt2) * 16 + t] = f2bf(gelu_f(acc1[Mt][nt2][r]));
        __syncthreads();
        // GEMM2 partial accumulate
        bf16x8 a2[4][4];
#pragma unroll
        for (int Mt = 0; Mt < 4; ++Mt)
#pragma unroll
            for (int ks = 0; ks < 4; ++ks)
                a2[Mt][ks] = *(const bf16x8*)&s_h[(Mt * 16 + t) * 136 + ks * 32 + g * 8];
#pragma unroll
        for (int ks = 0; ks < 4; ++ks) {
            bf16x8 bf0 = *(const bf16x8*)(pm2 + (size_t)((hc * 32 + (wid * 2 + 0) * 4 + ks) * 64 + lane) * 8);
            bf16x8 bf1 = *(const bf16x8*)(pm2 + (size_t)((hc * 32 + (wid * 2 + 1) * 4 + ks) * 64 + lane) * 8);
#pragma unroll
            for (int Mt = 0; Mt < 4; ++Mt) {
                out[Mt][0] = __builtin_amdgcn_mfma_f32_16x16x32_bf16(a2[Mt][ks], bf0, out[Mt][0], 0, 0, 0);
                out[Mt][1] = __builtin_amdgcn_mfma_f32_16x16x32_bf16(a2[Mt][ks], bf1, out[Mt][1], 0, 0, 0);
            }
        }
        __syncthreads();   // before next hc overwrites s_h
    }

    // residual add
#pragma unroll
    for (int Mt = 0; Mt < 4; ++Mt)
#pragma unroll
        for (int nt2 = 0; nt2 < 2; ++nt2)
#pragma unroll
            for (int r = 0; r < 4; ++r) {
                int tok = Mt * 16 + g * 4 + r;
                size_t addr = (size_t)(n0g + tok) * 128 + (wid * 2 + nt2) * 16 + t;
                x[addr] += out[Mt][nt2][r];
            }
}

// ---------------------------------------------------------------------------
// K5a: pack conv weights for MFMA A-fragments, folding BN scale.
__global__ __launch_bounds__(64) void k_pack(const float* __restrict__ w1,
                                             const float* __restrict__ b1,
                                             const float* __restrict__ bng,
                                             const float* __restrict__ bnb,
                                             unsigned short* __restrict__ pk,
                                             float* __restrict__ bias2) {
    const float rs = 0.9999950000374997f;   // rsqrt(1 + 1e-5)
    int blk = blockIdx.x;                   // (chunk*9+tap)*6 + cotile
    int lane = threadIdx.x;
    int ct = blk % 6;
    int taplin = blk / 6;
    int tap = taplin % 9, chunk = taplin / 9;
    int co = ct * 16 + (lane & 15);
    int cibase = chunk * 32 + (lane >> 4) * 8;
    u16x8 out;
#pragma unroll
    for (int j = 0; j < 8; ++j) {
        int ci = cibase + j;
        float v = 0.f;
        if (co < 88 && ci < 176) v = w1[(size_t)co * 1584 + ci * 9 + tap] * rs * bng[co];
        out[j] = f2bf(v);
    }
    *(u16x8*)(pk + ((size_t)blk * 64 + lane) * 8) = out;
    if (blk == 0) {
        for (int i = lane; i < 96; i += 64)
            bias2[i] = (i < 88) ? (b1[i] * rs * bng[i] + bnb[i]) : 0.f;
    }
}

// ---------------------------------------------------------------------------
// K5b: conv3x3 as bf16 implicit-GEMM MFMA. grid (8,8,4), 256 threads.
__global__ __launch_bounds__(256) void k_conv_mfma(const float* __restrict__ x,
                                                   const float* __restrict__ cost,
                                                   const unsigned short* __restrict__ pk,
                                                   const float* __restrict__ bias2,
                                                   float* __restrict__ h1) {
    __shared__ __align__(16) unsigned short s_p[324 * 40];
    int tid = threadIdx.x;
    int wid = tid >> 6, lane = tid & 63;
    int g = lane >> 4, t = lane & 15;
    int tx0 = blockIdx.x * 16, ty0 = blockIdx.y * 16, b = blockIdx.z;

    f32x4 acc[4][6];
#pragma unroll
    for (int p = 0; p < 4; ++p)
#pragma unroll
        for (int ct = 0; ct < 6; ++ct) acc[p][ct] = (f32x4){0.f, 0.f, 0.f, 0.f};

#pragma unroll 1
    for (int chunk = 0; chunk < 6; ++chunk) {
        if (chunk < 4) {
            int ci0 = chunk * 32;
            for (int u = tid; u < 648; u += 256) {
                int pos = u >> 1, half = u & 1;
                int yy = pos / 18, xx = pos - yy * 18;
                int gy = ty0 + yy - 1, gx = tx0 + xx - 1;
                u16x8 lo, hi;
                if (gy >= 0 && gy < 128 && gx >= 0 && gx < 128) {
                    const float4* src = (const float4*)&x[((size_t)(b << 14) + gy * 128 + gx) * 128 + ci0 + half * 16];
                    float4 v0 = src[0], v1 = src[1], v2 = src[2], v3 = src[3];
                    lo[0] = f2bf(v0.x); lo[1] = f2bf(v0.y); lo[2] = f2bf(v0.z); lo[3] = f2bf(v0.w);
                    lo[4] = f2bf(v1.x); lo[5] = f2bf(v1.y); lo[6] = f2bf(v1.z); lo[7] = f2bf(v1.w);
                    hi[0] = f2bf(v2.x); hi[1] = f2bf(v2.y); hi[2] = f2bf(v2.z); hi[3] = f2bf(v2.w);
                    hi[4] = f2bf(v3.x); hi[5] = f2bf(v3.y); hi[6] = f2bf(v3.z); hi[7] = f2bf(v3.w);
                } else {
                    lo = (u16x8)(unsigned short)0; hi = (u16x8)(unsigned short)0;
                }
                unsigned short* dst = &s_p[pos * 40 + half * 16];
                *(u16x8*)dst = lo;
                *(u16x8*)(dst + 8) = hi;
            }
        } else {
            int d0 = (chunk - 4) * 32;
            for (int u = tid; u < 576; u += 256) {
                int cl = u / 18, yy = u - cl * 18;
                int d = d0 + cl;
                int gy = ty0 + yy - 1;
                bool rowok = (d < 48) && (gy >= 0) && (gy < 128);
                const float* srow = cost + ((size_t)(b * 48 + (rowok ? d : 0)) << 14) + (rowok ? gy : 0) * 128;
                for (int xx = 0; xx < 18; ++xx) {
                    int gx = tx0 + xx - 1;
                    float v = (rowok && gx >= 0 && gx < 128) ? srow[gx] : 0.f;
                    s_p[(yy * 18 + xx) * 40 + cl] = f2bf(v);
                }
            }
        }
        __syncthreads();

#pragma unroll 1
        for (int tap = 0; tap < 9; ++tap) {
            int dy = tap / 3, dx = tap - dy * 3;
            const unsigned short* pkt = pk + ((size_t)(chunk * 9 + tap)) * 6 * 512;
            bf16x8 afr[6];
#pragma unroll
            for (int ct = 0; ct < 6; ++ct)
                afr[ct] = *(const bf16x8*)(pkt + ct * 512 + lane * 8);
            bf16x8 bfr[4];
#pragma unroll
            for (int p = 0; p < 4; ++p) {
                int pos = (wid * 4 + p + dy) * 18 + t + dx;
                bfr[p] = *(const bf16x8*)&s_p[pos * 40 + g * 8];
            }
#pragma unroll
            for (int p = 0; p < 4; ++p)
#pragma unroll
                for (int ct = 0; ct < 6; ++ct)
                    acc[p][ct] = __builtin_amdgcn_mfma_f32_16x16x32_bf16(afr[ct], bfr[p], acc[p][ct], 0, 0, 0);
        }
        __syncthreads();
    }

#pragma unroll
    for (int p = 0; p < 4; ++p) {
        int y = ty0 + wid * 4 + p;
#pragma unroll
        for (int ct = 0; ct < 6; ++ct) {
#pragma unroll
            for (int r = 0; r < 4; ++r) {
                int co = ct * 16 + g * 4 + r;
                if (co < 88) {
                    float v = acc[p][ct][r] + bias2[co];
                    h1[((size_t)(b * 88 + co) << 14) + y * 128 + tx0 + t] = fmaxf(v, 0.f);
                }
            }
        }
    }
}

// ---------------------------------------------------------------------------
// K6: pv = conv1x1(h1) + b2; softmax over D; pred = 4*sum(d*p). 256 blocks.
__global__ __launch_bounds__(256) void k_head(const float* __restrict__ h1,
                                              const float* __restrict__ w2, const float* __restrict__ b2,
                                              float* __restrict__ out) {
    __shared__ float s_wt[88 * 48];   // [k][d]
    __shared__ float s_b[48];
    int tid = threadIdx.x;
    for (int idx = tid; idx < 48 * 88; idx += 256) {
        int d = idx / 88, k = idx % 88;
        s_wt[k * 48 + d] = w2[idx];
    }
    if (tid < 48) s_b[tid] = b2[tid];
    __syncthreads();
    int px = blockIdx.x * 256 + tid;
    int b = px >> 14, r = px & 16383;
    float acc[48];
#pragma unroll
    for (int d = 0; d < 48; ++d) acc[d] = s_b[d];
    for (int k = 0; k < 88; ++k) {
        float hv = h1[((size_t)(b * 88 + k) << 14) + r];
        const float4* wrow = (const float4*)&s_wt[k * 48];
#pragma unroll
        for (int d4 = 0; d4 < 12; ++d4) {
            float4 wv = wrow[d4];
            acc[d4 * 4 + 0] += hv * wv.x;
            acc[d4 * 4 + 1] += hv * wv.y;
            acc[d4 * 4 + 2] += hv * wv.z;
            acc[d4 * 4 + 3] += hv * wv.w;
        }
    }
    float mx = -1e30f;
#pragma unroll
    for (int d = 0; d < 48; ++d) mx = fmaxf(mx, acc[d]);
    float sum = 0.f, wsum = 0.f;
#pragma unroll
    for (int d = 0; d < 48; ++d) {
        float e = expf(acc[d] - mx);
        sum += e;
        wsum += e * (float)d;
    }
    out[px] = 4.0f * wsum / sum;
}

// ---------------------------------------------------------------------------
extern "C" void kernel_launch(void* const* d_in, const int* in_sizes, int n_in,
                              void* d_out, int out_size, void* d_ws, size_t ws_size,
                              hipStream_t stream) {
    const float* feat_l = (const float*)d_in[0];
    const float* feat_r = (const float*)d_in[1];
    const float* wq = (const float*)d_in[2];
    const float* bq = (const float*)d_in[3];
    const float* wk = (const float*)d_in[4];
    const float* bk = (const float*)d_in[5];
    const float* wv = (const float*)d_in[6];
    const float* bv = (const float*)d_in[7];
    const float* wp = (const float*)d_in[8];
    const float* bp = (const float*)d_in[9];
    const float* rpb = (const float*)d_in[10];
    const float* ln1_g = (const float*)d_in[11];
    const float* ln1_b = (const float*)d_in[12];
    const float* ln2_g = (const float*)d_in[13];
    const float* ln2_b = (const float*)d_in[14];
    const float* mlp_w1 = (const float*)d_in[15];
    const float* mlp_b1 = (const float*)d_in[16];
    const float* mlp_w2 = (const float*)d_in[17];
    // d_in[18] = mlp_b2 is multiplied by 0.0 in the reference -> unused
    const float* un_w1 = (const float*)d_in[19];
    const float* un_b1 = (const float*)d_in[20];
    const float* un_w2 = (const float*)d_in[21];
    const float* un_b2 = (const float*)d_in[22];
    const float* dp_w1 = (const float*)d_in[23];
    const float* dp_b1 = (const float*)d_in[24];
    const float* bn_g = (const float*)d_in[25];
    const float* bn_b = (const float*)d_in[26];
    const float* dp_w2 = (const float*)d_in[27];
    const float* dp_b2 = (const float*)d_in[28];

    float* ws = (float*)d_ws;
    float* cost = ws;                               // 3,145,728 f
    float* x = ws + 3145728;                        // 8,388,608 f
    float* h1 = ws + 11534336;                      // 5,767,168 f
    unsigned short* pk = (unsigned short*)(ws + 17301504);       // 165,888 u16
    float* bias2 = ws + 17384448;                   // 96 f
    unsigned short* pkw = (unsigned short*)(ws + 17384544);      // 65,536 u16
    float* pb = ws + 17417312;                      // 32,768 f
    unsigned short* pm1 = (unsigned short*)(ws + 17450080);      // 65,536 u16
    unsigned short* pm2 = (unsigned short*)(ws + 17482848);      // 65,536 u16
    unsigned short* pu1 = (unsigned short*)(ws + 17515616);      // 16,384 u16
    unsigned short* pu2 = (unsigned short*)(ws + 17523808);      // 16,384 u16
    float* out = (float*)d_out;

    k_pack<<<324, 64, 0, stream>>>(dp_w1, dp_b1, bn_g, bn_b, pk, bias2);
    k_packw<<<128, 64, 0, stream>>>(wq, wk, wv, wp, pkw);
    k_packb<<<128, 64, 0, stream>>>(rpb, pb);
    k_packg<<<128, 64, 0, stream>>>(mlp_w1, pm1, 512);
    k_packg<<<128, 64, 0, stream>>>(mlp_w2, pm2, 128);
    k_packg<<<32, 64, 0, stream>>>(un_w1, pu1, 128);
    k_packg<<<32, 64, 0, stream>>>(un_w2, pu2, 128);
    k_cost<<<dim3(64, 4), 256, 0, stream>>>(feat_l, feat_r, cost);
    k_unary_mfma<<<1024, 256, 0, stream>>>(feat_l, pu1, un_b1, pu2, un_b2, x);
    k_attn_mfma<<<1024, 256, 0, stream>>>(feat_l, pkw, pb, bq, bk, bv, bp,
                                          ln1_g, ln1_b, x);
    k_mlp_mfma<<<1024, 256, 0, stream>>>(x, ln2_g, ln2_b, pm1, mlp_b1, pm2);
    k_conv_mfma<<<dim3(8, 8, 4), 256, 0, stream>>>(x, cost, pk, bias2, h1);
    k_head<<<256, 256, 0, stream>>>(h1, dp_w2, dp_b2, out);
}

// Round 5
// 355.931 us; speedup vs baseline: 6.8354x; 1.6013x over previous
//
#include <hip/hip_runtime.h>
#include <math.h>

// Dims
constexpr int Bn = 4, Cc = 128, Hh = 128, Wn = 128, Dd = 48;
constexpr float SCALE = 0.25f;       // 16^-0.5

typedef short  bf16x8 __attribute__((ext_vector_type(8)));
typedef float  f32x4  __attribute__((ext_vector_type(4)));
typedef unsigned short u16x8 __attribute__((ext_vector_type(8)));

static __device__ __forceinline__ float gelu_f(float v) {
    return 0.5f * v * (1.0f + erff(v * 0.70710678118654752f));
}

static __device__ __forceinline__ unsigned short f2bf(float f) {
    unsigned int u = __float_as_uint(f);
    u = (u + 0x7fffu + ((u >> 16) & 1u)) >> 16;   // RNE
    return (unsigned short)u;
}

static __device__ __forceinline__ unsigned int pack2bf(float a, float b) {
    return (unsigned int)f2bf(a) | ((unsigned int)f2bf(b) << 16);
}

// ---------------------------------------------------------------------------
// K1: cost volume, register-blocked band correlation.
// grid (2 wtiles, 64 hpairs, 4 b), 384 threads. Thread owns 4w x 4d; channels
// staged in LDS 16 at a time; all fr shifts are compile-time register indices.
__global__ __launch_bounds__(384) void k_cost(const float* __restrict__ fl,
                                              const float* __restrict__ fr,
                                              float* __restrict__ cost) {
    __shared__ float s_fl[2][16][64];
    __shared__ float s_fr[2][16][112];
    int tid = threadIdx.x;
    int w0 = blockIdx.x * 64;
    int hp = blockIdx.y, b = blockIdx.z;
    int row = tid / 192;               // uniform per wave (wave 3 boundary = 192)
    int r = tid - row * 192;
    int wg = r & 15, dg = r >> 4;      // wg 0..15, dg 0..11
    int W = wg * 4, D = dg * 4;        // both ≡ 0 (mod 4)
    int h = hp * 2 + row;
    float acc[4][4];
#pragma unroll
    for (int i = 0; i < 4; ++i)
#pragma unroll
        for (int j = 0; j < 4; ++j) acc[i][j] = 0.f;

#pragma unroll 1
    for (int ck = 0; ck < 8; ++ck) {
        int ci0 = ck * 16;
        // stage fl rows: 2 x 16c x 64w
        for (int i = tid; i < 512; i += 384) {
            int rr = i >> 8, rem = i & 255;
            int c = rem >> 4, k4 = rem & 15;
            float4 v = *(const float4*)&fl[((size_t)(b * 128 + ci0 + c) << 14) + (hp * 2 + rr) * 128 + w0 + k4 * 4];
            *(float4*)&s_fl[rr][c][k4 * 4] = v;
        }
        // stage fr window [w0-48, w0+63]: 2 x 16c x 112w (left zero-pad)
        for (int i = tid; i < 896; i += 384) {
            int rr = i / 448, rem = i - rr * 448;
            int c = rem / 28, k4 = rem - c * 28;
            int wgl = w0 - 48 + k4 * 4;
            float4 v = {0.f, 0.f, 0.f, 0.f};
            if (wgl >= 0)
                v = *(const float4*)&fr[((size_t)(b * 128 + ci0 + c) << 14) + (hp * 2 + rr) * 128 + wgl];
            *(float4*)&s_fr[rr][c][k4 * 4] = v;
        }
        __syncthreads();
#pragma unroll
        for (int c = 0; c < 16; ++c) {
            float4 flv = *(const float4*)&s_fl[row][c][W];
            int base = W - D + 44;    // ≡ 0 (mod 4), in [0, 104]
            float4 f0 = *(const float4*)&s_fr[row][c][base];
            float4 f1 = *(const float4*)&s_fr[row][c][base + 4];
            float fw[8] = {f0.x, f0.y, f0.z, f0.w, f1.x, f1.y, f1.z, f1.w};
            float fv[4] = {flv.x, flv.y, flv.z, flv.w};
            // fr element for (wv, dj): index wv - dj + 4 in [1,7] (compile-time)
#pragma unroll
            for (int dj = 0; dj < 4; ++dj)
#pragma unroll
                for (int wv = 0; wv < 4; ++wv)
                    acc[dj][wv] += fv[wv] * fw[wv - dj + 4];
        }
        __syncthreads();
    }
    const float inv = 1.0f / 128.0f;
#pragma unroll
    for (int dj = 0; dj < 4; ++dj) {
        float4 o = {acc[dj][0] * inv, acc[dj][1] * inv, acc[dj][2] * inv, acc[dj][3] * inv};
        *(float4*)&cost[((size_t)(b * 48 + D + dj) << 14) + h * 128 + w0 + W] = o;
    }
}

// ---------------------------------------------------------------------------
// Pack helpers (device), fused into one kernel to cut launch overhead.

// conv weights -> A-fragments, BN scale folded. blk 0..323
static __device__ void pack_conv(int blk, int lane,
                                 const float* __restrict__ w1, const float* __restrict__ b1,
                                 const float* __restrict__ bng, const float* __restrict__ bnb,
                                 unsigned short* __restrict__ pk, float* __restrict__ bias2) {
    const float rs = 0.9999950000374997f;   // rsqrt(1 + 1e-5)
    int ct = blk % 6;
    int taplin = blk / 6;
    int tap = taplin % 9, chunk = taplin / 9;
    int co = ct * 16 + (lane & 15);
    int cibase = chunk * 32 + (lane >> 4) * 8;
    u16x8 out;
#pragma unroll
    for (int j = 0; j < 8; ++j) {
        int ci = cibase + j;
        float v = 0.f;
        if (co < 88 && ci < 176) v = w1[(size_t)co * 1584 + ci * 9 + tap] * rs * bng[co];
        out[j] = f2bf(v);
    }
    *(u16x8*)(pk + ((size_t)blk * 64 + lane) * 8) = out;
    if (blk == 0) {
        for (int i = lane; i < 96; i += 64)
            bias2[i] = (i < 88) ? (b1[i] * rs * bng[i] + bnb[i]) : 0.f;
    }
}

// generic B-fragment pack of [K x ncols] f32 matrix
static __device__ void pack_gemmB(int blk, int lane,
                                  const float* __restrict__ W,
                                  unsigned short* __restrict__ out, int ncols) {
    int ntiles = ncols >> 4;
    int ks = blk & 3;
    int nt = (blk >> 2) % ntiles;
    int kc = blk / (4 * ntiles);
    int col = nt * 16 + (lane & 15);
    int k0 = kc * 128 + ks * 32 + (lane >> 4) * 8;
    u16x8 o;
#pragma unroll
    for (int j = 0; j < 8; ++j) o[j] = f2bf(W[(size_t)(k0 + j) * ncols + col]);
    *(u16x8*)(out + ((size_t)blk * 64 + lane) * 8) = o;
}

// rpb -> per-(head,tile) f32x4 C-init fragments. blk 0..127
static __device__ void pack_rpb(int blk, int lane,
                                const float* __restrict__ rpb, float* __restrict__ pb) {
    int nt = blk & 3, mt = (blk >> 2) & 3, hh = blk >> 4;
    int m = nt * 16 + (lane & 15);
    int g = lane >> 4;
    float o[4];
#pragma unroll
    for (int rr = 0; rr < 4; ++rr) {
        int n = mt * 16 + g * 4 + rr;
        int relidx = (((n >> 3) - (m >> 3)) + 7) * 15 + ((n & 7) - (m & 7)) + 7;
        o[rr] = rpb[relidx * 8 + hh];
    }
    float4 v = {o[0], o[1], o[2], o[3]};
    *(float4*)(pb + ((size_t)blk * 64 + lane) * 4) = v;
}

__global__ __launch_bounds__(64) void k_pack_all(
        const float* __restrict__ dp_w1, const float* __restrict__ dp_b1,
        const float* __restrict__ bn_g, const float* __restrict__ bn_b,
        unsigned short* __restrict__ pk, float* __restrict__ bias2,
        const float* __restrict__ wq, const float* __restrict__ wk,
        const float* __restrict__ wv, const float* __restrict__ wp,
        unsigned short* __restrict__ pkw,
        const float* __restrict__ rpb, float* __restrict__ pb,
        const float* __restrict__ mlp_w1, unsigned short* __restrict__ pm1,
        const float* __restrict__ mlp_w2, unsigned short* __restrict__ pm2,
        const float* __restrict__ un_w1, unsigned short* __restrict__ pu1,
        const float* __restrict__ un_w2, unsigned short* __restrict__ pu2) {
    int blk = blockIdx.x;
    int lane = threadIdx.x;
    if (blk < 324) {
        pack_conv(blk, lane, dp_w1, dp_b1, bn_g, bn_b, pk, bias2);
    } else if (blk < 452) {
        int bb = blk - 324;          // mat*32 + nt*4 + ks
        int mat = bb >> 5;
        const float* W = (mat == 0) ? wq : (mat == 1) ? wk : (mat == 2) ? wv : wp;
        pack_gemmB(bb & 31, lane, W, pkw + (size_t)mat * 16384, 128);
    } else if (blk < 580) {
        pack_rpb(blk - 452, lane, rpb, pb);
    } else if (blk < 708) {
        pack_gemmB(blk - 580, lane, mlp_w1, pm1, 512);
    } else if (blk < 836) {
        pack_gemmB(blk - 708, lane, mlp_w2, pm2, 128);
    } else if (blk < 868) {
        pack_gemmB(blk - 836, lane, un_w1, pu1, 128);
    } else {
        pack_gemmB(blk - 868, lane, un_w2, pu2, 128);
    }
}

// ---------------------------------------------------------------------------
// K3c: window attention, MFMA. 1024 blocks (one window), 256 threads (4 waves).
__global__ __launch_bounds__(256) void k_attn_mfma(const float* __restrict__ feat_l,
                                                   const unsigned short* __restrict__ pkw,
                                                   const float* __restrict__ pb,
                                                   const float* __restrict__ bq,
                                                   const float* __restrict__ bk,
                                                   const float* __restrict__ bv,
                                                   const float* __restrict__ bp,
                                                   const float* __restrict__ g1,
                                                   const float* __restrict__ bt1,
                                                   float* __restrict__ x) {
    // s_u: phase A = f32 staging sf[64][129]; phase B = per-wave scratch.
    // s_o: phase A = LN'd bf16 s_nf[64][136]; phase B (post-hoist) = attention output.
    __shared__ __align__(16) unsigned short s_u[4][6272];
    __shared__ __align__(16) unsigned short s_o[64 * 136];
    int tid = threadIdx.x;
    int wid = tid >> 6, lane = tid & 63;
    int g = lane >> 4, t = lane & 15;
    int bw = blockIdx.x;
    int b = bw >> 8, wh = (bw >> 4) & 15, ww = bw & 15;

    float* sf = (float*)&s_u[0][0];           // [64][129] f32 staging
    unsigned short* s_nf = s_o;               // [64][136] bf16 LN'd tokens

    for (int idx = tid; idx < 8192; idx += 256) {
        int c = idx >> 6, n = idx & 63;
        int hy = wh * 8 + (n >> 3), wx = ww * 8 + (n & 7);
        sf[n * 129 + c] = feat_l[((size_t)(b * 128 + c) << 14) + hy * 128 + wx];
    }
    __syncthreads();
    {
        int tok = tid >> 2, q = tid & 3;
        float s = 0.f, s2 = 0.f;
        for (int c = q * 32; c < q * 32 + 32; ++c) {
            float v = sf[tok * 129 + c];
            s += v; s2 += v * v;
        }
        s += __shfl_xor(s, 1); s += __shfl_xor(s, 2);
        s2 += __shfl_xor(s2, 1); s2 += __shfl_xor(s2, 2);
        float mean = s * (1.f / 128.f);
        float var = s2 * (1.f / 128.f) - mean * mean;
        float rstd = rsqrtf(var + 1e-5f);
        for (int c = q * 32; c < q * 32 + 32; c += 2) {
            float v0 = (sf[tok * 129 + c] - mean) * rstd * g1[c] + bt1[c];
            float v1 = (sf[tok * 129 + c + 1] - mean) * rstd * g1[c + 1] + bt1[c + 1];
            *(unsigned int*)&s_nf[tok * 136 + c] = pack2bf(v0, v1);
        }
    }
    __syncthreads();
    bf16x8 af[4][4];   // [Mt][ks]
#pragma unroll
    for (int Mt = 0; Mt < 4; ++Mt)
#pragma unroll
        for (int ks = 0; ks < 4; ++ks)
            af[Mt][ks] = *(const bf16x8*)&s_nf[(Mt * 16 + t) * 136 + ks * 32 + g * 8];
    __syncthreads();

    unsigned short* sQ = &s_u[wid][0];
    unsigned short* sK = sQ + 2560;
    unsigned short* sV = sQ + 5120;
    unsigned short* sP = sQ;

#pragma unroll 1
    for (int hi = 0; hi < 2; ++hi) {
        int h = wid + hi * 4;
        u16x8 z8 = {0, 0, 0, 0, 0, 0, 0, 0};
        *(u16x8*)&sQ[lane * 40 + 16] = z8;
        *(u16x8*)&sQ[lane * 40 + 24] = z8;
        *(u16x8*)&sK[lane * 40 + 16] = z8;
        *(u16x8*)&sK[lane * 40 + 24] = z8;

        float bqv = bq[h * 16 + t], bkv = bk[h * 16 + t], bvv = bv[h * 16 + t];
        f32x4 qa[4], ka[4], va[4];
#pragma unroll
        for (int Mt = 0; Mt < 4; ++Mt) {
            qa[Mt] = (f32x4){bqv, bqv, bqv, bqv};
            ka[Mt] = (f32x4){bkv, bkv, bkv, bkv};
            va[Mt] = (f32x4){bvv, bvv, bvv, bvv};
        }
#pragma unroll
        for (int ks = 0; ks < 4; ++ks) {
            const unsigned short* wbase = pkw + ((size_t)((h * 4 + ks) * 64 + lane) * 8);
            bf16x8 bfq = *(const bf16x8*)(wbase);
            bf16x8 bfk = *(const bf16x8*)(wbase + 16384);
            bf16x8 bfv = *(const bf16x8*)(wbase + 32768);
#pragma unroll
            for (int Mt = 0; Mt < 4; ++Mt) {
                qa[Mt] = __builtin_amdgcn_mfma_f32_16x16x32_bf16(af[Mt][ks], bfq, qa[Mt], 0, 0, 0);
                ka[Mt] = __builtin_amdgcn_mfma_f32_16x16x32_bf16(af[Mt][ks], bfk, ka[Mt], 0, 0, 0);
                va[Mt] = __builtin_amdgcn_mfma_f32_16x16x32_bf16(af[Mt][ks], bfv, va[Mt], 0, 0, 0);
            }
        }
#pragma unroll
        for (int Mt = 0; Mt < 4; ++Mt)
#pragma unroll
            for (int rr = 0; rr < 4; ++rr) {
                int tok = Mt * 16 + g * 4 + rr;
                sQ[tok * 40 + t] = f2bf(qa[Mt][rr] * SCALE);
                sK[tok * 40 + t] = f2bf(ka[Mt][rr]);
                sV[t * 72 + tok] = f2bf(va[Mt][rr]);
            }

        f32x4 s[4][4];
#pragma unroll
        for (int Mt = 0; Mt < 4; ++Mt)
#pragma unroll
            for (int Nt = 0; Nt < 4; ++Nt)
                s[Mt][Nt] = *(const f32x4*)(pb + ((size_t)((h * 16 + Mt * 4 + Nt) * 64 + lane) * 4));
        bf16x8 aq[4], bk2[4];
#pragma unroll
        for (int Mt = 0; Mt < 4; ++Mt) aq[Mt] = *(const bf16x8*)&sQ[(Mt * 16 + t) * 40 + g * 8];
#pragma unroll
        for (int Nt = 0; Nt < 4; ++Nt) bk2[Nt] = *(const bf16x8*)&sK[(Nt * 16 + t) * 40 + g * 8];
#pragma unroll
        for (int Mt = 0; Mt < 4; ++Mt)
#pragma unroll
            for (int Nt = 0; Nt < 4; ++Nt)
                s[Mt][Nt] = __builtin_amdgcn_mfma_f32_16x16x32_bf16(aq[Mt], bk2[Nt], s[Mt][Nt], 0, 0, 0);

        f32x4 rsm[4];
#pragma unroll
        for (int Mt = 0; Mt < 4; ++Mt) {
            f32x4 m = s[Mt][0];
#pragma unroll
            for (int Nt = 1; Nt < 4; ++Nt)
#pragma unroll
                for (int rr = 0; rr < 4; ++rr) m[rr] = fmaxf(m[rr], s[Mt][Nt][rr]);
#pragma unroll
            for (int sh = 1; sh <= 8; sh <<= 1)
#pragma unroll
                for (int rr = 0; rr < 4; ++rr) m[rr] = fmaxf(m[rr], __shfl_xor(m[rr], sh));
            f32x4 sum = (f32x4){0.f, 0.f, 0.f, 0.f};
#pragma unroll
            for (int Nt = 0; Nt < 4; ++Nt)
#pragma unroll
                for (int rr = 0; rr < 4; ++rr) {
                    float e = __expf(s[Mt][Nt][rr] - m[rr]);
                    s[Mt][Nt][rr] = e;
                    sum[rr] += e;
                }
#pragma unroll
            for (int sh = 1; sh <= 8; sh <<= 1)
#pragma unroll
                for (int rr = 0; rr < 4; ++rr) sum[rr] += __shfl_xor(sum[rr], sh);
            rsm[Mt] = sum;
        }
#pragma unroll
        for (int Mt = 0; Mt < 4; ++Mt)
#pragma unroll
            for (int Nt = 0; Nt < 4; ++Nt)
#pragma unroll
                for (int rr = 0; rr < 4; ++rr)
                    sP[(Mt * 16 + g * 4 + rr) * 72 + Nt * 16 + t] = f2bf(s[Mt][Nt][rr]);

        f32x4 oa[4];
#pragma unroll
        for (int Mt = 0; Mt < 4; ++Mt) oa[Mt] = (f32x4){0.f, 0.f, 0.f, 0.f};
#pragma unroll
        for (int ksv = 0; ksv < 2; ++ksv) {
            bf16x8 bv2 = *(const bf16x8*)&sV[t * 72 + ksv * 32 + g * 8];
#pragma unroll
            for (int Mt = 0; Mt < 4; ++Mt) {
                bf16x8 ap = *(const bf16x8*)&sP[(Mt * 16 + t) * 72 + ksv * 32 + g * 8];
                oa[Mt] = __builtin_amdgcn_mfma_f32_16x16x32_bf16(ap, bv2, oa[Mt], 0, 0, 0);
            }
        }
#pragma unroll
        for (int Mt = 0; Mt < 4; ++Mt)
#pragma unroll
            for (int rr = 0; rr < 4; ++rr)
                s_o[(Mt * 16 + g * 4 + rr) * 136 + h * 16 + t] = f2bf(oa[Mt][rr] / rsm[Mt][rr]);
    }
    __syncthreads();

    float bp0 = bp[wid * 32 + t], bp1 = bp[wid * 32 + 16 + t];
    f32x4 pa[4][2];
#pragma unroll
    for (int Mt = 0; Mt < 4; ++Mt) {
        pa[Mt][0] = (f32x4){bp0, bp0, bp0, bp0};
        pa[Mt][1] = (f32x4){bp1, bp1, bp1, bp1};
    }
#pragma unroll
    for (int ks = 0; ks < 4; ++ks) {
        bf16x8 b0 = *(const bf16x8*)(pkw + 49152 + (size_t)(((wid * 2 + 0) * 4 + ks) * 64 + lane) * 8);
        bf16x8 b1 = *(const bf16x8*)(pkw + 49152 + (size_t)(((wid * 2 + 1) * 4 + ks) * 64 + lane) * 8);
#pragma unroll
        for (int Mt = 0; Mt < 4; ++Mt) {
            bf16x8 a = *(const bf16x8*)&s_o[(Mt * 16 + t) * 136 + ks * 32 + g * 8];
            pa[Mt][0] = __builtin_amdgcn_mfma_f32_16x16x32_bf16(a, b0, pa[Mt][0], 0, 0, 0);
            pa[Mt][1] = __builtin_amdgcn_mfma_f32_16x16x32_bf16(a, b1, pa[Mt][1], 0, 0, 0);
        }
    }
#pragma unroll
    for (int Mt = 0; Mt < 4; ++Mt)
#pragma unroll
        for (int i = 0; i < 2; ++i)
#pragma unroll
            for (int rr = 0; rr < 4; ++rr) {
                int tok = Mt * 16 + g * 4 + rr;
                int hy = wh * 8 + (tok >> 3), wx = ww * 8 + (tok & 7);
                size_t addr = ((size_t)(b * 16384) + hy * 128 + wx) * 128 + (wid * 2 + i) * 16 + t;
                x[addr] += pa[Mt][i][rr];
            }
}

// ---------------------------------------------------------------------------
// K2: unary MLP via MFMA. 1024 blocks x 64 tokens, 256 threads (4 waves).
__global__ __launch_bounds__(256) void k_unary_mfma(const float* __restrict__ feat_l,
                                                    const unsigned short* __restrict__ pu1,
                                                    const float* __restrict__ b1,
                                                    const unsigned short* __restrict__ pu2,
                                                    const float* __restrict__ b2,
                                                    float* __restrict__ x) {
    __shared__ __align__(16) unsigned short s_a[64 * 136];
    __shared__ __align__(16) unsigned short s_h[64 * 136];
    int tid = threadIdx.x;
    int wid = tid >> 6, lane = tid & 63;
    int g = lane >> 4, t = lane & 15;
    int n0g = blockIdx.x * 64;
    int b = n0g >> 14;
    int nb = n0g & 16383;

    for (int idx = tid; idx < 4096; idx += 256) {
        int c2 = idx >> 6, nl = idx & 63;
        float v0 = feat_l[((size_t)(b * 128 + 2 * c2) << 14) + nb + nl];
        float v1 = feat_l[((size_t)(b * 128 + 2 * c2 + 1) << 14) + nb + nl];
        *(unsigned int*)&s_a[nl * 136 + 2 * c2] = pack2bf(v0, v1);
    }
    __syncthreads();

    bf16x8 af[4][4];
#pragma unroll
    for (int Mt = 0; Mt < 4; ++Mt)
#pragma unroll
        for (int ks = 0; ks < 4; ++ks)
            af[Mt][ks] = *(const bf16x8*)&s_a[(Mt * 16 + t) * 136 + ks * 32 + g * 8];

    f32x4 acc1[4][2];
#pragma unroll
    for (int nt2 = 0; nt2 < 2; ++nt2) {
        float bv = b1[(wid * 2 + nt2) * 16 + t];
#pragma unroll
        for (int Mt = 0; Mt < 4; ++Mt) acc1[Mt][nt2] = (f32x4){bv, bv, bv, bv};
    }
#pragma unroll
    for (int ks = 0; ks < 4; ++ks) {
        bf16x8 bf0 = *(const bf16x8*)(pu1 + (size_t)(((wid * 2 + 0) * 4 + ks) * 64 + lane) * 8);
        bf16x8 bf1 = *(const bf16x8*)(pu1 + (size_t)(((wid * 2 + 1) * 4 + ks) * 64 + lane) * 8);
#pragma unroll
        for (int Mt = 0; Mt < 4; ++Mt) {
            acc1[Mt][0] = __builtin_amdgcn_mfma_f32_16x16x32_bf16(af[Mt][ks], bf0, acc1[Mt][0], 0, 0, 0);
            acc1[Mt][1] = __builtin_amdgcn_mfma_f32_16x16x32_bf16(af[Mt][ks], bf1, acc1[Mt][1], 0, 0, 0);
        }
    }
#pragma unroll
    for (int Mt = 0; Mt < 4; ++Mt)
#pragma unroll
        for (int nt2 = 0; nt2 < 2; ++nt2)
#pragma unroll
            for (int rr = 0; rr < 4; ++rr)
                s_h[(Mt * 16 + g * 4 + rr) * 136 + (wid * 2 + nt2) * 16 + t] = f2bf(gelu_f(acc1[Mt][nt2][rr]));
    __syncthreads();

    bf16x8 a2[4][4];
#pragma unroll
    for (int Mt = 0; Mt < 4; ++Mt)
#pragma unroll
        for (int ks = 0; ks < 4; ++ks)
            a2[Mt][ks] = *(const bf16x8*)&s_h[(Mt * 16 + t) * 136 + ks * 32 + g * 8];

    f32x4 acc2[4][2];
#pragma unroll
    for (int nt2 = 0; nt2 < 2; ++nt2) {
        float bv = b2[(wid * 2 + nt2) * 16 + t];
#pragma unroll
        for (int Mt = 0; Mt < 4; ++Mt) acc2[Mt][nt2] = (f32x4){bv, bv, bv, bv};
    }
#pragma unroll
    for (int ks = 0; ks < 4; ++ks) {
        bf16x8 bf0 = *(const bf16x8*)(pu2 + (size_t)(((wid * 2 + 0) * 4 + ks) * 64 + lane) * 8);
        bf16x8 bf1 = *(const bf16x8*)(pu2 + (size_t)(((wid * 2 + 1) * 4 + ks) * 64 + lane) * 8);
#pragma unroll
        for (int Mt = 0; Mt < 4; ++Mt) {
            acc2[Mt][0] = __builtin_amdgcn_mfma_f32_16x16x32_bf16(a2[Mt][ks], bf0, acc2[Mt][0], 0, 0, 0);
            acc2[Mt][1] = __builtin_amdgcn_mfma_f32_16x16x32_bf16(a2[Mt][ks], bf1, acc2[Mt][1], 0, 0, 0);
        }
    }
#pragma unroll
    for (int Mt = 0; Mt < 4; ++Mt)
#pragma unroll
        for (int nt2 = 0; nt2 < 2; ++nt2)
#pragma unroll
            for (int rr = 0; rr < 4; ++rr) {
                int tok = Mt * 16 + g * 4 + rr;
                x[(size_t)(n0g + tok) * 128 + (wid * 2 + nt2) * 16 + t] = acc2[Mt][nt2][rr];
            }
}

// ---------------------------------------------------------------------------
// K4: x = x + gelu(LN2(x)@W1+b1)@W2 via MFMA. (mlp_b2 * 0 in ref -> not added)
__global__ __launch_bounds__(256) void k_mlp_mfma(float* __restrict__ x,
                                                  const float* __restrict__ g2,
                                                  const float* __restrict__ bt2,
                                                  const unsigned short* __restrict__ pm1,
                                                  const float* __restrict__ b1,
                                                  const unsigned short* __restrict__ pm2) {
    __shared__ __align__(16) char smem[51200];
    float* sf = (float*)smem;
    unsigned short* s_h = (unsigned short*)smem;
    unsigned short* s_a = (unsigned short*)(smem + 33792);
    int tid = threadIdx.x;
    int wid = tid >> 6, lane = tid & 63;
    int g = lane >> 4, t = lane & 15;
    int n0g = blockIdx.x * 64;

    for (int idx = tid; idx < 2048; idx += 256) {
        int n = idx >> 5, c4 = idx & 31;
        float4 v = *(const float4*)&x[(size_t)(n0g + n) * 128 + c4 * 4];
        *(float4*)&sf[n * 132 + c4 * 4] = v;
    }
    __syncthreads();
    {
        int tok = tid >> 2, q = tid & 3;
        float s = 0.f, s2 = 0.f;
        for (int c = q * 32; c < q * 32 + 32; ++c) {
            float v = sf[tok * 132 + c];
            s += v; s2 += v * v;
        }
        s += __shfl_xor(s, 1); s += __shfl_xor(s, 2);
        s2 += __shfl_xor(s2, 1); s2 += __shfl_xor(s2, 2);
        float mean = s * (1.f / 128.f);
        float var = s2 * (1.f / 128.f) - mean * mean;
        float rstd = rsqrtf(var + 1e-5f);
        for (int c = q * 32; c < q * 32 + 32; c += 2) {
            float v0 = (sf[tok * 132 + c] - mean) * rstd * g2[c] + bt2[c];
            float v1 = (sf[tok * 132 + c + 1] - mean) * rstd * g2[c + 1] + bt2[c + 1];
            *(unsigned int*)&s_a[tok * 136 + c] = pack2bf(v0, v1);
        }
    }
    __syncthreads();
    bf16x8 af[4][4];
#pragma unroll
    for (int Mt = 0; Mt < 4; ++Mt)
#pragma unroll
        for (int ks = 0; ks < 4; ++ks)
            af[Mt][ks] = *(const bf16x8*)&s_a[(Mt * 16 + t) * 136 + ks * 32 + g * 8];

    f32x4 out[4][2];
#pragma unroll
    for (int Mt = 0; Mt < 4; ++Mt) {
        out[Mt][0] = (f32x4){0.f, 0.f, 0.f, 0.f};
        out[Mt][1] = (f32x4){0.f, 0.f, 0.f, 0.f};
    }

#pragma unroll 1
    for (int hc = 0; hc < 4; ++hc) {
        f32x4 acc1[4][2];
#pragma unroll
        for (int nt2 = 0; nt2 < 2; ++nt2) {
            float bv = b1[hc * 128 + (wid * 2 + nt2) * 16 + t];
#pragma unroll
            for (int Mt = 0; Mt < 4; ++Mt) acc1[Mt][nt2] = (f32x4){bv, bv, bv, bv};
        }
#pragma unroll
        for (int ks = 0; ks < 4; ++ks) {
            bf16x8 bf0 = *(const bf16x8*)(pm1 + (size_t)(((hc * 8 + wid * 2 + 0) * 4 + ks) * 64 + lane) * 8);
            bf16x8 bf1 = *(const bf16x8*)(pm1 + (size_t)(((hc * 8 + wid * 2 + 1) * 4 + ks) * 64 + lane) * 8);
#pragma unroll
            for (int Mt = 0; Mt < 4; ++Mt) {
                acc1[Mt][0] = __builtin_amdgcn_mfma_f32_16x16x32_bf16(af[Mt][ks], bf0, acc1[Mt][0], 0, 0, 0);
                acc1[Mt][1] = __builtin_amdgcn_mfma_f32_16x16x32_bf16(af[Mt][ks], bf1, acc1[Mt][1], 0, 0, 0);
            }
        }
#pragma unroll
        for (int Mt = 0; Mt < 4; ++Mt)
#pragma unroll
            for (int nt2 = 0; nt2 < 2; ++nt2)
#pragma unroll
                for (int rr = 0; rr < 4; ++rr)
                    s_h[(Mt * 16 + g * 4 + rr) * 136 + (wid * 2 + nt2) * 16 + t] = f2bf(gelu_f(acc1[Mt][nt2][rr]));
        __syncthreads();
        bf16x8 a2[4][4];
#pragma unroll
        for (int Mt = 0; Mt < 4; ++Mt)
#pragma unroll
            for (int ks = 0; ks < 4; ++ks)
                a2[Mt][ks] = *(const bf16x8*)&s_h[(Mt * 16 + t) * 136 + ks * 32 + g * 8];
#pragma unroll
        for (int ks = 0; ks < 4; ++ks) {
            bf16x8 bf0 = *(const bf16x8*)(pm2 + (size_t)((hc * 32 + (wid * 2 + 0) * 4 + ks) * 64 + lane) * 8);
            bf16x8 bf1 = *(const bf16x8*)(pm2 + (size_t)((hc * 32 + (wid * 2 + 1) * 4 + ks) * 64 + lane) * 8);
#pragma unroll
            for (int Mt = 0; Mt < 4; ++Mt) {
                out[Mt][0] = __builtin_amdgcn_mfma_f32_16x16x32_bf16(a2[Mt][ks], bf0, out[Mt][0], 0, 0, 0);
                out[Mt][1] = __builtin_amdgcn_mfma_f32_16x16x32_bf16(a2[Mt][ks], bf1, out[Mt][1], 0, 0, 0);
            }
        }
        __syncthreads();
    }

#pragma unroll
    for (int Mt = 0; Mt < 4; ++Mt)
#pragma unroll
        for (int nt2 = 0; nt2 < 2; ++nt2)
#pragma unroll
            for (int rr = 0; rr < 4; ++rr) {
                int tok = Mt * 16 + g * 4 + rr;
                size_t addr = (size_t)(n0g + tok) * 128 + (wid * 2 + nt2) * 16 + t;
                x[addr] += out[Mt][nt2][rr];
            }
}

// ---------------------------------------------------------------------------
// K5b: conv3x3 as bf16 implicit-GEMM MFMA. grid (8,8,4), 256 threads.
__global__ __launch_bounds__(256) void k_conv_mfma(const float* __restrict__ x,
                                                   const float* __restrict__ cost,
                                                   const unsigned short* __restrict__ pk,
                                                   const float* __restrict__ bias2,
                                                   float* __restrict__ h1) {
    __shared__ __align__(16) unsigned short s_p[324 * 40];
    int tid = threadIdx.x;
    int wid = tid >> 6, lane = tid & 63;
    int g = lane >> 4, t = lane & 15;
    int tx0 = blockIdx.x * 16, ty0 = blockIdx.y * 16, b = blockIdx.z;

    f32x4 acc[4][6];
#pragma unroll
    for (int p = 0; p < 4; ++p)
#pragma unroll
        for (int ct = 0; ct < 6; ++ct) acc[p][ct] = (f32x4){0.f, 0.f, 0.f, 0.f};

#pragma unroll 1
    for (int chunk = 0; chunk < 6; ++chunk) {
        if (chunk < 4) {
            int ci0 = chunk * 32;
            for (int u = tid; u < 648; u += 256) {
                int pos = u >> 1, half = u & 1;
                int yy = pos / 18, xx = pos - yy * 18;
                int gy = ty0 + yy - 1, gx = tx0 + xx - 1;
                u16x8 lo, hi;
                if (gy >= 0 && gy < 128 && gx >= 0 && gx < 128) {
                    const float4* src = (const float4*)&x[((size_t)(b << 14) + gy * 128 + gx) * 128 + ci0 + half * 16];
                    float4 v0 = src[0], v1 = src[1], v2 = src[2], v3 = src[3];
                    lo[0] = f2bf(v0.x); lo[1] = f2bf(v0.y); lo[2] = f2bf(v0.z); lo[3] = f2bf(v0.w);
                    lo[4] = f2bf(v1.x); lo[5] = f2bf(v1.y); lo[6] = f2bf(v1.z); lo[7] = f2bf(v1.w);
                    hi[0] = f2bf(v2.x); hi[1] = f2bf(v2.y); hi[2] = f2bf(v2.z); hi[3] = f2bf(v2.w);
                    hi[4] = f2bf(v3.x); hi[5] = f2bf(v3.y); hi[6] = f2bf(v3.z); hi[7] = f2bf(v3.w);
                } else {
                    lo = (u16x8)(unsigned short)0; hi = (u16x8)(unsigned short)0;
                }
                unsigned short* dst = &s_p[pos * 40 + half * 16];
                *(u16x8*)dst = lo;
                *(u16x8*)(dst + 8) = hi;
            }
        } else {
            int d0 = (chunk - 4) * 32;
            for (int u = tid; u < 576; u += 256) {
                int cl = u / 18, yy = u - cl * 18;
                int d = d0 + cl;
                int gy = ty0 + yy - 1;
                bool rowok = (d < 48) && (gy >= 0) && (gy < 128);
                const float* srow = cost + ((size_t)(b * 48 + (rowok ? d : 0)) << 14) + (rowok ? gy : 0) * 128;
                for (int xx = 0; xx < 18; ++xx) {
                    int gx = tx0 + xx - 1;
                    float v = (rowok && gx >= 0 && gx < 128) ? srow[gx] : 0.f;
                    s_p[(yy * 18 + xx) * 40 + cl] = f2bf(v);
                }
            }
        }
        __syncthreads();

#pragma unroll 1
        for (int tap = 0; tap < 9; ++tap) {
            int dy = tap / 3, dx = tap - dy * 3;
            const unsigned short* pkt = pk + ((size_t)(chunk * 9 + tap)) * 6 * 512;
            bf16x8 afr[6];
#pragma unroll
            for (int ct = 0; ct < 6; ++ct)
                afr[ct] = *(const bf16x8*)(pkt + ct * 512 + lane * 8);
            bf16x8 bfr[4];
#pragma unroll
            for (int p = 0; p < 4; ++p) {
                int pos = (wid * 4 + p + dy) * 18 + t + dx;
                bfr[p] = *(const bf16x8*)&s_p[pos * 40 + g * 8];
            }
#pragma unroll
            for (int p = 0; p < 4; ++p)
#pragma unroll
                for (int ct = 0; ct < 6; ++ct)
                    acc[p][ct] = __builtin_amdgcn_mfma_f32_16x16x32_bf16(afr[ct], bfr[p], acc[p][ct], 0, 0, 0);
        }
        __syncthreads();
    }

#pragma unroll
    for (int p = 0; p < 4; ++p) {
        int y = ty0 + wid * 4 + p;
#pragma unroll
        for (int ct = 0; ct < 6; ++ct) {
#pragma unroll
            for (int rr = 0; rr < 4; ++rr) {
                int co = ct * 16 + g * 4 + rr;
                if (co < 88) {
                    float v = acc[p][ct][rr] + bias2[co];
                    h1[((size_t)(b * 88 + co) << 14) + y * 128 + tx0 + t] = fmaxf(v, 0.f);
                }
            }
        }
    }
}

// ---------------------------------------------------------------------------
// K6: pv = conv1x1(h1) + b2; softmax over D; pred = 4*sum(d*p). 256 blocks.
__global__ __launch_bounds__(256) void k_head(const float* __restrict__ h1,
                                              const float* __restrict__ w2, const float* __restrict__ b2,
                                              float* __restrict__ out) {
    __shared__ float s_wt[88 * 48];   // [k][d]
    __shared__ float s_b[48];
    int tid = threadIdx.x;
    for (int idx = tid; idx < 48 * 88; idx += 256) {
        int d = idx / 88, k = idx % 88;
        s_wt[k * 48 + d] = w2[idx];
    }
    if (tid < 48) s_b[tid] = b2[tid];
    __syncthreads();
    int px = blockIdx.x * 256 + tid;
    int b = px >> 14, r = px & 16383;
    float acc[48];
#pragma unroll
    for (int d = 0; d < 48; ++d) acc[d] = s_b[d];
    for (int k = 0; k < 88; ++k) {
        float hv = h1[((size_t)(b * 88 + k) << 14) + r];
        const float4* wrow = (const float4*)&s_wt[k * 48];
#pragma unroll
        for (int d4 = 0; d4 < 12; ++d4) {
            float4 wv = wrow[d4];
            acc[d4 * 4 + 0] += hv * wv.x;
            acc[d4 * 4 + 1] += hv * wv.y;
            acc[d4 * 4 + 2] += hv * wv.z;
            acc[d4 * 4 + 3] += hv * wv.w;
        }
    }
    float mx = -1e30f;
#pragma unroll
    for (int d = 0; d < 48; ++d) mx = fmaxf(mx, acc[d]);
    float sum = 0.f, wsum = 0.f;
#pragma unroll
    for (int d = 0; d < 48; ++d) {
        float e = expf(acc[d] - mx);
        sum += e;
        wsum += e * (float)d;
    }
    out[px] = 4.0f * wsum / sum;
}

// ---------------------------------------------------------------------------
extern "C" void kernel_launch(void* const* d_in, const int* in_sizes, int n_in,
                              void* d_out, int out_size, void* d_ws, size_t ws_size,
                              hipStream_t stream) {
    const float* feat_l = (const float*)d_in[0];
    const float* feat_r = (const float*)d_in[1];
    const float* wq = (const float*)d_in[2];
    const float* bq = (const float*)d_in[3];
    const float* wk = (const float*)d_in[4];
    const float* bk = (const float*)d_in[5];
    const float* wv = (const float*)d_in[6];
    const float* bv = (const float*)d_in[7];
    const float* wp = (const float*)d_in[8];
    const float* bp = (const float*)d_in[9];
    const float* rpb = (const float*)d_in[10];
    const float* ln1_g = (const float*)d_in[11];
    const float* ln1_b = (const float*)d_in[12];
    const float* ln2_g = (const float*)d_in[13];
    const float* ln2_b = (const float*)d_in[14];
    const float* mlp_w1 = (const float*)d_in[15];
    const float* mlp_b1 = (const float*)d_in[16];
    const float* mlp_w2 = (const float*)d_in[17];
    // d_in[18] = mlp_b2 is multiplied by 0.0 in the reference -> unused
    const float* un_w1 = (const float*)d_in[19];
    const float* un_b1 = (const float*)d_in[20];
    const float* un_w2 = (const float*)d_in[21];
    const float* un_b2 = (const float*)d_in[22];
    const float* dp_w1 = (const float*)d_in[23];
    const float* dp_b1 = (const float*)d_in[24];
    const float* bn_g = (const float*)d_in[25];
    const float* bn_b = (const float*)d_in[26];
    const float* dp_w2 = (const float*)d_in[27];
    const float* dp_b2 = (const float*)d_in[28];

    float* ws = (float*)d_ws;
    float* cost = ws;                               // 3,145,728 f
    float* x = ws + 3145728;                        // 8,388,608 f
    float* h1 = ws + 11534336;                      // 5,767,168 f
    unsigned short* pk = (unsigned short*)(ws + 17301504);       // 165,888 u16
    float* bias2 = ws + 17384448;                   // 96 f
    unsigned short* pkw = (unsigned short*)(ws + 17384544);      // 65,536 u16
    float* pb = ws + 17417312;                      // 32,768 f
    unsigned short* pm1 = (unsigned short*)(ws + 17450080);      // 65,536 u16
    unsigned short* pm2 = (unsigned short*)(ws + 17482848);      // 65,536 u16
    unsigned short* pu1 = (unsigned short*)(ws + 17515616);      // 16,384 u16
    unsigned short* pu2 = (unsigned short*)(ws + 17523808);      // 16,384 u16
    float* out = (float*)d_out;

    k_pack_all<<<900, 64, 0, stream>>>(dp_w1, dp_b1, bn_g, bn_b, pk, bias2,
                                       wq, wk, wv, wp, pkw, rpb, pb,
                                       mlp_w1, pm1, mlp_w2, pm2,
                                       un_w1, pu1, un_w2, pu2);
    k_cost<<<dim3(2, 64, 4), 384, 0, stream>>>(feat_l, feat_r, cost);
    k_unary_mfma<<<1024, 256, 0, stream>>>(feat_l, pu1, un_b1, pu2, un_b2, x);
    k_attn_mfma<<<1024, 256, 0, stream>>>(feat_l, pkw, pb, bq, bk, bv, bp,
                                          ln1_g, ln1_b, x);
    k_mlp_mfma<<<1024, 256, 0, stream>>>(x, ln2_g, ln2_b, pm1, mlp_b1, pm2);
    k_conv_mfma<<<dim3(8, 8, 4), 256, 0, stream>>>(x, cost, pk, bias2, h1);
    k_head<<<256, 256, 0, stream>>>(h1, dp_w2, dp_b2, out);
}

// Round 6
// 346.397 us; speedup vs baseline: 7.0236x; 1.0275x over previous
//
#include <hip/hip_runtime.h>
#include <math.h>

// Dims
constexpr int Bn = 4, Cc = 128, Hh = 128, Wn = 128, Dd = 48;
constexpr float SCALE = 0.25f;       // 16^-0.5

typedef short  bf16x8 __attribute__((ext_vector_type(8)));
typedef float  f32x4  __attribute__((ext_vector_type(4)));
typedef unsigned short u16x8 __attribute__((ext_vector_type(8)));

static __device__ __forceinline__ float gelu_f(float v) {
    return 0.5f * v * (1.0f + erff(v * 0.70710678118654752f));
}

static __device__ __forceinline__ unsigned short f2bf(float f) {
    unsigned int u = __float_as_uint(f);
    u = (u + 0x7fffu + ((u >> 16) & 1u)) >> 16;   // RNE
    return (unsigned short)u;
}

static __device__ __forceinline__ unsigned int pack2bf(float a, float b) {
    return (unsigned int)f2bf(a) | ((unsigned int)f2bf(b) << 16);
}

// ---------------------------------------------------------------------------
// K1: cost volume, register-blocked band correlation.
__global__ __launch_bounds__(384) void k_cost(const float* __restrict__ fl,
                                              const float* __restrict__ fr,
                                              float* __restrict__ cost) {
    __shared__ float s_fl[2][16][64];
    __shared__ float s_fr[2][16][112];
    int tid = threadIdx.x;
    int w0 = blockIdx.x * 64;
    int hp = blockIdx.y, b = blockIdx.z;
    int row = tid / 192;
    int r = tid - row * 192;
    int wg = r & 15, dg = r >> 4;
    int W = wg * 4, D = dg * 4;
    int h = hp * 2 + row;
    float acc[4][4];
#pragma unroll
    for (int i = 0; i < 4; ++i)
#pragma unroll
        for (int j = 0; j < 4; ++j) acc[i][j] = 0.f;

#pragma unroll 1
    for (int ck = 0; ck < 8; ++ck) {
        int ci0 = ck * 16;
        for (int i = tid; i < 512; i += 384) {
            int rr = i >> 8, rem = i & 255;
            int c = rem >> 4, k4 = rem & 15;
            float4 v = *(const float4*)&fl[((size_t)(b * 128 + ci0 + c) << 14) + (hp * 2 + rr) * 128 + w0 + k4 * 4];
            *(float4*)&s_fl[rr][c][k4 * 4] = v;
        }
        for (int i = tid; i < 896; i += 384) {
            int rr = i / 448, rem = i - rr * 448;
            int c = rem / 28, k4 = rem - c * 28;
            int wgl = w0 - 48 + k4 * 4;
            float4 v = {0.f, 0.f, 0.f, 0.f};
            if (wgl >= 0)
                v = *(const float4*)&fr[((size_t)(b * 128 + ci0 + c) << 14) + (hp * 2 + rr) * 128 + wgl];
            *(float4*)&s_fr[rr][c][k4 * 4] = v;
        }
        __syncthreads();
#pragma unroll
        for (int c = 0; c < 16; ++c) {
            float4 flv = *(const float4*)&s_fl[row][c][W];
            int base = W - D + 44;
            float4 f0 = *(const float4*)&s_fr[row][c][base];
            float4 f1 = *(const float4*)&s_fr[row][c][base + 4];
            float fw[8] = {f0.x, f0.y, f0.z, f0.w, f1.x, f1.y, f1.z, f1.w};
            float fv[4] = {flv.x, flv.y, flv.z, flv.w};
#pragma unroll
            for (int dj = 0; dj < 4; ++dj)
#pragma unroll
                for (int wv = 0; wv < 4; ++wv)
                    acc[dj][wv] += fv[wv] * fw[wv - dj + 4];
        }
        __syncthreads();
    }
    const float inv = 1.0f / 128.0f;
#pragma unroll
    for (int dj = 0; dj < 4; ++dj) {
        float4 o = {acc[dj][0] * inv, acc[dj][1] * inv, acc[dj][2] * inv, acc[dj][3] * inv};
        *(float4*)&cost[((size_t)(b * 48 + D + dj) << 14) + h * 128 + w0 + W] = o;
    }
}

// ---------------------------------------------------------------------------
// Pack helpers fused into one kernel.
static __device__ void pack_conv(int blk, int lane,
                                 const float* __restrict__ w1, const float* __restrict__ b1,
                                 const float* __restrict__ bng, const float* __restrict__ bnb,
                                 unsigned short* __restrict__ pk, float* __restrict__ bias2) {
    const float rs = 0.9999950000374997f;
    int ct = blk % 6;
    int taplin = blk / 6;
    int tap = taplin % 9, chunk = taplin / 9;
    int co = ct * 16 + (lane & 15);
    int cibase = chunk * 32 + (lane >> 4) * 8;
    u16x8 out;
#pragma unroll
    for (int j = 0; j < 8; ++j) {
        int ci = cibase + j;
        float v = 0.f;
        if (co < 88 && ci < 176) v = w1[(size_t)co * 1584 + ci * 9 + tap] * rs * bng[co];
        out[j] = f2bf(v);
    }
    *(u16x8*)(pk + ((size_t)blk * 64 + lane) * 8) = out;
    if (blk == 0) {
        for (int i = lane; i < 96; i += 64)
            bias2[i] = (i < 88) ? (b1[i] * rs * bng[i] + bnb[i]) : 0.f;
    }
}

static __device__ void pack_gemmB(int blk, int lane,
                                  const float* __restrict__ W,
                                  unsigned short* __restrict__ out, int ncols) {
    int ntiles = ncols >> 4;
    int ks = blk & 3;
    int nt = (blk >> 2) % ntiles;
    int kc = blk / (4 * ntiles);
    int col = nt * 16 + (lane & 15);
    int k0 = kc * 128 + ks * 32 + (lane >> 4) * 8;
    u16x8 o;
#pragma unroll
    for (int j = 0; j < 8; ++j) o[j] = f2bf(W[(size_t)(k0 + j) * ncols + col]);
    *(u16x8*)(out + ((size_t)blk * 64 + lane) * 8) = o;
}

static __device__ void pack_rpb(int blk, int lane,
                                const float* __restrict__ rpb, float* __restrict__ pb) {
    int nt = blk & 3, mt = (blk >> 2) & 3, hh = blk >> 4;
    int m = nt * 16 + (lane & 15);
    int g = lane >> 4;
    float o[4];
#pragma unroll
    for (int rr = 0; rr < 4; ++rr) {
        int n = mt * 16 + g * 4 + rr;
        int relidx = (((n >> 3) - (m >> 3)) + 7) * 15 + ((n & 7) - (m & 7)) + 7;
        o[rr] = rpb[relidx * 8 + hh];
    }
    float4 v = {o[0], o[1], o[2], o[3]};
    *(float4*)(pb + ((size_t)blk * 64 + lane) * 4) = v;
}

__global__ __launch_bounds__(64) void k_pack_all(
        const float* __restrict__ dp_w1, const float* __restrict__ dp_b1,
        const float* __restrict__ bn_g, const float* __restrict__ bn_b,
        unsigned short* __restrict__ pk, float* __restrict__ bias2,
        const float* __restrict__ wq, const float* __restrict__ wk,
        const float* __restrict__ wv, const float* __restrict__ wp,
        unsigned short* __restrict__ pkw,
        const float* __restrict__ rpb, float* __restrict__ pb,
        const float* __restrict__ mlp_w1, unsigned short* __restrict__ pm1,
        const float* __restrict__ mlp_w2, unsigned short* __restrict__ pm2,
        const float* __restrict__ un_w1, unsigned short* __restrict__ pu1,
        const float* __restrict__ un_w2, unsigned short* __restrict__ pu2) {
    int blk = blockIdx.x;
    int lane = threadIdx.x;
    if (blk < 324) {
        pack_conv(blk, lane, dp_w1, dp_b1, bn_g, bn_b, pk, bias2);
    } else if (blk < 452) {
        int bb = blk - 324;
        int mat = bb >> 5;
        const float* W = (mat == 0) ? wq : (mat == 1) ? wk : (mat == 2) ? wv : wp;
        pack_gemmB(bb & 31, lane, W, pkw + (size_t)mat * 16384, 128);
    } else if (blk < 580) {
        pack_rpb(blk - 452, lane, rpb, pb);
    } else if (blk < 708) {
        pack_gemmB(blk - 580, lane, mlp_w1, pm1, 512);
    } else if (blk < 836) {
        pack_gemmB(blk - 708, lane, mlp_w2, pm2, 128);
    } else if (blk < 868) {
        pack_gemmB(blk - 836, lane, un_w1, pu1, 128);
    } else {
        pack_gemmB(blk - 868, lane, un_w2, pu2, 128);
    }
}

// ---------------------------------------------------------------------------
// K3: attention core (no proj). 1024 blocks (1 window), 256 threads (4 waves).
// Wave w handles heads {w, w+4}; writes normalized o (bf16) to global.
__global__ __launch_bounds__(256, 3) void k_attn_core(const float* __restrict__ feat_l,
                                                      const unsigned short* __restrict__ pkw,
                                                      const float* __restrict__ pb,
                                                      const float* __restrict__ bq,
                                                      const float* __restrict__ bk,
                                                      const float* __restrict__ bv,
                                                      const float* __restrict__ g1,
                                                      const float* __restrict__ bt1,
                                                      unsigned short* __restrict__ o) {
    // 50176 B total. Phase A: s_nf[64][136] bf16 (17408 B) at offset 0.
    // Phase B (after reg hoist): per-wave scratch 12544 B each:
    //   sQ[64][40] | sK[64][40] | sV[16][72] ; sP[64][72] overlays sQ+sK.
    __shared__ __align__(16) unsigned short s_all[25088];
    int tid = threadIdx.x;
    int wid = tid >> 6, lane = tid & 63;
    int g = lane >> 4, t = lane & 15;
    int bw = blockIdx.x;
    int b = bw >> 8, wh = (bw >> 4) & 15, ww = bw & 15;
    unsigned short* s_nf = s_all;

    // ---- LayerNorm directly from global (4 lanes per token, 32 ch each) ----
    {
        int tok = tid >> 2, q = tid & 3;
        int hy = wh * 8 + (tok >> 3), wx = ww * 8 + (tok & 7);
        const float* basep = feat_l + (((size_t)(b * 128 + q * 32)) << 14) + hy * 128 + wx;
        float v[32];
#pragma unroll
        for (int i = 0; i < 32; ++i) v[i] = basep[(size_t)i << 14];
        float s = 0.f, s2 = 0.f;
#pragma unroll
        for (int i = 0; i < 32; ++i) { s += v[i]; s2 += v[i] * v[i]; }
        s += __shfl_xor(s, 1); s += __shfl_xor(s, 2);
        s2 += __shfl_xor(s2, 1); s2 += __shfl_xor(s2, 2);
        float mean = s * (1.f / 128.f);
        float var = s2 * (1.f / 128.f) - mean * mean;
        float rstd = rsqrtf(var + 1e-5f);
#pragma unroll
        for (int i = 0; i < 32; i += 2) {
            int c = q * 32 + i;
            float v0 = (v[i] - mean) * rstd * g1[c] + bt1[c];
            float v1 = (v[i + 1] - mean) * rstd * g1[c + 1] + bt1[c + 1];
            *(unsigned int*)&s_nf[tok * 136 + c] = pack2bf(v0, v1);
        }
    }
    __syncthreads();
    // ---- hoist X A-fragments to registers ----
    bf16x8 af[4][4];   // [Mt][ks]
#pragma unroll
    for (int Mt = 0; Mt < 4; ++Mt)
#pragma unroll
        for (int ks = 0; ks < 4; ++ks)
            af[Mt][ks] = *(const bf16x8*)&s_nf[(Mt * 16 + t) * 136 + ks * 32 + g * 8];
    __syncthreads();   // s_nf dead; s_all becomes per-wave scratch

    unsigned short* sQ = s_all + wid * 6272;
    unsigned short* sK = sQ + 2560;
    unsigned short* sV = sQ + 5120;
    unsigned short* sP = sQ;

#pragma unroll 1
    for (int hi = 0; hi < 2; ++hi) {
        int h = wid + hi * 4;
        u16x8 z8 = {0, 0, 0, 0, 0, 0, 0, 0};
        *(u16x8*)&sQ[lane * 40 + 16] = z8;
        *(u16x8*)&sQ[lane * 40 + 24] = z8;
        *(u16x8*)&sK[lane * 40 + 16] = z8;
        *(u16x8*)&sK[lane * 40 + 24] = z8;

        float bqv = bq[h * 16 + t], bkv = bk[h * 16 + t], bvv = bv[h * 16 + t];
        f32x4 qa[4], ka[4], va[4];
#pragma unroll
        for (int Mt = 0; Mt < 4; ++Mt) {
            qa[Mt] = (f32x4){bqv, bqv, bqv, bqv};
            ka[Mt] = (f32x4){bkv, bkv, bkv, bkv};
            va[Mt] = (f32x4){bvv, bvv, bvv, bvv};
        }
#pragma unroll
        for (int ks = 0; ks < 4; ++ks) {
            const unsigned short* wbase = pkw + ((size_t)((h * 4 + ks) * 64 + lane) * 8);
            bf16x8 bfq = *(const bf16x8*)(wbase);
            bf16x8 bfk = *(const bf16x8*)(wbase + 16384);
            bf16x8 bfv = *(const bf16x8*)(wbase + 32768);
#pragma unroll
            for (int Mt = 0; Mt < 4; ++Mt) {
                qa[Mt] = __builtin_amdgcn_mfma_f32_16x16x32_bf16(af[Mt][ks], bfq, qa[Mt], 0, 0, 0);
                ka[Mt] = __builtin_amdgcn_mfma_f32_16x16x32_bf16(af[Mt][ks], bfk, ka[Mt], 0, 0, 0);
                va[Mt] = __builtin_amdgcn_mfma_f32_16x16x32_bf16(af[Mt][ks], bfv, va[Mt], 0, 0, 0);
            }
        }
#pragma unroll
        for (int Mt = 0; Mt < 4; ++Mt)
#pragma unroll
            for (int rr = 0; rr < 4; ++rr) {
                int tok = Mt * 16 + g * 4 + rr;
                sQ[tok * 40 + t] = f2bf(qa[Mt][rr] * SCALE);
                sK[tok * 40 + t] = f2bf(ka[Mt][rr]);
                sV[t * 72 + tok] = f2bf(va[Mt][rr]);
            }

        // ---- S = Q K^T + bias(C-init) ----
        f32x4 s[4][4];
#pragma unroll
        for (int Mt = 0; Mt < 4; ++Mt)
#pragma unroll
            for (int Nt = 0; Nt < 4; ++Nt)
                s[Mt][Nt] = *(const f32x4*)(pb + ((size_t)((h * 16 + Mt * 4 + Nt) * 64 + lane) * 4));
        bf16x8 bk2[4];
#pragma unroll
        for (int Nt = 0; Nt < 4; ++Nt) bk2[Nt] = *(const bf16x8*)&sK[(Nt * 16 + t) * 40 + g * 8];
#pragma unroll
        for (int Mt = 0; Mt < 4; ++Mt) {
            bf16x8 aq = *(const bf16x8*)&sQ[(Mt * 16 + t) * 40 + g * 8];
#pragma unroll
            for (int Nt = 0; Nt < 4; ++Nt)
                s[Mt][Nt] = __builtin_amdgcn_mfma_f32_16x16x32_bf16(aq, bk2[Nt], s[Mt][Nt], 0, 0, 0);
        }

        // ---- softmax (unnormalized; divide at o write) ----
        f32x4 rsm[4];
#pragma unroll
        for (int Mt = 0; Mt < 4; ++Mt) {
            f32x4 m = s[Mt][0];
#pragma unroll
            for (int Nt = 1; Nt < 4; ++Nt)
#pragma unroll
                for (int rr = 0; rr < 4; ++rr) m[rr] = fmaxf(m[rr], s[Mt][Nt][rr]);
#pragma unroll
            for (int sh = 1; sh <= 8; sh <<= 1)
#pragma unroll
                for (int rr = 0; rr < 4; ++rr) m[rr] = fmaxf(m[rr], __shfl_xor(m[rr], sh));
            f32x4 sum = (f32x4){0.f, 0.f, 0.f, 0.f};
#pragma unroll
            for (int Nt = 0; Nt < 4; ++Nt)
#pragma unroll
                for (int rr = 0; rr < 4; ++rr) {
                    float e = __expf(s[Mt][Nt][rr] - m[rr]);
                    s[Mt][Nt][rr] = e;
                    sum[rr] += e;
                }
#pragma unroll
            for (int sh = 1; sh <= 8; sh <<= 1)
#pragma unroll
                for (int rr = 0; rr < 4; ++rr) sum[rr] += __shfl_xor(sum[rr], sh);
            rsm[Mt] = sum;
        }
#pragma unroll
        for (int Mt = 0; Mt < 4; ++Mt)
#pragma unroll
            for (int Nt = 0; Nt < 4; ++Nt)
#pragma unroll
                for (int rr = 0; rr < 4; ++rr)
                    sP[(Mt * 16 + g * 4 + rr) * 72 + Nt * 16 + t] = f2bf(s[Mt][Nt][rr]);

        // ---- O = P @ V, normalize, write to global o ----
        f32x4 oa[4];
#pragma unroll
        for (int Mt = 0; Mt < 4; ++Mt) oa[Mt] = (f32x4){0.f, 0.f, 0.f, 0.f};
#pragma unroll
        for (int ksv = 0; ksv < 2; ++ksv) {
            bf16x8 bv2 = *(const bf16x8*)&sV[t * 72 + ksv * 32 + g * 8];
#pragma unroll
            for (int Mt = 0; Mt < 4; ++Mt) {
                bf16x8 ap = *(const bf16x8*)&sP[(Mt * 16 + t) * 72 + ksv * 32 + g * 8];
                oa[Mt] = __builtin_amdgcn_mfma_f32_16x16x32_bf16(ap, bv2, oa[Mt], 0, 0, 0);
            }
        }
#pragma unroll
        for (int Mt = 0; Mt < 4; ++Mt)
#pragma unroll
            for (int rr = 0; rr < 4; ++rr) {
                int tok = Mt * 16 + g * 4 + rr;
                int hy = wh * 8 + (tok >> 3), wx = ww * 8 + (tok & 7);
                o[((size_t)(b * 16384) + hy * 128 + wx) * 128 + h * 16 + t] = f2bf(oa[Mt][rr] / rsm[Mt][rr]);
            }
    }
}

// ---------------------------------------------------------------------------
// K2: unary MLP via MFMA. 1024 blocks x 64 tokens, 256 threads (4 waves).
__global__ __launch_bounds__(256) void k_unary_mfma(const float* __restrict__ feat_l,
                                                    const unsigned short* __restrict__ pu1,
                                                    const float* __restrict__ b1,
                                                    const unsigned short* __restrict__ pu2,
                                                    const float* __restrict__ b2,
                                                    float* __restrict__ x) {
    __shared__ __align__(16) unsigned short s_a[64 * 136];
    __shared__ __align__(16) unsigned short s_h[64 * 136];
    int tid = threadIdx.x;
    int wid = tid >> 6, lane = tid & 63;
    int g = lane >> 4, t = lane & 15;
    int n0g = blockIdx.x * 64;
    int b = n0g >> 14;
    int nb = n0g & 16383;

    for (int idx = tid; idx < 4096; idx += 256) {
        int c2 = idx >> 6, nl = idx & 63;
        float v0 = feat_l[((size_t)(b * 128 + 2 * c2) << 14) + nb + nl];
        float v1 = feat_l[((size_t)(b * 128 + 2 * c2 + 1) << 14) + nb + nl];
        *(unsigned int*)&s_a[nl * 136 + 2 * c2] = pack2bf(v0, v1);
    }
    __syncthreads();

    bf16x8 af[4][4];
#pragma unroll
    for (int Mt = 0; Mt < 4; ++Mt)
#pragma unroll
        for (int ks = 0; ks < 4; ++ks)
            af[Mt][ks] = *(const bf16x8*)&s_a[(Mt * 16 + t) * 136 + ks * 32 + g * 8];

    f32x4 acc1[4][2];
#pragma unroll
    for (int nt2 = 0; nt2 < 2; ++nt2) {
        float bv = b1[(wid * 2 + nt2) * 16 + t];
#pragma unroll
        for (int Mt = 0; Mt < 4; ++Mt) acc1[Mt][nt2] = (f32x4){bv, bv, bv, bv};
    }
#pragma unroll
    for (int ks = 0; ks < 4; ++ks) {
        bf16x8 bf0 = *(const bf16x8*)(pu1 + (size_t)(((wid * 2 + 0) * 4 + ks) * 64 + lane) * 8);
        bf16x8 bf1 = *(const bf16x8*)(pu1 + (size_t)(((wid * 2 + 1) * 4 + ks) * 64 + lane) * 8);
#pragma unroll
        for (int Mt = 0; Mt < 4; ++Mt) {
            acc1[Mt][0] = __builtin_amdgcn_mfma_f32_16x16x32_bf16(af[Mt][ks], bf0, acc1[Mt][0], 0, 0, 0);
            acc1[Mt][1] = __builtin_amdgcn_mfma_f32_16x16x32_bf16(af[Mt][ks], bf1, acc1[Mt][1], 0, 0, 0);
        }
    }
#pragma unroll
    for (int Mt = 0; Mt < 4; ++Mt)
#pragma unroll
        for (int nt2 = 0; nt2 < 2; ++nt2)
#pragma unroll
            for (int rr = 0; rr < 4; ++rr)
                s_h[(Mt * 16 + g * 4 + rr) * 136 + (wid * 2 + nt2) * 16 + t] = f2bf(gelu_f(acc1[Mt][nt2][rr]));
    __syncthreads();

    bf16x8 a2[4][4];
#pragma unroll
    for (int Mt = 0; Mt < 4; ++Mt)
#pragma unroll
        for (int ks = 0; ks < 4; ++ks)
            a2[Mt][ks] = *(const bf16x8*)&s_h[(Mt * 16 + t) * 136 + ks * 32 + g * 8];

    f32x4 acc2[4][2];
#pragma unroll
    for (int nt2 = 0; nt2 < 2; ++nt2) {
        float bv = b2[(wid * 2 + nt2) * 16 + t];
#pragma unroll
        for (int Mt = 0; Mt < 4; ++Mt) acc2[Mt][nt2] = (f32x4){bv, bv, bv, bv};
    }
#pragma unroll
    for (int ks = 0; ks < 4; ++ks) {
        bf16x8 bf0 = *(const bf16x8*)(pu2 + (size_t)(((wid * 2 + 0) * 4 + ks) * 64 + lane) * 8);
        bf16x8 bf1 = *(const bf16x8*)(pu2 + (size_t)(((wid * 2 + 1) * 4 + ks) * 64 + lane) * 8);
#pragma unroll
        for (int Mt = 0; Mt < 4; ++Mt) {
            acc2[Mt][0] = __builtin_amdgcn_mfma_f32_16x16x32_bf16(a2[Mt][ks], bf0, acc2[Mt][0], 0, 0, 0);
            acc2[Mt][1] = __builtin_amdgcn_mfma_f32_16x16x32_bf16(a2[Mt][ks], bf1, acc2[Mt][1], 0, 0, 0);
        }
    }
#pragma unroll
    for (int Mt = 0; Mt < 4; ++Mt)
#pragma unroll
        for (int nt2 = 0; nt2 < 2; ++nt2)
#pragma unroll
            for (int rr = 0; rr < 4; ++rr) {
                int tok = Mt * 16 + g * 4 + rr;
                x[(size_t)(n0g + tok) * 128 + (wid * 2 + nt2) * 16 + t] = acc2[Mt][nt2][rr];
            }
}

// ---------------------------------------------------------------------------
// K4: x = (x + o@wp + bp) + mlp(LN2(...)). GEMM0 fused as proj.
// (mlp_b2 * 0 in ref -> not added)
__global__ __launch_bounds__(256) void k_mlp_mfma(float* __restrict__ x,
                                                  const unsigned short* __restrict__ o,
                                                  const unsigned short* __restrict__ pkw,
                                                  const float* __restrict__ bp,
                                                  const float* __restrict__ g2,
                                                  const float* __restrict__ bt2,
                                                  const unsigned short* __restrict__ pm1,
                                                  const float* __restrict__ b1,
                                                  const unsigned short* __restrict__ pm2) {
    __shared__ __align__(16) char smem[51200];
    float* sf = (float*)smem;                       // [64][132] f32
    unsigned short* s_h = (unsigned short*)smem;    // overlays sf after LN
    unsigned short* s_a = (unsigned short*)(smem + 33792);
    int tid = threadIdx.x;
    int wid = tid >> 6, lane = tid & 63;
    int g = lane >> 4, t = lane & 15;
    int n0g = blockIdx.x * 64;

    // GEMM0: out = o_tile @ wp + bp  (out doubles as final accumulator)
    f32x4 out[4][2];
    {
        float bp0 = bp[wid * 32 + t], bp1 = bp[wid * 32 + 16 + t];
#pragma unroll
        for (int Mt = 0; Mt < 4; ++Mt) {
            out[Mt][0] = (f32x4){bp0, bp0, bp0, bp0};
            out[Mt][1] = (f32x4){bp1, bp1, bp1, bp1};
        }
#pragma unroll
        for (int ks = 0; ks < 4; ++ks) {
            bf16x8 b0 = *(const bf16x8*)(pkw + 49152 + (size_t)(((wid * 2 + 0) * 4 + ks) * 64 + lane) * 8);
            bf16x8 b1v = *(const bf16x8*)(pkw + 49152 + (size_t)(((wid * 2 + 1) * 4 + ks) * 64 + lane) * 8);
#pragma unroll
            for (int Mt = 0; Mt < 4; ++Mt) {
                bf16x8 a = *(const bf16x8*)&o[(size_t)(n0g + Mt * 16 + t) * 128 + ks * 32 + g * 8];
                out[Mt][0] = __builtin_amdgcn_mfma_f32_16x16x32_bf16(a, b0, out[Mt][0], 0, 0, 0);
                out[Mt][1] = __builtin_amdgcn_mfma_f32_16x16x32_bf16(a, b1v, out[Mt][1], 0, 0, 0);
            }
        }
        // add unary x; stash x_pre_mlp into sf for LN
#pragma unroll
        for (int Mt = 0; Mt < 4; ++Mt)
#pragma unroll
            for (int nt2 = 0; nt2 < 2; ++nt2)
#pragma unroll
                for (int rr = 0; rr < 4; ++rr) {
                    int tok = Mt * 16 + g * 4 + rr;
                    int col = (wid * 2 + nt2) * 16 + t;
                    float v = out[Mt][nt2][rr] + x[(size_t)(n0g + tok) * 128 + col];
                    out[Mt][nt2][rr] = v;
                    sf[tok * 132 + col] = v;
                }
    }
    __syncthreads();
    // LN -> bf16 s_a
    {
        int tok = tid >> 2, q = tid & 3;
        float s = 0.f, s2 = 0.f;
        for (int c = q * 32; c < q * 32 + 32; ++c) {
            float v = sf[tok * 132 + c];
            s += v; s2 += v * v;
        }
        s += __shfl_xor(s, 1); s += __shfl_xor(s, 2);
        s2 += __shfl_xor(s2, 1); s2 += __shfl_xor(s2, 2);
        float mean = s * (1.f / 128.f);
        float var = s2 * (1.f / 128.f) - mean * mean;
        float rstd = rsqrtf(var + 1e-5f);
        for (int c = q * 32; c < q * 32 + 32; c += 2) {
            float v0 = (sf[tok * 132 + c] - mean) * rstd * g2[c] + bt2[c];
            float v1 = (sf[tok * 132 + c + 1] - mean) * rstd * g2[c + 1] + bt2[c + 1];
            *(unsigned int*)&s_a[tok * 136 + c] = pack2bf(v0, v1);
        }
    }
    __syncthreads();
    bf16x8 af[4][4];
#pragma unroll
    for (int Mt = 0; Mt < 4; ++Mt)
#pragma unroll
        for (int ks = 0; ks < 4; ++ks)
            af[Mt][ks] = *(const bf16x8*)&s_a[(Mt * 16 + t) * 136 + ks * 32 + g * 8];

#pragma unroll 1
    for (int hc = 0; hc < 4; ++hc) {
        f32x4 acc1[4][2];
#pragma unroll
        for (int nt2 = 0; nt2 < 2; ++nt2) {
            float bv = b1[hc * 128 + (wid * 2 + nt2) * 16 + t];
#pragma unroll
            for (int Mt = 0; Mt < 4; ++Mt) acc1[Mt][nt2] = (f32x4){bv, bv, bv, bv};
        }
#pragma unroll
        for (int ks = 0; ks < 4; ++ks) {
            bf16x8 bf0 = *(const bf16x8*)(pm1 + (size_t)(((hc * 8 + wid * 2 + 0) * 4 + ks) * 64 + lane) * 8);
            bf16x8 bf1 = *(const bf16x8*)(pm1 + (size_t)(((hc * 8 + wid * 2 + 1) * 4 + ks) * 64 + lane) * 8);
#pragma unroll
            for (int Mt = 0; Mt < 4; ++Mt) {
                acc1[Mt][0] = __builtin_amdgcn_mfma_f32_16x16x32_bf16(af[Mt][ks], bf0, acc1[Mt][0], 0, 0, 0);
                acc1[Mt][1] = __builtin_amdgcn_mfma_f32_16x16x32_bf16(af[Mt][ks], bf1, acc1[Mt][1], 0, 0, 0);
            }
        }
#pragma unroll
        for (int Mt = 0; Mt < 4; ++Mt)
#pragma unroll
            for (int nt2 = 0; nt2 < 2; ++nt2)
#pragma unroll
                for (int rr = 0; rr < 4; ++rr)
                    s_h[(Mt * 16 + g * 4 + rr) * 136 + (wid * 2 + nt2) * 16 + t] = f2bf(gelu_f(acc1[Mt][nt2][rr]));
        __syncthreads();
        bf16x8 a2[4][4];
#pragma unroll
        for (int Mt = 0; Mt < 4; ++Mt)
#pragma unroll
            for (int ks = 0; ks < 4; ++ks)
                a2[Mt][ks] = *(const bf16x8*)&s_h[(Mt * 16 + t) * 136 + ks * 32 + g * 8];
#pragma unroll
        for (int ks = 0; ks < 4; ++ks) {
            bf16x8 bf0 = *(const bf16x8*)(pm2 + (size_t)((hc * 32 + (wid * 2 + 0) * 4 + ks) * 64 + lane) * 8);
            bf16x8 bf1 = *(const bf16x8*)(pm2 + (size_t)((hc * 32 + (wid * 2 + 1) * 4 + ks) * 64 + lane) * 8);
#pragma unroll
            for (int Mt = 0; Mt < 4; ++Mt) {
                out[Mt][0] = __builtin_amdgcn_mfma_f32_16x16x32_bf16(a2[Mt][ks], bf0, out[Mt][0], 0, 0, 0);
                out[Mt][1] = __builtin_amdgcn_mfma_f32_16x16x32_bf16(a2[Mt][ks], bf1, out[Mt][1], 0, 0, 0);
            }
        }
        __syncthreads();
    }

    // final: x = x_pre_mlp + mlp_out  (pure store; out already holds both)
#pragma unroll
    for (int Mt = 0; Mt < 4; ++Mt)
#pragma unroll
        for (int nt2 = 0; nt2 < 2; ++nt2)
#pragma unroll
            for (int rr = 0; rr < 4; ++rr) {
                int tok = Mt * 16 + g * 4 + rr;
                size_t addr = (size_t)(n0g + tok) * 128 + (wid * 2 + nt2) * 16 + t;
                x[addr] = out[Mt][nt2][rr];
            }
}

// ---------------------------------------------------------------------------
// K5b: conv3x3 as bf16 implicit-GEMM MFMA. grid (8,8,4), 256 threads.
__global__ __launch_bounds__(256) void k_conv_mfma(const float* __restrict__ x,
                                                   const float* __restrict__ cost,
                                                   const unsigned short* __restrict__ pk,
                                                   const float* __restrict__ bias2,
                                                   float* __restrict__ h1) {
    __shared__ __align__(16) unsigned short s_p[324 * 40];
    int tid = threadIdx.x;
    int wid = tid >> 6, lane = tid & 63;
    int g = lane >> 4, t = lane & 15;
    int tx0 = blockIdx.x * 16, ty0 = blockIdx.y * 16, b = blockIdx.z;

    f32x4 acc[4][6];
#pragma unroll
    for (int p = 0; p < 4; ++p)
#pragma unroll
        for (int ct = 0; ct < 6; ++ct) acc[p][ct] = (f32x4){0.f, 0.f, 0.f, 0.f};

#pragma unroll 1
    for (int chunk = 0; chunk < 6; ++chunk) {
        if (chunk < 4) {
            int ci0 = chunk * 32;
            for (int u = tid; u < 648; u += 256) {
                int pos = u >> 1, half = u & 1;
                int yy = pos / 18, xx = pos - yy * 18;
                int gy = ty0 + yy - 1, gx = tx0 + xx - 1;
                u16x8 lo, hi;
                if (gy >= 0 && gy < 128 && gx >= 0 && gx < 128) {
                    const float4* src = (const float4*)&x[((size_t)(b << 14) + gy * 128 + gx) * 128 + ci0 + half * 16];
                    float4 v0 = src[0], v1 = src[1], v2 = src[2], v3 = src[3];
                    lo[0] = f2bf(v0.x); lo[1] = f2bf(v0.y); lo[2] = f2bf(v0.z); lo[3] = f2bf(v0.w);
                    lo[4] = f2bf(v1.x); lo[5] = f2bf(v1.y); lo[6] = f2bf(v1.z); lo[7] = f2bf(v1.w);
                    hi[0] = f2bf(v2.x); hi[1] = f2bf(v2.y); hi[2] = f2bf(v2.z); hi[3] = f2bf(v2.w);
                    hi[4] = f2bf(v3.x); hi[5] = f2bf(v3.y); hi[6] = f2bf(v3.z); hi[7] = f2bf(v3.w);
                } else {
                    lo = (u16x8)(unsigned short)0; hi = (u16x8)(unsigned short)0;
                }
                unsigned short* dst = &s_p[pos * 40 + half * 16];
                *(u16x8*)dst = lo;
                *(u16x8*)(dst + 8) = hi;
            }
        } else {
            int d0 = (chunk - 4) * 32;
            for (int u = tid; u < 576; u += 256) {
                int cl = u / 18, yy = u - cl * 18;
                int d = d0 + cl;
                int gy = ty0 + yy - 1;
                bool rowok = (d < 48) && (gy >= 0) && (gy < 128);
                const float* srow = cost + ((size_t)(b * 48 + (rowok ? d : 0)) << 14) + (rowok ? gy : 0) * 128;
                for (int xx = 0; xx < 18; ++xx) {
                    int gx = tx0 + xx - 1;
                    float v = (rowok && gx >= 0 && gx < 128) ? srow[gx] : 0.f;
                    s_p[(yy * 18 + xx) * 40 + cl] = f2bf(v);
                }
            }
        }
        __syncthreads();

#pragma unroll 1
        for (int tap = 0; tap < 9; ++tap) {
            int dy = tap / 3, dx = tap - dy * 3;
            const unsigned short* pkt = pk + ((size_t)(chunk * 9 + tap)) * 6 * 512;
            bf16x8 afr[6];
#pragma unroll
            for (int ct = 0; ct < 6; ++ct)
                afr[ct] = *(const bf16x8*)(pkt + ct * 512 + lane * 8);
            bf16x8 bfr[4];
#pragma unroll
            for (int p = 0; p < 4; ++p) {
                int pos = (wid * 4 + p + dy) * 18 + t + dx;
                bfr[p] = *(const bf16x8*)&s_p[pos * 40 + g * 8];
            }
#pragma unroll
            for (int p = 0; p < 4; ++p)
#pragma unroll
                for (int ct = 0; ct < 6; ++ct)
                    acc[p][ct] = __builtin_amdgcn_mfma_f32_16x16x32_bf16(afr[ct], bfr[p], acc[p][ct], 0, 0, 0);
        }
        __syncthreads();
    }

#pragma unroll
    for (int p = 0; p < 4; ++p) {
        int y = ty0 + wid * 4 + p;
#pragma unroll
        for (int ct = 0; ct < 6; ++ct) {
#pragma unroll
            for (int rr = 0; rr < 4; ++rr) {
                int co = ct * 16 + g * 4 + rr;
                if (co < 88) {
                    float v = acc[p][ct][rr] + bias2[co];
                    h1[((size_t)(b * 88 + co) << 14) + y * 128 + tx0 + t] = fmaxf(v, 0.f);
                }
            }
        }
    }
}

// ---------------------------------------------------------------------------
// K6: pv = conv1x1(h1) + b2; softmax over D; pred = 4*sum(d*p). 256 blocks.
__global__ __launch_bounds__(256) void k_head(const float* __restrict__ h1,
                                              const float* __restrict__ w2, const float* __restrict__ b2,
                                              float* __restrict__ out) {
    __shared__ float s_wt[88 * 48];   // [k][d]
    __shared__ float s_b[48];
    int tid = threadIdx.x;
    for (int idx = tid; idx < 48 * 88; idx += 256) {
        int d = idx / 88, k = idx % 88;
        s_wt[k * 48 + d] = w2[idx];
    }
    if (tid < 48) s_b[tid] = b2[tid];
    __syncthreads();
    int px = blockIdx.x * 256 + tid;
    int b = px >> 14, r = px & 16383;
    float acc[48];
#pragma unroll
    for (int d = 0; d < 48; ++d) acc[d] = s_b[d];
    for (int k = 0; k < 88; ++k) {
        float hv = h1[((size_t)(b * 88 + k) << 14) + r];
        const float4* wrow = (const float4*)&s_wt[k * 48];
#pragma unroll
        for (int d4 = 0; d4 < 12; ++d4) {
            float4 wv = wrow[d4];
            acc[d4 * 4 + 0] += hv * wv.x;
            acc[d4 * 4 + 1] += hv * wv.y;
            acc[d4 * 4 + 2] += hv * wv.z;
            acc[d4 * 4 + 3] += hv * wv.w;
        }
    }
    float mx = -1e30f;
#pragma unroll
    for (int d = 0; d < 48; ++d) mx = fmaxf(mx, acc[d]);
    float sum = 0.f, wsum = 0.f;
#pragma unroll
    for (int d = 0; d < 48; ++d) {
        float e = expf(acc[d] - mx);
        sum += e;
        wsum += e * (float)d;
    }
    out[px] = 4.0f * wsum / sum;
}

// ---------------------------------------------------------------------------
extern "C" void kernel_launch(void* const* d_in, const int* in_sizes, int n_in,
                              void* d_out, int out_size, void* d_ws, size_t ws_size,
                              hipStream_t stream) {
    const float* feat_l = (const float*)d_in[0];
    const float* feat_r = (const float*)d_in[1];
    const float* wq = (const float*)d_in[2];
    const float* bq = (const float*)d_in[3];
    const float* wk = (const float*)d_in[4];
    const float* bk = (const float*)d_in[5];
    const float* wv = (const float*)d_in[6];
    const float* bv = (const float*)d_in[7];
    const float* wp = (const float*)d_in[8];
    const float* bp = (const float*)d_in[9];
    const float* rpb = (const float*)d_in[10];
    const float* ln1_g = (const float*)d_in[11];
    const float* ln1_b = (const float*)d_in[12];
    const float* ln2_g = (const float*)d_in[13];
    const float* ln2_b = (const float*)d_in[14];
    const float* mlp_w1 = (const float*)d_in[15];
    const float* mlp_b1 = (const float*)d_in[16];
    const float* mlp_w2 = (const float*)d_in[17];
    // d_in[18] = mlp_b2 is multiplied by 0.0 in the reference -> unused
    const float* un_w1 = (const float*)d_in[19];
    const float* un_b1 = (const float*)d_in[20];
    const float* un_w2 = (const float*)d_in[21];
    const float* un_b2 = (const float*)d_in[22];
    const float* dp_w1 = (const float*)d_in[23];
    const float* dp_b1 = (const float*)d_in[24];
    const float* bn_g = (const float*)d_in[25];
    const float* bn_b = (const float*)d_in[26];
    const float* dp_w2 = (const float*)d_in[27];
    const float* dp_b2 = (const float*)d_in[28];

    float* ws = (float*)d_ws;
    float* cost = ws;                               // 3,145,728 f
    float* x = ws + 3145728;                        // 8,388,608 f
    float* h1 = ws + 11534336;                      // 5,767,168 f
    // o (attn output, bf16, 16 MB) overlays h1: o is dead before conv writes h1.
    unsigned short* o_ws = (unsigned short*)h1;
    unsigned short* pk = (unsigned short*)(ws + 17301504);       // 165,888 u16
    float* bias2 = ws + 17384448;                   // 96 f
    unsigned short* pkw = (unsigned short*)(ws + 17384544);      // 65,536 u16
    float* pb = ws + 17417312;                      // 32,768 f
    unsigned short* pm1 = (unsigned short*)(ws + 17450080);      // 65,536 u16
    unsigned short* pm2 = (unsigned short*)(ws + 17482848);      // 65,536 u16
    unsigned short* pu1 = (unsigned short*)(ws + 17515616);      // 16,384 u16
    unsigned short* pu2 = (unsigned short*)(ws + 17523808);      // 16,384 u16
    float* out = (float*)d_out;

    k_pack_all<<<900, 64, 0, stream>>>(dp_w1, dp_b1, bn_g, bn_b, pk, bias2,
                                       wq, wk, wv, wp, pkw, rpb, pb,
                                       mlp_w1, pm1, mlp_w2, pm2,
                                       un_w1, pu1, un_w2, pu2);
    k_cost<<<dim3(2, 64, 4), 384, 0, stream>>>(feat_l, feat_r, cost);
    k_attn_core<<<1024, 256, 0, stream>>>(feat_l, pkw, pb, bq, bk, bv,
                                          ln1_g, ln1_b, o_ws);
    k_unary_mfma<<<1024, 256, 0, stream>>>(feat_l, pu1, un_b1, pu2, un_b2, x);
    k_mlp_mfma<<<1024, 256, 0, stream>>>(x, o_ws, pkw, bp, ln2_g, ln2_b,
                                         pm1, mlp_b1, pm2);
    k_conv_mfma<<<dim3(8, 8, 4), 256, 0, stream>>>(x, cost, pk, bias2, h1);
    k_head<<<256, 256, 0, stream>>>(h1, dp_w2, dp_b2, out);
}

// Round 7
// 336.773 us; speedup vs baseline: 7.2243x; 1.0286x over previous
//
#include <hip/hip_runtime.h>
#include <math.h>

// Dims
constexpr int Bn = 4, Cc = 128, Hh = 128, Wn = 128, Dd = 48;
constexpr float SCALE = 0.25f;       // 16^-0.5

typedef short  bf16x8 __attribute__((ext_vector_type(8)));
typedef float  f32x4  __attribute__((ext_vector_type(4)));
typedef unsigned short u16x8 __attribute__((ext_vector_type(8)));

static __device__ __forceinline__ float gelu_f(float v) {
    return 0.5f * v * (1.0f + erff(v * 0.70710678118654752f));
}

static __device__ __forceinline__ unsigned short f2bf(float f) {
    unsigned int u = __float_as_uint(f);
    u = (u + 0x7fffu + ((u >> 16) & 1u)) >> 16;   // RNE
    return (unsigned short)u;
}

static __device__ __forceinline__ float bf2f(unsigned short u) {
    return __uint_as_float((unsigned int)u << 16);
}

static __device__ __forceinline__ unsigned int pack2bf(float a, float b) {
    return (unsigned int)f2bf(a) | ((unsigned int)f2bf(b) << 16);
}

// Packed-o address: fragment (Mt,ks), lane l, window (b,wh,ww).
// Bijective permutation of the window's own nf bytes -> safe in-place overlay.
static __device__ __forceinline__ size_t opk_addr(int b, int wh, int ww, int Mt, int ks, int lane) {
    return ((size_t)(b * 16384) + (wh * 8 + Mt * 2 + (ks >> 1)) * 128 + ww * 8) * 128
           + (ks & 1) * 512 + lane * 8;
}

// ---------------------------------------------------------------------------
// K1: cost volume, register-blocked band correlation.
__global__ __launch_bounds__(384) void k_cost(const float* __restrict__ fl,
                                              const float* __restrict__ fr,
                                              float* __restrict__ cost) {
    __shared__ float s_fl[2][16][64];
    __shared__ float s_fr[2][16][112];
    int tid = threadIdx.x;
    int w0 = blockIdx.x * 64;
    int hp = blockIdx.y, b = blockIdx.z;
    int row = tid / 192;
    int r = tid - row * 192;
    int wg = r & 15, dg = r >> 4;
    int W = wg * 4, D = dg * 4;
    int h = hp * 2 + row;
    float acc[4][4];
#pragma unroll
    for (int i = 0; i < 4; ++i)
#pragma unroll
        for (int j = 0; j < 4; ++j) acc[i][j] = 0.f;

#pragma unroll 1
    for (int ck = 0; ck < 8; ++ck) {
        int ci0 = ck * 16;
        for (int i = tid; i < 512; i += 384) {
            int rr = i >> 8, rem = i & 255;
            int c = rem >> 4, k4 = rem & 15;
            float4 v = *(const float4*)&fl[((size_t)(b * 128 + ci0 + c) << 14) + (hp * 2 + rr) * 128 + w0 + k4 * 4];
            *(float4*)&s_fl[rr][c][k4 * 4] = v;
        }
        for (int i = tid; i < 896; i += 384) {
            int rr = i / 448, rem = i - rr * 448;
            int c = rem / 28, k4 = rem - c * 28;
            int wgl = w0 - 48 + k4 * 4;
            float4 v = {0.f, 0.f, 0.f, 0.f};
            if (wgl >= 0)
                v = *(const float4*)&fr[((size_t)(b * 128 + ci0 + c) << 14) + (hp * 2 + rr) * 128 + wgl];
            *(float4*)&s_fr[rr][c][k4 * 4] = v;
        }
        __syncthreads();
#pragma unroll
        for (int c = 0; c < 16; ++c) {
            float4 flv = *(const float4*)&s_fl[row][c][W];
            int base = W - D + 44;
            float4 f0 = *(const float4*)&s_fr[row][c][base];
            float4 f1 = *(const float4*)&s_fr[row][c][base + 4];
            float fw[8] = {f0.x, f0.y, f0.z, f0.w, f1.x, f1.y, f1.z, f1.w};
            float fv[4] = {flv.x, flv.y, flv.z, flv.w};
#pragma unroll
            for (int dj = 0; dj < 4; ++dj)
#pragma unroll
                for (int wv = 0; wv < 4; ++wv)
                    acc[dj][wv] += fv[wv] * fw[wv - dj + 4];
        }
        __syncthreads();
    }
    const float inv = 1.0f / 128.0f;
#pragma unroll
    for (int dj = 0; dj < 4; ++dj) {
        float4 o = {acc[dj][0] * inv, acc[dj][1] * inv, acc[dj][2] * inv, acc[dj][3] * inv};
        *(float4*)&cost[((size_t)(b * 48 + D + dj) << 14) + h * 128 + w0 + W] = o;
    }
}

// ---------------------------------------------------------------------------
// Pack helpers fused into one kernel.
static __device__ void pack_conv(int blk, int lane,
                                 const float* __restrict__ w1, const float* __restrict__ b1,
                                 const float* __restrict__ bng, const float* __restrict__ bnb,
                                 unsigned short* __restrict__ pk, float* __restrict__ bias2) {
    const float rs = 0.9999950000374997f;
    int ct = blk % 6;
    int taplin = blk / 6;
    int tap = taplin % 9, chunk = taplin / 9;
    int co = ct * 16 + (lane & 15);
    int cibase = chunk * 32 + (lane >> 4) * 8;
    u16x8 out;
#pragma unroll
    for (int j = 0; j < 8; ++j) {
        int ci = cibase + j;
        float v = 0.f;
        if (co < 88 && ci < 176) v = w1[(size_t)co * 1584 + ci * 9 + tap] * rs * bng[co];
        out[j] = f2bf(v);
    }
    *(u16x8*)(pk + ((size_t)blk * 64 + lane) * 8) = out;
    if (blk == 0) {
        for (int i = lane; i < 96; i += 64)
            bias2[i] = (i < 88) ? (b1[i] * rs * bng[i] + bnb[i]) : 0.f;
    }
}

static __device__ void pack_gemmB(int blk, int lane,
                                  const float* __restrict__ W,
                                  unsigned short* __restrict__ out, int ncols) {
    int ntiles = ncols >> 4;
    int ks = blk & 3;
    int nt = (blk >> 2) % ntiles;
    int kc = blk / (4 * ntiles);
    int col = nt * 16 + (lane & 15);
    int k0 = kc * 128 + ks * 32 + (lane >> 4) * 8;
    u16x8 o;
#pragma unroll
    for (int j = 0; j < 8; ++j) o[j] = f2bf(W[(size_t)(k0 + j) * ncols + col]);
    *(u16x8*)(out + ((size_t)blk * 64 + lane) * 8) = o;
}

static __device__ void pack_rpb(int blk, int lane,
                                const float* __restrict__ rpb, float* __restrict__ pb) {
    int nt = blk & 3, mt = (blk >> 2) & 3, hh = blk >> 4;
    int m = nt * 16 + (lane & 15);
    int g = lane >> 4;
    float o[4];
#pragma unroll
    for (int rr = 0; rr < 4; ++rr) {
        int n = mt * 16 + g * 4 + rr;
        int relidx = (((n >> 3) - (m >> 3)) + 7) * 15 + ((n & 7) - (m & 7)) + 7;
        o[rr] = rpb[relidx * 8 + hh];
    }
    float4 v = {o[0], o[1], o[2], o[3]};
    *(float4*)(pb + ((size_t)blk * 64 + lane) * 4) = v;
}

__global__ __launch_bounds__(64) void k_pack_all(
        const float* __restrict__ dp_w1, const float* __restrict__ dp_b1,
        const float* __restrict__ bn_g, const float* __restrict__ bn_b,
        unsigned short* __restrict__ pk, float* __restrict__ bias2,
        const float* __restrict__ wq, const float* __restrict__ wk,
        const float* __restrict__ wv, const float* __restrict__ wp,
        unsigned short* __restrict__ pkw,
        const float* __restrict__ rpb, float* __restrict__ pb,
        const float* __restrict__ mlp_w1, unsigned short* __restrict__ pm1,
        const float* __restrict__ mlp_w2, unsigned short* __restrict__ pm2,
        const float* __restrict__ un_w1, unsigned short* __restrict__ pu1,
        const float* __restrict__ un_w2, unsigned short* __restrict__ pu2) {
    int blk = blockIdx.x;
    int lane = threadIdx.x;
    if (blk < 324) {
        pack_conv(blk, lane, dp_w1, dp_b1, bn_g, bn_b, pk, bias2);
    } else if (blk < 452) {
        int bb = blk - 324;
        int mat = bb >> 5;
        const float* W = (mat == 0) ? wq : (mat == 1) ? wk : (mat == 2) ? wv : wp;
        pack_gemmB(bb & 31, lane, W, pkw + (size_t)mat * 16384, 128);
    } else if (blk < 580) {
        pack_rpb(blk - 452, lane, rpb, pb);
    } else if (blk < 708) {
        pack_gemmB(blk - 580, lane, mlp_w1, pm1, 512);
    } else if (blk < 836) {
        pack_gemmB(blk - 708, lane, mlp_w2, pm2, 128);
    } else if (blk < 868) {
        pack_gemmB(blk - 836, lane, un_w1, pu1, 128);
    } else {
        pack_gemmB(blk - 868, lane, un_w2, pu2, 128);
    }
}

// ---------------------------------------------------------------------------
// K2: unary MLP via MFMA + LN1 producer. 1024 blocks x 64 tokens, 4 waves.
// Writes x = unary(tok) and nf = LN1(tok) (token-major bf16).
__global__ __launch_bounds__(256) void k_unary_mfma(const float* __restrict__ feat_l,
                                                    const unsigned short* __restrict__ pu1,
                                                    const float* __restrict__ b1,
                                                    const unsigned short* __restrict__ pu2,
                                                    const float* __restrict__ b2,
                                                    const float* __restrict__ g1,
                                                    const float* __restrict__ bt1,
                                                    float* __restrict__ x,
                                                    unsigned short* __restrict__ nf) {
    __shared__ __align__(16) unsigned short s_a[64 * 136];
    __shared__ __align__(16) unsigned short s_h[64 * 136];
    int tid = threadIdx.x;
    int wid = tid >> 6, lane = tid & 63;
    int g = lane >> 4, t = lane & 15;
    int n0g = blockIdx.x * 64;
    int b = n0g >> 14;
    int nb = n0g & 16383;

    for (int idx = tid; idx < 4096; idx += 256) {
        int c2 = idx >> 6, nl = idx & 63;
        float v0 = feat_l[((size_t)(b * 128 + 2 * c2) << 14) + nb + nl];
        float v1 = feat_l[((size_t)(b * 128 + 2 * c2 + 1) << 14) + nb + nl];
        *(unsigned int*)&s_a[nl * 136 + 2 * c2] = pack2bf(v0, v1);
    }
    __syncthreads();

    // ---- LN1 -> nf (token-major bf16), independent of the unary GEMM ----
    {
        int tok = tid >> 2, q = tid & 3;
        float v[32];
        float s = 0.f, s2 = 0.f;
#pragma unroll
        for (int i = 0; i < 32; ++i) {
            float vv = bf2f(s_a[tok * 136 + q * 32 + i]);
            v[i] = vv; s += vv; s2 += vv * vv;
        }
        s += __shfl_xor(s, 1); s += __shfl_xor(s, 2);
        s2 += __shfl_xor(s2, 1); s2 += __shfl_xor(s2, 2);
        float mean = s * (1.f / 128.f);
        float var = s2 * (1.f / 128.f) - mean * mean;
        float rstd = rsqrtf(var + 1e-5f);
        size_t base = (size_t)(n0g + tok) * 128 + q * 32;
#pragma unroll
        for (int i = 0; i < 32; i += 2) {
            int c = q * 32 + i;
            float v0 = (v[i] - mean) * rstd * g1[c] + bt1[c];
            float v1 = (v[i + 1] - mean) * rstd * g1[c + 1] + bt1[c + 1];
            *(unsigned int*)&nf[base + i] = pack2bf(v0, v1);
        }
    }

    bf16x8 af[4][4];
#pragma unroll
    for (int Mt = 0; Mt < 4; ++Mt)
#pragma unroll
        for (int ks = 0; ks < 4; ++ks)
            af[Mt][ks] = *(const bf16x8*)&s_a[(Mt * 16 + t) * 136 + ks * 32 + g * 8];

    f32x4 acc1[4][2];
#pragma unroll
    for (int nt2 = 0; nt2 < 2; ++nt2) {
        float bv = b1[(wid * 2 + nt2) * 16 + t];
#pragma unroll
        for (int Mt = 0; Mt < 4; ++Mt) acc1[Mt][nt2] = (f32x4){bv, bv, bv, bv};
    }
#pragma unroll
    for (int ks = 0; ks < 4; ++ks) {
        bf16x8 bf0 = *(const bf16x8*)(pu1 + (size_t)(((wid * 2 + 0) * 4 + ks) * 64 + lane) * 8);
        bf16x8 bf1 = *(const bf16x8*)(pu1 + (size_t)(((wid * 2 + 1) * 4 + ks) * 64 + lane) * 8);
#pragma unroll
        for (int Mt = 0; Mt < 4; ++Mt) {
            acc1[Mt][0] = __builtin_amdgcn_mfma_f32_16x16x32_bf16(af[Mt][ks], bf0, acc1[Mt][0], 0, 0, 0);
            acc1[Mt][1] = __builtin_amdgcn_mfma_f32_16x16x32_bf16(af[Mt][ks], bf1, acc1[Mt][1], 0, 0, 0);
        }
    }
#pragma unroll
    for (int Mt = 0; Mt < 4; ++Mt)
#pragma unroll
        for (int nt2 = 0; nt2 < 2; ++nt2)
#pragma unroll
            for (int rr = 0; rr < 4; ++rr)
                s_h[(Mt * 16 + g * 4 + rr) * 136 + (wid * 2 + nt2) * 16 + t] = f2bf(gelu_f(acc1[Mt][nt2][rr]));
    __syncthreads();

    bf16x8 a2[4][4];
#pragma unroll
    for (int Mt = 0; Mt < 4; ++Mt)
#pragma unroll
        for (int ks = 0; ks < 4; ++ks)
            a2[Mt][ks] = *(const bf16x8*)&s_h[(Mt * 16 + t) * 136 + ks * 32 + g * 8];

    f32x4 acc2[4][2];
#pragma unroll
    for (int nt2 = 0; nt2 < 2; ++nt2) {
        float bv = b2[(wid * 2 + nt2) * 16 + t];
#pragma unroll
        for (int Mt = 0; Mt < 4; ++Mt) acc2[Mt][nt2] = (f32x4){bv, bv, bv, bv};
    }
#pragma unroll
    for (int ks = 0; ks < 4; ++ks) {
        bf16x8 bf0 = *(const bf16x8*)(pu2 + (size_t)(((wid * 2 + 0) * 4 + ks) * 64 + lane) * 8);
        bf16x8 bf1 = *(const bf16x8*)(pu2 + (size_t)(((wid * 2 + 1) * 4 + ks) * 64 + lane) * 8);
#pragma unroll
        for (int Mt = 0; Mt < 4; ++Mt) {
            acc2[Mt][0] = __builtin_amdgcn_mfma_f32_16x16x32_bf16(a2[Mt][ks], bf0, acc2[Mt][0], 0, 0, 0);
            acc2[Mt][1] = __builtin_amdgcn_mfma_f32_16x16x32_bf16(a2[Mt][ks], bf1, acc2[Mt][1], 0, 0, 0);
        }
    }
#pragma unroll
    for (int Mt = 0; Mt < 4; ++Mt)
#pragma unroll
        for (int nt2 = 0; nt2 < 2; ++nt2)
#pragma unroll
            for (int rr = 0; rr < 4; ++rr) {
                int tok = Mt * 16 + g * 4 + rr;
                x[(size_t)(n0g + tok) * 128 + (wid * 2 + nt2) * 16 + t] = acc2[Mt][nt2][rr];
            }
}

// ---------------------------------------------------------------------------
// K3: attention core. 1024 blocks (1 window), 256 threads (4 waves).
// Reads LN'd tokens from nf; writes fragment-packed o IN PLACE over nf
// (bijective per-window address permutation; one barrier separates phases).
__global__ __launch_bounds__(256, 3) void k_attn_core(const unsigned short* __restrict__ nf,
                                                      const unsigned short* __restrict__ pkw,
                                                      const float* __restrict__ pb,
                                                      const float* __restrict__ bq,
                                                      const float* __restrict__ bk,
                                                      const float* __restrict__ bv,
                                                      unsigned short* __restrict__ opk) {
    // per-wave scratch 12544 B: sQ[64][40] | sK[64][40] | sV[16][72]
    // sP[64][72] overlays sQ+sK; sO[64][16] overlays sP head-by-head.
    __shared__ __align__(16) unsigned short s_all[25088];
    int tid = threadIdx.x;
    int wid = tid >> 6, lane = tid & 63;
    int g = lane >> 4, t = lane & 15;
    int bw = blockIdx.x;
    int b = bw >> 8, wh = (bw >> 4) & 15, ww = bw & 15;

    // ---- A-fragments directly from nf (window footprint 16KB, L1-resident) ----
    bf16x8 af[4][4];   // [Mt][ks]
#pragma unroll
    for (int Mt = 0; Mt < 4; ++Mt) {
        int tok = Mt * 16 + t;
        size_t gtok = (size_t)(b * 16384) + (wh * 8 + (tok >> 3)) * 128 + ww * 8 + (tok & 7);
#pragma unroll
        for (int ks = 0; ks < 4; ++ks)
            af[Mt][ks] = *(const bf16x8*)&nf[gtok * 128 + ks * 32 + g * 8];
    }
    __syncthreads();   // all nf reads complete before any in-place opk write

    unsigned short* sQ = s_all + wid * 6272;
    unsigned short* sK = sQ + 2560;
    unsigned short* sV = sQ + 5120;
    unsigned short* sP = sQ;
    unsigned short* sO = sQ;

#pragma unroll 1
    for (int hi = 0; hi < 2; ++hi) {
        int h = wid + hi * 4;
        u16x8 z8 = {0, 0, 0, 0, 0, 0, 0, 0};
        *(u16x8*)&sQ[lane * 40 + 16] = z8;
        *(u16x8*)&sQ[lane * 40 + 24] = z8;
        *(u16x8*)&sK[lane * 40 + 16] = z8;
        *(u16x8*)&sK[lane * 40 + 24] = z8;

        // ---- QKV projection for head h ----
        float bqv = bq[h * 16 + t], bkv = bk[h * 16 + t], bvv = bv[h * 16 + t];
        f32x4 qa[4], ka[4], va[4];
#pragma unroll
        for (int Mt = 0; Mt < 4; ++Mt) {
            qa[Mt] = (f32x4){bqv, bqv, bqv, bqv};
            ka[Mt] = (f32x4){bkv, bkv, bkv, bkv};
            va[Mt] = (f32x4){bvv, bvv, bvv, bvv};
        }
#pragma unroll
        for (int ks = 0; ks < 4; ++ks) {
            const unsigned short* wbase = pkw + ((size_t)((h * 4 + ks) * 64 + lane) * 8);
            bf16x8 bfq = *(const bf16x8*)(wbase);
            bf16x8 bfk = *(const bf16x8*)(wbase + 16384);
            bf16x8 bfv = *(const bf16x8*)(wbase + 32768);
#pragma unroll
            for (int Mt = 0; Mt < 4; ++Mt) {
                qa[Mt] = __builtin_amdgcn_mfma_f32_16x16x32_bf16(af[Mt][ks], bfq, qa[Mt], 0, 0, 0);
                ka[Mt] = __builtin_amdgcn_mfma_f32_16x16x32_bf16(af[Mt][ks], bfk, ka[Mt], 0, 0, 0);
                va[Mt] = __builtin_amdgcn_mfma_f32_16x16x32_bf16(af[Mt][ks], bfv, va[Mt], 0, 0, 0);
            }
        }
#pragma unroll
        for (int Mt = 0; Mt < 4; ++Mt)
#pragma unroll
            for (int rr = 0; rr < 4; ++rr) {
                int tok = Mt * 16 + g * 4 + rr;
                sQ[tok * 40 + t] = f2bf(qa[Mt][rr] * SCALE);
                sK[tok * 40 + t] = f2bf(ka[Mt][rr]);
                sV[t * 72 + tok] = f2bf(va[Mt][rr]);
            }

        // ---- S = Q K^T + bias(C-init) ----
        f32x4 s[4][4];
#pragma unroll
        for (int Mt = 0; Mt < 4; ++Mt)
#pragma unroll
            for (int Nt = 0; Nt < 4; ++Nt)
                s[Mt][Nt] = *(const f32x4*)(pb + ((size_t)((h * 16 + Mt * 4 + Nt) * 64 + lane) * 4));
        bf16x8 bk2[4];
#pragma unroll
        for (int Nt = 0; Nt < 4; ++Nt) bk2[Nt] = *(const bf16x8*)&sK[(Nt * 16 + t) * 40 + g * 8];
#pragma unroll
        for (int Mt = 0; Mt < 4; ++Mt) {
            bf16x8 aq = *(const bf16x8*)&sQ[(Mt * 16 + t) * 40 + g * 8];
#pragma unroll
            for (int Nt = 0; Nt < 4; ++Nt)
                s[Mt][Nt] = __builtin_amdgcn_mfma_f32_16x16x32_bf16(aq, bk2[Nt], s[Mt][Nt], 0, 0, 0);
        }

        // ---- softmax (unnormalized; divide at sO write) ----
        f32x4 rsm[4];
#pragma unroll
        for (int Mt = 0; Mt < 4; ++Mt) {
            f32x4 m = s[Mt][0];
#pragma unroll
            for (int Nt = 1; Nt < 4; ++Nt)
#pragma unroll
                for (int rr = 0; rr < 4; ++rr) m[rr] = fmaxf(m[rr], s[Mt][Nt][rr]);
#pragma unroll
            for (int sh = 1; sh <= 8; sh <<= 1)
#pragma unroll
                for (int rr = 0; rr < 4; ++rr) m[rr] = fmaxf(m[rr], __shfl_xor(m[rr], sh));
            f32x4 sum = (f32x4){0.f, 0.f, 0.f, 0.f};
#pragma unroll
            for (int Nt = 0; Nt < 4; ++Nt)
#pragma unroll
                for (int rr = 0; rr < 4; ++rr) {
                    float e = __expf(s[Mt][Nt][rr] - m[rr]);
                    s[Mt][Nt][rr] = e;
                    sum[rr] += e;
                }
#pragma unroll
            for (int sh = 1; sh <= 8; sh <<= 1)
#pragma unroll
                for (int rr = 0; rr < 4; ++rr) sum[rr] += __shfl_xor(sum[rr], sh);
            rsm[Mt] = sum;
        }
#pragma unroll
        for (int Mt = 0; Mt < 4; ++Mt)
#pragma unroll
            for (int Nt = 0; Nt < 4; ++Nt)
#pragma unroll
                for (int rr = 0; rr < 4; ++rr)
                    sP[(Mt * 16 + g * 4 + rr) * 72 + Nt * 16 + t] = f2bf(s[Mt][Nt][rr]);

        // ---- O = P @ V ----
        f32x4 oa[4];
#pragma unroll
        for (int Mt = 0; Mt < 4; ++Mt) oa[Mt] = (f32x4){0.f, 0.f, 0.f, 0.f};
#pragma unroll
        for (int ksv = 0; ksv < 2; ++ksv) {
            bf16x8 bv2 = *(const bf16x8*)&sV[t * 72 + ksv * 32 + g * 8];
#pragma unroll
            for (int Mt = 0; Mt < 4; ++Mt) {
                bf16x8 ap = *(const bf16x8*)&sP[(Mt * 16 + t) * 72 + ksv * 32 + g * 8];
                oa[Mt] = __builtin_amdgcn_mfma_f32_16x16x32_bf16(ap, bv2, oa[Mt], 0, 0, 0);
            }
        }
        // ---- normalize -> wave-local LDS transpose -> packed 16B/lane stores ----
#pragma unroll
        for (int Mt = 0; Mt < 4; ++Mt)
#pragma unroll
            for (int rr = 0; rr < 4; ++rr)
                sO[(Mt * 16 + g * 4 + rr) * 16 + t] = f2bf(oa[Mt][rr] / rsm[Mt][rr]);
        // DS ops within a wave are in-order: reads below see the writes above.
        int ksf = h >> 1;
        if ((g >> 1) == (h & 1)) {
#pragma unroll
            for (int Mt = 0; Mt < 4; ++Mt) {
                bf16x8 v8 = *(const bf16x8*)&sO[(Mt * 16 + t) * 16 + (g & 1) * 8];
                *(bf16x8*)&opk[opk_addr(b, wh, ww, Mt, ksf, lane)] = v8;
            }
        }
    }
}

// ---------------------------------------------------------------------------
// K4: per-WINDOW block: x = (x + o@wp + bp) + mlp(LN2(...)).
// o read from fragment-packed opk. (mlp_b2 * 0 in ref -> not added)
__global__ __launch_bounds__(256) void k_mlp_mfma(float* __restrict__ x,
                                                  const unsigned short* __restrict__ opk,
                                                  const unsigned short* __restrict__ pkw,
                                                  const float* __restrict__ bp,
                                                  const float* __restrict__ g2,
                                                  const float* __restrict__ bt2,
                                                  const unsigned short* __restrict__ pm1,
                                                  const float* __restrict__ b1,
                                                  const unsigned short* __restrict__ pm2) {
    __shared__ __align__(16) char smem[51200];
    float* sf = (float*)smem;                       // [64][132] f32
    unsigned short* s_h = (unsigned short*)smem;    // overlays sf after LN
    unsigned short* s_a = (unsigned short*)(smem + 33792);
    int tid = threadIdx.x;
    int wid = tid >> 6, lane = tid & 63;
    int g = lane >> 4, t = lane & 15;
    int bw = blockIdx.x;
    int b = bw >> 8, wh = (bw >> 4) & 15, ww = bw & 15;

    // window-local token -> global token
    auto gtok_of = [&](int tok) -> size_t {
        return (size_t)(b * 16384) + (wh * 8 + (tok >> 3)) * 128 + ww * 8 + (tok & 7);
    };

    // GEMM0: out = o_window @ wp + bp  (out doubles as final accumulator)
    f32x4 out[4][2];
    {
        float bp0 = bp[wid * 32 + t], bp1 = bp[wid * 32 + 16 + t];
#pragma unroll
        for (int Mt = 0; Mt < 4; ++Mt) {
            out[Mt][0] = (f32x4){bp0, bp0, bp0, bp0};
            out[Mt][1] = (f32x4){bp1, bp1, bp1, bp1};
        }
#pragma unroll
        for (int ks = 0; ks < 4; ++ks) {
            bf16x8 b0 = *(const bf16x8*)(pkw + 49152 + (size_t)(((wid * 2 + 0) * 4 + ks) * 64 + lane) * 8);
            bf16x8 b1v = *(const bf16x8*)(pkw + 49152 + (size_t)(((wid * 2 + 1) * 4 + ks) * 64 + lane) * 8);
#pragma unroll
            for (int Mt = 0; Mt < 4; ++Mt) {
                bf16x8 a = *(const bf16x8*)&opk[opk_addr(b, wh, ww, Mt, ks, lane)];
                out[Mt][0] = __builtin_amdgcn_mfma_f32_16x16x32_bf16(a, b0, out[Mt][0], 0, 0, 0);
                out[Mt][1] = __builtin_amdgcn_mfma_f32_16x16x32_bf16(a, b1v, out[Mt][1], 0, 0, 0);
            }
        }
        // add unary x; stash x_pre_mlp into sf for LN
#pragma unroll
        for (int Mt = 0; Mt < 4; ++Mt)
#pragma unroll
            for (int nt2 = 0; nt2 < 2; ++nt2)
#pragma unroll
                for (int rr = 0; rr < 4; ++rr) {
                    int tok = Mt * 16 + g * 4 + rr;
                    int col = (wid * 2 + nt2) * 16 + t;
                    float v = out[Mt][nt2][rr] + x[gtok_of(tok) * 128 + col];
                    out[Mt][nt2][rr] = v;
                    sf[tok * 132 + col] = v;
                }
    }
    __syncthreads();
    // LN2 -> bf16 s_a
    {
        int tok = tid >> 2, q = tid & 3;
        float s = 0.f, s2 = 0.f;
        for (int c = q * 32; c < q * 32 + 32; ++c) {
            float v = sf[tok * 132 + c];
            s += v; s2 += v * v;
        }
        s += __shfl_xor(s, 1); s += __shfl_xor(s, 2);
        s2 += __shfl_xor(s2, 1); s2 += __shfl_xor(s2, 2);
        float mean = s * (1.f / 128.f);
        float var = s2 * (1.f / 128.f) - mean * mean;
        float rstd = rsqrtf(var + 1e-5f);
        for (int c = q * 32; c < q * 32 + 32; c += 2) {
            float v0 = (sf[tok * 132 + c] - mean) * rstd * g2[c] + bt2[c];
            float v1 = (sf[tok * 132 + c + 1] - mean) * rstd * g2[c + 1] + bt2[c + 1];
            *(unsigned int*)&s_a[tok * 136 + c] = pack2bf(v0, v1);
        }
    }
    __syncthreads();
    bf16x8 af[4][4];
#pragma unroll
    for (int Mt = 0; Mt < 4; ++Mt)
#pragma unroll
        for (int ks = 0; ks < 4; ++ks)
            af[Mt][ks] = *(const bf16x8*)&s_a[(Mt * 16 + t) * 136 + ks * 32 + g * 8];

#pragma unroll 1
    for (int hc = 0; hc < 4; ++hc) {
        f32x4 acc1[4][2];
#pragma unroll
        for (int nt2 = 0; nt2 < 2; ++nt2) {
            float bv = b1[hc * 128 + (wid * 2 + nt2) * 16 + t];
#pragma unroll
            for (int Mt = 0; Mt < 4; ++Mt) acc1[Mt][nt2] = (f32x4){bv, bv, bv, bv};
        }
#pragma unroll
        for (int ks = 0; ks < 4; ++ks) {
            bf16x8 bf0 = *(const bf16x8*)(pm1 + (size_t)(((hc * 8 + wid * 2 + 0) * 4 + ks) * 64 + lane) * 8);
            bf16x8 bf1 = *(const bf16x8*)(pm1 + (size_t)(((hc * 8 + wid * 2 + 1) * 4 + ks) * 64 + lane) * 8);
#pragma unroll
            for (int Mt = 0; Mt < 4; ++Mt) {
                acc1[Mt][0] = __builtin_amdgcn_mfma_f32_16x16x32_bf16(af[Mt][ks], bf0, acc1[Mt][0], 0, 0, 0);
                acc1[Mt][1] = __builtin_amdgcn_mfma_f32_16x16x32_bf16(af[Mt][ks], bf1, acc1[Mt][1], 0, 0, 0);
            }
        }
#pragma unroll
        for (int Mt = 0; Mt < 4; ++Mt)
#pragma unroll
            for (int nt2 = 0; nt2 < 2; ++nt2)
#pragma unroll
                for (int rr = 0; rr < 4; ++rr)
                    s_h[(Mt * 16 + g * 4 + rr) * 136 + (wid * 2 + nt2) * 16 + t] = f2bf(gelu_f(acc1[Mt][nt2][rr]));
        __syncthreads();
        bf16x8 a2[4][4];
#pragma unroll
        for (int Mt = 0; Mt < 4; ++Mt)
#pragma unroll
            for (int ks = 0; ks < 4; ++ks)
                a2[Mt][ks] = *(const bf16x8*)&s_h[(Mt * 16 + t) * 136 + ks * 32 + g * 8];
#pragma unroll
        for (int ks = 0; ks < 4; ++ks) {
            bf16x8 bf0 = *(const bf16x8*)(pm2 + (size_t)((hc * 32 + (wid * 2 + 0) * 4 + ks) * 64 + lane) * 8);
            bf16x8 bf1 = *(const bf16x8*)(pm2 + (size_t)((hc * 32 + (wid * 2 + 1) * 4 + ks) * 64 + lane) * 8);
#pragma unroll
            for (int Mt = 0; Mt < 4; ++Mt) {
                out[Mt][0] = __builtin_amdgcn_mfma_f32_16x16x32_bf16(a2[Mt][ks], bf0, out[Mt][0], 0, 0, 0);
                out[Mt][1] = __builtin_amdgcn_mfma_f32_16x16x32_bf16(a2[Mt][ks], bf1, out[Mt][1], 0, 0, 0);
            }
        }
        __syncthreads();
    }

    // final: x = x_pre_mlp + mlp_out
#pragma unroll
    for (int Mt = 0; Mt < 4; ++Mt)
#pragma unroll
        for (int nt2 = 0; nt2 < 2; ++nt2)
#pragma unroll
            for (int rr = 0; rr < 4; ++rr) {
                int tok = Mt * 16 + g * 4 + rr;
                x[gtok_of(tok) * 128 + (wid * 2 + nt2) * 16 + t] = out[Mt][nt2][rr];
            }
}

// ---------------------------------------------------------------------------
// K5b: conv3x3 as bf16 implicit-GEMM MFMA. grid (8,8,4), 256 threads.
__global__ __launch_bounds__(256) void k_conv_mfma(const float* __restrict__ x,
                                                   const float* __restrict__ cost,
                                                   const unsigned short* __restrict__ pk,
                                                   const float* __restrict__ bias2,
                                                   float* __restrict__ h1) {
    __shared__ __align__(16) unsigned short s_p[324 * 40];
    int tid = threadIdx.x;
    int wid = tid >> 6, lane = tid & 63;
    int g = lane >> 4, t = lane & 15;
    int tx0 = blockIdx.x * 16, ty0 = blockIdx.y * 16, b = blockIdx.z;

    f32x4 acc[4][6];
#pragma unroll
    for (int p = 0; p < 4; ++p)
#pragma unroll
        for (int ct = 0; ct < 6; ++ct) acc[p][ct] = (f32x4){0.f, 0.f, 0.f, 0.f};

#pragma unroll 1
    for (int chunk = 0; chunk < 6; ++chunk) {
        if (chunk < 4) {
            int ci0 = chunk * 32;
            for (int u = tid; u < 648; u += 256) {
                int pos = u >> 1, half = u & 1;
                int yy = pos / 18, xx = pos - yy * 18;
                int gy = ty0 + yy - 1, gx = tx0 + xx - 1;
                u16x8 lo, hi;
                if (gy >= 0 && gy < 128 && gx >= 0 && gx < 128) {
                    const float4* src = (const float4*)&x[((size_t)(b << 14) + gy * 128 + gx) * 128 + ci0 + half * 16];
                    float4 v0 = src[0], v1 = src[1], v2 = src[2], v3 = src[3];
                    lo[0] = f2bf(v0.x); lo[1] = f2bf(v0.y); lo[2] = f2bf(v0.z); lo[3] = f2bf(v0.w);
                    lo[4] = f2bf(v1.x); lo[5] = f2bf(v1.y); lo[6] = f2bf(v1.z); lo[7] = f2bf(v1.w);
                    hi[0] = f2bf(v2.x); hi[1] = f2bf(v2.y); hi[2] = f2bf(v2.z); hi[3] = f2bf(v2.w);
                    hi[4] = f2bf(v3.x); hi[5] = f2bf(v3.y); hi[6] = f2bf(v3.z); hi[7] = f2bf(v3.w);
                } else {
                    lo = (u16x8)(unsigned short)0; hi = (u16x8)(unsigned short)0;
                }
                unsigned short* dst = &s_p[pos * 40 + half * 16];
                *(u16x8*)dst = lo;
                *(u16x8*)(dst + 8) = hi;
            }
        } else {
            int d0 = (chunk - 4) * 32;
            for (int u = tid; u < 576; u += 256) {
                int cl = u / 18, yy = u - cl * 18;
                int d = d0 + cl;
                int gy = ty0 + yy - 1;
                bool rowok = (d < 48) && (gy >= 0) && (gy < 128);
                const float* srow = cost + ((size_t)(b * 48 + (rowok ? d : 0)) << 14) + (rowok ? gy : 0) * 128;
                for (int xx = 0; xx < 18; ++xx) {
                    int gx = tx0 + xx - 1;
                    float v = (rowok && gx >= 0 && gx < 128) ? srow[gx] : 0.f;
                    s_p[(yy * 18 + xx) * 40 + cl] = f2bf(v);
                }
            }
        }
        __syncthreads();

#pragma unroll 1
        for (int tap = 0; tap < 9; ++tap) {
            int dy = tap / 3, dx = tap - dy * 3;
            const unsigned short* pkt = pk + ((size_t)(chunk * 9 + tap)) * 6 * 512;
            bf16x8 afr[6];
#pragma unroll
            for (int ct = 0; ct < 6; ++ct)
                afr[ct] = *(const bf16x8*)(pkt + ct * 512 + lane * 8);
            bf16x8 bfr[4];
#pragma unroll
            for (int p = 0; p < 4; ++p) {
                int pos = (wid * 4 + p + dy) * 18 + t + dx;
                bfr[p] = *(const bf16x8*)&s_p[pos * 40 + g * 8];
            }
#pragma unroll
            for (int p = 0; p < 4; ++p)
#pragma unroll
                for (int ct = 0; ct < 6; ++ct)
                    acc[p][ct] = __builtin_amdgcn_mfma_f32_16x16x32_bf16(afr[ct], bfr[p], acc[p][ct], 0, 0, 0);
        }
        __syncthreads();
    }

#pragma unroll
    for (int p = 0; p < 4; ++p) {
        int y = ty0 + wid * 4 + p;
#pragma unroll
        for (int ct = 0; ct < 6; ++ct) {
#pragma unroll
            for (int rr = 0; rr < 4; ++rr) {
                int co = ct * 16 + g * 4 + rr;
                if (co < 88) {
                    float v = acc[p][ct][rr] + bias2[co];
                    h1[((size_t)(b * 88 + co) << 14) + y * 128 + tx0 + t] = fmaxf(v, 0.f);
                }
            }
        }
    }
}

// ---------------------------------------------------------------------------
// K6: pv = conv1x1(h1) + b2; softmax over D; pred = 4*sum(d*p). 256 blocks.
__global__ __launch_bounds__(256) void k_head(const float* __restrict__ h1,
                                              const float* __restrict__ w2, const float* __restrict__ b2,
                                              float* __restrict__ out) {
    __shared__ float s_wt[88 * 48];   // [k][d]
    __shared__ float s_b[48];
    int tid = threadIdx.x;
    for (int idx = tid; idx < 48 * 88; idx += 256) {
        int d = idx / 88, k = idx % 88;
        s_wt[k * 48 + d] = w2[idx];
    }
    if (tid < 48) s_b[tid] = b2[tid];
    __syncthreads();
    int px = blockIdx.x * 256 + tid;
    int b = px >> 14, r = px & 16383;
    float acc[48];
#pragma unroll
    for (int d = 0; d < 48; ++d) acc[d] = s_b[d];
    for (int k = 0; k < 88; ++k) {
        float hv = h1[((size_t)(b * 88 + k) << 14) + r];
        const float4* wrow = (const float4*)&s_wt[k * 48];
#pragma unroll
        for (int d4 = 0; d4 < 12; ++d4) {
            float4 wv = wrow[d4];
            acc[d4 * 4 + 0] += hv * wv.x;
            acc[d4 * 4 + 1] += hv * wv.y;
            acc[d4 * 4 + 2] += hv * wv.z;
            acc[d4 * 4 + 3] += hv * wv.w;
        }
    }
    float mx = -1e30f;
#pragma unroll
    for (int d = 0; d < 48; ++d) mx = fmaxf(mx, acc[d]);
    float sum = 0.f, wsum = 0.f;
#pragma unroll
    for (int d = 0; d < 48; ++d) {
        float e = expf(acc[d] - mx);
        sum += e;
        wsum += e * (float)d;
    }
    out[px] = 4.0f * wsum / sum;
}

// ---------------------------------------------------------------------------
extern "C" void kernel_launch(void* const* d_in, const int* in_sizes, int n_in,
                              void* d_out, int out_size, void* d_ws, size_t ws_size,
                              hipStream_t stream) {
    const float* feat_l = (const float*)d_in[0];
    const float* feat_r = (const float*)d_in[1];
    const float* wq = (const float*)d_in[2];
    const float* bq = (const float*)d_in[3];
    const float* wk = (const float*)d_in[4];
    const float* bk = (const float*)d_in[5];
    const float* wv = (const float*)d_in[6];
    const float* bv = (const float*)d_in[7];
    const float* wp = (const float*)d_in[8];
    const float* bp = (const float*)d_in[9];
    const float* rpb = (const float*)d_in[10];
    const float* ln1_g = (const float*)d_in[11];
    const float* ln1_b = (const float*)d_in[12];
    const float* ln2_g = (const float*)d_in[13];
    const float* ln2_b = (const float*)d_in[14];
    const float* mlp_w1 = (const float*)d_in[15];
    const float* mlp_b1 = (const float*)d_in[16];
    const float* mlp_w2 = (const float*)d_in[17];
    // d_in[18] = mlp_b2 is multiplied by 0.0 in the reference -> unused
    const float* un_w1 = (const float*)d_in[19];
    const float* un_b1 = (const float*)d_in[20];
    const float* un_w2 = (const float*)d_in[21];
    const float* un_b2 = (const float*)d_in[22];
    const float* dp_w1 = (const float*)d_in[23];
    const float* dp_b1 = (const float*)d_in[24];
    const float* bn_g = (const float*)d_in[25];
    const float* bn_b = (const float*)d_in[26];
    const float* dp_w2 = (const float*)d_in[27];
    const float* dp_b2 = (const float*)d_in[28];

    float* ws = (float*)d_ws;
    float* cost = ws;                               // 3,145,728 f
    float* x = ws + 3145728;                        // 8,388,608 f
    float* h1 = ws + 11534336;                      // 5,767,168 f
    // nf (LN1'd tokens, bf16, 16 MB) overlays h1; attn converts it IN PLACE to
    // packed o; mlp consumes o; conv then overwrites region with h1.
    unsigned short* nfo = (unsigned short*)h1;
    unsigned short* pk = (unsigned short*)(ws + 17301504);       // 165,888 u16
    float* bias2 = ws + 17384448;                   // 96 f
    unsigned short* pkw = (unsigned short*)(ws + 17384544);      // 65,536 u16
    float* pb = ws + 17417312;                      // 32,768 f
    unsigned short* pm1 = (unsigned short*)(ws + 17450080);      // 65,536 u16
    unsigned short* pm2 = (unsigned short*)(ws + 17482848);      // 65,536 u16
    unsigned short* pu1 = (unsigned short*)(ws + 17515616);      // 16,384 u16
    unsigned short* pu2 = (unsigned short*)(ws + 17523808);      // 16,384 u16
    float* out = (float*)d_out;

    k_pack_all<<<900, 64, 0, stream>>>(dp_w1, dp_b1, bn_g, bn_b, pk, bias2,
                                       wq, wk, wv, wp, pkw, rpb, pb,
                                       mlp_w1, pm1, mlp_w2, pm2,
                                       un_w1, pu1, un_w2, pu2);
    k_cost<<<dim3(2, 64, 4), 384, 0, stream>>>(feat_l, feat_r, cost);
    k_unary_mfma<<<1024, 256, 0, stream>>>(feat_l, pu1, un_b1, pu2, un_b2,
                                           ln1_g, ln1_b, x, nfo);
    k_attn_core<<<1024, 256, 0, stream>>>(nfo, pkw, pb, bq, bk, bv, nfo);
    k_mlp_mfma<<<1024, 256, 0, stream>>>(x, nfo, pkw, bp, ln2_g, ln2_b,
                                         pm1, mlp_b1, pm2);
    k_conv_mfma<<<dim3(8, 8, 4), 256, 0, stream>>>(x, cost, pk, bias2, h1);
    k_head<<<256, 256, 0, stream>>>(h1, dp_w2, dp_b2, out);
}

// Round 8
// 304.172 us; speedup vs baseline: 7.9986x; 1.1072x over previous
//
#include <hip/hip_runtime.h>
#include <math.h>

// Dims
constexpr int Bn = 4, Cc = 128, Hh = 128, Wn = 128, Dd = 48;
constexpr float SCALE = 0.25f;       // 16^-0.5

typedef short  bf16x8 __attribute__((ext_vector_type(8)));
typedef short  bf16x4 __attribute__((ext_vector_type(4)));
typedef float  f32x4  __attribute__((ext_vector_type(4)));
typedef unsigned short u16x8 __attribute__((ext_vector_type(8)));

// tanh-form GELU: v * sigmoid(1.59576912 v + 0.07135481 v^3).
// |err| vs exact erf-GELU < ~3e-4*|v| -- far under bf16 rounding.
static __device__ __forceinline__ float gelu_f(float v) {
    float u = v * (1.5957691216f + 0.0713548162f * v * v);
    return v / (1.0f + __expf(-u));
}

static __device__ __forceinline__ unsigned short f2bf(float f) {
    unsigned int u = __float_as_uint(f);
    u = (u + 0x7fffu + ((u >> 16) & 1u)) >> 16;   // RNE
    return (unsigned short)u;
}

static __device__ __forceinline__ float bf2f(unsigned short u) {
    return __uint_as_float((unsigned int)u << 16);
}

static __device__ __forceinline__ unsigned int pack2bf(float a, float b) {
    return (unsigned int)f2bf(a) | ((unsigned int)f2bf(b) << 16);
}

// Packed-o address: fragment (Mt,ks), lane l, window (b,wh,ww).
// Bijective permutation of the window's own nf bytes -> safe in-place overlay.
static __device__ __forceinline__ size_t opk_addr(int b, int wh, int ww, int Mt, int ks, int lane) {
    return ((size_t)(b * 16384) + (wh * 8 + Mt * 2 + (ks >> 1)) * 128 + ww * 8) * 128
           + (ks & 1) * 512 + lane * 8;
}

// ---------------------------------------------------------------------------
// K1: cost volume, register-blocked band correlation.
__global__ __launch_bounds__(384) void k_cost(const float* __restrict__ fl,
                                              const float* __restrict__ fr,
                                              float* __restrict__ cost) {
    __shared__ float s_fl[2][16][64];
    __shared__ float s_fr[2][16][112];
    int tid = threadIdx.x;
    int w0 = blockIdx.x * 64;
    int hp = blockIdx.y, b = blockIdx.z;
    int row = tid / 192;
    int r = tid - row * 192;
    int wg = r & 15, dg = r >> 4;
    int W = wg * 4, D = dg * 4;
    int h = hp * 2 + row;
    float acc[4][4];
#pragma unroll
    for (int i = 0; i < 4; ++i)
#pragma unroll
        for (int j = 0; j < 4; ++j) acc[i][j] = 0.f;

#pragma unroll 1
    for (int ck = 0; ck < 8; ++ck) {
        int ci0 = ck * 16;
        for (int i = tid; i < 512; i += 384) {
            int rr = i >> 8, rem = i & 255;
            int c = rem >> 4, k4 = rem & 15;
            float4 v = *(const float4*)&fl[((size_t)(b * 128 + ci0 + c) << 14) + (hp * 2 + rr) * 128 + w0 + k4 * 4];
            *(float4*)&s_fl[rr][c][k4 * 4] = v;
        }
        for (int i = tid; i < 896; i += 384) {
            int rr = i / 448, rem = i - rr * 448;
            int c = rem / 28, k4 = rem - c * 28;
            int wgl = w0 - 48 + k4 * 4;
            float4 v = {0.f, 0.f, 0.f, 0.f};
            if (wgl >= 0)
                v = *(const float4*)&fr[((size_t)(b * 128 + ci0 + c) << 14) + (hp * 2 + rr) * 128 + wgl];
            *(float4*)&s_fr[rr][c][k4 * 4] = v;
        }
        __syncthreads();
#pragma unroll
        for (int c = 0; c < 16; ++c) {
            float4 flv = *(const float4*)&s_fl[row][c][W];
            int base = W - D + 44;
            float4 f0 = *(const float4*)&s_fr[row][c][base];
            float4 f1 = *(const float4*)&s_fr[row][c][base + 4];
            float fw[8] = {f0.x, f0.y, f0.z, f0.w, f1.x, f1.y, f1.z, f1.w};
            float fv[4] = {flv.x, flv.y, flv.z, flv.w};
#pragma unroll
            for (int dj = 0; dj < 4; ++dj)
#pragma unroll
                for (int wv = 0; wv < 4; ++wv)
                    acc[dj][wv] += fv[wv] * fw[wv - dj + 4];
        }
        __syncthreads();
    }
    const float inv = 1.0f / 128.0f;
#pragma unroll
    for (int dj = 0; dj < 4; ++dj) {
        float4 o = {acc[dj][0] * inv, acc[dj][1] * inv, acc[dj][2] * inv, acc[dj][3] * inv};
        *(float4*)&cost[((size_t)(b * 48 + D + dj) << 14) + h * 128 + w0 + W] = o;
    }
}

// ---------------------------------------------------------------------------
// Pack helpers fused into one kernel.
static __device__ void pack_conv(int blk, int lane,
                                 const float* __restrict__ w1, const float* __restrict__ b1,
                                 const float* __restrict__ bng, const float* __restrict__ bnb,
                                 unsigned short* __restrict__ pk, float* __restrict__ bias2) {
    const float rs = 0.9999950000374997f;
    int ct = blk % 6;
    int taplin = blk / 6;
    int tap = taplin % 9, chunk = taplin / 9;
    int co = ct * 16 + (lane & 15);
    int cibase = chunk * 32 + (lane >> 4) * 8;
    u16x8 out;
#pragma unroll
    for (int j = 0; j < 8; ++j) {
        int ci = cibase + j;
        float v = 0.f;
        if (co < 88 && ci < 176) v = w1[(size_t)co * 1584 + ci * 9 + tap] * rs * bng[co];
        out[j] = f2bf(v);
    }
    *(u16x8*)(pk + ((size_t)blk * 64 + lane) * 8) = out;
    if (blk == 0) {
        for (int i = lane; i < 96; i += 64)
            bias2[i] = (i < 88) ? (b1[i] * rs * bng[i] + bnb[i]) : 0.f;
    }
}

static __device__ void pack_gemmB(int blk, int lane,
                                  const float* __restrict__ W,
                                  unsigned short* __restrict__ out, int ncols) {
    int ntiles = ncols >> 4;
    int ks = blk & 3;
    int nt = (blk >> 2) % ntiles;
    int kc = blk / (4 * ntiles);
    int col = nt * 16 + (lane & 15);
    int k0 = kc * 128 + ks * 32 + (lane >> 4) * 8;
    u16x8 o;
#pragma unroll
    for (int j = 0; j < 8; ++j) o[j] = f2bf(W[(size_t)(k0 + j) * ncols + col]);
    *(u16x8*)(out + ((size_t)blk * 64 + lane) * 8) = o;
}

static __device__ void pack_rpb(int blk, int lane,
                                const float* __restrict__ rpb, float* __restrict__ pb) {
    int nt = blk & 3, mt = (blk >> 2) & 3, hh = blk >> 4;
    int m = nt * 16 + (lane & 15);
    int g = lane >> 4;
    float o[4];
#pragma unroll
    for (int rr = 0; rr < 4; ++rr) {
        int n = mt * 16 + g * 4 + rr;
        int relidx = (((n >> 3) - (m >> 3)) + 7) * 15 + ((n & 7) - (m & 7)) + 7;
        o[rr] = rpb[relidx * 8 + hh];
    }
    float4 v = {o[0], o[1], o[2], o[3]};
    *(float4*)(pb + ((size_t)blk * 64 + lane) * 4) = v;
}

__global__ __launch_bounds__(64) void k_pack_all(
        const float* __restrict__ dp_w1, const float* __restrict__ dp_b1,
        const float* __restrict__ bn_g, const float* __restrict__ bn_b,
        unsigned short* __restrict__ pk, float* __restrict__ bias2,
        const float* __restrict__ wq, const float* __restrict__ wk,
        const float* __restrict__ wv, const float* __restrict__ wp,
        unsigned short* __restrict__ pkw,
        const float* __restrict__ rpb, float* __restrict__ pb,
        const float* __restrict__ mlp_w1, unsigned short* __restrict__ pm1,
        const float* __restrict__ mlp_w2, unsigned short* __restrict__ pm2,
        const float* __restrict__ un_w1, unsigned short* __restrict__ pu1,
        const float* __restrict__ un_w2, unsigned short* __restrict__ pu2) {
    int blk = blockIdx.x;
    int lane = threadIdx.x;
    if (blk < 324) {
        pack_conv(blk, lane, dp_w1, dp_b1, bn_g, bn_b, pk, bias2);
    } else if (blk < 452) {
        int bb = blk - 324;
        int mat = bb >> 5;
        const float* W = (mat == 0) ? wq : (mat == 1) ? wk : (mat == 2) ? wv : wp;
        pack_gemmB(bb & 31, lane, W, pkw + (size_t)mat * 16384, 128);
    } else if (blk < 580) {
        pack_rpb(blk - 452, lane, rpb, pb);
    } else if (blk < 708) {
        pack_gemmB(blk - 580, lane, mlp_w1, pm1, 512);
    } else if (blk < 836) {
        pack_gemmB(blk - 708, lane, mlp_w2, pm2, 128);
    } else if (blk < 868) {
        pack_gemmB(blk - 836, lane, un_w1, pu1, 128);
    } else {
        pack_gemmB(blk - 868, lane, un_w2, pu2, 128);
    }
}

// ---------------------------------------------------------------------------
// K2: unary MLP via MFMA + LN1 producer. 1024 blocks x 64 tokens, 4 waves.
// Writes x = unary(tok) and nf = LN1(tok) (token-major bf16).
__global__ __launch_bounds__(256) void k_unary_mfma(const float* __restrict__ feat_l,
                                                    const unsigned short* __restrict__ pu1,
                                                    const float* __restrict__ b1,
                                                    const unsigned short* __restrict__ pu2,
                                                    const float* __restrict__ b2,
                                                    const float* __restrict__ g1,
                                                    const float* __restrict__ bt1,
                                                    float* __restrict__ x,
                                                    unsigned short* __restrict__ nf) {
    __shared__ __align__(16) unsigned short s_a[64 * 136];
    __shared__ __align__(16) unsigned short s_h[64 * 136];
    int tid = threadIdx.x;
    int wid = tid >> 6, lane = tid & 63;
    int g = lane >> 4, t = lane & 15;
    int n0g = blockIdx.x * 64;
    int b = n0g >> 14;
    int nb = n0g & 16383;

    for (int idx = tid; idx < 4096; idx += 256) {
        int c2 = idx >> 6, nl = idx & 63;
        float v0 = feat_l[((size_t)(b * 128 + 2 * c2) << 14) + nb + nl];
        float v1 = feat_l[((size_t)(b * 128 + 2 * c2 + 1) << 14) + nb + nl];
        *(unsigned int*)&s_a[nl * 136 + 2 * c2] = pack2bf(v0, v1);
    }
    __syncthreads();

    // ---- LN1 -> nf (token-major bf16), vectorized loads/stores ----
    {
        int tok = tid >> 2, q = tid & 3;
        float v[32];
#pragma unroll
        for (int i8 = 0; i8 < 4; ++i8) {
            u16x8 r8 = *(const u16x8*)&s_a[tok * 136 + q * 32 + i8 * 8];
#pragma unroll
            for (int j = 0; j < 8; ++j) v[i8 * 8 + j] = bf2f(r8[j]);
        }
        float s = 0.f, s2 = 0.f;
#pragma unroll
        for (int i = 0; i < 32; ++i) { s += v[i]; s2 += v[i] * v[i]; }
        s += __shfl_xor(s, 1); s += __shfl_xor(s, 2);
        s2 += __shfl_xor(s2, 1); s2 += __shfl_xor(s2, 2);
        float mean = s * (1.f / 128.f);
        float var = s2 * (1.f / 128.f) - mean * mean;
        float rstd = rsqrtf(var + 1e-5f);
        size_t base = (size_t)(n0g + tok) * 128 + q * 32;
#pragma unroll
        for (int i8 = 0; i8 < 4; ++i8) {
            u16x8 o8;
#pragma unroll
            for (int j = 0; j < 8; ++j) {
                int c = q * 32 + i8 * 8 + j;
                o8[j] = f2bf((v[i8 * 8 + j] - mean) * rstd * g1[c] + bt1[c]);
            }
            *(u16x8*)&nf[base + i8 * 8] = o8;
        }
    }

    bf16x8 af[4][4];
#pragma unroll
    for (int Mt = 0; Mt < 4; ++Mt)
#pragma unroll
        for (int ks = 0; ks < 4; ++ks)
            af[Mt][ks] = *(const bf16x8*)&s_a[(Mt * 16 + t) * 136 + ks * 32 + g * 8];

    f32x4 acc1[4][2];
#pragma unroll
    for (int nt2 = 0; nt2 < 2; ++nt2) {
        float bv = b1[(wid * 2 + nt2) * 16 + t];
#pragma unroll
        for (int Mt = 0; Mt < 4; ++Mt) acc1[Mt][nt2] = (f32x4){bv, bv, bv, bv};
    }
#pragma unroll
    for (int ks = 0; ks < 4; ++ks) {
        bf16x8 bf0 = *(const bf16x8*)(pu1 + (size_t)(((wid * 2 + 0) * 4 + ks) * 64 + lane) * 8);
        bf16x8 bf1 = *(const bf16x8*)(pu1 + (size_t)(((wid * 2 + 1) * 4 + ks) * 64 + lane) * 8);
#pragma unroll
        for (int Mt = 0; Mt < 4; ++Mt) {
            acc1[Mt][0] = __builtin_amdgcn_mfma_f32_16x16x32_bf16(af[Mt][ks], bf0, acc1[Mt][0], 0, 0, 0);
            acc1[Mt][1] = __builtin_amdgcn_mfma_f32_16x16x32_bf16(af[Mt][ks], bf1, acc1[Mt][1], 0, 0, 0);
        }
    }
#pragma unroll
    for (int Mt = 0; Mt < 4; ++Mt)
#pragma unroll
        for (int nt2 = 0; nt2 < 2; ++nt2)
#pragma unroll
            for (int rr = 0; rr < 4; ++rr)
                s_h[(Mt * 16 + g * 4 + rr) * 136 + (wid * 2 + nt2) * 16 + t] = f2bf(gelu_f(acc1[Mt][nt2][rr]));
    __syncthreads();

    bf16x8 a2[4][4];
#pragma unroll
    for (int Mt = 0; Mt < 4; ++Mt)
#pragma unroll
        for (int ks = 0; ks < 4; ++ks)
            a2[Mt][ks] = *(const bf16x8*)&s_h[(Mt * 16 + t) * 136 + ks * 32 + g * 8];

    f32x4 acc2[4][2];
#pragma unroll
    for (int nt2 = 0; nt2 < 2; ++nt2) {
        float bv = b2[(wid * 2 + nt2) * 16 + t];
#pragma unroll
        for (int Mt = 0; Mt < 4; ++Mt) acc2[Mt][nt2] = (f32x4){bv, bv, bv, bv};
    }
#pragma unroll
    for (int ks = 0; ks < 4; ++ks) {
        bf16x8 bf0 = *(const bf16x8*)(pu2 + (size_t)(((wid * 2 + 0) * 4 + ks) * 64 + lane) * 8);
        bf16x8 bf1 = *(const bf16x8*)(pu2 + (size_t)(((wid * 2 + 1) * 4 + ks) * 64 + lane) * 8);
#pragma unroll
        for (int Mt = 0; Mt < 4; ++Mt) {
            acc2[Mt][0] = __builtin_amdgcn_mfma_f32_16x16x32_bf16(a2[Mt][ks], bf0, acc2[Mt][0], 0, 0, 0);
            acc2[Mt][1] = __builtin_amdgcn_mfma_f32_16x16x32_bf16(a2[Mt][ks], bf1, acc2[Mt][1], 0, 0, 0);
        }
    }
#pragma unroll
    for (int Mt = 0; Mt < 4; ++Mt)
#pragma unroll
        for (int nt2 = 0; nt2 < 2; ++nt2)
#pragma unroll
            for (int rr = 0; rr < 4; ++rr) {
                int tok = Mt * 16 + g * 4 + rr;
                x[(size_t)(n0g + tok) * 128 + (wid * 2 + nt2) * 16 + t] = acc2[Mt][nt2][rr];
            }
}

// ---------------------------------------------------------------------------
// K3: attention core. 1024 blocks (1 window), 256 threads (4 waves).
// Reads LN'd tokens from nf; writes fragment-packed o IN PLACE over nf.
// K-padding of Q/K is done with REGISTER zeros (lanes g>=2), no LDS pad storage.
__global__ __launch_bounds__(256, 3) void k_attn_core(const unsigned short* nf,
                                                      const unsigned short* __restrict__ pkw,
                                                      const float* __restrict__ pb,
                                                      const float* __restrict__ bq,
                                                      const float* __restrict__ bk,
                                                      const float* __restrict__ bv,
                                                      unsigned short* opk) {
    // per-wave scratch 11520 B (5760 shorts):
    //   sQ[64][24] (3072B) | sK[64][24] (3072B) at base (overlaid by sP[64][72] 9216B)
    //   sV[16][72] (2304B) at +4608 shorts.  sO[64][16] overlays sP.
    __shared__ __align__(16) unsigned short s_all[4 * 5760];
    int tid = threadIdx.x;
    int wid = tid >> 6, lane = tid & 63;
    int g = lane >> 4, t = lane & 15;
    int bw = blockIdx.x;
    int b = bw >> 8, wh = (bw >> 4) & 15, ww = bw & 15;

    // ---- A-fragments directly from nf (window footprint 16KB, L1/L2-resident) ----
    bf16x8 af[4][4];   // [Mt][ks]
#pragma unroll
    for (int Mt = 0; Mt < 4; ++Mt) {
        int tok = Mt * 16 + t;
        size_t gtok = (size_t)(b * 16384) + (wh * 8 + (tok >> 3)) * 128 + ww * 8 + (tok & 7);
#pragma unroll
        for (int ks = 0; ks < 4; ++ks)
            af[Mt][ks] = *(const bf16x8*)&nf[gtok * 128 + ks * 32 + g * 8];
    }
    __syncthreads();   // all nf reads complete before any in-place opk write

    unsigned short* sQ = s_all + wid * 5760;
    unsigned short* sK = sQ + 1536;
    unsigned short* sV = sQ + 4608;
    unsigned short* sP = sQ;
    unsigned short* sO = sQ;

    const bf16x8 z8v = {0, 0, 0, 0, 0, 0, 0, 0};

#pragma unroll
    for (int hi = 0; hi < 2; ++hi) {
        int h = wid + hi * 4;

        // ---- QKV projection for head h ----
        float bqv = bq[h * 16 + t], bkv = bk[h * 16 + t], bvv = bv[h * 16 + t];
        f32x4 qa[4], ka[4], va[4];
#pragma unroll
        for (int Mt = 0; Mt < 4; ++Mt) {
            qa[Mt] = (f32x4){bqv, bqv, bqv, bqv};
            ka[Mt] = (f32x4){bkv, bkv, bkv, bkv};
            va[Mt] = (f32x4){bvv, bvv, bvv, bvv};
        }
#pragma unroll
        for (int ks = 0; ks < 4; ++ks) {
            const unsigned short* wbase = pkw + ((size_t)((h * 4 + ks) * 64 + lane) * 8);
            bf16x8 bfq = *(const bf16x8*)(wbase);
            bf16x8 bfk = *(const bf16x8*)(wbase + 16384);
            bf16x8 bfv = *(const bf16x8*)(wbase + 32768);
#pragma unroll
            for (int Mt = 0; Mt < 4; ++Mt) {
                qa[Mt] = __builtin_amdgcn_mfma_f32_16x16x32_bf16(af[Mt][ks], bfq, qa[Mt], 0, 0, 0);
                ka[Mt] = __builtin_amdgcn_mfma_f32_16x16x32_bf16(af[Mt][ks], bfk, ka[Mt], 0, 0, 0);
                va[Mt] = __builtin_amdgcn_mfma_f32_16x16x32_bf16(af[Mt][ks], bfv, va[Mt], 0, 0, 0);
            }
        }
        // Q,K: [tok][24] scalar writes (2-way bank alias, free). V: packed b64.
#pragma unroll
        for (int Mt = 0; Mt < 4; ++Mt) {
            bf16x4 vv;
#pragma unroll
            for (int rr = 0; rr < 4; ++rr) {
                int tok = Mt * 16 + g * 4 + rr;
                sQ[tok * 24 + t] = f2bf(qa[Mt][rr] * SCALE);
                sK[tok * 24 + t] = f2bf(ka[Mt][rr]);
                vv[rr] = (short)f2bf(va[Mt][rr]);
            }
            *(bf16x4*)&sV[t * 72 + Mt * 16 + g * 4] = vv;
        }

        // ---- S = Q K^T + bias(C-init); K-pad lanes (g>=2) feed zeros ----
        f32x4 s[4][4];
#pragma unroll
        for (int Mt = 0; Mt < 4; ++Mt)
#pragma unroll
            for (int Nt = 0; Nt < 4; ++Nt)
                s[Mt][Nt] = *(const f32x4*)(pb + ((size_t)((h * 16 + Mt * 4 + Nt) * 64 + lane) * 4));
        bf16x8 bk2[4];
#pragma unroll
        for (int Nt = 0; Nt < 4; ++Nt)
            bk2[Nt] = (g < 2) ? *(const bf16x8*)&sK[(Nt * 16 + t) * 24 + g * 8] : z8v;
#pragma unroll
        for (int Mt = 0; Mt < 4; ++Mt) {
            bf16x8 aq = (g < 2) ? *(const bf16x8*)&sQ[(Mt * 16 + t) * 24 + g * 8] : z8v;
#pragma unroll
            for (int Nt = 0; Nt < 4; ++Nt)
                s[Mt][Nt] = __builtin_amdgcn_mfma_f32_16x16x32_bf16(aq, bk2[Nt], s[Mt][Nt], 0, 0, 0);
        }

        // ---- softmax (unnormalized; divide at sO write) ----
        f32x4 rsm[4];
#pragma unroll
        for (int Mt = 0; Mt < 4; ++Mt) {
            f32x4 m = s[Mt][0];
#pragma unroll
            for (int Nt = 1; Nt < 4; ++Nt)
#pragma unroll
                for (int rr = 0; rr < 4; ++rr) m[rr] = fmaxf(m[rr], s[Mt][Nt][rr]);
#pragma unroll
            for (int sh = 1; sh <= 8; sh <<= 1)
#pragma unroll
                for (int rr = 0; rr < 4; ++rr) m[rr] = fmaxf(m[rr], __shfl_xor(m[rr], sh));
            f32x4 sum = (f32x4){0.f, 0.f, 0.f, 0.f};
#pragma unroll
            for (int Nt = 0; Nt < 4; ++Nt)
#pragma unroll
                for (int rr = 0; rr < 4; ++rr) {
                    float e = __expf(s[Mt][Nt][rr] - m[rr]);
                    s[Mt][Nt][rr] = e;
                    sum[rr] += e;
                }
#pragma unroll
            for (int sh = 1; sh <= 8; sh <<= 1)
#pragma unroll
                for (int rr = 0; rr < 4; ++rr) sum[rr] += __shfl_xor(sum[rr], sh);
            rsm[Mt] = sum;
        }
#pragma unroll
        for (int Mt = 0; Mt < 4; ++Mt)
#pragma unroll
            for (int Nt = 0; Nt < 4; ++Nt)
#pragma unroll
                for (int rr = 0; rr < 4; ++rr)
                    sP[(Mt * 16 + g * 4 + rr) * 72 + Nt * 16 + t] = f2bf(s[Mt][Nt][rr]);

        // ---- O = P @ V ----
        f32x4 oa[4];
#pragma unroll
        for (int Mt = 0; Mt < 4; ++Mt) oa[Mt] = (f32x4){0.f, 0.f, 0.f, 0.f};
#pragma unroll
        for (int ksv = 0; ksv < 2; ++ksv) {
            bf16x8 bv2 = *(const bf16x8*)&sV[t * 72 + ksv * 32 + g * 8];
#pragma unroll
            for (int Mt = 0; Mt < 4; ++Mt) {
                bf16x8 ap = *(const bf16x8*)&sP[(Mt * 16 + t) * 72 + ksv * 32 + g * 8];
                oa[Mt] = __builtin_amdgcn_mfma_f32_16x16x32_bf16(ap, bv2, oa[Mt], 0, 0, 0);
            }
        }
        // ---- normalize -> wave-local LDS transpose -> packed 16B/lane stores ----
#pragma unroll
        for (int Mt = 0; Mt < 4; ++Mt)
#pragma unroll
            for (int rr = 0; rr < 4; ++rr)
                sO[(Mt * 16 + g * 4 + rr) * 16 + t] = f2bf(oa[Mt][rr] / rsm[Mt][rr]);
        // DS ops within a wave are in-order: reads below see the writes above.
        int ksf = h >> 1;
        if ((g >> 1) == (h & 1)) {
#pragma unroll
            for (int Mt = 0; Mt < 4; ++Mt) {
                bf16x8 v8 = *(const bf16x8*)&sO[(Mt * 16 + t) * 16 + (g & 1) * 8];
                *(bf16x8*)&opk[opk_addr(b, wh, ww, Mt, ksf, lane)] = v8;
            }
        }
    }
}

// ---------------------------------------------------------------------------
// K4: per-WINDOW block: x = (x + o@wp + bp) + mlp(LN2(...)).
// o read from fragment-packed opk. (mlp_b2 * 0 in ref -> not added)
__global__ __launch_bounds__(256) void k_mlp_mfma(float* __restrict__ x,
                                                  const unsigned short* __restrict__ opk,
                                                  const unsigned short* __restrict__ pkw,
                                                  const float* __restrict__ bp,
                                                  const float* __restrict__ g2,
                                                  const float* __restrict__ bt2,
                                                  const unsigned short* __restrict__ pm1,
                                                  const float* __restrict__ b1,
                                                  const unsigned short* __restrict__ pm2) {
    __shared__ __align__(16) char smem[51200];
    float* sf = (float*)smem;                       // [64][132] f32
    unsigned short* s_h = (unsigned short*)smem;    // overlays sf after LN
    unsigned short* s_a = (unsigned short*)(smem + 33792);
    int tid = threadIdx.x;
    int wid = tid >> 6, lane = tid & 63;
    int g = lane >> 4, t = lane & 15;
    int bw = blockIdx.x;
    int b = bw >> 8, wh = (bw >> 4) & 15, ww = bw & 15;

    auto gtok_of = [&](int tok) -> size_t {
        return (size_t)(b * 16384) + (wh * 8 + (tok >> 3)) * 128 + ww * 8 + (tok & 7);
    };

    // GEMM0: out = o_window @ wp + bp  (out doubles as final accumulator)
    f32x4 out[4][2];
    {
        float bp0 = bp[wid * 32 + t], bp1 = bp[wid * 32 + 16 + t];
#pragma unroll
        for (int Mt = 0; Mt < 4; ++Mt) {
            out[Mt][0] = (f32x4){bp0, bp0, bp0, bp0};
            out[Mt][1] = (f32x4){bp1, bp1, bp1, bp1};
        }
#pragma unroll
        for (int ks = 0; ks < 4; ++ks) {
            bf16x8 b0 = *(const bf16x8*)(pkw + 49152 + (size_t)(((wid * 2 + 0) * 4 + ks) * 64 + lane) * 8);
            bf16x8 b1v = *(const bf16x8*)(pkw + 49152 + (size_t)(((wid * 2 + 1) * 4 + ks) * 64 + lane) * 8);
#pragma unroll
            for (int Mt = 0; Mt < 4; ++Mt) {
                bf16x8 a = *(const bf16x8*)&opk[opk_addr(b, wh, ww, Mt, ks, lane)];
                out[Mt][0] = __builtin_amdgcn_mfma_f32_16x16x32_bf16(a, b0, out[Mt][0], 0, 0, 0);
                out[Mt][1] = __builtin_amdgcn_mfma_f32_16x16x32_bf16(a, b1v, out[Mt][1], 0, 0, 0);
            }
        }
        // add unary x; stash x_pre_mlp into sf for LN
#pragma unroll
        for (int Mt = 0; Mt < 4; ++Mt)
#pragma unroll
            for (int nt2 = 0; nt2 < 2; ++nt2)
#pragma unroll
                for (int rr = 0; rr < 4; ++rr) {
                    int tok = Mt * 16 + g * 4 + rr;
                    int col = (wid * 2 + nt2) * 16 + t;
                    float v = out[Mt][nt2][rr] + x[gtok_of(tok) * 128 + col];
                    out[Mt][nt2][rr] = v;
                    sf[tok * 132 + col] = v;
                }
    }
    __syncthreads();
    // LN2 -> bf16 s_a
    {
        int tok = tid >> 2, q = tid & 3;
        float s = 0.f, s2 = 0.f;
        for (int c = q * 32; c < q * 32 + 32; ++c) {
            float v = sf[tok * 132 + c];
            s += v; s2 += v * v;
        }
        s += __shfl_xor(s, 1); s += __shfl_xor(s, 2);
        s2 += __shfl_xor(s2, 1); s2 += __shfl_xor(s2, 2);
        float mean = s * (1.f / 128.f);
        float var = s2 * (1.f / 128.f) - mean * mean;
        float rstd = rsqrtf(var + 1e-5f);
        for (int c = q * 32; c < q * 32 + 32; c += 2) {
            float v0 = (sf[tok * 132 + c] - mean) * rstd * g2[c] + bt2[c];
            float v1 = (sf[tok * 132 + c + 1] - mean) * rstd * g2[c + 1] + bt2[c + 1];
            *(unsigned int*)&s_a[tok * 136 + c] = pack2bf(v0, v1);
        }
    }
    __syncthreads();
    bf16x8 af[4][4];
#pragma unroll
    for (int Mt = 0; Mt < 4; ++Mt)
#pragma unroll
        for (int ks = 0; ks < 4; ++ks)
            af[Mt][ks] = *(const bf16x8*)&s_a[(Mt * 16 + t) * 136 + ks * 32 + g * 8];

#pragma unroll 1
    for (int hc = 0; hc < 4; ++hc) {
        f32x4 acc1[4][2];
#pragma unroll
        for (int nt2 = 0; nt2 < 2; ++nt2) {
            float bv = b1[hc * 128 + (wid * 2 + nt2) * 16 + t];
#pragma unroll
            for (int Mt = 0; Mt < 4; ++Mt) acc1[Mt][nt2] = (f32x4){bv, bv, bv, bv};
        }
#pragma unroll
        for (int ks = 0; ks < 4; ++ks) {
            bf16x8 bf0 = *(const bf16x8*)(pm1 + (size_t)(((hc * 8 + wid * 2 + 0) * 4 + ks) * 64 + lane) * 8);
            bf16x8 bf1 = *(const bf16x8*)(pm1 + (size_t)(((hc * 8 + wid * 2 + 1) * 4 + ks) * 64 + lane) * 8);
#pragma unroll
            for (int Mt = 0; Mt < 4; ++Mt) {
                acc1[Mt][0] = __builtin_amdgcn_mfma_f32_16x16x32_bf16(af[Mt][ks], bf0, acc1[Mt][0], 0, 0, 0);
                acc1[Mt][1] = __builtin_amdgcn_mfma_f32_16x16x32_bf16(af[Mt][ks], bf1, acc1[Mt][1], 0, 0, 0);
            }
        }
#pragma unroll
        for (int Mt = 0; Mt < 4; ++Mt)
#pragma unroll
            for (int nt2 = 0; nt2 < 2; ++nt2)
#pragma unroll
                for (int rr = 0; rr < 4; ++rr)
                    s_h[(Mt * 16 + g * 4 + rr) * 136 + (wid * 2 + nt2) * 16 + t] = f2bf(gelu_f(acc1[Mt][nt2][rr]));
        __syncthreads();
        bf16x8 a2[4][4];
#pragma unroll
        for (int Mt = 0; Mt < 4; ++Mt)
#pragma unroll
            for (int ks = 0; ks < 4; ++ks)
                a2[Mt][ks] = *(const bf16x8*)&s_h[(Mt * 16 + t) * 136 + ks * 32 + g * 8];
#pragma unroll
        for (int ks = 0; ks < 4; ++ks) {
            bf16x8 bf0 = *(const bf16x8*)(pm2 + (size_t)((hc * 32 + (wid * 2 + 0) * 4 + ks) * 64 + lane) * 8);
            bf16x8 bf1 = *(const bf16x8*)(pm2 + (size_t)((hc * 32 + (wid * 2 + 1) * 4 + ks) * 64 + lane) * 8);
#pragma unroll
            for (int Mt = 0; Mt < 4; ++Mt) {
                out[Mt][0] = __builtin_amdgcn_mfma_f32_16x16x32_bf16(a2[Mt][ks], bf0, out[Mt][0], 0, 0, 0);
                out[Mt][1] = __builtin_amdgcn_mfma_f32_16x16x32_bf16(a2[Mt][ks], bf1, out[Mt][1], 0, 0, 0);
            }
        }
        __syncthreads();
    }

    // final: x = x_pre_mlp + mlp_out
#pragma unroll
    for (int Mt = 0; Mt < 4; ++Mt)
#pragma unroll
        for (int nt2 = 0; nt2 < 2; ++nt2)
#pragma unroll
            for (int rr = 0; rr < 4; ++rr) {
                int tok = Mt * 16 + g * 4 + rr;
                x[gtok_of(tok) * 128 + (wid * 2 + nt2) * 16 + t] = out[Mt][nt2][rr];
            }
}

// ---------------------------------------------------------------------------
// K5b: conv3x3 as bf16 implicit-GEMM MFMA. grid (8,8,4), 256 threads.
__global__ __launch_bounds__(256) void k_conv_mfma(const float* __restrict__ x,
                                                   const float* __restrict__ cost,
                                                   const unsigned short* __restrict__ pk,
                                                   const float* __restrict__ bias2,
                                                   float* __restrict__ h1) {
    __shared__ __align__(16) unsigned short s_p[324 * 40];
    int tid = threadIdx.x;
    int wid = tid >> 6, lane = tid & 63;
    int g = lane >> 4, t = lane & 15;
    int tx0 = blockIdx.x * 16, ty0 = blockIdx.y * 16, b = blockIdx.z;

    f32x4 acc[4][6];
#pragma unroll
    for (int p = 0; p < 4; ++p)
#pragma unroll
        for (int ct = 0; ct < 6; ++ct) acc[p][ct] = (f32x4){0.f, 0.f, 0.f, 0.f};

#pragma unroll 1
    for (int chunk = 0; chunk < 6; ++chunk) {
        if (chunk < 4) {
            int ci0 = chunk * 32;
            for (int u = tid; u < 648; u += 256) {
                int pos = u >> 1, half = u & 1;
                int yy = pos / 18, xx = pos - yy * 18;
                int gy = ty0 + yy - 1, gx = tx0 + xx - 1;
                u16x8 lo, hi;
                if (gy >= 0 && gy < 128 && gx >= 0 && gx < 128) {
                    const float4* src = (const float4*)&x[((size_t)(b << 14) + gy * 128 + gx) * 128 + ci0 + half * 16];
                    float4 v0 = src[0], v1 = src[1], v2 = src[2], v3 = src[3];
                    lo[0] = f2bf(v0.x); lo[1] = f2bf(v0.y); lo[2] = f2bf(v0.z); lo[3] = f2bf(v0.w);
                    lo[4] = f2bf(v1.x); lo[5] = f2bf(v1.y); lo[6] = f2bf(v1.z); lo[7] = f2bf(v1.w);
                    hi[0] = f2bf(v2.x); hi[1] = f2bf(v2.y); hi[2] = f2bf(v2.z); hi[3] = f2bf(v2.w);
                    hi[4] = f2bf(v3.x); hi[5] = f2bf(v3.y); hi[6] = f2bf(v3.z); hi[7] = f2bf(v3.w);
                } else {
                    lo = (u16x8)(unsigned short)0; hi = (u16x8)(unsigned short)0;
                }
                unsigned short* dst = &s_p[pos * 40 + half * 16];
                *(u16x8*)dst = lo;
                *(u16x8*)(dst + 8) = hi;
            }
        } else {
            int d0 = (chunk - 4) * 32;
            for (int u = tid; u < 576; u += 256) {
                int cl = u / 18, yy = u - cl * 18;
                int d = d0 + cl;
                int gy = ty0 + yy - 1;
                bool rowok = (d < 48) && (gy >= 0) && (gy < 128);
                const float* srow = cost + ((size_t)(b * 48 + (rowok ? d : 0)) << 14) + (rowok ? gy : 0) * 128;
                for (int xx = 0; xx < 18; ++xx) {
                    int gx = tx0 + xx - 1;
                    float v = (rowok && gx >= 0 && gx < 128) ? srow[gx] : 0.f;
                    s_p[(yy * 18 + xx) * 40 + cl] = f2bf(v);
                }
            }
        }
        __syncthreads();

#pragma unroll 1
        for (int tap = 0; tap < 9; ++tap) {
            int dy = tap / 3, dx = tap - dy * 3;
            const unsigned short* pkt = pk + ((size_t)(chunk * 9 + tap)) * 6 * 512;
            bf16x8 afr[6];
#pragma unroll
            for (int ct = 0; ct < 6; ++ct)
                afr[ct] = *(const bf16x8*)(pkt + ct * 512 + lane * 8);
            bf16x8 bfr[4];
#pragma unroll
            for (int p = 0; p < 4; ++p) {
                int pos = (wid * 4 + p + dy) * 18 + t + dx;
                bfr[p] = *(const bf16x8*)&s_p[pos * 40 + g * 8];
            }
#pragma unroll
            for (int p = 0; p < 4; ++p)
#pragma unroll
                for (int ct = 0; ct < 6; ++ct)
                    acc[p][ct] = __builtin_amdgcn_mfma_f32_16x16x32_bf16(afr[ct], bfr[p], acc[p][ct], 0, 0, 0);
        }
        __syncthreads();
    }

#pragma unroll
    for (int p = 0; p < 4; ++p) {
        int y = ty0 + wid * 4 + p;
#pragma unroll
        for (int ct = 0; ct < 6; ++ct) {
#pragma unroll
            for (int rr = 0; rr < 4; ++rr) {
                int co = ct * 16 + g * 4 + rr;
                if (co < 88) {
                    float v = acc[p][ct][rr] + bias2[co];
                    h1[((size_t)(b * 88 + co) << 14) + y * 128 + tx0 + t] = fmaxf(v, 0.f);
                }
            }
        }
    }
}

// ---------------------------------------------------------------------------
// K6: pv = conv1x1(h1) + b2; softmax over D; pred = 4*sum(d*p). 256 blocks.
__global__ __launch_bounds__(256) void k_head(const float* __restrict__ h1,
                                              const float* __restrict__ w2, const float* __restrict__ b2,
                                              float* __restrict__ out) {
    __shared__ float s_wt[88 * 48];   // [k][d]
    __shared__ float s_b[48];
    int tid = threadIdx.x;
    for (int idx = tid; idx < 48 * 88; idx += 256) {
        int d = idx / 88, k = idx % 88;
        s_wt[k * 48 + d] = w2[idx];
    }
    if (tid < 48) s_b[tid] = b2[tid];
    __syncthreads();
    int px = blockIdx.x * 256 + tid;
    int b = px >> 14, r = px & 16383;
    float acc[48];
#pragma unroll
    for (int d = 0; d < 48; ++d) acc[d] = s_b[d];
    for (int k = 0; k < 88; ++k) {
        float hv = h1[((size_t)(b * 88 + k) << 14) + r];
        const float4* wrow = (const float4*)&s_wt[k * 48];
#pragma unroll
        for (int d4 = 0; d4 < 12; ++d4) {
            float4 wv = wrow[d4];
            acc[d4 * 4 + 0] += hv * wv.x;
            acc[d4 * 4 + 1] += hv * wv.y;
            acc[d4 * 4 + 2] += hv * wv.z;
            acc[d4 * 4 + 3] += hv * wv.w;
        }
    }
    float mx = -1e30f;
#pragma unroll
    for (int d = 0; d < 48; ++d) mx = fmaxf(mx, acc[d]);
    float sum = 0.f, wsum = 0.f;
#pragma unroll
    for (int d = 0; d < 48; ++d) {
        float e = expf(acc[d] - mx);
        sum += e;
        wsum += e * (float)d;
    }
    out[px] = 4.0f * wsum / sum;
}

// ---------------------------------------------------------------------------
extern "C" void kernel_launch(void* const* d_in, const int* in_sizes, int n_in,
                              void* d_out, int out_size, void* d_ws, size_t ws_size,
                              hipStream_t stream) {
    const float* feat_l = (const float*)d_in[0];
    const float* feat_r = (const float*)d_in[1];
    const float* wq = (const float*)d_in[2];
    const float* bq = (const float*)d_in[3];
    const float* wk = (const float*)d_in[4];
    const float* bk = (const float*)d_in[5];
    const float* wv = (const float*)d_in[6];
    const float* bv = (const float*)d_in[7];
    const float* wp = (const float*)d_in[8];
    const float* bp = (const float*)d_in[9];
    const float* rpb = (const float*)d_in[10];
    const float* ln1_g = (const float*)d_in[11];
    const float* ln1_b = (const float*)d_in[12];
    const float* ln2_g = (const float*)d_in[13];
    const float* ln2_b = (const float*)d_in[14];
    const float* mlp_w1 = (const float*)d_in[15];
    const float* mlp_b1 = (const float*)d_in[16];
    const float* mlp_w2 = (const float*)d_in[17];
    // d_in[18] = mlp_b2 is multiplied by 0.0 in the reference -> unused
    const float* un_w1 = (const float*)d_in[19];
    const float* un_b1 = (const float*)d_in[20];
    const float* un_w2 = (const float*)d_in[21];
    const float* un_b2 = (const float*)d_in[22];
    const float* dp_w1 = (const float*)d_in[23];
    const float* dp_b1 = (const float*)d_in[24];
    const float* bn_g = (const float*)d_in[25];
    const float* bn_b = (const float*)d_in[26];
    const float* dp_w2 = (const float*)d_in[27];
    const float* dp_b2 = (const float*)d_in[28];

    float* ws = (float*)d_ws;
    float* cost = ws;                               // 3,145,728 f
    float* x = ws + 3145728;                        // 8,388,608 f
    float* h1 = ws + 11534336;                      // 5,767,168 f
    // nf (LN1'd tokens, bf16, 16 MB) overlays h1; attn converts it IN PLACE to
    // packed o; mlp consumes o; conv then overwrites region with h1.
    unsigned short* nfo = (unsigned short*)h1;
    unsigned short* pk = (unsigned short*)(ws + 17301504);       // 165,888 u16
    float* bias2 = ws + 17384448;                   // 96 f
    unsigned short* pkw = (unsigned short*)(ws + 17384544);      // 65,536 u16
    float* pb = ws + 17417312;                      // 32,768 f
    unsigned short* pm1 = (unsigned short*)(ws + 17450080);      // 65,536 u16
    unsigned short* pm2 = (unsigned short*)(ws + 17482848);      // 65,536 u16
    unsigned short* pu1 = (unsigned short*)(ws + 17515616);      // 16,384 u16
    unsigned short* pu2 = (unsigned short*)(ws + 17523808);      // 16,384 u16
    float* out = (float*)d_out;

    k_pack_all<<<900, 64, 0, stream>>>(dp_w1, dp_b1, bn_g, bn_b, pk, bias2,
                                       wq, wk, wv, wp, pkw, rpb, pb,
                                       mlp_w1, pm1, mlp_w2, pm2,
                                       un_w1, pu1, un_w2, pu2);
    k_cost<<<dim3(2, 64, 4), 384, 0, stream>>>(feat_l, feat_r, cost);
    k_unary_mfma<<<1024, 256, 0, stream>>>(feat_l, pu1, un_b1, pu2, un_b2,
                                           ln1_g, ln1_b, x, nfo);
    k_attn_core<<<1024, 256, 0, stream>>>(nfo, pkw, pb, bq, bk, bv, nfo);
    k_mlp_mfma<<<1024, 256, 0, stream>>>(x, nfo, pkw, bp, ln2_g, ln2_b,
                                         pm1, mlp_b1, pm2);
    k_conv_mfma<<<dim3(8, 8, 4), 256, 0, stream>>>(x, cost, pk, bias2, h1);
    k_head<<<256, 256, 0, stream>>>(h1, dp_w2, dp_b2, out);
}

// Round 9
// 293.743 us; speedup vs baseline: 8.2825x; 1.0355x over previous
//
#include <hip/hip_runtime.h>
#include <math.h>

// Dims
constexpr int Bn = 4, Cc = 128, Hh = 128, Wn = 128, Dd = 48;
constexpr float SCALE = 0.25f;       // 16^-0.5

typedef short  bf16x8 __attribute__((ext_vector_type(8)));
typedef short  bf16x4 __attribute__((ext_vector_type(4)));
typedef float  f32x4  __attribute__((ext_vector_type(4)));
typedef unsigned short u16x8 __attribute__((ext_vector_type(8)));

// tanh-form GELU: v * sigmoid(1.59576912 v + 0.07135481 v^3).
static __device__ __forceinline__ float gelu_f(float v) {
    float u = v * (1.5957691216f + 0.0713548162f * v * v);
    return v / (1.0f + __expf(-u));
}

static __device__ __forceinline__ unsigned short f2bf(float f) {
    unsigned int u = __float_as_uint(f);
    u = (u + 0x7fffu + ((u >> 16) & 1u)) >> 16;   // RNE
    return (unsigned short)u;
}

static __device__ __forceinline__ float bf2f(unsigned short u) {
    return __uint_as_float((unsigned int)u << 16);
}

static __device__ __forceinline__ unsigned int pack2bf(float a, float b) {
    return (unsigned int)f2bf(a) | ((unsigned int)f2bf(b) << 16);
}

// Packed-o address: fragment (Mt,ks), lane l, window (b,wh,ww).
// Bijective permutation of the window's own nf bytes -> safe in-place overlay.
static __device__ __forceinline__ size_t opk_addr(int b, int wh, int ww, int Mt, int ks, int lane) {
    return ((size_t)(b * 16384) + (wh * 8 + Mt * 2 + (ks >> 1)) * 128 + ww * 8) * 128
           + (ks & 1) * 512 + lane * 8;
}

// ---------------------------------------------------------------------------
// K1: cost volume, register-blocked band correlation.
__global__ __launch_bounds__(384) void k_cost(const float* __restrict__ fl,
                                              const float* __restrict__ fr,
                                              float* __restrict__ cost) {
    __shared__ float s_fl[2][16][64];
    __shared__ float s_fr[2][16][112];
    int tid = threadIdx.x;
    int w0 = blockIdx.x * 64;
    int hp = blockIdx.y, b = blockIdx.z;
    int row = tid / 192;
    int r = tid - row * 192;
    int wg = r & 15, dg = r >> 4;
    int W = wg * 4, D = dg * 4;
    int h = hp * 2 + row;
    float acc[4][4];
#pragma unroll
    for (int i = 0; i < 4; ++i)
#pragma unroll
        for (int j = 0; j < 4; ++j) acc[i][j] = 0.f;

#pragma unroll 1
    for (int ck = 0; ck < 8; ++ck) {
        int ci0 = ck * 16;
        for (int i = tid; i < 512; i += 384) {
            int rr = i >> 8, rem = i & 255;
            int c = rem >> 4, k4 = rem & 15;
            float4 v = *(const float4*)&fl[((size_t)(b * 128 + ci0 + c) << 14) + (hp * 2 + rr) * 128 + w0 + k4 * 4];
            *(float4*)&s_fl[rr][c][k4 * 4] = v;
        }
        for (int i = tid; i < 896; i += 384) {
            int rr = i / 448, rem = i - rr * 448;
            int c = rem / 28, k4 = rem - c * 28;
            int wgl = w0 - 48 + k4 * 4;
            float4 v = {0.f, 0.f, 0.f, 0.f};
            if (wgl >= 0)
                v = *(const float4*)&fr[((size_t)(b * 128 + ci0 + c) << 14) + (hp * 2 + rr) * 128 + wgl];
            *(float4*)&s_fr[rr][c][k4 * 4] = v;
        }
        __syncthreads();
#pragma unroll
        for (int c = 0; c < 16; ++c) {
            float4 flv = *(const float4*)&s_fl[row][c][W];
            int base = W - D + 44;
            float4 f0 = *(const float4*)&s_fr[row][c][base];
            float4 f1 = *(const float4*)&s_fr[row][c][base + 4];
            float fw[8] = {f0.x, f0.y, f0.z, f0.w, f1.x, f1.y, f1.z, f1.w};
            float fv[4] = {flv.x, flv.y, flv.z, flv.w};
#pragma unroll
            for (int dj = 0; dj < 4; ++dj)
#pragma unroll
                for (int wv = 0; wv < 4; ++wv)
                    acc[dj][wv] += fv[wv] * fw[wv - dj + 4];
        }
        __syncthreads();
    }
    const float inv = 1.0f / 128.0f;
#pragma unroll
    for (int dj = 0; dj < 4; ++dj) {
        float4 o = {acc[dj][0] * inv, acc[dj][1] * inv, acc[dj][2] * inv, acc[dj][3] * inv};
        *(float4*)&cost[((size_t)(b * 48 + D + dj) << 14) + h * 128 + w0 + W] = o;
    }
}

// ---------------------------------------------------------------------------
// Pack helpers fused into one kernel.
static __device__ void pack_conv(int blk, int lane,
                                 const float* __restrict__ w1, const float* __restrict__ b1,
                                 const float* __restrict__ bng, const float* __restrict__ bnb,
                                 unsigned short* __restrict__ pk, float* __restrict__ bias2) {
    const float rs = 0.9999950000374997f;
    int ct = blk % 6;
    int taplin = blk / 6;
    int tap = taplin % 9, chunk = taplin / 9;
    int co = ct * 16 + (lane & 15);
    int cibase = chunk * 32 + (lane >> 4) * 8;
    u16x8 out;
#pragma unroll
    for (int j = 0; j < 8; ++j) {
        int ci = cibase + j;
        float v = 0.f;
        if (co < 88 && ci < 176) v = w1[(size_t)co * 1584 + ci * 9 + tap] * rs * bng[co];
        out[j] = f2bf(v);
    }
    *(u16x8*)(pk + ((size_t)blk * 64 + lane) * 8) = out;
    if (blk == 0) {
        for (int i = lane; i < 96; i += 64)
            bias2[i] = (i < 88) ? (b1[i] * rs * bng[i] + bnb[i]) : 0.f;
    }
}

static __device__ void pack_gemmB(int blk, int lane,
                                  const float* __restrict__ W,
                                  unsigned short* __restrict__ out, int ncols) {
    int ntiles = ncols >> 4;
    int ks = blk & 3;
    int nt = (blk >> 2) % ntiles;
    int kc = blk / (4 * ntiles);
    int col = nt * 16 + (lane & 15);
    int k0 = kc * 128 + ks * 32 + (lane >> 4) * 8;
    u16x8 o;
#pragma unroll
    for (int j = 0; j < 8; ++j) o[j] = f2bf(W[(size_t)(k0 + j) * ncols + col]);
    *(u16x8*)(out + ((size_t)blk * 64 + lane) * 8) = o;
}

// rpb packed for the TRANSPOSED score layout: s[Mtk][Ntq], lane (g,t):
// tok_q = Ntq*16 + t (col), tok_k = Mtk*16 + g*4 + rr (row).
static __device__ void pack_rpb(int blk, int lane,
                                const float* __restrict__ rpb, float* __restrict__ pb) {
    int nt = blk & 3, mt = (blk >> 2) & 3, hh = blk >> 4;
    int tq = nt * 16 + (lane & 15);
    int g = lane >> 4;
    float o[4];
#pragma unroll
    for (int rr = 0; rr < 4; ++rr) {
        int tk = mt * 16 + g * 4 + rr;
        int relidx = (((tq >> 3) - (tk >> 3)) + 7) * 15 + ((tq & 7) - (tk & 7)) + 7;
        o[rr] = rpb[relidx * 8 + hh];
    }
    float4 v = {o[0], o[1], o[2], o[3]};
    *(float4*)(pb + ((size_t)blk * 64 + lane) * 4) = v;
}

__global__ __launch_bounds__(64) void k_pack_all(
        const float* __restrict__ dp_w1, const float* __restrict__ dp_b1,
        const float* __restrict__ bn_g, const float* __restrict__ bn_b,
        unsigned short* __restrict__ pk, float* __restrict__ bias2,
        const float* __restrict__ wq, const float* __restrict__ wk,
        const float* __restrict__ wv, const float* __restrict__ wp,
        unsigned short* __restrict__ pkw,
        const float* __restrict__ rpb, float* __restrict__ pb,
        const float* __restrict__ mlp_w1, unsigned short* __restrict__ pm1,
        const float* __restrict__ mlp_w2, unsigned short* __restrict__ pm2,
        const float* __restrict__ un_w1, unsigned short* __restrict__ pu1,
        const float* __restrict__ un_w2, unsigned short* __restrict__ pu2) {
    int blk = blockIdx.x;
    int lane = threadIdx.x;
    if (blk < 324) {
        pack_conv(blk, lane, dp_w1, dp_b1, bn_g, bn_b, pk, bias2);
    } else if (blk < 452) {
        int bb = blk - 324;
        int mat = bb >> 5;
        const float* W = (mat == 0) ? wq : (mat == 1) ? wk : (mat == 2) ? wv : wp;
        pack_gemmB(bb & 31, lane, W, pkw + (size_t)mat * 16384, 128);
    } else if (blk < 580) {
        pack_rpb(blk - 452, lane, rpb, pb);
    } else if (blk < 708) {
        pack_gemmB(blk - 580, lane, mlp_w1, pm1, 512);
    } else if (blk < 836) {
        pack_gemmB(blk - 708, lane, mlp_w2, pm2, 128);
    } else if (blk < 868) {
        pack_gemmB(blk - 836, lane, un_w1, pu1, 128);
    } else {
        pack_gemmB(blk - 868, lane, un_w2, pu2, 128);
    }
}

// ---------------------------------------------------------------------------
// K2: unary MLP via MFMA + LN1 producer. 1024 blocks x 64 tokens, 4 waves.
__global__ __launch_bounds__(256) void k_unary_mfma(const float* __restrict__ feat_l,
                                                    const unsigned short* __restrict__ pu1,
                                                    const float* __restrict__ b1,
                                                    const unsigned short* __restrict__ pu2,
                                                    const float* __restrict__ b2,
                                                    const float* __restrict__ g1,
                                                    const float* __restrict__ bt1,
                                                    float* __restrict__ x,
                                                    unsigned short* __restrict__ nf) {
    __shared__ __align__(16) unsigned short s_a[64 * 136];
    __shared__ __align__(16) unsigned short s_h[64 * 136];
    int tid = threadIdx.x;
    int wid = tid >> 6, lane = tid & 63;
    int g = lane >> 4, t = lane & 15;
    int n0g = blockIdx.x * 64;
    int b = n0g >> 14;
    int nb = n0g & 16383;

    for (int idx = tid; idx < 4096; idx += 256) {
        int c2 = idx >> 6, nl = idx & 63;
        float v0 = feat_l[((size_t)(b * 128 + 2 * c2) << 14) + nb + nl];
        float v1 = feat_l[((size_t)(b * 128 + 2 * c2 + 1) << 14) + nb + nl];
        *(unsigned int*)&s_a[nl * 136 + 2 * c2] = pack2bf(v0, v1);
    }
    __syncthreads();

    // ---- LN1 -> nf (token-major bf16), vectorized loads/stores ----
    {
        int tok = tid >> 2, q = tid & 3;
        float v[32];
#pragma unroll
        for (int i8 = 0; i8 < 4; ++i8) {
            u16x8 r8 = *(const u16x8*)&s_a[tok * 136 + q * 32 + i8 * 8];
#pragma unroll
            for (int j = 0; j < 8; ++j) v[i8 * 8 + j] = bf2f(r8[j]);
        }
        float s = 0.f, s2 = 0.f;
#pragma unroll
        for (int i = 0; i < 32; ++i) { s += v[i]; s2 += v[i] * v[i]; }
        s += __shfl_xor(s, 1); s += __shfl_xor(s, 2);
        s2 += __shfl_xor(s2, 1); s2 += __shfl_xor(s2, 2);
        float mean = s * (1.f / 128.f);
        float var = s2 * (1.f / 128.f) - mean * mean;
        float rstd = rsqrtf(var + 1e-5f);
        size_t base = (size_t)(n0g + tok) * 128 + q * 32;
#pragma unroll
        for (int i8 = 0; i8 < 4; ++i8) {
            u16x8 o8;
#pragma unroll
            for (int j = 0; j < 8; ++j) {
                int c = q * 32 + i8 * 8 + j;
                o8[j] = f2bf((v[i8 * 8 + j] - mean) * rstd * g1[c] + bt1[c]);
            }
            *(u16x8*)&nf[base + i8 * 8] = o8;
        }
    }

    bf16x8 af[4][4];
#pragma unroll
    for (int Mt = 0; Mt < 4; ++Mt)
#pragma unroll
        for (int ks = 0; ks < 4; ++ks)
            af[Mt][ks] = *(const bf16x8*)&s_a[(Mt * 16 + t) * 136 + ks * 32 + g * 8];

    f32x4 acc1[4][2];
#pragma unroll
    for (int nt2 = 0; nt2 < 2; ++nt2) {
        float bv = b1[(wid * 2 + nt2) * 16 + t];
#pragma unroll
        for (int Mt = 0; Mt < 4; ++Mt) acc1[Mt][nt2] = (f32x4){bv, bv, bv, bv};
    }
#pragma unroll
    for (int ks = 0; ks < 4; ++ks) {
        bf16x8 bf0 = *(const bf16x8*)(pu1 + (size_t)(((wid * 2 + 0) * 4 + ks) * 64 + lane) * 8);
        bf16x8 bf1 = *(const bf16x8*)(pu1 + (size_t)(((wid * 2 + 1) * 4 + ks) * 64 + lane) * 8);
#pragma unroll
        for (int Mt = 0; Mt < 4; ++Mt) {
            acc1[Mt][0] = __builtin_amdgcn_mfma_f32_16x16x32_bf16(af[Mt][ks], bf0, acc1[Mt][0], 0, 0, 0);
            acc1[Mt][1] = __builtin_amdgcn_mfma_f32_16x16x32_bf16(af[Mt][ks], bf1, acc1[Mt][1], 0, 0, 0);
        }
    }
#pragma unroll
    for (int Mt = 0; Mt < 4; ++Mt)
#pragma unroll
        for (int nt2 = 0; nt2 < 2; ++nt2)
#pragma unroll
            for (int rr = 0; rr < 4; ++rr)
                s_h[(Mt * 16 + g * 4 + rr) * 136 + (wid * 2 + nt2) * 16 + t] = f2bf(gelu_f(acc1[Mt][nt2][rr]));
    __syncthreads();

    bf16x8 a2[4][4];
#pragma unroll
    for (int Mt = 0; Mt < 4; ++Mt)
#pragma unroll
        for (int ks = 0; ks < 4; ++ks)
            a2[Mt][ks] = *(const bf16x8*)&s_h[(Mt * 16 + t) * 136 + ks * 32 + g * 8];

    f32x4 acc2[4][2];
#pragma unroll
    for (int nt2 = 0; nt2 < 2; ++nt2) {
        float bv = b2[(wid * 2 + nt2) * 16 + t];
#pragma unroll
        for (int Mt = 0; Mt < 4; ++Mt) acc2[Mt][nt2] = (f32x4){bv, bv, bv, bv};
    }
#pragma unroll
    for (int ks = 0; ks < 4; ++ks) {
        bf16x8 bf0 = *(const bf16x8*)(pu2 + (size_t)(((wid * 2 + 0) * 4 + ks) * 64 + lane) * 8);
        bf16x8 bf1 = *(const bf16x8*)(pu2 + (size_t)(((wid * 2 + 1) * 4 + ks) * 64 + lane) * 8);
#pragma unroll
        for (int Mt = 0; Mt < 4; ++Mt) {
            acc2[Mt][0] = __builtin_amdgcn_mfma_f32_16x16x32_bf16(a2[Mt][ks], bf0, acc2[Mt][0], 0, 0, 0);
            acc2[Mt][1] = __builtin_amdgcn_mfma_f32_16x16x32_bf16(a2[Mt][ks], bf1, acc2[Mt][1], 0, 0, 0);
        }
    }
#pragma unroll
    for (int Mt = 0; Mt < 4; ++Mt)
#pragma unroll
        for (int nt2 = 0; nt2 < 2; ++nt2)
#pragma unroll
            for (int rr = 0; rr < 4; ++rr) {
                int tok = Mt * 16 + g * 4 + rr;
                x[(size_t)(n0g + tok) * 128 + (wid * 2 + nt2) * 16 + t] = acc2[Mt][nt2][rr];
            }
}

// ---------------------------------------------------------------------------
// K3: attention core. 1024 blocks (1 window), 256 threads (4 waves).
// Computes S^T = K Q^T (lane holds 16 tok_k for fixed tok_q) -> softmax is
// per-lane 16-reduce + 2 shfl_xor. P normalized in-layout, packed b64 writes.
__global__ __launch_bounds__(256, 3) void k_attn_core(const unsigned short* nf,
                                                      const unsigned short* __restrict__ pkw,
                                                      const float* __restrict__ pb,
                                                      const float* __restrict__ bq,
                                                      const float* __restrict__ bk,
                                                      const float* __restrict__ bv,
                                                      unsigned short* opk) {
    // per-wave scratch 11520 B (5760 shorts):
    //   sQ[64][24] | sK[64][24] at base (overlaid by sP[64][72] = [tok_q][tok_k])
    //   sV[16][72] at +4608 shorts.  sO[64][16] overlays sP.
    __shared__ __align__(16) unsigned short s_all[4 * 5760];
    int tid = threadIdx.x;
    int wid = tid >> 6, lane = tid & 63;
    int g = lane >> 4, t = lane & 15;
    int bw = blockIdx.x;
    int b = bw >> 8, wh = (bw >> 4) & 15, ww = bw & 15;

    // ---- A-fragments directly from nf ----
    bf16x8 af[4][4];   // [Mt][ks]
#pragma unroll
    for (int Mt = 0; Mt < 4; ++Mt) {
        int tok = Mt * 16 + t;
        size_t gtok = (size_t)(b * 16384) + (wh * 8 + (tok >> 3)) * 128 + ww * 8 + (tok & 7);
#pragma unroll
        for (int ks = 0; ks < 4; ++ks)
            af[Mt][ks] = *(const bf16x8*)&nf[gtok * 128 + ks * 32 + g * 8];
    }
    __syncthreads();   // all nf reads complete before any in-place opk write

    unsigned short* sQ = s_all + wid * 5760;
    unsigned short* sK = sQ + 1536;
    unsigned short* sV = sQ + 4608;
    unsigned short* sP = sQ;
    unsigned short* sO = sQ;

    const bf16x8 z8v = {0, 0, 0, 0, 0, 0, 0, 0};

#pragma unroll
    for (int hi = 0; hi < 2; ++hi) {
        int h = wid + hi * 4;

        // ---- QKV projection for head h ----
        float bqv = bq[h * 16 + t], bkv = bk[h * 16 + t], bvv = bv[h * 16 + t];
        f32x4 qa[4], ka[4], va[4];
#pragma unroll
        for (int Mt = 0; Mt < 4; ++Mt) {
            qa[Mt] = (f32x4){bqv, bqv, bqv, bqv};
            ka[Mt] = (f32x4){bkv, bkv, bkv, bkv};
            va[Mt] = (f32x4){bvv, bvv, bvv, bvv};
        }
#pragma unroll
        for (int ks = 0; ks < 4; ++ks) {
            const unsigned short* wbase = pkw + ((size_t)((h * 4 + ks) * 64 + lane) * 8);
            bf16x8 bfq = *(const bf16x8*)(wbase);
            bf16x8 bfk = *(const bf16x8*)(wbase + 16384);
            bf16x8 bfv = *(const bf16x8*)(wbase + 32768);
#pragma unroll
            for (int Mt = 0; Mt < 4; ++Mt) {
                qa[Mt] = __builtin_amdgcn_mfma_f32_16x16x32_bf16(af[Mt][ks], bfq, qa[Mt], 0, 0, 0);
                ka[Mt] = __builtin_amdgcn_mfma_f32_16x16x32_bf16(af[Mt][ks], bfk, ka[Mt], 0, 0, 0);
                va[Mt] = __builtin_amdgcn_mfma_f32_16x16x32_bf16(af[Mt][ks], bfv, va[Mt], 0, 0, 0);
            }
        }
        // Q,K: [tok][24] scalar writes. V: packed b64 transposed [d][tok].
#pragma unroll
        for (int Mt = 0; Mt < 4; ++Mt) {
            bf16x4 vv;
#pragma unroll
            for (int rr = 0; rr < 4; ++rr) {
                int tok = Mt * 16 + g * 4 + rr;
                sQ[tok * 24 + t] = f2bf(qa[Mt][rr] * SCALE);
                sK[tok * 24 + t] = f2bf(ka[Mt][rr]);
                vv[rr] = (short)f2bf(va[Mt][rr]);
            }
            *(bf16x4*)&sV[t * 72 + Mt * 16 + g * 4] = vv;
        }

        // ---- S^T = K Q^T + bias(C-init); pad lanes (g>=2) feed zeros ----
        // C layout: lane (g,t): tok_q = Ntq*16 + t, tok_k = Mtk*16 + g*4 + rr.
        f32x4 s[4][4];   // [Mtk][Ntq]
#pragma unroll
        for (int Mtk = 0; Mtk < 4; ++Mtk)
#pragma unroll
            for (int Ntq = 0; Ntq < 4; ++Ntq)
                s[Mtk][Ntq] = *(const f32x4*)(pb + ((size_t)((h * 16 + Mtk * 4 + Ntq) * 64 + lane) * 4));
        bf16x8 bQ[4];
#pragma unroll
        for (int Ntq = 0; Ntq < 4; ++Ntq)
            bQ[Ntq] = (g < 2) ? *(const bf16x8*)&sQ[(Ntq * 16 + t) * 24 + g * 8] : z8v;
#pragma unroll
        for (int Mtk = 0; Mtk < 4; ++Mtk) {
            bf16x8 aK = (g < 2) ? *(const bf16x8*)&sK[(Mtk * 16 + t) * 24 + g * 8] : z8v;
#pragma unroll
            for (int Ntq = 0; Ntq < 4; ++Ntq)
                s[Mtk][Ntq] = __builtin_amdgcn_mfma_f32_16x16x32_bf16(aK, bQ[Ntq], s[Mtk][Ntq], 0, 0, 0);
        }

        // ---- softmax: per-lane 16-reduce + 2 shuffles per q-tile; normalize
        //      and write P (b64-packed) in [tok_q][tok_k] layout ----
#pragma unroll
        for (int Ntq = 0; Ntq < 4; ++Ntq) {
            float m = s[0][Ntq][0];
#pragma unroll
            for (int Mtk = 0; Mtk < 4; ++Mtk)
#pragma unroll
                for (int rr = 0; rr < 4; ++rr) m = fmaxf(m, s[Mtk][Ntq][rr]);
            m = fmaxf(m, __shfl_xor(m, 16));
            m = fmaxf(m, __shfl_xor(m, 32));
            float sum = 0.f;
#pragma unroll
            for (int Mtk = 0; Mtk < 4; ++Mtk)
#pragma unroll
                for (int rr = 0; rr < 4; ++rr) {
                    float e = __expf(s[Mtk][Ntq][rr] - m);
                    s[Mtk][Ntq][rr] = e;
                    sum += e;
                }
            sum += __shfl_xor(sum, 16);
            sum += __shfl_xor(sum, 32);
            float inv = 1.0f / sum;
#pragma unroll
            for (int Mtk = 0; Mtk < 4; ++Mtk) {
                bf16x4 pv;
#pragma unroll
                for (int rr = 0; rr < 4; ++rr) pv[rr] = (short)f2bf(s[Mtk][Ntq][rr] * inv);
                *(bf16x4*)&sP[(Ntq * 16 + t) * 72 + Mtk * 16 + g * 4] = pv;
            }
        }

        // ---- O = P @ V (P already normalized) ----
        f32x4 oa[4];
#pragma unroll
        for (int Mt = 0; Mt < 4; ++Mt) oa[Mt] = (f32x4){0.f, 0.f, 0.f, 0.f};
#pragma unroll
        for (int ksv = 0; ksv < 2; ++ksv) {
            bf16x8 bv2 = *(const bf16x8*)&sV[t * 72 + ksv * 32 + g * 8];
#pragma unroll
            for (int Mt = 0; Mt < 4; ++Mt) {
                bf16x8 ap = *(const bf16x8*)&sP[(Mt * 16 + t) * 72 + ksv * 32 + g * 8];
                oa[Mt] = __builtin_amdgcn_mfma_f32_16x16x32_bf16(ap, bv2, oa[Mt], 0, 0, 0);
            }
        }
        // ---- wave-local LDS transpose -> packed 16B/lane stores ----
#pragma unroll
        for (int Mt = 0; Mt < 4; ++Mt)
#pragma unroll
            for (int rr = 0; rr < 4; ++rr)
                sO[(Mt * 16 + g * 4 + rr) * 16 + t] = f2bf(oa[Mt][rr]);
        int ksf = h >> 1;
        if ((g >> 1) == (h & 1)) {
#pragma unroll
            for (int Mt = 0; Mt < 4; ++Mt) {
                bf16x8 v8 = *(const bf16x8*)&sO[(Mt * 16 + t) * 16 + (g & 1) * 8];
                *(bf16x8*)&opk[opk_addr(b, wh, ww, Mt, ksf, lane)] = v8;
            }
        }
    }
}

// ---------------------------------------------------------------------------
// K4: per-WINDOW block: x = (x + o@wp + bp) + mlp(LN2(...)).
__global__ __launch_bounds__(256) void k_mlp_mfma(float* __restrict__ x,
                                                  const unsigned short* __restrict__ opk,
                                                  const unsigned short* __restrict__ pkw,
                                                  const float* __restrict__ bp,
                                                  const float* __restrict__ g2,
                                                  const float* __restrict__ bt2,
                                                  const unsigned short* __restrict__ pm1,
                                                  const float* __restrict__ b1,
                                                  const unsigned short* __restrict__ pm2) {
    __shared__ __align__(16) char smem[51200];
    float* sf = (float*)smem;                       // [64][132] f32
    unsigned short* s_h = (unsigned short*)smem;    // overlays sf after LN
    unsigned short* s_a = (unsigned short*)(smem + 33792);
    int tid = threadIdx.x;
    int wid = tid >> 6, lane = tid & 63;
    int g = lane >> 4, t = lane & 15;
    int bw = blockIdx.x;
    int b = bw >> 8, wh = (bw >> 4) & 15, ww = bw & 15;

    auto gtok_of = [&](int tok) -> size_t {
        return (size_t)(b * 16384) + (wh * 8 + (tok >> 3)) * 128 + ww * 8 + (tok & 7);
    };

    f32x4 out[4][2];
    {
        float bp0 = bp[wid * 32 + t], bp1 = bp[wid * 32 + 16 + t];
#pragma unroll
        for (int Mt = 0; Mt < 4; ++Mt) {
            out[Mt][0] = (f32x4){bp0, bp0, bp0, bp0};
            out[Mt][1] = (f32x4){bp1, bp1, bp1, bp1};
        }
#pragma unroll
        for (int ks = 0; ks < 4; ++ks) {
            bf16x8 b0 = *(const bf16x8*)(pkw + 49152 + (size_t)(((wid * 2 + 0) * 4 + ks) * 64 + lane) * 8);
            bf16x8 b1v = *(const bf16x8*)(pkw + 49152 + (size_t)(((wid * 2 + 1) * 4 + ks) * 64 + lane) * 8);
#pragma unroll
            for (int Mt = 0; Mt < 4; ++Mt) {
                bf16x8 a = *(const bf16x8*)&opk[opk_addr(b, wh, ww, Mt, ks, lane)];
                out[Mt][0] = __builtin_amdgcn_mfma_f32_16x16x32_bf16(a, b0, out[Mt][0], 0, 0, 0);
                out[Mt][1] = __builtin_amdgcn_mfma_f32_16x16x32_bf16(a, b1v, out[Mt][1], 0, 0, 0);
            }
        }
#pragma unroll
        for (int Mt = 0; Mt < 4; ++Mt)
#pragma unroll
            for (int nt2 = 0; nt2 < 2; ++nt2)
#pragma unroll
                for (int rr = 0; rr < 4; ++rr) {
                    int tok = Mt * 16 + g * 4 + rr;
                    int col = (wid * 2 + nt2) * 16 + t;
                    float v = out[Mt][nt2][rr] + x[gtok_of(tok) * 128 + col];
                    out[Mt][nt2][rr] = v;
                    sf[tok * 132 + col] = v;
                }
    }
    __syncthreads();
    {
        int tok = tid >> 2, q = tid & 3;
        float s = 0.f, s2 = 0.f;
        for (int c = q * 32; c < q * 32 + 32; ++c) {
            float v = sf[tok * 132 + c];
            s += v; s2 += v * v;
        }
        s += __shfl_xor(s, 1); s += __shfl_xor(s, 2);
        s2 += __shfl_xor(s2, 1); s2 += __shfl_xor(s2, 2);
        float mean = s * (1.f / 128.f);
        float var = s2 * (1.f / 128.f) - mean * mean;
        float rstd = rsqrtf(var + 1e-5f);
        for (int c = q * 32; c < q * 32 + 32; c += 2) {
            float v0 = (sf[tok * 132 + c] - mean) * rstd * g2[c] + bt2[c];
            float v1 = (sf[tok * 132 + c + 1] - mean) * rstd * g2[c + 1] + bt2[c + 1];
            *(unsigned int*)&s_a[tok * 136 + c] = pack2bf(v0, v1);
        }
    }
    __syncthreads();
    bf16x8 af[4][4];
#pragma unroll
    for (int Mt = 0; Mt < 4; ++Mt)
#pragma unroll
        for (int ks = 0; ks < 4; ++ks)
            af[Mt][ks] = *(const bf16x8*)&s_a[(Mt * 16 + t) * 136 + ks * 32 + g * 8];

#pragma unroll 1
    for (int hc = 0; hc < 4; ++hc) {
        f32x4 acc1[4][2];
#pragma unroll
        for (int nt2 = 0; nt2 < 2; ++nt2) {
            float bv = b1[hc * 128 + (wid * 2 + nt2) * 16 + t];
#pragma unroll
            for (int Mt = 0; Mt < 4; ++Mt) acc1[Mt][nt2] = (f32x4){bv, bv, bv, bv};
        }
#pragma unroll
        for (int ks = 0; ks < 4; ++ks) {
            bf16x8 bf0 = *(const bf16x8*)(pm1 + (size_t)(((hc * 8 + wid * 2 + 0) * 4 + ks) * 64 + lane) * 8);
            bf16x8 bf1 = *(const bf16x8*)(pm1 + (size_t)(((hc * 8 + wid * 2 + 1) * 4 + ks) * 64 + lane) * 8);
#pragma unroll
            for (int Mt = 0; Mt < 4; ++Mt) {
                acc1[Mt][0] = __builtin_amdgcn_mfma_f32_16x16x32_bf16(af[Mt][ks], bf0, acc1[Mt][0], 0, 0, 0);
                acc1[Mt][1] = __builtin_amdgcn_mfma_f32_16x16x32_bf16(af[Mt][ks], bf1, acc1[Mt][1], 0, 0, 0);
            }
        }
#pragma unroll
        for (int Mt = 0; Mt < 4; ++Mt)
#pragma unroll
            for (int nt2 = 0; nt2 < 2; ++nt2)
#pragma unroll
                for (int rr = 0; rr < 4; ++rr)
                    s_h[(Mt * 16 + g * 4 + rr) * 136 + (wid * 2 + nt2) * 16 + t] = f2bf(gelu_f(acc1[Mt][nt2][rr]));
        __syncthreads();
        bf16x8 a2[4][4];
#pragma unroll
        for (int Mt = 0; Mt < 4; ++Mt)
#pragma unroll
            for (int ks = 0; ks < 4; ++ks)
                a2[Mt][ks] = *(const bf16x8*)&s_h[(Mt * 16 + t) * 136 + ks * 32 + g * 8];
#pragma unroll
        for (int ks = 0; ks < 4; ++ks) {
            bf16x8 bf0 = *(const bf16x8*)(pm2 + (size_t)((hc * 32 + (wid * 2 + 0) * 4 + ks) * 64 + lane) * 8);
            bf16x8 bf1 = *(const bf16x8*)(pm2 + (size_t)((hc * 32 + (wid * 2 + 1) * 4 + ks) * 64 + lane) * 8);
#pragma unroll
            for (int Mt = 0; Mt < 4; ++Mt) {
                out[Mt][0] = __builtin_amdgcn_mfma_f32_16x16x32_bf16(a2[Mt][ks], bf0, out[Mt][0], 0, 0, 0);
                out[Mt][1] = __builtin_amdgcn_mfma_f32_16x16x32_bf16(a2[Mt][ks], bf1, out[Mt][1], 0, 0, 0);
            }
        }
        __syncthreads();
    }

#pragma unroll
    for (int Mt = 0; Mt < 4; ++Mt)
#pragma unroll
        for (int nt2 = 0; nt2 < 2; ++nt2)
#pragma unroll
            for (int rr = 0; rr < 4; ++rr) {
                int tok = Mt * 16 + g * 4 + rr;
                x[gtok_of(tok) * 128 + (wid * 2 + nt2) * 16 + t] = out[Mt][nt2][rr];
            }
}

// ---------------------------------------------------------------------------
// K5b: conv3x3 as bf16 implicit-GEMM MFMA. grid (8,8,4), 256 threads.
__global__ __launch_bounds__(256) void k_conv_mfma(const float* __restrict__ x,
                                                   const float* __restrict__ cost,
                                                   const unsigned short* __restrict__ pk,
                                                   const float* __restrict__ bias2,
                                                   float* __restrict__ h1) {
    __shared__ __align__(16) unsigned short s_p[324 * 40];
    int tid = threadIdx.x;
    int wid = tid >> 6, lane = tid & 63;
    int g = lane >> 4, t = lane & 15;
    int tx0 = blockIdx.x * 16, ty0 = blockIdx.y * 16, b = blockIdx.z;

    f32x4 acc[4][6];
#pragma unroll
    for (int p = 0; p < 4; ++p)
#pragma unroll
        for (int ct = 0; ct < 6; ++ct) acc[p][ct] = (f32x4){0.f, 0.f, 0.f, 0.f};

#pragma unroll 1
    for (int chunk = 0; chunk < 6; ++chunk) {
        if (chunk < 4) {
            int ci0 = chunk * 32;
            for (int u = tid; u < 648; u += 256) {
                int pos = u >> 1, half = u & 1;
                int yy = pos / 18, xx = pos - yy * 18;
                int gy = ty0 + yy - 1, gx = tx0 + xx - 1;
                u16x8 lo, hi;
                if (gy >= 0 && gy < 128 && gx >= 0 && gx < 128) {
                    const float4* src = (const float4*)&x[((size_t)(b << 14) + gy * 128 + gx) * 128 + ci0 + half * 16];
                    float4 v0 = src[0], v1 = src[1], v2 = src[2], v3 = src[3];
                    lo[0] = f2bf(v0.x); lo[1] = f2bf(v0.y); lo[2] = f2bf(v0.z); lo[3] = f2bf(v0.w);
                    lo[4] = f2bf(v1.x); lo[5] = f2bf(v1.y); lo[6] = f2bf(v1.z); lo[7] = f2bf(v1.w);
                    hi[0] = f2bf(v2.x); hi[1] = f2bf(v2.y); hi[2] = f2bf(v2.z); hi[3] = f2bf(v2.w);
                    hi[4] = f2bf(v3.x); hi[5] = f2bf(v3.y); hi[6] = f2bf(v3.z); hi[7] = f2bf(v3.w);
                } else {
                    lo = (u16x8)(unsigned short)0; hi = (u16x8)(unsigned short)0;
                }
                unsigned short* dst = &s_p[pos * 40 + half * 16];
                *(u16x8*)dst = lo;
                *(u16x8*)(dst + 8) = hi;
            }
        } else {
            int d0 = (chunk - 4) * 32;
            // lane-contiguous positions -> coalesced 4B cost loads
            for (int u = tid; u < 32 * 324; u += 256) {
                int cl = u / 324, r = u - cl * 324;
                int yy = r / 18, xx = r - yy * 18;
                int d = d0 + cl;
                int gy = ty0 + yy - 1, gx = tx0 + xx - 1;
                float v = 0.f;
                if (d < 48 && gy >= 0 && gy < 128 && gx >= 0 && gx < 128)
                    v = cost[((size_t)(b * 48 + d) << 14) + gy * 128 + gx];
                s_p[r * 40 + cl] = f2bf(v);
            }
        }
        __syncthreads();

#pragma unroll 1
        for (int tap = 0; tap < 9; ++tap) {
            int dy = tap / 3, dx = tap - dy * 3;
            const unsigned short* pkt = pk + ((size_t)(chunk * 9 + tap)) * 6 * 512;
            bf16x8 afr[6];
#pragma unroll
            for (int ct = 0; ct < 6; ++ct)
                afr[ct] = *(const bf16x8*)(pkt + ct * 512 + lane * 8);
            bf16x8 bfr[4];
#pragma unroll
            for (int p = 0; p < 4; ++p) {
                int pos = (wid * 4 + p + dy) * 18 + t + dx;
                bfr[p] = *(const bf16x8*)&s_p[pos * 40 + g * 8];
            }
#pragma unroll
            for (int p = 0; p < 4; ++p)
#pragma unroll
                for (int ct = 0; ct < 6; ++ct)
                    acc[p][ct] = __builtin_amdgcn_mfma_f32_16x16x32_bf16(afr[ct], bfr[p], acc[p][ct], 0, 0, 0);
        }
        __syncthreads();
    }

#pragma unroll
    for (int p = 0; p < 4; ++p) {
        int y = ty0 + wid * 4 + p;
#pragma unroll
        for (int ct = 0; ct < 6; ++ct) {
#pragma unroll
            for (int rr = 0; rr < 4; ++rr) {
                int co = ct * 16 + g * 4 + rr;
                if (co < 88) {
                    float v = acc[p][ct][rr] + bias2[co];
                    h1[((size_t)(b * 88 + co) << 14) + y * 128 + tx0 + t] = fmaxf(v, 0.f);
                }
            }
        }
    }
}

// ---------------------------------------------------------------------------
// K6: pv = conv1x1(h1) + b2; softmax over D; pred = 4*sum(d*p). 256 blocks.
__global__ __launch_bounds__(256) void k_head(const float* __restrict__ h1,
                                              const float* __restrict__ w2, const float* __restrict__ b2,
                                              float* __restrict__ out) {
    __shared__ float s_wt[88 * 48];   // [k][d]
    __shared__ float s_b[48];
    int tid = threadIdx.x;
    for (int idx = tid; idx < 48 * 88; idx += 256) {
        int d = idx / 88, k = idx % 88;
        s_wt[k * 48 + d] = w2[idx];
    }
    if (tid < 48) s_b[tid] = b2[tid];
    __syncthreads();
    int px = blockIdx.x * 256 + tid;
    int b = px >> 14, r = px & 16383;
    float acc[48];
#pragma unroll
    for (int d = 0; d < 48; ++d) acc[d] = s_b[d];
    for (int k = 0; k < 88; ++k) {
        float hv = h1[((size_t)(b * 88 + k) << 14) + r];
        const float4* wrow = (const float4*)&s_wt[k * 48];
#pragma unroll
        for (int d4 = 0; d4 < 12; ++d4) {
            float4 wv = wrow[d4];
            acc[d4 * 4 + 0] += hv * wv.x;
            acc[d4 * 4 + 1] += hv * wv.y;
            acc[d4 * 4 + 2] += hv * wv.z;
            acc[d4 * 4 + 3] += hv * wv.w;
        }
    }
    float mx = -1e30f;
#pragma unroll
    for (int d = 0; d < 48; ++d) mx = fmaxf(mx, acc[d]);
    float sum = 0.f, wsum = 0.f;
#pragma unroll
    for (int d = 0; d < 48; ++d) {
        float e = expf(acc[d] - mx);
        sum += e;
        wsum += e * (float)d;
    }
    out[px] = 4.0f * wsum / sum;
}

// ---------------------------------------------------------------------------
extern "C" void kernel_launch(void* const* d_in, const int* in_sizes, int n_in,
                              void* d_out, int out_size, void* d_ws, size_t ws_size,
                              hipStream_t stream) {
    const float* feat_l = (const float*)d_in[0];
    const float* feat_r = (const float*)d_in[1];
    const float* wq = (const float*)d_in[2];
    const float* bq = (const float*)d_in[3];
    const float* wk = (const float*)d_in[4];
    const float* bk = (const float*)d_in[5];
    const float* wv = (const float*)d_in[6];
    const float* bv = (const float*)d_in[7];
    const float* wp = (const float*)d_in[8];
    const float* bp = (const float*)d_in[9];
    const float* rpb = (const float*)d_in[10];
    const float* ln1_g = (const float*)d_in[11];
    const float* ln1_b = (const float*)d_in[12];
    const float* ln2_g = (const float*)d_in[13];
    const float* ln2_b = (const float*)d_in[14];
    const float* mlp_w1 = (const float*)d_in[15];
    const float* mlp_b1 = (const float*)d_in[16];
    const float* mlp_w2 = (const float*)d_in[17];
    // d_in[18] = mlp_b2 is multiplied by 0.0 in the reference -> unused
    const float* un_w1 = (const float*)d_in[19];
    const float* un_b1 = (const float*)d_in[20];
    const float* un_w2 = (const float*)d_in[21];
    const float* un_b2 = (const float*)d_in[22];
    const float* dp_w1 = (const float*)d_in[23];
    const float* dp_b1 = (const float*)d_in[24];
    const float* bn_g = (const float*)d_in[25];
    const float* bn_b = (const float*)d_in[26];
    const float* dp_w2 = (const float*)d_in[27];
    const float* dp_b2 = (const float*)d_in[28];

    float* ws = (float*)d_ws;
    float* cost = ws;                               // 3,145,728 f
    float* x = ws + 3145728;                        // 8,388,608 f
    float* h1 = ws + 11534336;                      // 5,767,168 f
    unsigned short* nfo = (unsigned short*)h1;      // nf/o overlay (dead before conv)
    unsigned short* pk = (unsigned short*)(ws + 17301504);       // 165,888 u16
    float* bias2 = ws + 17384448;                   // 96 f
    unsigned short* pkw = (unsigned short*)(ws + 17384544);      // 65,536 u16
    float* pb = ws + 17417312;                      // 32,768 f
    unsigned short* pm1 = (unsigned short*)(ws + 17450080);      // 65,536 u16
    unsigned short* pm2 = (unsigned short*)(ws + 17482848);      // 65,536 u16
    unsigned short* pu1 = (unsigned short*)(ws + 17515616);      // 16,384 u16
    unsigned short* pu2 = (unsigned short*)(ws + 17523808);      // 16,384 u16
    float* out = (float*)d_out;

    k_pack_all<<<900, 64, 0, stream>>>(dp_w1, dp_b1, bn_g, bn_b, pk, bias2,
                                       wq, wk, wv, wp, pkw, rpb, pb,
                                       mlp_w1, pm1, mlp_w2, pm2,
                                       un_w1, pu1, un_w2, pu2);
    k_cost<<<dim3(2, 64, 4), 384, 0, stream>>>(feat_l, feat_r, cost);
    k_unary_mfma<<<1024, 256, 0, stream>>>(feat_l, pu1, un_b1, pu2, un_b2,
                                           ln1_g, ln1_b, x, nfo);
    k_attn_core<<<1024, 256, 0, stream>>>(nfo, pkw, pb, bq, bk, bv, nfo);
    k_mlp_mfma<<<1024, 256, 0, stream>>>(x, nfo, pkw, bp, ln2_g, ln2_b,
                                         pm1, mlp_b1, pm2);
    k_conv_mfma<<<dim3(8, 8, 4), 256, 0, stream>>>(x, cost, pk, bias2, h1);
    k_head<<<256, 256, 0, stream>>>(h1, dp_w2, dp_b2, out);
}

// Round 10
// 286.560 us; speedup vs baseline: 8.4902x; 1.0251x over previous
//
#include <hip/hip_runtime.h>
#include <math.h>

// Dims
constexpr int Bn = 4, Cc = 128, Hh = 128, Wn = 128, Dd = 48;
constexpr float SCALE = 0.25f;       // 16^-0.5

typedef short  bf16x8 __attribute__((ext_vector_type(8)));
typedef short  bf16x4 __attribute__((ext_vector_type(4)));
typedef float  f32x4  __attribute__((ext_vector_type(4)));
typedef unsigned short u16x8 __attribute__((ext_vector_type(8)));

// Native cast -> compiler emits v_cvt_pk_bf16_f32 (RNE, same as manual round).
static __device__ __forceinline__ unsigned short f2bf(float f) {
    return __builtin_bit_cast(unsigned short, (__bf16)f);
}

static __device__ __forceinline__ float bf2f(unsigned short u) {
    return __uint_as_float((unsigned int)u << 16);
}

static __device__ __forceinline__ unsigned int pack2bf(float a, float b) {
    return (unsigned int)f2bf(a) | ((unsigned int)f2bf(b) << 16);
}

// tanh-form GELU with hardware rcp: v * sigmoid(1.59576912 v + 0.07135481 v^3)
static __device__ __forceinline__ float gelu_f(float v) {
    float u = v * (1.5957691216f + 0.0713548162f * v * v);
    return v * __builtin_amdgcn_rcpf(1.0f + __expf(-u));
}

// Packed-o address: fragment (Mt,ks), lane l, window (b,wh,ww).
static __device__ __forceinline__ size_t opk_addr(int b, int wh, int ww, int Mt, int ks, int lane) {
    return ((size_t)(b * 16384) + (wh * 8 + Mt * 2 + (ks >> 1)) * 128 + ww * 8) * 128
           + (ks & 1) * 512 + lane * 8;
}

// ---------------------------------------------------------------------------
// K1: cost volume, register-blocked band correlation.
__global__ __launch_bounds__(384) void k_cost(const float* __restrict__ fl,
                                              const float* __restrict__ fr,
                                              float* __restrict__ cost) {
    __shared__ float s_fl[2][16][64];
    __shared__ float s_fr[2][16][112];
    int tid = threadIdx.x;
    int w0 = blockIdx.x * 64;
    int hp = blockIdx.y, b = blockIdx.z;
    int row = tid / 192;
    int r = tid - row * 192;
    int wg = r & 15, dg = r >> 4;
    int W = wg * 4, D = dg * 4;
    int h = hp * 2 + row;
    float acc[4][4];
#pragma unroll
    for (int i = 0; i < 4; ++i)
#pragma unroll
        for (int j = 0; j < 4; ++j) acc[i][j] = 0.f;

#pragma unroll 1
    for (int ck = 0; ck < 8; ++ck) {
        int ci0 = ck * 16;
        for (int i = tid; i < 512; i += 384) {
            int rr = i >> 8, rem = i & 255;
            int c = rem >> 4, k4 = rem & 15;
            float4 v = *(const float4*)&fl[((size_t)(b * 128 + ci0 + c) << 14) + (hp * 2 + rr) * 128 + w0 + k4 * 4];
            *(float4*)&s_fl[rr][c][k4 * 4] = v;
        }
        for (int i = tid; i < 896; i += 384) {
            int rr = i / 448, rem = i - rr * 448;
            int c = rem / 28, k4 = rem - c * 28;
            int wgl = w0 - 48 + k4 * 4;
            float4 v = {0.f, 0.f, 0.f, 0.f};
            if (wgl >= 0)
                v = *(const float4*)&fr[((size_t)(b * 128 + ci0 + c) << 14) + (hp * 2 + rr) * 128 + wgl];
            *(float4*)&s_fr[rr][c][k4 * 4] = v;
        }
        __syncthreads();
#pragma unroll
        for (int c = 0; c < 16; ++c) {
            float4 flv = *(const float4*)&s_fl[row][c][W];
            int base = W - D + 44;
            float4 f0 = *(const float4*)&s_fr[row][c][base];
            float4 f1 = *(const float4*)&s_fr[row][c][base + 4];
            float fw[8] = {f0.x, f0.y, f0.z, f0.w, f1.x, f1.y, f1.z, f1.w};
            float fv[4] = {flv.x, flv.y, flv.z, flv.w};
#pragma unroll
            for (int dj = 0; dj < 4; ++dj)
#pragma unroll
                for (int wv = 0; wv < 4; ++wv)
                    acc[dj][wv] += fv[wv] * fw[wv - dj + 4];
        }
        __syncthreads();
    }
    const float inv = 1.0f / 128.0f;
#pragma unroll
    for (int dj = 0; dj < 4; ++dj) {
        float4 o = {acc[dj][0] * inv, acc[dj][1] * inv, acc[dj][2] * inv, acc[dj][3] * inv};
        *(float4*)&cost[((size_t)(b * 48 + D + dj) << 14) + h * 128 + w0 + W] = o;
    }
}

// ---------------------------------------------------------------------------
// Pack helpers fused into one kernel.
static __device__ void pack_conv(int blk, int lane,
                                 const float* __restrict__ w1, const float* __restrict__ b1,
                                 const float* __restrict__ bng, const float* __restrict__ bnb,
                                 unsigned short* __restrict__ pk, float* __restrict__ bias2) {
    const float rs = 0.9999950000374997f;
    int ct = blk % 6;
    int taplin = blk / 6;
    int tap = taplin % 9, chunk = taplin / 9;
    int co = ct * 16 + (lane & 15);
    int cibase = chunk * 32 + (lane >> 4) * 8;
    u16x8 out;
#pragma unroll
    for (int j = 0; j < 8; ++j) {
        int ci = cibase + j;
        float v = 0.f;
        if (co < 88 && ci < 176) v = w1[(size_t)co * 1584 + ci * 9 + tap] * rs * bng[co];
        out[j] = f2bf(v);
    }
    *(u16x8*)(pk + ((size_t)blk * 64 + lane) * 8) = out;
    if (blk == 0) {
        for (int i = lane; i < 96; i += 64)
            bias2[i] = (i < 88) ? (b1[i] * rs * bng[i] + bnb[i]) : 0.f;
    }
}

static __device__ void pack_gemmB(int blk, int lane,
                                  const float* __restrict__ W,
                                  unsigned short* __restrict__ out, int ncols) {
    int ntiles = ncols >> 4;
    int ks = blk & 3;
    int nt = (blk >> 2) % ntiles;
    int kc = blk / (4 * ntiles);
    int col = nt * 16 + (lane & 15);
    int k0 = kc * 128 + ks * 32 + (lane >> 4) * 8;
    u16x8 o;
#pragma unroll
    for (int j = 0; j < 8; ++j) o[j] = f2bf(W[(size_t)(k0 + j) * ncols + col]);
    *(u16x8*)(out + ((size_t)blk * 64 + lane) * 8) = o;
}

// rpb packed for the TRANSPOSED score layout.
static __device__ void pack_rpb(int blk, int lane,
                                const float* __restrict__ rpb, float* __restrict__ pb) {
    int nt = blk & 3, mt = (blk >> 2) & 3, hh = blk >> 4;
    int tq = nt * 16 + (lane & 15);
    int g = lane >> 4;
    float o[4];
#pragma unroll
    for (int rr = 0; rr < 4; ++rr) {
        int tk = mt * 16 + g * 4 + rr;
        int relidx = (((tq >> 3) - (tk >> 3)) + 7) * 15 + ((tq & 7) - (tk & 7)) + 7;
        o[rr] = rpb[relidx * 8 + hh];
    }
    float4 v = {o[0], o[1], o[2], o[3]};
    *(float4*)(pb + ((size_t)blk * 64 + lane) * 4) = v;
}

__global__ __launch_bounds__(64) void k_pack_all(
        const float* __restrict__ dp_w1, const float* __restrict__ dp_b1,
        const float* __restrict__ bn_g, const float* __restrict__ bn_b,
        unsigned short* __restrict__ pk, float* __restrict__ bias2,
        const float* __restrict__ wq, const float* __restrict__ wk,
        const float* __restrict__ wv, const float* __restrict__ wp,
        unsigned short* __restrict__ pkw,
        const float* __restrict__ rpb, float* __restrict__ pb,
        const float* __restrict__ mlp_w1, unsigned short* __restrict__ pm1,
        const float* __restrict__ mlp_w2, unsigned short* __restrict__ pm2,
        const float* __restrict__ un_w1, unsigned short* __restrict__ pu1,
        const float* __restrict__ un_w2, unsigned short* __restrict__ pu2) {
    int blk = blockIdx.x;
    int lane = threadIdx.x;
    if (blk < 324) {
        pack_conv(blk, lane, dp_w1, dp_b1, bn_g, bn_b, pk, bias2);
    } else if (blk < 452) {
        int bb = blk - 324;
        int mat = bb >> 5;
        const float* W = (mat == 0) ? wq : (mat == 1) ? wk : (mat == 2) ? wv : wp;
        pack_gemmB(bb & 31, lane, W, pkw + (size_t)mat * 16384, 128);
    } else if (blk < 580) {
        pack_rpb(blk - 452, lane, rpb, pb);
    } else if (blk < 708) {
        pack_gemmB(blk - 580, lane, mlp_w1, pm1, 512);
    } else if (blk < 836) {
        pack_gemmB(blk - 708, lane, mlp_w2, pm2, 128);
    } else if (blk < 868) {
        pack_gemmB(blk - 836, lane, un_w1, pu1, 128);
    } else {
        pack_gemmB(blk - 868, lane, un_w2, pu2, 128);
    }
}

// ---------------------------------------------------------------------------
// K2: unary MLP via MFMA + LN1 producer. 1024 blocks x 64 tokens, 4 waves.
__global__ __launch_bounds__(256) void k_unary_mfma(const float* __restrict__ feat_l,
                                                    const unsigned short* __restrict__ pu1,
                                                    const float* __restrict__ b1,
                                                    const unsigned short* __restrict__ pu2,
                                                    const float* __restrict__ b2,
                                                    const float* __restrict__ g1,
                                                    const float* __restrict__ bt1,
                                                    float* __restrict__ x,
                                                    unsigned short* __restrict__ nf) {
    __shared__ __align__(16) unsigned short s_a[64 * 136];
    __shared__ __align__(16) unsigned short s_h[64 * 136];
    int tid = threadIdx.x;
    int wid = tid >> 6, lane = tid & 63;
    int g = lane >> 4, t = lane & 15;
    int n0g = blockIdx.x * 64;
    int b = n0g >> 14;
    int nb = n0g & 16383;

    for (int idx = tid; idx < 4096; idx += 256) {
        int c2 = idx >> 6, nl = idx & 63;
        float v0 = feat_l[((size_t)(b * 128 + 2 * c2) << 14) + nb + nl];
        float v1 = feat_l[((size_t)(b * 128 + 2 * c2 + 1) << 14) + nb + nl];
        *(unsigned int*)&s_a[nl * 136 + 2 * c2] = pack2bf(v0, v1);
    }
    __syncthreads();

    // ---- LN1 -> nf (token-major bf16) ----
    {
        int tok = tid >> 2, q = tid & 3;
        float v[32];
#pragma unroll
        for (int i8 = 0; i8 < 4; ++i8) {
            u16x8 r8 = *(const u16x8*)&s_a[tok * 136 + q * 32 + i8 * 8];
#pragma unroll
            for (int j = 0; j < 8; ++j) v[i8 * 8 + j] = bf2f(r8[j]);
        }
        float s = 0.f, s2 = 0.f;
#pragma unroll
        for (int i = 0; i < 32; ++i) { s += v[i]; s2 += v[i] * v[i]; }
        s += __shfl_xor(s, 1); s += __shfl_xor(s, 2);
        s2 += __shfl_xor(s2, 1); s2 += __shfl_xor(s2, 2);
        float mean = s * (1.f / 128.f);
        float var = s2 * (1.f / 128.f) - mean * mean;
        float rstd = rsqrtf(var + 1e-5f);
        size_t base = (size_t)(n0g + tok) * 128 + q * 32;
#pragma unroll
        for (int i8 = 0; i8 < 4; ++i8) {
            u16x8 o8;
#pragma unroll
            for (int j = 0; j < 8; ++j) {
                int c = q * 32 + i8 * 8 + j;
                o8[j] = f2bf((v[i8 * 8 + j] - mean) * rstd * g1[c] + bt1[c]);
            }
            *(u16x8*)&nf[base + i8 * 8] = o8;
        }
    }

    bf16x8 af[4][4];
#pragma unroll
    for (int Mt = 0; Mt < 4; ++Mt)
#pragma unroll
        for (int ks = 0; ks < 4; ++ks)
            af[Mt][ks] = *(const bf16x8*)&s_a[(Mt * 16 + t) * 136 + ks * 32 + g * 8];

    f32x4 acc1[4][2];
#pragma unroll
    for (int nt2 = 0; nt2 < 2; ++nt2) {
        float bv = b1[(wid * 2 + nt2) * 16 + t];
#pragma unroll
        for (int Mt = 0; Mt < 4; ++Mt) acc1[Mt][nt2] = (f32x4){bv, bv, bv, bv};
    }
#pragma unroll
    for (int ks = 0; ks < 4; ++ks) {
        bf16x8 bf0 = *(const bf16x8*)(pu1 + (size_t)(((wid * 2 + 0) * 4 + ks) * 64 + lane) * 8);
        bf16x8 bf1 = *(const bf16x8*)(pu1 + (size_t)(((wid * 2 + 1) * 4 + ks) * 64 + lane) * 8);
#pragma unroll
        for (int Mt = 0; Mt < 4; ++Mt) {
            acc1[Mt][0] = __builtin_amdgcn_mfma_f32_16x16x32_bf16(af[Mt][ks], bf0, acc1[Mt][0], 0, 0, 0);
            acc1[Mt][1] = __builtin_amdgcn_mfma_f32_16x16x32_bf16(af[Mt][ks], bf1, acc1[Mt][1], 0, 0, 0);
        }
    }
#pragma unroll
    for (int Mt = 0; Mt < 4; ++Mt)
#pragma unroll
        for (int nt2 = 0; nt2 < 2; ++nt2)
#pragma unroll
            for (int rr = 0; rr < 4; ++rr)
                s_h[(Mt * 16 + g * 4 + rr) * 136 + (wid * 2 + nt2) * 16 + t] = f2bf(gelu_f(acc1[Mt][nt2][rr]));
    __syncthreads();

    bf16x8 a2[4][4];
#pragma unroll
    for (int Mt = 0; Mt < 4; ++Mt)
#pragma unroll
        for (int ks = 0; ks < 4; ++ks)
            a2[Mt][ks] = *(const bf16x8*)&s_h[(Mt * 16 + t) * 136 + ks * 32 + g * 8];

    f32x4 acc2[4][2];
#pragma unroll
    for (int nt2 = 0; nt2 < 2; ++nt2) {
        float bv = b2[(wid * 2 + nt2) * 16 + t];
#pragma unroll
        for (int Mt = 0; Mt < 4; ++Mt) acc2[Mt][nt2] = (f32x4){bv, bv, bv, bv};
    }
#pragma unroll
    for (int ks = 0; ks < 4; ++ks) {
        bf16x8 bf0 = *(const bf16x8*)(pu2 + (size_t)(((wid * 2 + 0) * 4 + ks) * 64 + lane) * 8);
        bf16x8 bf1 = *(const bf16x8*)(pu2 + (size_t)(((wid * 2 + 1) * 4 + ks) * 64 + lane) * 8);
#pragma unroll
        for (int Mt = 0; Mt < 4; ++Mt) {
            acc2[Mt][0] = __builtin_amdgcn_mfma_f32_16x16x32_bf16(a2[Mt][ks], bf0, acc2[Mt][0], 0, 0, 0);
            acc2[Mt][1] = __builtin_amdgcn_mfma_f32_16x16x32_bf16(a2[Mt][ks], bf1, acc2[Mt][1], 0, 0, 0);
        }
    }
#pragma unroll
    for (int Mt = 0; Mt < 4; ++Mt)
#pragma unroll
        for (int nt2 = 0; nt2 < 2; ++nt2)
#pragma unroll
            for (int rr = 0; rr < 4; ++rr) {
                int tok = Mt * 16 + g * 4 + rr;
                x[(size_t)(n0g + tok) * 128 + (wid * 2 + nt2) * 16 + t] = acc2[Mt][nt2][rr];
            }
}

// ---------------------------------------------------------------------------
// K3: attention core (S^T = K Q^T form). 1024 blocks, 256 threads (4 waves).
__global__ __launch_bounds__(256, 3) void k_attn_core(const unsigned short* nf,
                                                      const unsigned short* __restrict__ pkw,
                                                      const float* __restrict__ pb,
                                                      const float* __restrict__ bq,
                                                      const float* __restrict__ bk,
                                                      const float* __restrict__ bv,
                                                      unsigned short* opk) {
    __shared__ __align__(16) unsigned short s_all[4 * 5760];
    int tid = threadIdx.x;
    int wid = tid >> 6, lane = tid & 63;
    int g = lane >> 4, t = lane & 15;
    int bw = blockIdx.x;
    int b = bw >> 8, wh = (bw >> 4) & 15, ww = bw & 15;

    bf16x8 af[4][4];   // [Mt][ks]
#pragma unroll
    for (int Mt = 0; Mt < 4; ++Mt) {
        int tok = Mt * 16 + t;
        size_t gtok = (size_t)(b * 16384) + (wh * 8 + (tok >> 3)) * 128 + ww * 8 + (tok & 7);
#pragma unroll
        for (int ks = 0; ks < 4; ++ks)
            af[Mt][ks] = *(const bf16x8*)&nf[gtok * 128 + ks * 32 + g * 8];
    }
    __syncthreads();

    unsigned short* sQ = s_all + wid * 5760;
    unsigned short* sK = sQ + 1536;
    unsigned short* sV = sQ + 4608;
    unsigned short* sP = sQ;
    unsigned short* sO = sQ;

    const bf16x8 z8v = {0, 0, 0, 0, 0, 0, 0, 0};

#pragma unroll
    for (int hi = 0; hi < 2; ++hi) {
        int h = wid + hi * 4;

        float bqv = bq[h * 16 + t], bkv = bk[h * 16 + t], bvv = bv[h * 16 + t];
        f32x4 qa[4], ka[4], va[4];
#pragma unroll
        for (int Mt = 0; Mt < 4; ++Mt) {
            qa[Mt] = (f32x4){bqv, bqv, bqv, bqv};
            ka[Mt] = (f32x4){bkv, bkv, bkv, bkv};
            va[Mt] = (f32x4){bvv, bvv, bvv, bvv};
        }
#pragma unroll
        for (int ks = 0; ks < 4; ++ks) {
            const unsigned short* wbase = pkw + ((size_t)((h * 4 + ks) * 64 + lane) * 8);
            bf16x8 bfq = *(const bf16x8*)(wbase);
            bf16x8 bfk = *(const bf16x8*)(wbase + 16384);
            bf16x8 bfv = *(const bf16x8*)(wbase + 32768);
#pragma unroll
            for (int Mt = 0; Mt < 4; ++Mt) {
                qa[Mt] = __builtin_amdgcn_mfma_f32_16x16x32_bf16(af[Mt][ks], bfq, qa[Mt], 0, 0, 0);
                ka[Mt] = __builtin_amdgcn_mfma_f32_16x16x32_bf16(af[Mt][ks], bfk, ka[Mt], 0, 0, 0);
                va[Mt] = __builtin_amdgcn_mfma_f32_16x16x32_bf16(af[Mt][ks], bfv, va[Mt], 0, 0, 0);
            }
        }
#pragma unroll
        for (int Mt = 0; Mt < 4; ++Mt) {
            bf16x4 vv;
#pragma unroll
            for (int rr = 0; rr < 4; ++rr) {
                int tok = Mt * 16 + g * 4 + rr;
                sQ[tok * 24 + t] = f2bf(qa[Mt][rr] * SCALE);
                sK[tok * 24 + t] = f2bf(ka[Mt][rr]);
                vv[rr] = (short)f2bf(va[Mt][rr]);
            }
            *(bf16x4*)&sV[t * 72 + Mt * 16 + g * 4] = vv;
        }

        // ---- S^T = K Q^T + bias(C-init); pad lanes (g>=2) feed zeros ----
        f32x4 s[4][4];   // [Mtk][Ntq]
#pragma unroll
        for (int Mtk = 0; Mtk < 4; ++Mtk)
#pragma unroll
            for (int Ntq = 0; Ntq < 4; ++Ntq)
                s[Mtk][Ntq] = *(const f32x4*)(pb + ((size_t)((h * 16 + Mtk * 4 + Ntq) * 64 + lane) * 4));
        bf16x8 bQ[4];
#pragma unroll
        for (int Ntq = 0; Ntq < 4; ++Ntq)
            bQ[Ntq] = (g < 2) ? *(const bf16x8*)&sQ[(Ntq * 16 + t) * 24 + g * 8] : z8v;
#pragma unroll
        for (int Mtk = 0; Mtk < 4; ++Mtk) {
            bf16x8 aK = (g < 2) ? *(const bf16x8*)&sK[(Mtk * 16 + t) * 24 + g * 8] : z8v;
#pragma unroll
            for (int Ntq = 0; Ntq < 4; ++Ntq)
                s[Mtk][Ntq] = __builtin_amdgcn_mfma_f32_16x16x32_bf16(aK, bQ[Ntq], s[Mtk][Ntq], 0, 0, 0);
        }

        // ---- softmax: per-lane 16-reduce + 2 shuffles per q-tile ----
#pragma unroll
        for (int Ntq = 0; Ntq < 4; ++Ntq) {
            float m = s[0][Ntq][0];
#pragma unroll
            for (int Mtk = 0; Mtk < 4; ++Mtk)
#pragma unroll
                for (int rr = 0; rr < 4; ++rr) m = fmaxf(m, s[Mtk][Ntq][rr]);
            m = fmaxf(m, __shfl_xor(m, 16));
            m = fmaxf(m, __shfl_xor(m, 32));
            float sum = 0.f;
#pragma unroll
            for (int Mtk = 0; Mtk < 4; ++Mtk)
#pragma unroll
                for (int rr = 0; rr < 4; ++rr) {
                    float e = __expf(s[Mtk][Ntq][rr] - m);
                    s[Mtk][Ntq][rr] = e;
                    sum += e;
                }
            sum += __shfl_xor(sum, 16);
            sum += __shfl_xor(sum, 32);
            float inv = __builtin_amdgcn_rcpf(sum);
#pragma unroll
            for (int Mtk = 0; Mtk < 4; ++Mtk) {
                bf16x4 pv;
#pragma unroll
                for (int rr = 0; rr < 4; ++rr) pv[rr] = (short)f2bf(s[Mtk][Ntq][rr] * inv);
                *(bf16x4*)&sP[(Ntq * 16 + t) * 72 + Mtk * 16 + g * 4] = pv;
            }
        }

        // ---- O = P @ V ----
        f32x4 oa[4];
#pragma unroll
        for (int Mt = 0; Mt < 4; ++Mt) oa[Mt] = (f32x4){0.f, 0.f, 0.f, 0.f};
#pragma unroll
        for (int ksv = 0; ksv < 2; ++ksv) {
            bf16x8 bv2 = *(const bf16x8*)&sV[t * 72 + ksv * 32 + g * 8];
#pragma unroll
            for (int Mt = 0; Mt < 4; ++Mt) {
                bf16x8 ap = *(const bf16x8*)&sP[(Mt * 16 + t) * 72 + ksv * 32 + g * 8];
                oa[Mt] = __builtin_amdgcn_mfma_f32_16x16x32_bf16(ap, bv2, oa[Mt], 0, 0, 0);
            }
        }
#pragma unroll
        for (int Mt = 0; Mt < 4; ++Mt)
#pragma unroll
            for (int rr = 0; rr < 4; ++rr)
                sO[(Mt * 16 + g * 4 + rr) * 16 + t] = f2bf(oa[Mt][rr]);
        int ksf = h >> 1;
        if ((g >> 1) == (h & 1)) {
#pragma unroll
            for (int Mt = 0; Mt < 4; ++Mt) {
                bf16x8 v8 = *(const bf16x8*)&sO[(Mt * 16 + t) * 16 + (g & 1) * 8];
                *(bf16x8*)&opk[opk_addr(b, wh, ww, Mt, ksf, lane)] = v8;
            }
        }
    }
}

// ---------------------------------------------------------------------------
// K4: per-WINDOW block: x = (x + o@wp + bp) + mlp(LN2(...)).
// Hidden processed in 2 chunks of 256 (s_h [64][264] overlays sf exactly).
__global__ __launch_bounds__(256) void k_mlp_mfma(float* __restrict__ x,
                                                  const unsigned short* __restrict__ opk,
                                                  const unsigned short* __restrict__ pkw,
                                                  const float* __restrict__ bp,
                                                  const float* __restrict__ g2,
                                                  const float* __restrict__ bt2,
                                                  const unsigned short* __restrict__ pm1,
                                                  const float* __restrict__ b1,
                                                  const unsigned short* __restrict__ pm2) {
    __shared__ __align__(16) char smem[51200];
    float* sf = (float*)smem;                       // [64][132] f32 (33792 B)
    unsigned short* s_h = (unsigned short*)smem;    // [64][264] bf16 overlays sf
    unsigned short* s_a = (unsigned short*)(smem + 33792);   // [64][136]
    int tid = threadIdx.x;
    int wid = tid >> 6, lane = tid & 63;
    int g = lane >> 4, t = lane & 15;
    int bw = blockIdx.x;
    int b = bw >> 8, wh = (bw >> 4) & 15, ww = bw & 15;

    auto gtok_of = [&](int tok) -> size_t {
        return (size_t)(b * 16384) + (wh * 8 + (tok >> 3)) * 128 + ww * 8 + (tok & 7);
    };

    // GEMM0: out = o_window @ wp + bp  (out doubles as final accumulator)
    f32x4 out[4][2];
    {
        float bp0 = bp[wid * 32 + t], bp1 = bp[wid * 32 + 16 + t];
#pragma unroll
        for (int Mt = 0; Mt < 4; ++Mt) {
            out[Mt][0] = (f32x4){bp0, bp0, bp0, bp0};
            out[Mt][1] = (f32x4){bp1, bp1, bp1, bp1};
        }
#pragma unroll
        for (int ks = 0; ks < 4; ++ks) {
            bf16x8 b0 = *(const bf16x8*)(pkw + 49152 + (size_t)(((wid * 2 + 0) * 4 + ks) * 64 + lane) * 8);
            bf16x8 b1v = *(const bf16x8*)(pkw + 49152 + (size_t)(((wid * 2 + 1) * 4 + ks) * 64 + lane) * 8);
#pragma unroll
            for (int Mt = 0; Mt < 4; ++Mt) {
                bf16x8 a = *(const bf16x8*)&opk[opk_addr(b, wh, ww, Mt, ks, lane)];
                out[Mt][0] = __builtin_amdgcn_mfma_f32_16x16x32_bf16(a, b0, out[Mt][0], 0, 0, 0);
                out[Mt][1] = __builtin_amdgcn_mfma_f32_16x16x32_bf16(a, b1v, out[Mt][1], 0, 0, 0);
            }
        }
#pragma unroll
        for (int Mt = 0; Mt < 4; ++Mt)
#pragma unroll
            for (int nt2 = 0; nt2 < 2; ++nt2)
#pragma unroll
                for (int rr = 0; rr < 4; ++rr) {
                    int tok = Mt * 16 + g * 4 + rr;
                    int col = (wid * 2 + nt2) * 16 + t;
                    float v = out[Mt][nt2][rr] + x[gtok_of(tok) * 128 + col];
                    out[Mt][nt2][rr] = v;
                    sf[tok * 132 + col] = v;
                }
    }
    __syncthreads();
    // LN2 -> bf16 s_a
    {
        int tok = tid >> 2, q = tid & 3;
        float s = 0.f, s2 = 0.f;
        for (int c = q * 32; c < q * 32 + 32; ++c) {
            float v = sf[tok * 132 + c];
            s += v; s2 += v * v;
        }
        s += __shfl_xor(s, 1); s += __shfl_xor(s, 2);
        s2 += __shfl_xor(s2, 1); s2 += __shfl_xor(s2, 2);
        float mean = s * (1.f / 128.f);
        float var = s2 * (1.f / 128.f) - mean * mean;
        float rstd = rsqrtf(var + 1e-5f);
        for (int c = q * 32; c < q * 32 + 32; c += 2) {
            float v0 = (sf[tok * 132 + c] - mean) * rstd * g2[c] + bt2[c];
            float v1 = (sf[tok * 132 + c + 1] - mean) * rstd * g2[c + 1] + bt2[c + 1];
            *(unsigned int*)&s_a[tok * 136 + c] = pack2bf(v0, v1);
        }
    }
    __syncthreads();   // sf dead; s_h region free
    bf16x8 af[4][4];
#pragma unroll
    for (int Mt = 0; Mt < 4; ++Mt)
#pragma unroll
        for (int ks = 0; ks < 4; ++ks)
            af[Mt][ks] = *(const bf16x8*)&s_a[(Mt * 16 + t) * 136 + ks * 32 + g * 8];

#pragma unroll 1
    for (int hc = 0; hc < 2; ++hc) {
        // GEMM1: wave covers 4 col-tiles of this 256-wide chunk, in 2 halves.
#pragma unroll
        for (int jh = 0; jh < 2; ++jh) {
            f32x4 acc1[4][2];
#pragma unroll
            for (int j2 = 0; j2 < 2; ++j2) {
                float bv = b1[hc * 256 + (wid * 4 + jh * 2 + j2) * 16 + t];
#pragma unroll
                for (int Mt = 0; Mt < 4; ++Mt) acc1[Mt][j2] = (f32x4){bv, bv, bv, bv};
            }
#pragma unroll
            for (int ks = 0; ks < 4; ++ks) {
                int nt0 = hc * 16 + wid * 4 + jh * 2;
                bf16x8 bf0 = *(const bf16x8*)(pm1 + (size_t)((((nt0 + 0) * 4 + ks) * 64 + lane) * 8));
                bf16x8 bf1 = *(const bf16x8*)(pm1 + (size_t)((((nt0 + 1) * 4 + ks) * 64 + lane) * 8));
#pragma unroll
                for (int Mt = 0; Mt < 4; ++Mt) {
                    acc1[Mt][0] = __builtin_amdgcn_mfma_f32_16x16x32_bf16(af[Mt][ks], bf0, acc1[Mt][0], 0, 0, 0);
                    acc1[Mt][1] = __builtin_amdgcn_mfma_f32_16x16x32_bf16(af[Mt][ks], bf1, acc1[Mt][1], 0, 0, 0);
                }
            }
#pragma unroll
            for (int Mt = 0; Mt < 4; ++Mt)
#pragma unroll
                for (int j2 = 0; j2 < 2; ++j2)
#pragma unroll
                    for (int rr = 0; rr < 4; ++rr)
                        s_h[(Mt * 16 + g * 4 + rr) * 264 + (wid * 4 + jh * 2 + j2) * 16 + t] =
                            f2bf(gelu_f(acc1[Mt][j2][rr]));
        }
        __syncthreads();
        // GEMM2: K=256 over this chunk, accumulate into out.
#pragma unroll
        for (int kt = 0; kt < 8; ++kt) {
            int kc = hc * 2 + (kt >> 2), ks = kt & 3;
            bf16x8 bf0 = *(const bf16x8*)(pm2 + (size_t)(((kc * 32 + (wid * 2 + 0) * 4 + ks) * 64 + lane) * 8));
            bf16x8 bf1 = *(const bf16x8*)(pm2 + (size_t)(((kc * 32 + (wid * 2 + 1) * 4 + ks) * 64 + lane) * 8));
#pragma unroll
            for (int Mt = 0; Mt < 4; ++Mt) {
                bf16x8 a2 = *(const bf16x8*)&s_h[(Mt * 16 + t) * 264 + kt * 32 + g * 8];
                out[Mt][0] = __builtin_amdgcn_mfma_f32_16x16x32_bf16(a2, bf0, out[Mt][0], 0, 0, 0);
                out[Mt][1] = __builtin_amdgcn_mfma_f32_16x16x32_bf16(a2, bf1, out[Mt][1], 0, 0, 0);
            }
        }
        __syncthreads();   // before next hc overwrites s_h
    }

    // final: x = x_pre_mlp + mlp_out
#pragma unroll
    for (int Mt = 0; Mt < 4; ++Mt)
#pragma unroll
        for (int nt2 = 0; nt2 < 2; ++nt2)
#pragma unroll
            for (int rr = 0; rr < 4; ++rr) {
                int tok = Mt * 16 + g * 4 + rr;
                x[gtok_of(tok) * 128 + (wid * 2 + nt2) * 16 + t] = out[Mt][nt2][rr];
            }
}

// ---------------------------------------------------------------------------
// K5b: conv3x3 as bf16 implicit-GEMM MFMA. grid (8,8,4), 256 threads.
__global__ __launch_bounds__(256) void k_conv_mfma(const float* __restrict__ x,
                                                   const float* __restrict__ cost,
                                                   const unsigned short* __restrict__ pk,
                                                   const float* __restrict__ bias2,
                                                   float* __restrict__ h1) {
    __shared__ __align__(16) unsigned short s_p[324 * 40];
    int tid = threadIdx.x;
    int wid = tid >> 6, lane = tid & 63;
    int g = lane >> 4, t = lane & 15;
    int tx0 = blockIdx.x * 16, ty0 = blockIdx.y * 16, b = blockIdx.z;

    f32x4 acc[4][6];
#pragma unroll
    for (int p = 0; p < 4; ++p)
#pragma unroll
        for (int ct = 0; ct < 6; ++ct) acc[p][ct] = (f32x4){0.f, 0.f, 0.f, 0.f};

#pragma unroll 1
    for (int chunk = 0; chunk < 6; ++chunk) {
        if (chunk < 4) {
            int ci0 = chunk * 32;
            for (int u = tid; u < 648; u += 256) {
                int pos = u >> 1, half = u & 1;
                int yy = pos / 18, xx = pos - yy * 18;
                int gy = ty0 + yy - 1, gx = tx0 + xx - 1;
                u16x8 lo, hi;
                if (gy >= 0 && gy < 128 && gx >= 0 && gx < 128) {
                    const float4* src = (const float4*)&x[((size_t)(b << 14) + gy * 128 + gx) * 128 + ci0 + half * 16];
                    float4 v0 = src[0], v1 = src[1], v2 = src[2], v3 = src[3];
                    lo[0] = f2bf(v0.x); lo[1] = f2bf(v0.y); lo[2] = f2bf(v0.z); lo[3] = f2bf(v0.w);
                    lo[4] = f2bf(v1.x); lo[5] = f2bf(v1.y); lo[6] = f2bf(v1.z); lo[7] = f2bf(v1.w);
                    hi[0] = f2bf(v2.x); hi[1] = f2bf(v2.y); hi[2] = f2bf(v2.z); hi[3] = f2bf(v2.w);
                    hi[4] = f2bf(v3.x); hi[5] = f2bf(v3.y); hi[6] = f2bf(v3.z); hi[7] = f2bf(v3.w);
                } else {
                    lo = (u16x8)(unsigned short)0; hi = (u16x8)(unsigned short)0;
                }
                unsigned short* dst = &s_p[pos * 40 + half * 16];
                *(u16x8*)dst = lo;
                *(u16x8*)(dst + 8) = hi;
            }
        } else {
            int d0 = (chunk - 4) * 32;
            for (int u = tid; u < 32 * 324; u += 256) {
                int cl = u / 324, r = u - cl * 324;
                int yy = r / 18, xx = r - yy * 18;
                int d = d0 + cl;
                int gy = ty0 + yy - 1, gx = tx0 + xx - 1;
                float v = 0.f;
                if (d < 48 && gy >= 0 && gy < 128 && gx >= 0 && gx < 128)
                    v = cost[((size_t)(b * 48 + d) << 14) + gy * 128 + gx];
                s_p[r * 40 + cl] = f2bf(v);
            }
        }
        __syncthreads();

#pragma unroll 1
        for (int tap = 0; tap < 9; ++tap) {
            int dy = tap / 3, dx = tap - dy * 3;
            const unsigned short* pkt = pk + ((size_t)(chunk * 9 + tap)) * 6 * 512;
            bf16x8 afr[6];
#pragma unroll
            for (int ct = 0; ct < 6; ++ct)
                afr[ct] = *(const bf16x8*)(pkt + ct * 512 + lane * 8);
            bf16x8 bfr[4];
#pragma unroll
            for (int p = 0; p < 4; ++p) {
                int pos = (wid * 4 + p + dy) * 18 + t + dx;
                bfr[p] = *(const bf16x8*)&s_p[pos * 40 + g * 8];
            }
#pragma unroll
            for (int p = 0; p < 4; ++p)
#pragma unroll
                for (int ct = 0; ct < 6; ++ct)
                    acc[p][ct] = __builtin_amdgcn_mfma_f32_16x16x32_bf16(afr[ct], bfr[p], acc[p][ct], 0, 0, 0);
        }
        __syncthreads();
    }

#pragma unroll
    for (int p = 0; p < 4; ++p) {
        int y = ty0 + wid * 4 + p;
#pragma unroll
        for (int ct = 0; ct < 6; ++ct) {
#pragma unroll
            for (int rr = 0; rr < 4; ++rr) {
                int co = ct * 16 + g * 4 + rr;
                if (co < 88) {
                    float v = acc[p][ct][rr] + bias2[co];
                    h1[((size_t)(b * 88 + co) << 14) + y * 128 + tx0 + t] = fmaxf(v, 0.f);
                }
            }
        }
    }
}

// ---------------------------------------------------------------------------
// K6: pv = conv1x1(h1) + b2; softmax over D; pred = 4*sum(d*p). 256 blocks.
__global__ __launch_bounds__(256) void k_head(const float* __restrict__ h1,
                                              const float* __restrict__ w2, const float* __restrict__ b2,
                                              float* __restrict__ out) {
    __shared__ float s_wt[88 * 48];   // [k][d]
    __shared__ float s_b[48];
    int tid = threadIdx.x;
    for (int idx = tid; idx < 48 * 88; idx += 256) {
        int d = idx / 88, k = idx % 88;
        s_wt[k * 48 + d] = w2[idx];
    }
    if (tid < 48) s_b[tid] = b2[tid];
    __syncthreads();
    int px = blockIdx.x * 256 + tid;
    int b = px >> 14, r = px & 16383;
    float acc[48];
#pragma unroll
    for (int d = 0; d < 48; ++d) acc[d] = s_b[d];
    for (int k = 0; k < 88; ++k) {
        float hv = h1[((size_t)(b * 88 + k) << 14) + r];
        const float4* wrow = (const float4*)&s_wt[k * 48];
#pragma unroll
        for (int d4 = 0; d4 < 12; ++d4) {
            float4 wv = wrow[d4];
            acc[d4 * 4 + 0] += hv * wv.x;
            acc[d4 * 4 + 1] += hv * wv.y;
            acc[d4 * 4 + 2] += hv * wv.z;
            acc[d4 * 4 + 3] += hv * wv.w;
        }
    }
    float mx = -1e30f;
#pragma unroll
    for (int d = 0; d < 48; ++d) mx = fmaxf(mx, acc[d]);
    float sum = 0.f, wsum = 0.f;
#pragma unroll
    for (int d = 0; d < 48; ++d) {
        float e = __expf(acc[d] - mx);
        sum += e;
        wsum += e * (float)d;
    }
    out[px] = 4.0f * wsum * __builtin_amdgcn_rcpf(sum);
}

// ---------------------------------------------------------------------------
extern "C" void kernel_launch(void* const* d_in, const int* in_sizes, int n_in,
                              void* d_out, int out_size, void* d_ws, size_t ws_size,
                              hipStream_t stream) {
    const float* feat_l = (const float*)d_in[0];
    const float* feat_r = (const float*)d_in[1];
    const float* wq = (const float*)d_in[2];
    const float* bq = (const float*)d_in[3];
    const float* wk = (const float*)d_in[4];
    const float* bk = (const float*)d_in[5];
    const float* wv = (const float*)d_in[6];
    const float* bv = (const float*)d_in[7];
    const float* wp = (const float*)d_in[8];
    const float* bp = (const float*)d_in[9];
    const float* rpb = (const float*)d_in[10];
    const float* ln1_g = (const float*)d_in[11];
    const float* ln1_b = (const float*)d_in[12];
    const float* ln2_g = (const float*)d_in[13];
    const float* ln2_b = (const float*)d_in[14];
    const float* mlp_w1 = (const float*)d_in[15];
    const float* mlp_b1 = (const float*)d_in[16];
    const float* mlp_w2 = (const float*)d_in[17];
    // d_in[18] = mlp_b2 is multiplied by 0.0 in the reference -> unused
    const float* un_w1 = (const float*)d_in[19];
    const float* un_b1 = (const float*)d_in[20];
    const float* un_w2 = (const float*)d_in[21];
    const float* un_b2 = (const float*)d_in[22];
    const float* dp_w1 = (const float*)d_in[23];
    const float* dp_b1 = (const float*)d_in[24];
    const float* bn_g = (const float*)d_in[25];
    const float* bn_b = (const float*)d_in[26];
    const float* dp_w2 = (const float*)d_in[27];
    const float* dp_b2 = (const float*)d_in[28];

    float* ws = (float*)d_ws;
    float* cost = ws;                               // 3,145,728 f
    float* x = ws + 3145728;                        // 8,388,608 f
    float* h1 = ws + 11534336;                      // 5,767,168 f
    unsigned short* nfo = (unsigned short*)h1;      // nf/o overlay (dead before conv)
    unsigned short* pk = (unsigned short*)(ws + 17301504);       // 165,888 u16
    float* bias2 = ws + 17384448;                   // 96 f
    unsigned short* pkw = (unsigned short*)(ws + 17384544);      // 65,536 u16
    float* pb = ws + 17417312;                      // 32,768 f
    unsigned short* pm1 = (unsigned short*)(ws + 17450080);      // 65,536 u16
    unsigned short* pm2 = (unsigned short*)(ws + 17482848);      // 65,536 u16
    unsigned short* pu1 = (unsigned short*)(ws + 17515616);      // 16,384 u16
    unsigned short* pu2 = (unsigned short*)(ws + 17523808);      // 16,384 u16
    float* out = (float*)d_out;

    k_pack_all<<<900, 64, 0, stream>>>(dp_w1, dp_b1, bn_g, bn_b, pk, bias2,
                                       wq, wk, wv, wp, pkw, rpb, pb,
                                       mlp_w1, pm1, mlp_w2, pm2,
                                       un_w1, pu1, un_w2, pu2);
    k_cost<<<dim3(2, 64, 4), 384, 0, stream>>>(feat_l, feat_r, cost);
    k_unary_mfma<<<1024, 256, 0, stream>>>(feat_l, pu1, un_b1, pu2, un_b2,
                                           ln1_g, ln1_b, x, nfo);
    k_attn_core<<<1024, 256, 0, stream>>>(nfo, pkw, pb, bq, bk, bv, nfo);
    k_mlp_mfma<<<1024, 256, 0, stream>>>(x, nfo, pkw, bp, ln2_g, ln2_b,
                                         pm1, mlp_b1, pm2);
    k_conv_mfma<<<dim3(8, 8, 4), 256, 0, stream>>>(x, cost, pk, bias2, h1);
    k_head<<<256, 256, 0, stream>>>(h1, dp_w2, dp_b2, out);
}

// Round 11
// 261.831 us; speedup vs baseline: 9.2920x; 1.0944x over previous
//
#include <hip/hip_runtime.h>
#include <math.h>

// Dims
constexpr int Bn = 4, Cc = 128, Hh = 128, Wn = 128, Dd = 48;
constexpr float SCALE = 0.25f;       // 16^-0.5

typedef short  bf16x8 __attribute__((ext_vector_type(8)));
typedef short  bf16x4 __attribute__((ext_vector_type(4)));
typedef float  f32x4  __attribute__((ext_vector_type(4)));
typedef unsigned short u16x8 __attribute__((ext_vector_type(8)));

// Native cast -> compiler emits v_cvt_pk_bf16_f32 (RNE).
static __device__ __forceinline__ unsigned short f2bf(float f) {
    return __builtin_bit_cast(unsigned short, (__bf16)f);
}

static __device__ __forceinline__ float bf2f(unsigned short u) {
    return __uint_as_float((unsigned int)u << 16);
}

static __device__ __forceinline__ unsigned int pack2bf(float a, float b) {
    return (unsigned int)f2bf(a) | ((unsigned int)f2bf(b) << 16);
}

// tanh-form GELU with hardware rcp.
static __device__ __forceinline__ float gelu_f(float v) {
    float u = v * (1.5957691216f + 0.0713548162f * v * v);
    return v * __builtin_amdgcn_rcpf(1.0f + __expf(-u));
}

// Packed-o address: fragment (Mt,ks), lane l, window (b,wh,ww).
static __device__ __forceinline__ size_t opk_addr(int b, int wh, int ww, int Mt, int ks, int lane) {
    return ((size_t)(b * 16384) + (wh * 8 + Mt * 2 + (ks >> 1)) * 128 + ww * 8) * 128
           + (ks & 1) * 512 + lane * 8;
}

// ---------------------------------------------------------------------------
// K1: cost volume -> bf16 pixel-major [b][h][w][64] (d 48..63 zero-padded).
__global__ __launch_bounds__(384) void k_cost(const float* __restrict__ fl,
                                              const float* __restrict__ fr,
                                              unsigned short* __restrict__ costbf) {
    __shared__ float s_fl[2][16][64];
    __shared__ float s_fr[2][16][112];
    int tid = threadIdx.x;
    int w0 = blockIdx.x * 64;
    int hp = blockIdx.y, b = blockIdx.z;
    int row = tid / 192;
    int r = tid - row * 192;
    int wg = r & 15, dg = r >> 4;
    int W = wg * 4, D = dg * 4;
    int h = hp * 2 + row;
    float acc[4][4];
#pragma unroll
    for (int i = 0; i < 4; ++i)
#pragma unroll
        for (int j = 0; j < 4; ++j) acc[i][j] = 0.f;

#pragma unroll 1
    for (int ck = 0; ck < 8; ++ck) {
        int ci0 = ck * 16;
        for (int i = tid; i < 512; i += 384) {
            int rr = i >> 8, rem = i & 255;
            int c = rem >> 4, k4 = rem & 15;
            float4 v = *(const float4*)&fl[((size_t)(b * 128 + ci0 + c) << 14) + (hp * 2 + rr) * 128 + w0 + k4 * 4];
            *(float4*)&s_fl[rr][c][k4 * 4] = v;
        }
        for (int i = tid; i < 896; i += 384) {
            int rr = i / 448, rem = i - rr * 448;
            int c = rem / 28, k4 = rem - c * 28;
            int wgl = w0 - 48 + k4 * 4;
            float4 v = {0.f, 0.f, 0.f, 0.f};
            if (wgl >= 0)
                v = *(const float4*)&fr[((size_t)(b * 128 + ci0 + c) << 14) + (hp * 2 + rr) * 128 + wgl];
            *(float4*)&s_fr[rr][c][k4 * 4] = v;
        }
        __syncthreads();
#pragma unroll
        for (int c = 0; c < 16; ++c) {
            float4 flv = *(const float4*)&s_fl[row][c][W];
            int base = W - D + 44;
            float4 f0 = *(const float4*)&s_fr[row][c][base];
            float4 f1 = *(const float4*)&s_fr[row][c][base + 4];
            float fw[8] = {f0.x, f0.y, f0.z, f0.w, f1.x, f1.y, f1.z, f1.w};
            float fv[4] = {flv.x, flv.y, flv.z, flv.w};
#pragma unroll
            for (int dj = 0; dj < 4; ++dj)
#pragma unroll
                for (int wv = 0; wv < 4; ++wv)
                    acc[dj][wv] += fv[wv] * fw[wv - dj + 4];
        }
        __syncthreads();
    }
    const float inv = 1.0f / 128.0f;
    unsigned short* cb = costbf + ((size_t)(b << 14) + h * 128 + w0 + W) * 64;
    const u16x8 z8 = {0, 0, 0, 0, 0, 0, 0, 0};
#pragma unroll
    for (int wv = 0; wv < 4; ++wv) {
        bf16x4 o4;
#pragma unroll
        for (int dj = 0; dj < 4; ++dj) o4[dj] = (short)f2bf(acc[dj][wv] * inv);
        *(bf16x4*)&cb[wv * 64 + D] = o4;
        if (D == 44) {                 // zero-pad d = 48..63
            *(u16x8*)&cb[wv * 64 + 48] = z8;
            *(u16x8*)&cb[wv * 64 + 56] = z8;
        }
    }
}

// ---------------------------------------------------------------------------
// Pack helpers fused into one kernel.
static __device__ void pack_conv(int blk, int lane,
                                 const float* __restrict__ w1, const float* __restrict__ b1,
                                 const float* __restrict__ bng, const float* __restrict__ bnb,
                                 unsigned short* __restrict__ pk, float* __restrict__ bias2) {
    const float rs = 0.9999950000374997f;
    int ct = blk % 6;
    int taplin = blk / 6;
    int tap = taplin % 9, chunk = taplin / 9;
    int co = ct * 16 + (lane & 15);
    int cibase = chunk * 32 + (lane >> 4) * 8;
    u16x8 out;
#pragma unroll
    for (int j = 0; j < 8; ++j) {
        int ci = cibase + j;
        float v = 0.f;
        if (co < 88 && ci < 176) v = w1[(size_t)co * 1584 + ci * 9 + tap] * rs * bng[co];
        out[j] = f2bf(v);
    }
    *(u16x8*)(pk + ((size_t)blk * 64 + lane) * 8) = out;
    if (blk == 0) {
        for (int i = lane; i < 96; i += 64)
            bias2[i] = (i < 88) ? (b1[i] * rs * bng[i] + bnb[i]) : 0.f;
    }
}

static __device__ void pack_gemmB(int blk, int lane,
                                  const float* __restrict__ W,
                                  unsigned short* __restrict__ out, int ncols) {
    int ntiles = ncols >> 4;
    int ks = blk & 3;
    int nt = (blk >> 2) % ntiles;
    int kc = blk / (4 * ntiles);
    int col = nt * 16 + (lane & 15);
    int k0 = kc * 128 + ks * 32 + (lane >> 4) * 8;
    u16x8 o;
#pragma unroll
    for (int j = 0; j < 8; ++j) o[j] = f2bf(W[(size_t)(k0 + j) * ncols + col]);
    *(u16x8*)(out + ((size_t)blk * 64 + lane) * 8) = o;
}

// rpb packed for the TRANSPOSED score layout.
static __device__ void pack_rpb(int blk, int lane,
                                const float* __restrict__ rpb, float* __restrict__ pb) {
    int nt = blk & 3, mt = (blk >> 2) & 3, hh = blk >> 4;
    int tq = nt * 16 + (lane & 15);
    int g = lane >> 4;
    float o[4];
#pragma unroll
    for (int rr = 0; rr < 4; ++rr) {
        int tk = mt * 16 + g * 4 + rr;
        int relidx = (((tq >> 3) - (tk >> 3)) + 7) * 15 + ((tq & 7) - (tk & 7)) + 7;
        o[rr] = rpb[relidx * 8 + hh];
    }
    float4 v = {o[0], o[1], o[2], o[3]};
    *(float4*)(pb + ((size_t)blk * 64 + lane) * 4) = v;
}

__global__ __launch_bounds__(64) void k_pack_all(
        const float* __restrict__ dp_w1, const float* __restrict__ dp_b1,
        const float* __restrict__ bn_g, const float* __restrict__ bn_b,
        unsigned short* __restrict__ pk, float* __restrict__ bias2,
        const float* __restrict__ wq, const float* __restrict__ wk,
        const float* __restrict__ wv, const float* __restrict__ wp,
        unsigned short* __restrict__ pkw,
        const float* __restrict__ rpb, float* __restrict__ pb,
        const float* __restrict__ mlp_w1, unsigned short* __restrict__ pm1,
        const float* __restrict__ mlp_w2, unsigned short* __restrict__ pm2,
        const float* __restrict__ un_w1, unsigned short* __restrict__ pu1,
        const float* __restrict__ un_w2, unsigned short* __restrict__ pu2) {
    int blk = blockIdx.x;
    int lane = threadIdx.x;
    if (blk < 324) {
        pack_conv(blk, lane, dp_w1, dp_b1, bn_g, bn_b, pk, bias2);
    } else if (blk < 452) {
        int bb = blk - 324;
        int mat = bb >> 5;
        const float* W = (mat == 0) ? wq : (mat == 1) ? wk : (mat == 2) ? wv : wp;
        pack_gemmB(bb & 31, lane, W, pkw + (size_t)mat * 16384, 128);
    } else if (blk < 580) {
        pack_rpb(blk - 452, lane, rpb, pb);
    } else if (blk < 708) {
        pack_gemmB(blk - 580, lane, mlp_w1, pm1, 512);
    } else if (blk < 836) {
        pack_gemmB(blk - 708, lane, mlp_w2, pm2, 128);
    } else if (blk < 868) {
        pack_gemmB(blk - 836, lane, un_w1, pu1, 128);
    } else {
        pack_gemmB(blk - 868, lane, un_w2, pu2, 128);
    }
}

// ---------------------------------------------------------------------------
// K2: unary MLP via MFMA + LN1 producer. 1024 blocks x 64 tokens, 4 waves.
__global__ __launch_bounds__(256) void k_unary_mfma(const float* __restrict__ feat_l,
                                                    const unsigned short* __restrict__ pu1,
                                                    const float* __restrict__ b1,
                                                    const unsigned short* __restrict__ pu2,
                                                    const float* __restrict__ b2,
                                                    const float* __restrict__ g1,
                                                    const float* __restrict__ bt1,
                                                    float* __restrict__ x,
                                                    unsigned short* __restrict__ nf) {
    __shared__ __align__(16) unsigned short s_a[64 * 136];
    __shared__ __align__(16) unsigned short s_h[64 * 136];
    int tid = threadIdx.x;
    int wid = tid >> 6, lane = tid & 63;
    int g = lane >> 4, t = lane & 15;
    int n0g = blockIdx.x * 64;
    int b = n0g >> 14;
    int nb = n0g & 16383;

    for (int idx = tid; idx < 4096; idx += 256) {
        int c2 = idx >> 6, nl = idx & 63;
        float v0 = feat_l[((size_t)(b * 128 + 2 * c2) << 14) + nb + nl];
        float v1 = feat_l[((size_t)(b * 128 + 2 * c2 + 1) << 14) + nb + nl];
        *(unsigned int*)&s_a[nl * 136 + 2 * c2] = pack2bf(v0, v1);
    }
    __syncthreads();

    // ---- LN1 -> nf (token-major bf16) ----
    {
        int tok = tid >> 2, q = tid & 3;
        float v[32];
#pragma unroll
        for (int i8 = 0; i8 < 4; ++i8) {
            u16x8 r8 = *(const u16x8*)&s_a[tok * 136 + q * 32 + i8 * 8];
#pragma unroll
            for (int j = 0; j < 8; ++j) v[i8 * 8 + j] = bf2f(r8[j]);
        }
        float s = 0.f, s2 = 0.f;
#pragma unroll
        for (int i = 0; i < 32; ++i) { s += v[i]; s2 += v[i] * v[i]; }
        s += __shfl_xor(s, 1); s += __shfl_xor(s, 2);
        s2 += __shfl_xor(s2, 1); s2 += __shfl_xor(s2, 2);
        float mean = s * (1.f / 128.f);
        float var = s2 * (1.f / 128.f) - mean * mean;
        float rstd = rsqrtf(var + 1e-5f);
        size_t base = (size_t)(n0g + tok) * 128 + q * 32;
#pragma unroll
        for (int i8 = 0; i8 < 4; ++i8) {
            u16x8 o8;
#pragma unroll
            for (int j = 0; j < 8; ++j) {
                int c = q * 32 + i8 * 8 + j;
                o8[j] = f2bf((v[i8 * 8 + j] - mean) * rstd * g1[c] + bt1[c]);
            }
            *(u16x8*)&nf[base + i8 * 8] = o8;
        }
    }

    bf16x8 af[4][4];
#pragma unroll
    for (int Mt = 0; Mt < 4; ++Mt)
#pragma unroll
        for (int ks = 0; ks < 4; ++ks)
            af[Mt][ks] = *(const bf16x8*)&s_a[(Mt * 16 + t) * 136 + ks * 32 + g * 8];

    f32x4 acc1[4][2];
#pragma unroll
    for (int nt2 = 0; nt2 < 2; ++nt2) {
        float bv = b1[(wid * 2 + nt2) * 16 + t];
#pragma unroll
        for (int Mt = 0; Mt < 4; ++Mt) acc1[Mt][nt2] = (f32x4){bv, bv, bv, bv};
    }
#pragma unroll
    for (int ks = 0; ks < 4; ++ks) {
        bf16x8 bf0 = *(const bf16x8*)(pu1 + (size_t)(((wid * 2 + 0) * 4 + ks) * 64 + lane) * 8);
        bf16x8 bf1 = *(const bf16x8*)(pu1 + (size_t)(((wid * 2 + 1) * 4 + ks) * 64 + lane) * 8);
#pragma unroll
        for (int Mt = 0; Mt < 4; ++Mt) {
            acc1[Mt][0] = __builtin_amdgcn_mfma_f32_16x16x32_bf16(af[Mt][ks], bf0, acc1[Mt][0], 0, 0, 0);
            acc1[Mt][1] = __builtin_amdgcn_mfma_f32_16x16x32_bf16(af[Mt][ks], bf1, acc1[Mt][1], 0, 0, 0);
        }
    }
#pragma unroll
    for (int Mt = 0; Mt < 4; ++Mt)
#pragma unroll
        for (int nt2 = 0; nt2 < 2; ++nt2)
#pragma unroll
            for (int rr = 0; rr < 4; ++rr)
                s_h[(Mt * 16 + g * 4 + rr) * 136 + (wid * 2 + nt2) * 16 + t] = f2bf(gelu_f(acc1[Mt][nt2][rr]));
    __syncthreads();

    bf16x8 a2[4][4];
#pragma unroll
    for (int Mt = 0; Mt < 4; ++Mt)
#pragma unroll
        for (int ks = 0; ks < 4; ++ks)
            a2[Mt][ks] = *(const bf16x8*)&s_h[(Mt * 16 + t) * 136 + ks * 32 + g * 8];

    f32x4 acc2[4][2];
#pragma unroll
    for (int nt2 = 0; nt2 < 2; ++nt2) {
        float bv = b2[(wid * 2 + nt2) * 16 + t];
#pragma unroll
        for (int Mt = 0; Mt < 4; ++Mt) acc2[Mt][nt2] = (f32x4){bv, bv, bv, bv};
    }
#pragma unroll
    for (int ks = 0; ks < 4; ++ks) {
        bf16x8 bf0 = *(const bf16x8*)(pu2 + (size_t)(((wid * 2 + 0) * 4 + ks) * 64 + lane) * 8);
        bf16x8 bf1 = *(const bf16x8*)(pu2 + (size_t)(((wid * 2 + 1) * 4 + ks) * 64 + lane) * 8);
#pragma unroll
        for (int Mt = 0; Mt < 4; ++Mt) {
            acc2[Mt][0] = __builtin_amdgcn_mfma_f32_16x16x32_bf16(a2[Mt][ks], bf0, acc2[Mt][0], 0, 0, 0);
            acc2[Mt][1] = __builtin_amdgcn_mfma_f32_16x16x32_bf16(a2[Mt][ks], bf1, acc2[Mt][1], 0, 0, 0);
        }
    }
#pragma unroll
    for (int Mt = 0; Mt < 4; ++Mt)
#pragma unroll
        for (int nt2 = 0; nt2 < 2; ++nt2)
#pragma unroll
            for (int rr = 0; rr < 4; ++rr) {
                int tok = Mt * 16 + g * 4 + rr;
                x[(size_t)(n0g + tok) * 128 + (wid * 2 + nt2) * 16 + t] = acc2[Mt][nt2][rr];
            }
}

// ---------------------------------------------------------------------------
// K3: attention core (S^T = K Q^T form). 1024 blocks, 256 threads (4 waves).
__global__ __launch_bounds__(256, 3) void k_attn_core(const unsigned short* nf,
                                                      const unsigned short* __restrict__ pkw,
                                                      const float* __restrict__ pb,
                                                      const float* __restrict__ bq,
                                                      const float* __restrict__ bk,
                                                      const float* __restrict__ bv,
                                                      unsigned short* opk) {
    __shared__ __align__(16) unsigned short s_all[4 * 5760];
    int tid = threadIdx.x;
    int wid = tid >> 6, lane = tid & 63;
    int g = lane >> 4, t = lane & 15;
    int bw = blockIdx.x;
    int b = bw >> 8, wh = (bw >> 4) & 15, ww = bw & 15;

    bf16x8 af[4][4];   // [Mt][ks]
#pragma unroll
    for (int Mt = 0; Mt < 4; ++Mt) {
        int tok = Mt * 16 + t;
        size_t gtok = (size_t)(b * 16384) + (wh * 8 + (tok >> 3)) * 128 + ww * 8 + (tok & 7);
#pragma unroll
        for (int ks = 0; ks < 4; ++ks)
            af[Mt][ks] = *(const bf16x8*)&nf[gtok * 128 + ks * 32 + g * 8];
    }
    __syncthreads();

    unsigned short* sQ = s_all + wid * 5760;
    unsigned short* sK = sQ + 1536;
    unsigned short* sV = sQ + 4608;
    unsigned short* sP = sQ;
    unsigned short* sO = sQ;

    const bf16x8 z8v = {0, 0, 0, 0, 0, 0, 0, 0};

#pragma unroll
    for (int hi = 0; hi < 2; ++hi) {
        int h = wid + hi * 4;

        float bqv = bq[h * 16 + t], bkv = bk[h * 16 + t], bvv = bv[h * 16 + t];
        f32x4 qa[4], ka[4], va[4];
#pragma unroll
        for (int Mt = 0; Mt < 4; ++Mt) {
            qa[Mt] = (f32x4){bqv, bqv, bqv, bqv};
            ka[Mt] = (f32x4){bkv, bkv, bkv, bkv};
            va[Mt] = (f32x4){bvv, bvv, bvv, bvv};
        }
#pragma unroll
        for (int ks = 0; ks < 4; ++ks) {
            const unsigned short* wbase = pkw + ((size_t)((h * 4 + ks) * 64 + lane) * 8);
            bf16x8 bfq = *(const bf16x8*)(wbase);
            bf16x8 bfk = *(const bf16x8*)(wbase + 16384);
            bf16x8 bfv = *(const bf16x8*)(wbase + 32768);
#pragma unroll
            for (int Mt = 0; Mt < 4; ++Mt) {
                qa[Mt] = __builtin_amdgcn_mfma_f32_16x16x32_bf16(af[Mt][ks], bfq, qa[Mt], 0, 0, 0);
                ka[Mt] = __builtin_amdgcn_mfma_f32_16x16x32_bf16(af[Mt][ks], bfk, ka[Mt], 0, 0, 0);
                va[Mt] = __builtin_amdgcn_mfma_f32_16x16x32_bf16(af[Mt][ks], bfv, va[Mt], 0, 0, 0);
            }
        }
#pragma unroll
        for (int Mt = 0; Mt < 4; ++Mt) {
            bf16x4 vv;
#pragma unroll
            for (int rr = 0; rr < 4; ++rr) {
                int tok = Mt * 16 + g * 4 + rr;
                sQ[tok * 24 + t] = f2bf(qa[Mt][rr] * SCALE);
                sK[tok * 24 + t] = f2bf(ka[Mt][rr]);
                vv[rr] = (short)f2bf(va[Mt][rr]);
            }
            *(bf16x4*)&sV[t * 72 + Mt * 16 + g * 4] = vv;
        }

        // ---- S^T = K Q^T + bias(C-init); pad lanes (g>=2) feed zeros ----
        f32x4 s[4][4];   // [Mtk][Ntq]
#pragma unroll
        for (int Mtk = 0; Mtk < 4; ++Mtk)
#pragma unroll
            for (int Ntq = 0; Ntq < 4; ++Ntq)
                s[Mtk][Ntq] = *(const f32x4*)(pb + ((size_t)((h * 16 + Mtk * 4 + Ntq) * 64 + lane) * 4));
        bf16x8 bQ[4];
#pragma unroll
        for (int Ntq = 0; Ntq < 4; ++Ntq)
            bQ[Ntq] = (g < 2) ? *(const bf16x8*)&sQ[(Ntq * 16 + t) * 24 + g * 8] : z8v;
#pragma unroll
        for (int Mtk = 0; Mtk < 4; ++Mtk) {
            bf16x8 aK = (g < 2) ? *(const bf16x8*)&sK[(Mtk * 16 + t) * 24 + g * 8] : z8v;
#pragma unroll
            for (int Ntq = 0; Ntq < 4; ++Ntq)
                s[Mtk][Ntq] = __builtin_amdgcn_mfma_f32_16x16x32_bf16(aK, bQ[Ntq], s[Mtk][Ntq], 0, 0, 0);
        }

        // ---- softmax: per-lane 16-reduce + 2 shuffles per q-tile ----
#pragma unroll
        for (int Ntq = 0; Ntq < 4; ++Ntq) {
            float m = s[0][Ntq][0];
#pragma unroll
            for (int Mtk = 0; Mtk < 4; ++Mtk)
#pragma unroll
                for (int rr = 0; rr < 4; ++rr) m = fmaxf(m, s[Mtk][Ntq][rr]);
            m = fmaxf(m, __shfl_xor(m, 16));
            m = fmaxf(m, __shfl_xor(m, 32));
            float sum = 0.f;
#pragma unroll
            for (int Mtk = 0; Mtk < 4; ++Mtk)
#pragma unroll
                for (int rr = 0; rr < 4; ++rr) {
                    float e = __expf(s[Mtk][Ntq][rr] - m);
                    s[Mtk][Ntq][rr] = e;
                    sum += e;
                }
            sum += __shfl_xor(sum, 16);
            sum += __shfl_xor(sum, 32);
            float inv = __builtin_amdgcn_rcpf(sum);
#pragma unroll
            for (int Mtk = 0; Mtk < 4; ++Mtk) {
                bf16x4 pv;
#pragma unroll
                for (int rr = 0; rr < 4; ++rr) pv[rr] = (short)f2bf(s[Mtk][Ntq][rr] * inv);
                *(bf16x4*)&sP[(Ntq * 16 + t) * 72 + Mtk * 16 + g * 4] = pv;
            }
        }

        // ---- O = P @ V ----
        f32x4 oa[4];
#pragma unroll
        for (int Mt = 0; Mt < 4; ++Mt) oa[Mt] = (f32x4){0.f, 0.f, 0.f, 0.f};
#pragma unroll
        for (int ksv = 0; ksv < 2; ++ksv) {
            bf16x8 bv2 = *(const bf16x8*)&sV[t * 72 + ksv * 32 + g * 8];
#pragma unroll
            for (int Mt = 0; Mt < 4; ++Mt) {
                bf16x8 ap = *(const bf16x8*)&sP[(Mt * 16 + t) * 72 + ksv * 32 + g * 8];
                oa[Mt] = __builtin_amdgcn_mfma_f32_16x16x32_bf16(ap, bv2, oa[Mt], 0, 0, 0);
            }
        }
#pragma unroll
        for (int Mt = 0; Mt < 4; ++Mt)
#pragma unroll
            for (int rr = 0; rr < 4; ++rr)
                sO[(Mt * 16 + g * 4 + rr) * 16 + t] = f2bf(oa[Mt][rr]);
        int ksf = h >> 1;
        if ((g >> 1) == (h & 1)) {
#pragma unroll
            for (int Mt = 0; Mt < 4; ++Mt) {
                bf16x8 v8 = *(const bf16x8*)&sO[(Mt * 16 + t) * 16 + (g & 1) * 8];
                *(bf16x8*)&opk[opk_addr(b, wh, ww, Mt, ksf, lane)] = v8;
            }
        }
    }
}

// ---------------------------------------------------------------------------
// K4: per-WINDOW block: x = (x + o@wp + bp) + mlp(LN2(...)).
__global__ __launch_bounds__(256) void k_mlp_mfma(float* __restrict__ x,
                                                  const unsigned short* __restrict__ opk,
                                                  const unsigned short* __restrict__ pkw,
                                                  const float* __restrict__ bp,
                                                  const float* __restrict__ g2,
                                                  const float* __restrict__ bt2,
                                                  const unsigned short* __restrict__ pm1,
                                                  const float* __restrict__ b1,
                                                  const unsigned short* __restrict__ pm2) {
    __shared__ __align__(16) char smem[51200];
    float* sf = (float*)smem;                       // [64][132] f32 (33792 B)
    unsigned short* s_h = (unsigned short*)smem;    // [64][264] bf16 overlays sf
    unsigned short* s_a = (unsigned short*)(smem + 33792);   // [64][136]
    int tid = threadIdx.x;
    int wid = tid >> 6, lane = tid & 63;
    int g = lane >> 4, t = lane & 15;
    int bw = blockIdx.x;
    int b = bw >> 8, wh = (bw >> 4) & 15, ww = bw & 15;

    auto gtok_of = [&](int tok) -> size_t {
        return (size_t)(b * 16384) + (wh * 8 + (tok >> 3)) * 128 + ww * 8 + (tok & 7);
    };

    f32x4 out[4][2];
    {
        float bp0 = bp[wid * 32 + t], bp1 = bp[wid * 32 + 16 + t];
#pragma unroll
        for (int Mt = 0; Mt < 4; ++Mt) {
            out[Mt][0] = (f32x4){bp0, bp0, bp0, bp0};
            out[Mt][1] = (f32x4){bp1, bp1, bp1, bp1};
        }
#pragma unroll
        for (int ks = 0; ks < 4; ++ks) {
            bf16x8 b0 = *(const bf16x8*)(pkw + 49152 + (size_t)(((wid * 2 + 0) * 4 + ks) * 64 + lane) * 8);
            bf16x8 b1v = *(const bf16x8*)(pkw + 49152 + (size_t)(((wid * 2 + 1) * 4 + ks) * 64 + lane) * 8);
#pragma unroll
            for (int Mt = 0; Mt < 4; ++Mt) {
                bf16x8 a = *(const bf16x8*)&opk[opk_addr(b, wh, ww, Mt, ks, lane)];
                out[Mt][0] = __builtin_amdgcn_mfma_f32_16x16x32_bf16(a, b0, out[Mt][0], 0, 0, 0);
                out[Mt][1] = __builtin_amdgcn_mfma_f32_16x16x32_bf16(a, b1v, out[Mt][1], 0, 0, 0);
            }
        }
#pragma unroll
        for (int Mt = 0; Mt < 4; ++Mt)
#pragma unroll
            for (int nt2 = 0; nt2 < 2; ++nt2)
#pragma unroll
                for (int rr = 0; rr < 4; ++rr) {
                    int tok = Mt * 16 + g * 4 + rr;
                    int col = (wid * 2 + nt2) * 16 + t;
                    float v = out[Mt][nt2][rr] + x[gtok_of(tok) * 128 + col];
                    out[Mt][nt2][rr] = v;
                    sf[tok * 132 + col] = v;
                }
    }
    __syncthreads();
    {
        int tok = tid >> 2, q = tid & 3;
        float s = 0.f, s2 = 0.f;
        for (int c = q * 32; c < q * 32 + 32; ++c) {
            float v = sf[tok * 132 + c];
            s += v; s2 += v * v;
        }
        s += __shfl_xor(s, 1); s += __shfl_xor(s, 2);
        s2 += __shfl_xor(s2, 1); s2 += __shfl_xor(s2, 2);
        float mean = s * (1.f / 128.f);
        float var = s2 * (1.f / 128.f) - mean * mean;
        float rstd = rsqrtf(var + 1e-5f);
        for (int c = q * 32; c < q * 32 + 32; c += 2) {
            float v0 = (sf[tok * 132 + c] - mean) * rstd * g2[c] + bt2[c];
            float v1 = (sf[tok * 132 + c + 1] - mean) * rstd * g2[c + 1] + bt2[c + 1];
            *(unsigned int*)&s_a[tok * 136 + c] = pack2bf(v0, v1);
        }
    }
    __syncthreads();
    bf16x8 af[4][4];
#pragma unroll
    for (int Mt = 0; Mt < 4; ++Mt)
#pragma unroll
        for (int ks = 0; ks < 4; ++ks)
            af[Mt][ks] = *(const bf16x8*)&s_a[(Mt * 16 + t) * 136 + ks * 32 + g * 8];

#pragma unroll 1
    for (int hc = 0; hc < 2; ++hc) {
#pragma unroll
        for (int jh = 0; jh < 2; ++jh) {
            f32x4 acc1[4][2];
#pragma unroll
            for (int j2 = 0; j2 < 2; ++j2) {
                float bv = b1[hc * 256 + (wid * 4 + jh * 2 + j2) * 16 + t];
#pragma unroll
                for (int Mt = 0; Mt < 4; ++Mt) acc1[Mt][j2] = (f32x4){bv, bv, bv, bv};
            }
#pragma unroll
            for (int ks = 0; ks < 4; ++ks) {
                int nt0 = hc * 16 + wid * 4 + jh * 2;
                bf16x8 bf0 = *(const bf16x8*)(pm1 + (size_t)((((nt0 + 0) * 4 + ks) * 64 + lane) * 8));
                bf16x8 bf1 = *(const bf16x8*)(pm1 + (size_t)((((nt0 + 1) * 4 + ks) * 64 + lane) * 8));
#pragma unroll
                for (int Mt = 0; Mt < 4; ++Mt) {
                    acc1[Mt][0] = __builtin_amdgcn_mfma_f32_16x16x32_bf16(af[Mt][ks], bf0, acc1[Mt][0], 0, 0, 0);
                    acc1[Mt][1] = __builtin_amdgcn_mfma_f32_16x16x32_bf16(af[Mt][ks], bf1, acc1[Mt][1], 0, 0, 0);
                }
            }
#pragma unroll
            for (int Mt = 0; Mt < 4; ++Mt)
#pragma unroll
                for (int j2 = 0; j2 < 2; ++j2)
#pragma unroll
                    for (int rr = 0; rr < 4; ++rr)
                        s_h[(Mt * 16 + g * 4 + rr) * 264 + (wid * 4 + jh * 2 + j2) * 16 + t] =
                            f2bf(gelu_f(acc1[Mt][j2][rr]));
        }
        __syncthreads();
#pragma unroll
        for (int kt = 0; kt < 8; ++kt) {
            int kc = hc * 2 + (kt >> 2), ks = kt & 3;
            bf16x8 bf0 = *(const bf16x8*)(pm2 + (size_t)(((kc * 32 + (wid * 2 + 0) * 4 + ks) * 64 + lane) * 8));
            bf16x8 bf1 = *(const bf16x8*)(pm2 + (size_t)(((kc * 32 + (wid * 2 + 1) * 4 + ks) * 64 + lane) * 8));
#pragma unroll
            for (int Mt = 0; Mt < 4; ++Mt) {
                bf16x8 a2 = *(const bf16x8*)&s_h[(Mt * 16 + t) * 264 + kt * 32 + g * 8];
                out[Mt][0] = __builtin_amdgcn_mfma_f32_16x16x32_bf16(a2, bf0, out[Mt][0], 0, 0, 0);
                out[Mt][1] = __builtin_amdgcn_mfma_f32_16x16x32_bf16(a2, bf1, out[Mt][1], 0, 0, 0);
            }
        }
        __syncthreads();
    }

#pragma unroll
    for (int Mt = 0; Mt < 4; ++Mt)
#pragma unroll
        for (int nt2 = 0; nt2 < 2; ++nt2)
#pragma unroll
            for (int rr = 0; rr < 4; ++rr) {
                int tok = Mt * 16 + g * 4 + rr;
                x[gtok_of(tok) * 128 + (wid * 2 + nt2) * 16 + t] = out[Mt][nt2][rr];
            }
}

// ---------------------------------------------------------------------------
// K5b: conv3x3 as bf16 implicit-GEMM MFMA. grid (8,16,4) = 512 blocks, 16x8 tile.
// Wave handles 2 output rows; cost read from bf16 pixel-major costbf.
__global__ __launch_bounds__(256) void k_conv_mfma(const float* __restrict__ x,
                                                   const unsigned short* __restrict__ costbf,
                                                   const unsigned short* __restrict__ pk,
                                                   const float* __restrict__ bias2,
                                                   float* __restrict__ h1) {
    __shared__ __align__(16) unsigned short s_p[180 * 40];   // [pos 10x18][ci 32 pad40]
    int tid = threadIdx.x;
    int wid = tid >> 6, lane = tid & 63;
    int g = lane >> 4, t = lane & 15;
    int tx0 = blockIdx.x * 16, ty0 = blockIdx.y * 8, b = blockIdx.z;

    f32x4 acc[2][6];
#pragma unroll
    for (int p = 0; p < 2; ++p)
#pragma unroll
        for (int ct = 0; ct < 6; ++ct) acc[p][ct] = (f32x4){0.f, 0.f, 0.f, 0.f};

#pragma unroll 1
    for (int chunk = 0; chunk < 6; ++chunk) {
        if (chunk < 4) {
            int ci0 = chunk * 32;
            for (int u = tid; u < 360; u += 256) {
                int pos = u >> 1, half = u & 1;
                int yy = pos / 18, xx = pos - yy * 18;
                int gy = ty0 + yy - 1, gx = tx0 + xx - 1;
                u16x8 lo, hi;
                if (gy >= 0 && gy < 128 && gx >= 0 && gx < 128) {
                    const float4* src = (const float4*)&x[((size_t)(b << 14) + gy * 128 + gx) * 128 + ci0 + half * 16];
                    float4 v0 = src[0], v1 = src[1], v2 = src[2], v3 = src[3];
                    lo[0] = f2bf(v0.x); lo[1] = f2bf(v0.y); lo[2] = f2bf(v0.z); lo[3] = f2bf(v0.w);
                    lo[4] = f2bf(v1.x); lo[5] = f2bf(v1.y); lo[6] = f2bf(v1.z); lo[7] = f2bf(v1.w);
                    hi[0] = f2bf(v2.x); hi[1] = f2bf(v2.y); hi[2] = f2bf(v2.z); hi[3] = f2bf(v2.w);
                    hi[4] = f2bf(v3.x); hi[5] = f2bf(v3.y); hi[6] = f2bf(v3.z); hi[7] = f2bf(v3.w);
                } else {
                    lo = (u16x8)(unsigned short)0; hi = (u16x8)(unsigned short)0;
                }
                unsigned short* dst = &s_p[pos * 40 + half * 16];
                *(u16x8*)dst = lo;
                *(u16x8*)(dst + 8) = hi;
            }
        } else {
            int d0 = (chunk - 4) * 32;
            for (int u = tid; u < 180; u += 256) {
                int yy = u / 18, xx = u - yy * 18;
                int gy = ty0 + yy - 1, gx = tx0 + xx - 1;
                u16x8 lo = (u16x8)(unsigned short)0, hi = (u16x8)(unsigned short)0;
                if (gy >= 0 && gy < 128 && gx >= 0 && gx < 128) {
                    const u16x8* src = (const u16x8*)&costbf[((size_t)(b << 14) + gy * 128 + gx) * 64 + d0];
                    lo = src[0]; hi = src[1];
                    u16x8 l2 = src[2], h2 = src[3];
                    *(u16x8*)&s_p[u * 40 + 16] = l2;
                    *(u16x8*)&s_p[u * 40 + 24] = h2;
                } else {
                    *(u16x8*)&s_p[u * 40 + 16] = lo;
                    *(u16x8*)&s_p[u * 40 + 24] = hi;
                }
                *(u16x8*)&s_p[u * 40 + 0] = lo;
                *(u16x8*)&s_p[u * 40 + 8] = hi;
            }
        }
        __syncthreads();

#pragma unroll 1
        for (int tap = 0; tap < 9; ++tap) {
            int dy = tap / 3, dx = tap - dy * 3;
            const unsigned short* pkt = pk + ((size_t)(chunk * 9 + tap)) * 6 * 512;
            bf16x8 afr[6];
#pragma unroll
            for (int ct = 0; ct < 6; ++ct)
                afr[ct] = *(const bf16x8*)(pkt + ct * 512 + lane * 8);
            bf16x8 bfr[2];
#pragma unroll
            for (int p = 0; p < 2; ++p) {
                int pos = (wid * 2 + p + dy) * 18 + t + dx;
                bfr[p] = *(const bf16x8*)&s_p[pos * 40 + g * 8];
            }
#pragma unroll
            for (int p = 0; p < 2; ++p)
#pragma unroll
                for (int ct = 0; ct < 6; ++ct)
                    acc[p][ct] = __builtin_amdgcn_mfma_f32_16x16x32_bf16(afr[ct], bfr[p], acc[p][ct], 0, 0, 0);
        }
        __syncthreads();
    }

#pragma unroll
    for (int p = 0; p < 2; ++p) {
        int y = ty0 + wid * 2 + p;
#pragma unroll
        for (int ct = 0; ct < 6; ++ct) {
#pragma unroll
            for (int rr = 0; rr < 4; ++rr) {
                int co = ct * 16 + g * 4 + rr;
                if (co < 88) {
                    float v = acc[p][ct][rr] + bias2[co];
                    h1[((size_t)(b * 88 + co) << 14) + y * 128 + tx0 + t] = fmaxf(v, 0.f);
                }
            }
        }
    }
}

// ---------------------------------------------------------------------------
// K6: pv = conv1x1(h1) + b2; softmax over D; pred = 4*sum(d*p). 256 blocks.
__global__ __launch_bounds__(256) void k_head(const float* __restrict__ h1,
                                              const float* __restrict__ w2, const float* __restrict__ b2,
                                              float* __restrict__ out) {
    __shared__ float s_wt[88 * 48];   // [k][d]
    __shared__ float s_b[48];
    int tid = threadIdx.x;
    for (int idx = tid; idx < 48 * 88; idx += 256) {
        int d = idx / 88, k = idx % 88;
        s_wt[k * 48 + d] = w2[idx];
    }
    if (tid < 48) s_b[tid] = b2[tid];
    __syncthreads();
    int px = blockIdx.x * 256 + tid;
    int b = px >> 14, r = px & 16383;
    float acc[48];
#pragma unroll
    for (int d = 0; d < 48; ++d) acc[d] = s_b[d];
    for (int k = 0; k < 88; ++k) {
        float hv = h1[((size_t)(b * 88 + k) << 14) + r];
        const float4* wrow = (const float4*)&s_wt[k * 48];
#pragma unroll
        for (int d4 = 0; d4 < 12; ++d4) {
            float4 wv = wrow[d4];
            acc[d4 * 4 + 0] += hv * wv.x;
            acc[d4 * 4 + 1] += hv * wv.y;
            acc[d4 * 4 + 2] += hv * wv.z;
            acc[d4 * 4 + 3] += hv * wv.w;
        }
    }
    float mx = -1e30f;
#pragma unroll
    for (int d = 0; d < 48; ++d) mx = fmaxf(mx, acc[d]);
    float sum = 0.f, wsum = 0.f;
#pragma unroll
    for (int d = 0; d < 48; ++d) {
        float e = __expf(acc[d] - mx);
        sum += e;
        wsum += e * (float)d;
    }
    out[px] = 4.0f * wsum * __builtin_amdgcn_rcpf(sum);
}

// ---------------------------------------------------------------------------
extern "C" void kernel_launch(void* const* d_in, const int* in_sizes, int n_in,
                              void* d_out, int out_size, void* d_ws, size_t ws_size,
                              hipStream_t stream) {
    const float* feat_l = (const float*)d_in[0];
    const float* feat_r = (const float*)d_in[1];
    const float* wq = (const float*)d_in[2];
    const float* bq = (const float*)d_in[3];
    const float* wk = (const float*)d_in[4];
    const float* bk = (const float*)d_in[5];
    const float* wv = (const float*)d_in[6];
    const float* bv = (const float*)d_in[7];
    const float* wp = (const float*)d_in[8];
    const float* bp = (const float*)d_in[9];
    const float* rpb = (const float*)d_in[10];
    const float* ln1_g = (const float*)d_in[11];
    const float* ln1_b = (const float*)d_in[12];
    const float* ln2_g = (const float*)d_in[13];
    const float* ln2_b = (const float*)d_in[14];
    const float* mlp_w1 = (const float*)d_in[15];
    const float* mlp_b1 = (const float*)d_in[16];
    const float* mlp_w2 = (const float*)d_in[17];
    // d_in[18] = mlp_b2 is multiplied by 0.0 in the reference -> unused
    const float* un_w1 = (const float*)d_in[19];
    const float* un_b1 = (const float*)d_in[20];
    const float* un_w2 = (const float*)d_in[21];
    const float* un_b2 = (const float*)d_in[22];
    const float* dp_w1 = (const float*)d_in[23];
    const float* dp_b1 = (const float*)d_in[24];
    const float* bn_g = (const float*)d_in[25];
    const float* bn_b = (const float*)d_in[26];
    const float* dp_w2 = (const float*)d_in[27];
    const float* dp_b2 = (const float*)d_in[28];

    float* ws = (float*)d_ws;
    unsigned short* costbf = (unsigned short*)ws;   // 4*16384*64 u16 = 8.4 MB (in old cost region)
    float* x = ws + 3145728;                        // 8,388,608 f
    float* h1 = ws + 11534336;                      // 5,767,168 f
    unsigned short* nfo = (unsigned short*)h1;      // nf/o overlay (dead before conv)
    unsigned short* pk = (unsigned short*)(ws + 17301504);       // 165,888 u16
    float* bias2 = ws + 17384448;                   // 96 f
    unsigned short* pkw = (unsigned short*)(ws + 17384544);      // 65,536 u16
    float* pb = ws + 17417312;                      // 32,768 f
    unsigned short* pm1 = (unsigned short*)(ws + 17450080);      // 65,536 u16
    unsigned short* pm2 = (unsigned short*)(ws + 17482848);      // 65,536 u16
    unsigned short* pu1 = (unsigned short*)(ws + 17515616);      // 16,384 u16
    unsigned short* pu2 = (unsigned short*)(ws + 17523808);      // 16,384 u16
    float* out = (float*)d_out;

    k_pack_all<<<900, 64, 0, stream>>>(dp_w1, dp_b1, bn_g, bn_b, pk, bias2,
                                       wq, wk, wv, wp, pkw, rpb, pb,
                                       mlp_w1, pm1, mlp_w2, pm2,
                                       un_w1, pu1, un_w2, pu2);
    k_cost<<<dim3(2, 64, 4), 384, 0, stream>>>(feat_l, feat_r, costbf);
    k_unary_mfma<<<1024, 256, 0, stream>>>(feat_l, pu1, un_b1, pu2, un_b2,
                                           ln1_g, ln1_b, x, nfo);
    k_attn_core<<<1024, 256, 0, stream>>>(nfo, pkw, pb, bq, bk, bv, nfo);
    k_mlp_mfma<<<1024, 256, 0, stream>>>(x, nfo, pkw, bp, ln2_g, ln2_b,
                                         pm1, mlp_b1, pm2);
    k_conv_mfma<<<dim3(8, 16, 4), 256, 0, stream>>>(x, costbf, pk, bias2, h1);
    k_head<<<256, 256, 0, stream>>>(h1, dp_w2, dp_b2, out);
}